// Round 1
// baseline (1064.737 us; speedup 1.0000x reference)
//
#include <hip/hip_runtime.h>
#include <math.h>

#define DEV __device__ __forceinline__

DEV float siluf(float x){ return x / (1.f + __expf(-x)); }
DEV float softplusf(float x){ return (x > 20.f) ? x : log1pf(__expf(x)); }

// ---------- block reduction helpers (wave64) ----------
DEV void blk_sum2(float &a, float &b, float* sm){
    int lane = threadIdx.x & 63, wid = threadIdx.x >> 6, nw = blockDim.x >> 6;
    #pragma unroll
    for (int off = 32; off; off >>= 1){ a += __shfl_down(a, off); b += __shfl_down(b, off); }
    if (lane == 0){ sm[wid] = a; sm[8 + wid] = b; }
    __syncthreads();
    float ra = 0.f, rb = 0.f;
    for (int i = 0; i < nw; i++){ ra += sm[i]; rb += sm[8 + i]; }
    __syncthreads();
    a = ra; b = rb;
}
DEV float blk_sum1(float v, float* sm){
    int lane = threadIdx.x & 63, wid = threadIdx.x >> 6, nw = blockDim.x >> 6;
    #pragma unroll
    for (int off = 32; off; off >>= 1) v += __shfl_down(v, off);
    if (lane == 0) sm[wid] = v;
    __syncthreads();
    float r = 0.f;
    for (int i = 0; i < nw; i++) r += sm[i];
    __syncthreads();
    return r;
}
DEV float blk_max1(float v, float* sm){
    int lane = threadIdx.x & 63, wid = threadIdx.x >> 6, nw = blockDim.x >> 6;
    #pragma unroll
    for (int off = 32; off; off >>= 1) v = fmaxf(v, __shfl_down(v, off));
    if (lane == 0) sm[wid] = v;
    __syncthreads();
    float r = -3.4e38f;
    for (int i = 0; i < nw; i++) r = fmaxf(r, sm[i]);
    __syncthreads();
    return r;
}

// ---------- K1: pos-embed + gather ----------
// xs[b,l,c] = x[b,c,ph,pw] + pe[p,c], p = sorted_index[b,l]
__global__ void k_embed(const float* __restrict__ x, const int* __restrict__ sidx,
                        float* __restrict__ xs){
    int bl = blockIdx.x; int b = bl >> 8; int c = threadIdx.x;
    int p = sidx[bl];
    int hh = p >> 4, ww = p & 15;
    int pos = (c < 64) ? hh : ww;
    int jm = c & 63;
    float om = __expf(-(float)(jm & 31) * 0.28782313662425574f); // ln(10000)/32
    float ang = (float)pos * om;
    float pe = (jm < 32) ? sinf(ang) : cosf(ang);
    xs[(size_t)bl * 128 + c] = x[((size_t)(b * 128 + c)) * 256 + p] + pe;
}

// ---------- LayerNorm (block per row, blockDim == dim) ----------
__global__ void k_ln(const float* __restrict__ in, const float* __restrict__ w,
                     const float* __restrict__ bb, float* __restrict__ out, int dim){
    __shared__ float sm[16];
    int row = blockIdx.x, t = threadIdx.x;
    float v = in[(size_t)row * dim + t];
    float a = v, q = v * v;
    blk_sum2(a, q, sm);
    float inv = 1.f / (float)dim;
    float mu = a * inv;
    float var = q * inv - mu * mu;
    float rs = rsqrtf(var + 1e-5f);
    out[(size_t)row * dim + t] = (v - mu) * rs * w[t] + bb[t];
}

// ---------- transposed LayerNorm for spectral: rows (b,i), dim 256 over l ----------
__global__ void k_ln_t(const float* __restrict__ h1, const float* __restrict__ w,
                       const float* __restrict__ bb, float* __restrict__ out){
    __shared__ float sm[16];
    int row = blockIdx.x; int b = row >> 7, i = row & 127; int t = threadIdx.x; // 256 thr
    float v = h1[((size_t)(b * 256 + t)) * 128 + i];
    float a = v, q = v * v;
    blk_sum2(a, q, sm);
    float mu = a * (1.f / 256.f);
    float var = q * (1.f / 256.f) - mu * mu;
    float rs = rsqrtf(var + 1e-5f);
    out[(size_t)row * 256 + t] = (v - mu) * rs * w[t] + bb[t];
}

// ---------- generic fp32 GEMM: out[r,j] = sum_k A[r,k]*W[j,k]  (+epilogue) ----------
// mode 0: +bias (bias may be null). mode 1: + res[r*N+j]. mode 2 (N==256):
//   b=r>>7, i=r&127; oi=((b*256+j)*128+i); out[oi] = acc + res[oi]
__global__ __launch_bounds__(256) void k_gemm(const float* __restrict__ A,
                                              const float* __restrict__ W,
                                              const float* __restrict__ bias,
                                              const float* __restrict__ res,
                                              float* __restrict__ out,
                                              int M, int N, int K, int mode){
    __shared__ float As[16][64];
    __shared__ float Ws[16][64];
    int j0 = blockIdx.x * 64, r0 = blockIdx.y * 64;
    int tid = threadIdx.x;
    int cg = tid & 15, rg = tid >> 4;
    float acc[4][4] = {};
    for (int k0 = 0; k0 < K; k0 += 16){
        #pragma unroll
        for (int it = 0; it < 4; it++){
            int idx = tid + it * 256;
            int rr = idx & 63, kk = idx >> 6;
            As[kk][rr] = A[(size_t)(r0 + rr) * K + k0 + kk];
            Ws[kk][rr] = (j0 + rr < N) ? W[(size_t)(j0 + rr) * K + k0 + kk] : 0.f;
        }
        __syncthreads();
        #pragma unroll
        for (int kk = 0; kk < 16; kk++){
            float4 a4 = *(const float4*)(&As[kk][rg << 2]);
            float4 w4 = *(const float4*)(&Ws[kk][cg << 2]);
            float av_[4] = {a4.x, a4.y, a4.z, a4.w};
            float wv_[4] = {w4.x, w4.y, w4.z, w4.w};
            #pragma unroll
            for (int ri = 0; ri < 4; ri++)
                #pragma unroll
                for (int ci = 0; ci < 4; ci++)
                    acc[ri][ci] = fmaf(av_[ri], wv_[ci], acc[ri][ci]);
        }
        __syncthreads();
    }
    #pragma unroll
    for (int ri = 0; ri < 4; ri++){
        int r = r0 + (rg << 2) + ri;
        #pragma unroll
        for (int ci = 0; ci < 4; ci++){
            int j = j0 + (cg << 2) + ci;
            if (j < N){
                float v = acc[ri][ci];
                if (mode == 0){
                    if (bias) v += bias[j];
                    out[(size_t)r * N + j] = v;
                } else if (mode == 1){
                    out[(size_t)r * N + j] = v + res[(size_t)r * N + j];
                } else {
                    int b2 = r >> 7, ii = r & 127;
                    size_t oi = ((size_t)(b2 * 256 + j)) * 128 + ii;
                    out[oi] = v + res[oi];
                }
            }
        }
    }
}

// ---------- dt/dA: dt = softplus(zx[..,off+h]+dt_bias[h]); dA = exp(-dt*exp(A_log[h])) ----------
__global__ void k_dt(const float* __restrict__ zx, const float* __restrict__ dtb,
                     const float* __restrict__ Al, float* __restrict__ dt,
                     float* __restrict__ dA, int total, int lognh, int stride, int off){
    int idx = blockIdx.x * 256 + threadIdx.x;
    if (idx >= total) return;
    int nhm = (1 << lognh) - 1;
    int h = idx & nhm, r = idx >> lognh;
    float xv = zx[(size_t)r * stride + off + h] + dtb[h];
    float d = softplusf(xv);
    dt[idx] = d;
    dA[idx] = __expf(-d * __expf(Al[h]));
}

// ---------- causal depthwise conv(4) + bias + silu over xBC slice of zx ----------
__global__ void k_conv(const float* __restrict__ zx, const float* __restrict__ cw,
                       const float* __restrict__ cb, float* __restrict__ xc,
                       int L, int D, int stride, int off){
    int bl = blockIdx.x;
    int l = bl & (L - 1);
    const float* base = zx + (size_t)bl * stride + off;
    for (int d = threadIdx.x; d < D; d += blockDim.x){
        float acc = cb[d];
        #pragma unroll
        for (int k = 0; k < 4; k++){
            int dl = l + k - 3;
            if (dl >= 0) acc += base[(ptrdiff_t)(k - 3) * stride + d] * cw[d * 4 + k];
        }
        xc[(size_t)bl * D + d] = siluf(acc);
    }
}

// ---------- SSD scan, LDS double-buffered chunks ----------
// block = (b,h); 256 thr: p = tid>>2 (64), ng = tid&3, each thread 16 n-states
#define SCH 16
__global__ __launch_bounds__(256) void k_scan(const float* __restrict__ xc,
                                              const float* __restrict__ dt,
                                              const float* __restrict__ dA,
                                              const float* __restrict__ Dp,
                                              float* __restrict__ y,
                                              int L, int nh, int xcs, int bo, int co, int ys){
    __shared__ float sx[2][SCH][64];
    __shared__ float sB[2][SCH][64];
    __shared__ float sC[2][SCH][64];
    __shared__ float sdt[2][SCH][2];
    int blk = blockIdx.x;
    int b = blk / nh, h = blk - b * nh;
    int tid = threadIdx.x;
    int p = tid >> 2, ng = tid & 3, n0 = ng << 4;
    float hs[16];
    #pragma unroll
    for (int i = 0; i < 16; i++) hs[i] = 0.f;
    float Dh = Dp[h];
    const float* xbase = xc + (size_t)b * L * xcs;
    const float* dtp = dt + (size_t)b * L * nh + h;
    const float* dap = dA + (size_t)b * L * nh + h;
    float* yp = y + (size_t)b * L * ys + h * 64 + p;
    int nch = L / SCH;
    float rx[4], rB[4], rC[4], rdt = 0.f, rda = 0.f;

    auto issue = [&](int c){
        int l0 = c * SCH;
        #pragma unroll
        for (int k = 0; k < 4; k++){
            int idx = tid + k * 256;
            int s = idx >> 6, n = idx & 63;
            const float* row = xbase + (size_t)(l0 + s) * xcs;
            rx[k] = row[h * 64 + n];
            rB[k] = row[bo + n];
            rC[k] = row[co + n];
        }
        if (tid < SCH){
            rdt = dtp[(size_t)(l0 + tid) * nh];
            rda = dap[(size_t)(l0 + tid) * nh];
        }
    };
    auto commit = [&](int buf){
        #pragma unroll
        for (int k = 0; k < 4; k++){
            int idx = tid + k * 256;
            int s = idx >> 6, n = idx & 63;
            sx[buf][s][n] = rx[k];
            sB[buf][s][n] = rB[k];
            sC[buf][s][n] = rC[k];
        }
        if (tid < SCH){ sdt[buf][tid][0] = rdt; sdt[buf][tid][1] = rda; }
    };

    issue(0); commit(0);
    __syncthreads();
    for (int c = 0; c < nch; c++){
        int buf = c & 1;
        if (c + 1 < nch) issue(c + 1);
        #pragma unroll 2
        for (int s = 0; s < SCH; s++){
            float dtv = sdt[buf][s][0];
            float dAv = sdt[buf][s][1];
            float xh = sx[buf][s][p];
            float dtx = dtv * xh;
            float part = 0.f;
            #pragma unroll
            for (int qq = 0; qq < 4; qq++){
                float4 B4 = *(const float4*)(&sB[buf][s][n0 + qq * 4]);
                float4 C4 = *(const float4*)(&sC[buf][s][n0 + qq * 4]);
                float* hq = hs + qq * 4;
                hq[0] = fmaf(hq[0], dAv, dtx * B4.x); part = fmaf(hq[0], C4.x, part);
                hq[1] = fmaf(hq[1], dAv, dtx * B4.y); part = fmaf(hq[1], C4.y, part);
                hq[2] = fmaf(hq[2], dAv, dtx * B4.z); part = fmaf(hq[2], C4.z, part);
                hq[3] = fmaf(hq[3], dAv, dtx * B4.w); part = fmaf(hq[3], C4.w, part);
            }
            part += __shfl_xor(part, 1);
            part += __shfl_xor(part, 2);
            if (ng == 0) yp[(size_t)(c * SCH + s) * ys] = part + Dh * xh;
        }
        if (c + 1 < nch){
            commit(buf ^ 1);
        }
        __syncthreads();
    }
}

// ---------- gate (silu(z)) + RMSNorm ----------
__global__ __launch_bounds__(256) void k_gate(const float* __restrict__ y,
                                              const float* __restrict__ zx,
                                              const float* __restrict__ rw,
                                              float* __restrict__ out,
                                              int dinner, int zstride){
    __shared__ float sm[16];
    int row = blockIdx.x, t = threadIdx.x;
    float v0, v1 = 0.f, ss;
    v0 = y[(size_t)row * dinner + t] * siluf(zx[(size_t)row * zstride + t]);
    ss = v0 * v0;
    if (dinner == 512){
        v1 = y[(size_t)row * dinner + t + 256] * siluf(zx[(size_t)row * zstride + t + 256]);
        ss += v1 * v1;
    }
    float tot = blk_sum1(ss, sm);
    float sc = rsqrtf(tot / (float)dinner + 1e-5f);
    out[(size_t)row * dinner + t] = v0 * sc * rw[t];
    if (dinner == 512) out[(size_t)row * dinner + t + 256] = v1 * sc * rw[t + 256];
}

// ---------- center projection + q ----------
__global__ void k_center_q(const float* __restrict__ xs, const float* __restrict__ cw,
                           const float* __restrict__ cb, const float* __restrict__ qw,
                           const float* __restrict__ qb, float* __restrict__ q){
    __shared__ float xr[640];
    __shared__ float cen[128];
    int b = blockIdx.x, t = threadIdx.x; // 128 thr
    for (int idx = t; idx < 640; idx += 128)
        xr[idx] = xs[(size_t)b * 256 * 128 + idx];
    __syncthreads();
    float acc = cb[t];
    for (int c = 0; c < 128; c++){
        const float* wp = cw + (size_t)(t * 128 + c) * 5;
        #pragma unroll
        for (int l = 0; l < 5; l++) acc += xr[l * 128 + c] * wp[l];
    }
    cen[t] = acc;
    __syncthreads();
    float qa = qb[t];
    const float* wr = qw + (size_t)t * 128;
    for (int o = 0; o < 128; o++) qa += cen[o] * wr[o];
    q[b * 128 + t] = qa;
}

// ---------- attention softmax over l (block per (b,h)) ----------
__global__ void k_attn(const float* __restrict__ q, const float* __restrict__ k,
                       float* __restrict__ attn){
    __shared__ float sm[16];
    __shared__ float qh[16];
    int blk = blockIdx.x; int b = blk >> 3, h = blk & 7; int l = threadIdx.x; // 256 thr
    if (l < 16) qh[l] = q[b * 128 + h * 16 + l];
    __syncthreads();
    const float* kp = k + ((size_t)(b * 256 + l)) * 128 + h * 16;
    float s = 0.f;
    #pragma unroll
    for (int d = 0; d < 16; d++) s += qh[d] * kp[d];
    s *= 0.25f;
    float mx = blk_max1(s, sm);
    float e = __expf(s - mx);
    float sum = blk_sum1(e, sm);
    attn[(size_t)blk * 256 + l] = e / sum;
}

// ---------- attention out: (v*attn) @ ao_w.T + ao_b, add into xs ----------
__global__ void k_attn_out(const float* __restrict__ v, const float* __restrict__ attn,
                           const float* __restrict__ ow, const float* __restrict__ ob,
                           float* __restrict__ xs){
    __shared__ float vp[128];
    int bl = blockIdx.x; int b = bl >> 8, l = bl & 255; int t = threadIdx.x; // 128 thr
    float a = attn[((size_t)((b << 3) + (t >> 4))) * 256 + l];
    vp[t] = v[(size_t)bl * 128 + t] * a;
    __syncthreads();
    float acc = ob[t];
    const float* wr = ow + (size_t)t * 128;
    for (int j = 0; j < 128; j++) acc += vp[j] * wr[j];
    xs[(size_t)bl * 128 + t] += acc;
}

// ---------- spectral q2/k2/v2 (8 channels per block) ----------
__global__ __launch_bounds__(256) void k_spe_qkv(const float* __restrict__ xs,
                                                 const float* __restrict__ sqw, const float* __restrict__ sqb,
                                                 const float* __restrict__ skw, const float* __restrict__ skb,
                                                 const float* __restrict__ svw, const float* __restrict__ svb,
                                                 float* __restrict__ q2, float* __restrict__ k2,
                                                 float* __restrict__ v2){
    __shared__ float xt[8][256];
    int blk = blockIdx.x; int b = blk >> 4; int i0 = (blk & 15) << 3;
    int t = threadIdx.x;
    for (int idx = t; idx < 8 * 256; idx += 256){
        int ii = idx >> 8, tt = idx & 255;
        xt[ii][tt] = xs[((size_t)(b * 256 + tt)) * 128 + i0 + ii];
    }
    __syncthreads();
    int j = t;
    float aq[8] = {}, ak_[8] = {}, av_[8] = {};
    const float* wq = sqw + (size_t)j * 256;
    const float* wk = skw + (size_t)j * 256;
    const float* wv = svw + (size_t)j * 256;
    for (int tt = 0; tt < 256; tt++){
        float wqv = wq[tt], wkv = wk[tt], wvv = wv[tt];
        #pragma unroll
        for (int ii = 0; ii < 8; ii++){
            float xv = xt[ii][tt];
            aq[ii] = fmaf(xv, wqv, aq[ii]);
            ak_[ii] = fmaf(xv, wkv, ak_[ii]);
            av_[ii] = fmaf(xv, wvv, av_[ii]);
        }
    }
    float bq = sqb[j], bk = skb[j], bv = svb[j];
    #pragma unroll
    for (int ii = 0; ii < 8; ii++){
        size_t row = (size_t)(b * 128 + i0 + ii) * 256 + j;
        q2[row] = aq[ii] + bq;
        k2[row] = ak_[ii] + bk;
        v2[row] = av_[ii] + bv;
    }
}

// ---------- spectral attention matrix + softmax (8 rows per block, 128 thr) ----------
__global__ __launch_bounds__(128) void k_attn2(const float* __restrict__ q2,
                                               const float* __restrict__ k2,
                                               float* __restrict__ attn2){
    __shared__ float qs[8][256];
    __shared__ float lg[8][128];
    __shared__ float mxs[8], sms[8];
    int blk = blockIdx.x; int b = blk >> 4; int i0 = (blk & 15) << 3;
    int j = threadIdx.x;
    for (int idx = j; idx < 8 * 256; idx += 128){
        int ii = idx >> 8, d = idx & 255;
        qs[ii][d] = q2[((size_t)(b * 128 + i0 + ii)) * 256 + d];
    }
    __syncthreads();
    const float* kr = k2 + ((size_t)(b * 128 + j)) * 256;
    float acc[8] = {};
    for (int d = 0; d < 256; d++){
        float kv = kr[d];
        #pragma unroll
        for (int ii = 0; ii < 8; ii++) acc[ii] = fmaf(qs[ii][d], kv, acc[ii]);
    }
    #pragma unroll
    for (int ii = 0; ii < 8; ii++) lg[ii][j] = acc[ii] * (1.f / 16.f);
    __syncthreads();
    if (j < 8){
        float mx = -3.4e38f;
        for (int tt = 0; tt < 128; tt++) mx = fmaxf(mx, lg[j][tt]);
        float sm = 0.f;
        for (int tt = 0; tt < 128; tt++) sm += __expf(lg[j][tt] - mx);
        mxs[j] = mx; sms[j] = 1.f / sm;
    }
    __syncthreads();
    #pragma unroll
    for (int ii = 0; ii < 8; ii++)
        attn2[((size_t)(b * 128 + i0 + ii)) * 128 + j] =
            __expf(lg[ii][j] - mxs[ii]) * sms[ii];
}

// ---------- (attn2 @ v2) @ so_w.T + so_b, transposed add into xs ----------
__global__ __launch_bounds__(256) void k_av_so(const float* __restrict__ attn2,
                                               const float* __restrict__ v2,
                                               const float* __restrict__ sow,
                                               const float* __restrict__ sob,
                                               float* __restrict__ xs){
    __shared__ float a2[8][128];
    __shared__ float av[8][256];
    int blk = blockIdx.x; int b = blk >> 4; int i0 = (blk & 15) << 3;
    int t = threadIdx.x;
    for (int idx = t; idx < 8 * 128; idx += 256){
        int ii = idx >> 7, j = idx & 127;
        a2[ii][j] = attn2[((size_t)(b * 128 + i0 + ii)) * 128 + j];
    }
    __syncthreads();
    {
        float acc[8] = {};
        const float* vb = v2 + (size_t)b * 128 * 256 + t;
        for (int j = 0; j < 128; j++){
            float vv = vb[(size_t)j * 256];
            #pragma unroll
            for (int ii = 0; ii < 8; ii++) acc[ii] = fmaf(a2[ii][j], vv, acc[ii]);
        }
        #pragma unroll
        for (int ii = 0; ii < 8; ii++) av[ii][t] = acc[ii];
    }
    __syncthreads();
    float acc[8] = {};
    const float* wr = sow + (size_t)t * 256;
    for (int d = 0; d < 256; d++){
        float wv = wr[d];
        #pragma unroll
        for (int ii = 0; ii < 8; ii++) acc[ii] = fmaf(av[ii][d], wv, acc[ii]);
    }
    float bias = sob[t];
    float* xp = xs + ((size_t)(b * 256 + t)) * 128 + i0;
    #pragma unroll
    for (int ii = 0; ii < 8; ii++) xp[ii] += acc[ii] + bias;
}

// ---------- unsort scatter ----------
__global__ void k_scatter(const float* __restrict__ xs, const int* __restrict__ sidx,
                          float* __restrict__ xr){
    int bl = blockIdx.x; int b = bl >> 8;
    int p = sidx[bl];
    xr[((size_t)(b * 256 + p)) * 128 + threadIdx.x] = xs[(size_t)bl * 128 + threadIdx.x];
}

// ---------- 3x3 stride-2 conv (NHWC x HWIO) + LayerNorm ----------
__global__ __launch_bounds__(256) void k_dsconv(const float* __restrict__ xr,
                                                const float* __restrict__ w,
                                                const float* __restrict__ lnw,
                                                const float* __restrict__ lnb,
                                                float* __restrict__ out){
    __shared__ float xin[3][16][128];
    __shared__ float ob[8][128];
    __shared__ float mus[8], rss[8];
    int blk = blockIdx.x; int b = blk >> 3, oh = blk & 7;
    int t = threadIdx.x;
    for (int idx = t; idx < 3 * 16 * 128; idx += 256){
        int kh = idx / 2048; int rem = idx & 2047;
        int iw = rem >> 7, c = rem & 127;
        int ih = oh * 2 - 1 + kh;
        float v = 0.f;
        if (ih >= 0 && ih < 16)
            v = xr[((size_t)(b * 256 + ih * 16 + iw)) * 128 + c];
        xin[kh][iw][c] = v;
    }
    __syncthreads();
    int o = t & 127, half = t >> 7;
    float acc[4] = {};
    for (int kh = 0; kh < 3; kh++){
        for (int kw = 0; kw < 3; kw++){
            const float* wp = w + ((size_t)((kh * 3 + kw) * 128)) * 128 + o;
            int iw0 = half * 2 - 1 + kw;
            for (int ic = 0; ic < 128; ic++){
                float wv = wp[(size_t)ic * 128];
                #pragma unroll
                for (int qq = 0; qq < 4; qq++){
                    int iw = iw0 + 4 * qq;
                    if (iw >= 0) acc[qq] = fmaf(xin[kh][iw][ic], wv, acc[qq]);
                }
            }
        }
    }
    #pragma unroll
    for (int qq = 0; qq < 4; qq++) ob[half + qq * 2][o] = acc[qq];
    __syncthreads();
    if (t < 8){
        float s = 0.f, ss = 0.f;
        for (int i = 0; i < 128; i++){ float v = ob[t][i]; s += v; ss += v * v; }
        float mu = s * (1.f / 128.f);
        float var = ss * (1.f / 128.f) - mu * mu;
        mus[t] = mu; rss[t] = rsqrtf(var + 1e-5f);
    }
    __syncthreads();
    #pragma unroll
    for (int qq = 0; qq < 4; qq++){
        int ow = half + qq * 2;
        out[((size_t)((b * 8 + oh) * 8 + ow)) * 128 + o] =
            (acc[qq] - mus[ow]) * rss[ow] * lnw[o] + lnb[o];
    }
}

extern "C" void kernel_launch(void* const* d_in, const int* in_sizes, int n_in,
                              void* d_out, int out_size, void* d_ws, size_t ws_size,
                              hipStream_t stream) {
    const float* x          = (const float*)d_in[0];
    const int*   sidx       = (const int*)  d_in[1];
    const float* spa_ln_w   = (const float*)d_in[2];
    const float* spa_ln_b   = (const float*)d_in[3];
    const float* spa_in_w   = (const float*)d_in[4];
    const float* spa_conv_w = (const float*)d_in[5];
    const float* spa_conv_b = (const float*)d_in[6];
    const float* spa_dt_bias= (const float*)d_in[7];
    const float* spa_A_log  = (const float*)d_in[8];
    const float* spa_D      = (const float*)d_in[9];
    const float* spa_rms_w  = (const float*)d_in[10];
    const float* spa_out_w  = (const float*)d_in[11];
    const float* spe_ln_w   = (const float*)d_in[12];
    const float* spe_ln_b   = (const float*)d_in[13];
    const float* spe_in_w   = (const float*)d_in[14];
    const float* spe_conv_w = (const float*)d_in[15];
    const float* spe_conv_b = (const float*)d_in[16];
    const float* spe_dt_bias= (const float*)d_in[17];
    const float* spe_A_log  = (const float*)d_in[18];
    const float* spe_D      = (const float*)d_in[19];
    const float* spe_rms_w  = (const float*)d_in[20];
    const float* spe_out_w  = (const float*)d_in[21];
    const float* norm_w     = (const float*)d_in[22];
    const float* norm_b     = (const float*)d_in[23];
    const float* cprj_w     = (const float*)d_in[24];
    const float* cprj_b     = (const float*)d_in[25];
    const float* aq_w       = (const float*)d_in[26];
    const float* aq_b       = (const float*)d_in[27];
    const float* ak_w       = (const float*)d_in[28];
    const float* ak_b       = (const float*)d_in[29];
    const float* av_w       = (const float*)d_in[30];
    const float* av_b       = (const float*)d_in[31];
    const float* ao_w       = (const float*)d_in[32];
    const float* ao_b       = (const float*)d_in[33];
    const float* sq_w       = (const float*)d_in[34];
    const float* sq_b       = (const float*)d_in[35];
    const float* sk_w       = (const float*)d_in[36];
    const float* sk_b       = (const float*)d_in[37];
    const float* sv_w       = (const float*)d_in[38];
    const float* sv_b       = (const float*)d_in[39];
    const float* so_w       = (const float*)d_in[40];
    const float* so_b       = (const float*)d_in[41];
    const float* ds_conv_w  = (const float*)d_in[42];
    const float* ds_ln_w    = (const float*)d_in[43];
    const float* ds_ln_b    = (const float*)d_in[44];

    float* ws = (float*)d_ws;
    // arena (floats); total used 7,946,240 floats = 30.3 MB
    float* xs   = ws + 0;        // 16*256*128
    float* lnb_ = ws + 524288;   // 524288 (spatial 4096x128 / spectral 2048x256)
    float* zx   = ws + 1048576;  // 16*256*644 (spectral 16*128*1160 fits)
    float* xc   = ws + 3686400;  // 16*256*384 (spectral 16*128*640 fits)
    float* dtb  = ws + 5259264;  // 32768
    float* dAb  = ws + 5292032;  // 32768
    float* yb   = ws + 5324800;  // 16*256*256 == 16*128*512
    float* gb   = ws + 6373376;  // same size
    float* h1   = ws + 7421952;  // 16*256*128
    // attention-stage aliases (zx/xc/yb arenas are dead by then)
    float* kb    = ws + 1048576;
    float* vb    = ws + 1572864;
    float* attnb = ws + 2097152;
    float* qb    = ws + 2129920;
    float* q2    = ws + 3686400;
    float* k2    = ws + 4210688;
    float* v2    = ws + 4734976;
    float* attn2 = ws + 5324800;
    float* xr    = ws + 5586944;

    k_embed<<<4096, 128, 0, stream>>>(x, sidx, xs);

    for (int i = 0; i < 2; i++){
        // ---- spatial mamba (L=256, d=128, d_inner=256, nh=4) ----
        k_ln<<<4096, 128, 0, stream>>>(xs, spa_ln_w + i * 128, spa_ln_b + i * 128, lnb_, 128);
        k_gemm<<<dim3(11, 64), 256, 0, stream>>>(lnb_, spa_in_w + (size_t)i * 644 * 128,
                                                 nullptr, nullptr, zx, 4096, 644, 128, 0);
        k_dt<<<64, 256, 0, stream>>>(zx, spa_dt_bias + i * 4, spa_A_log + i * 4,
                                     dtb, dAb, 4096 * 4, 2, 644, 640);
        k_conv<<<4096, 256, 0, stream>>>(zx, spa_conv_w + (size_t)i * 384 * 4,
                                         spa_conv_b + i * 384, xc, 256, 384, 644, 256);
        k_scan<<<64, 256, 0, stream>>>(xc, dtb, dAb, spa_D + i * 4, yb,
                                       256, 4, 384, 256, 320, 256);
        k_gate<<<4096, 256, 0, stream>>>(yb, zx, spa_rms_w + i * 256, gb, 256, 644);
        k_gemm<<<dim3(2, 64), 256, 0, stream>>>(gb, spa_out_w + (size_t)i * 128 * 256,
                                                nullptr, xs, h1, 4096, 128, 256, 1);
        // ---- spectral mamba (L=128 over channels, d=256, d_inner=512, nh=8) ----
        k_ln_t<<<2048, 256, 0, stream>>>(h1, spe_ln_w + i * 256, spe_ln_b + i * 256, lnb_);
        k_gemm<<<dim3(19, 32), 256, 0, stream>>>(lnb_, spe_in_w + (size_t)i * 1160 * 256,
                                                 nullptr, nullptr, zx, 2048, 1160, 256, 0);
        k_dt<<<64, 256, 0, stream>>>(zx, spe_dt_bias + i * 8, spe_A_log + i * 8,
                                     dtb, dAb, 2048 * 8, 3, 1160, 1152);
        k_conv<<<2048, 256, 0, stream>>>(zx, spe_conv_w + (size_t)i * 640 * 4,
                                         spe_conv_b + i * 640, xc, 128, 640, 1160, 512);
        k_scan<<<128, 256, 0, stream>>>(xc, dtb, dAb, spe_D + i * 8, yb,
                                        128, 8, 640, 512, 576, 512);
        k_gate<<<2048, 256, 0, stream>>>(yb, zx, spe_rms_w + i * 512, gb, 512, 1160);
        k_gemm<<<dim3(4, 32), 256, 0, stream>>>(gb, spe_out_w + (size_t)i * 256 * 512,
                                                nullptr, h1, xs, 2048, 256, 512, 2);
    }

    // ---- final LN (in place) ----
    k_ln<<<4096, 128, 0, stream>>>(xs, norm_w, norm_b, xs, 128);
    // ---- center + q ----
    k_center_q<<<16, 128, 0, stream>>>(xs, cprj_w, cprj_b, aq_w, aq_b, qb);
    // ---- k, v ----
    k_gemm<<<dim3(2, 64), 256, 0, stream>>>(xs, ak_w, ak_b, nullptr, kb, 4096, 128, 128, 0);
    k_gemm<<<dim3(2, 64), 256, 0, stream>>>(xs, av_w, av_b, nullptr, vb, 4096, 128, 128, 0);
    // ---- attention softmax + out (adds into xs) ----
    k_attn<<<128, 256, 0, stream>>>(qb, kb, attnb);
    k_attn_out<<<4096, 128, 0, stream>>>(vb, attnb, ao_w, ao_b, xs);
    // ---- spectral attention ----
    k_spe_qkv<<<256, 256, 0, stream>>>(xs, sq_w, sq_b, sk_w, sk_b, sv_w, sv_b, q2, k2, v2);
    k_attn2<<<256, 128, 0, stream>>>(q2, k2, attn2);
    k_av_so<<<256, 256, 0, stream>>>(attn2, v2, so_w, so_b, xs);
    // ---- unsort + downsample conv + LN ----
    k_scatter<<<4096, 128, 0, stream>>>(xs, sidx, xr);
    k_dsconv<<<128, 256, 0, stream>>>(xr, ds_conv_w, ds_ln_w, ds_ln_b, (float*)d_out);
}

// Round 2
// 979.779 us; speedup vs baseline: 1.0867x; 1.0867x over previous
//
#include <hip/hip_runtime.h>
#include <math.h>

#define DEV __device__ __forceinline__

DEV float siluf(float x){ return x / (1.f + __expf(-x)); }
DEV float softplusf(float x){ return (x > 20.f) ? x : log1pf(__expf(x)); }

// ---------- block reduction helpers (wave64) ----------
DEV void blk_sum2(float &a, float &b, float* sm){
    int lane = threadIdx.x & 63, wid = threadIdx.x >> 6, nw = blockDim.x >> 6;
    #pragma unroll
    for (int off = 32; off; off >>= 1){ a += __shfl_down(a, off); b += __shfl_down(b, off); }
    if (lane == 0){ sm[wid] = a; sm[8 + wid] = b; }
    __syncthreads();
    float ra = 0.f, rb = 0.f;
    for (int i = 0; i < nw; i++){ ra += sm[i]; rb += sm[8 + i]; }
    __syncthreads();
    a = ra; b = rb;
}
DEV float blk_sum1(float v, float* sm){
    int lane = threadIdx.x & 63, wid = threadIdx.x >> 6, nw = blockDim.x >> 6;
    #pragma unroll
    for (int off = 32; off; off >>= 1) v += __shfl_down(v, off);
    if (lane == 0) sm[wid] = v;
    __syncthreads();
    float r = 0.f;
    for (int i = 0; i < nw; i++) r += sm[i];
    __syncthreads();
    return r;
}
DEV float blk_max1(float v, float* sm){
    int lane = threadIdx.x & 63, wid = threadIdx.x >> 6, nw = blockDim.x >> 6;
    #pragma unroll
    for (int off = 32; off; off >>= 1) v = fmaxf(v, __shfl_down(v, off));
    if (lane == 0) sm[wid] = v;
    __syncthreads();
    float r = -3.4e38f;
    for (int i = 0; i < nw; i++) r = fmaxf(r, sm[i]);
    __syncthreads();
    return r;
}

// ---------- K1: pos-embed + gather ----------
__global__ void k_embed(const float* __restrict__ x, const int* __restrict__ sidx,
                        float* __restrict__ xs){
    int bl = blockIdx.x; int b = bl >> 8; int c = threadIdx.x;
    int p = sidx[bl];
    int hh = p >> 4, ww = p & 15;
    int pos = (c < 64) ? hh : ww;
    int jm = c & 63;
    float om = __expf(-(float)(jm & 31) * 0.28782313662425574f); // ln(10000)/32
    float ang = (float)pos * om;
    float pe = (jm < 32) ? sinf(ang) : cosf(ang);
    xs[(size_t)bl * 128 + c] = x[((size_t)(b * 128 + c)) * 256 + p] + pe;
}

// ---------- LayerNorm (block per row, blockDim == dim) ----------
__global__ void k_ln(const float* __restrict__ in, const float* __restrict__ w,
                     const float* __restrict__ bb, float* __restrict__ out, int dim){
    __shared__ float sm[16];
    int row = blockIdx.x, t = threadIdx.x;
    float v = in[(size_t)row * dim + t];
    float a = v, q = v * v;
    blk_sum2(a, q, sm);
    float inv = 1.f / (float)dim;
    float mu = a * inv;
    float var = q * inv - mu * mu;
    float rs = rsqrtf(var + 1e-5f);
    out[(size_t)row * dim + t] = (v - mu) * rs * w[t] + bb[t];
}

// ---------- transposed LayerNorm for spectral ----------
__global__ void k_ln_t(const float* __restrict__ h1, const float* __restrict__ w,
                       const float* __restrict__ bb, float* __restrict__ out){
    __shared__ float sm[16];
    int row = blockIdx.x; int b = row >> 7, i = row & 127; int t = threadIdx.x; // 256 thr
    float v = h1[((size_t)(b * 256 + t)) * 128 + i];
    float a = v, q = v * v;
    blk_sum2(a, q, sm);
    float mu = a * (1.f / 256.f);
    float var = q * (1.f / 256.f) - mu * mu;
    float rs = rsqrtf(var + 1e-5f);
    out[(size_t)row * 256 + t] = (v - mu) * rs * w[t] + bb[t];
}

// ---------- 64x64-tile fp32 GEMM: out[r,j] = sum_k A[r,k]*W[j,k] (+epilogue) ----------
__global__ __launch_bounds__(256) void k_gemm(const float* __restrict__ A,
                                              const float* __restrict__ W,
                                              const float* __restrict__ bias,
                                              const float* __restrict__ res,
                                              float* __restrict__ out,
                                              int M, int N, int K, int mode){
    __shared__ float As[16][64];
    __shared__ float Ws[16][64];
    int j0 = blockIdx.x * 64, r0 = blockIdx.y * 64;
    int tid = threadIdx.x;
    int cg = tid & 15, rg = tid >> 4;
    float acc[4][4] = {};
    for (int k0 = 0; k0 < K; k0 += 16){
        #pragma unroll
        for (int it = 0; it < 4; it++){
            int idx = tid + it * 256;
            int rr = idx & 63, kk = idx >> 6;
            As[kk][rr] = A[(size_t)(r0 + rr) * K + k0 + kk];
            Ws[kk][rr] = (j0 + rr < N) ? W[(size_t)(j0 + rr) * K + k0 + kk] : 0.f;
        }
        __syncthreads();
        #pragma unroll
        for (int kk = 0; kk < 16; kk++){
            float4 a4 = *(const float4*)(&As[kk][rg << 2]);
            float4 w4 = *(const float4*)(&Ws[kk][cg << 2]);
            float av_[4] = {a4.x, a4.y, a4.z, a4.w};
            float wv_[4] = {w4.x, w4.y, w4.z, w4.w};
            #pragma unroll
            for (int ri = 0; ri < 4; ri++)
                #pragma unroll
                for (int ci = 0; ci < 4; ci++)
                    acc[ri][ci] = fmaf(av_[ri], wv_[ci], acc[ri][ci]);
        }
        __syncthreads();
    }
    #pragma unroll
    for (int ri = 0; ri < 4; ri++){
        int r = r0 + (rg << 2) + ri;
        #pragma unroll
        for (int ci = 0; ci < 4; ci++){
            int j = j0 + (cg << 2) + ci;
            if (j < N){
                float v = acc[ri][ci];
                if (mode == 0){
                    if (bias) v += bias[j];
                    out[(size_t)r * N + j] = v;
                } else if (mode == 1){
                    out[(size_t)r * N + j] = v + res[(size_t)r * N + j];
                } else {
                    int b2 = r >> 7, ii = r & 127;
                    size_t oi = ((size_t)(b2 * 256 + j)) * 128 + ii;
                    out[oi] = v + res[oi];
                }
            }
        }
    }
}

// ---------- 128x128-tile fp32 GEMM (no bias), coalesced staging ----------
__global__ __launch_bounds__(256) void k_gemm128(const float* __restrict__ A,
                                                 const float* __restrict__ W,
                                                 float* __restrict__ out,
                                                 int M, int N, int K){
    __shared__ float As[16][132];
    __shared__ float Ws[16][132];
    int j0 = blockIdx.x * 128, r0 = blockIdx.y * 128;
    int tid = threadIdx.x;
    int cg = tid & 15, rg = tid >> 4; // 8 cols, 8 rows each
    float acc[8][8] = {};
    for (int k0 = 0; k0 < K; k0 += 16){
        #pragma unroll
        for (int it = 0; it < 2; it++){
            int id = tid + it * 256;
            int row = id >> 2, kg = id & 3;
            float4 a4 = *(const float4*)(A + (size_t)(r0 + row) * K + k0 + kg * 4);
            As[kg * 4 + 0][row] = a4.x; As[kg * 4 + 1][row] = a4.y;
            As[kg * 4 + 2][row] = a4.z; As[kg * 4 + 3][row] = a4.w;
            float4 w4 = make_float4(0.f, 0.f, 0.f, 0.f);
            if (j0 + row < N)
                w4 = *(const float4*)(W + (size_t)(j0 + row) * K + k0 + kg * 4);
            Ws[kg * 4 + 0][row] = w4.x; Ws[kg * 4 + 1][row] = w4.y;
            Ws[kg * 4 + 2][row] = w4.z; Ws[kg * 4 + 3][row] = w4.w;
        }
        __syncthreads();
        #pragma unroll
        for (int kk = 0; kk < 16; kk++){
            float a[8], w[8];
            *(float4*)(a)     = *(const float4*)(&As[kk][rg * 8]);
            *(float4*)(a + 4) = *(const float4*)(&As[kk][rg * 8 + 4]);
            *(float4*)(w)     = *(const float4*)(&Ws[kk][cg * 8]);
            *(float4*)(w + 4) = *(const float4*)(&Ws[kk][cg * 8 + 4]);
            #pragma unroll
            for (int ri = 0; ri < 8; ri++)
                #pragma unroll
                for (int ci = 0; ci < 8; ci++)
                    acc[ri][ci] = fmaf(a[ri], w[ci], acc[ri][ci]);
        }
        __syncthreads();
    }
    #pragma unroll
    for (int ri = 0; ri < 8; ri++){
        int r = r0 + rg * 8 + ri;
        #pragma unroll
        for (int ci = 0; ci < 8; ci++){
            int j = j0 + cg * 8 + ci;
            if (j < N) out[(size_t)r * N + j] = acc[ri][ci];
        }
    }
}

// ---------- causal depthwise conv(4)+bias+silu, fused dt/dA ----------
__global__ void k_conv(const float* __restrict__ zx, const float* __restrict__ cw,
                       const float* __restrict__ cb, float* __restrict__ xc,
                       const float* __restrict__ dtbias, const float* __restrict__ Al,
                       float* __restrict__ dt, float* __restrict__ dA,
                       int L, int D, int stride, int off, int nh, int dtoff){
    int bl = blockIdx.x;
    int l = bl & (L - 1);
    const float* base = zx + (size_t)bl * stride + off;
    for (int d = threadIdx.x; d < D; d += blockDim.x){
        float acc = cb[d];
        #pragma unroll
        for (int k = 0; k < 4; k++){
            int dl = l + k - 3;
            if (dl >= 0) acc += base[(ptrdiff_t)(k - 3) * stride + d] * cw[d * 4 + k];
        }
        xc[(size_t)bl * D + d] = siluf(acc);
    }
    int t = threadIdx.x;
    if (t < nh){
        float xv = zx[(size_t)bl * stride + dtoff + t] + dtbias[t];
        float d = softplusf(xv);
        dt[(size_t)bl * nh + t] = d;
        dA[(size_t)bl * nh + t] = __expf(-d * __expf(Al[t]));
    }
}

// ---------- SSD scan, LDS double-buffered chunks ----------
#define SCH 16
__global__ __launch_bounds__(256) void k_scan(const float* __restrict__ xc,
                                              const float* __restrict__ dt,
                                              const float* __restrict__ dA,
                                              const float* __restrict__ Dp,
                                              float* __restrict__ y,
                                              int L, int nh, int xcs, int bo, int co, int ys){
    __shared__ float sx[2][SCH][64];
    __shared__ float sB[2][SCH][64];
    __shared__ float sC[2][SCH][64];
    __shared__ float sdt[2][SCH][2];
    int blk = blockIdx.x;
    int b = blk / nh, h = blk - b * nh;
    int tid = threadIdx.x;
    int p = tid >> 2, ng = tid & 3, n0 = ng << 4;
    float hs[16];
    #pragma unroll
    for (int i = 0; i < 16; i++) hs[i] = 0.f;
    float Dh = Dp[h];
    const float* xbase = xc + (size_t)b * L * xcs;
    const float* dtp = dt + (size_t)b * L * nh + h;
    const float* dap = dA + (size_t)b * L * nh + h;
    float* yp = y + (size_t)b * L * ys + h * 64 + p;
    int nch = L / SCH;
    float rx[4], rB[4], rC[4], rdt = 0.f, rda = 0.f;

    auto issue = [&](int c){
        int l0 = c * SCH;
        #pragma unroll
        for (int k = 0; k < 4; k++){
            int idx = tid + k * 256;
            int s = idx >> 6, n = idx & 63;
            const float* row = xbase + (size_t)(l0 + s) * xcs;
            rx[k] = row[h * 64 + n];
            rB[k] = row[bo + n];
            rC[k] = row[co + n];
        }
        if (tid < SCH){
            rdt = dtp[(size_t)(l0 + tid) * nh];
            rda = dap[(size_t)(l0 + tid) * nh];
        }
    };
    auto commit = [&](int buf){
        #pragma unroll
        for (int k = 0; k < 4; k++){
            int idx = tid + k * 256;
            int s = idx >> 6, n = idx & 63;
            sx[buf][s][n] = rx[k];
            sB[buf][s][n] = rB[k];
            sC[buf][s][n] = rC[k];
        }
        if (tid < SCH){ sdt[buf][tid][0] = rdt; sdt[buf][tid][1] = rda; }
    };

    issue(0); commit(0);
    __syncthreads();
    for (int c = 0; c < nch; c++){
        int buf = c & 1;
        if (c + 1 < nch) issue(c + 1);
        #pragma unroll 2
        for (int s = 0; s < SCH; s++){
            float dtv = sdt[buf][s][0];
            float dAv = sdt[buf][s][1];
            float xh = sx[buf][s][p];
            float dtx = dtv * xh;
            float part = 0.f;
            #pragma unroll
            for (int qq = 0; qq < 4; qq++){
                float4 B4 = *(const float4*)(&sB[buf][s][n0 + qq * 4]);
                float4 C4 = *(const float4*)(&sC[buf][s][n0 + qq * 4]);
                float* hq = hs + qq * 4;
                hq[0] = fmaf(hq[0], dAv, dtx * B4.x); part = fmaf(hq[0], C4.x, part);
                hq[1] = fmaf(hq[1], dAv, dtx * B4.y); part = fmaf(hq[1], C4.y, part);
                hq[2] = fmaf(hq[2], dAv, dtx * B4.z); part = fmaf(hq[2], C4.z, part);
                hq[3] = fmaf(hq[3], dAv, dtx * B4.w); part = fmaf(hq[3], C4.w, part);
            }
            part += __shfl_xor(part, 1);
            part += __shfl_xor(part, 2);
            if (ng == 0) yp[(size_t)(c * SCH + s) * ys] = part + Dh * xh;
        }
        if (c + 1 < nch){
            commit(buf ^ 1);
        }
        __syncthreads();
    }
}

// ---------- gate (silu(z)) + RMSNorm ----------
__global__ __launch_bounds__(256) void k_gate(const float* __restrict__ y,
                                              const float* __restrict__ zx,
                                              const float* __restrict__ rw,
                                              float* __restrict__ out,
                                              int dinner, int zstride){
    __shared__ float sm[16];
    int row = blockIdx.x, t = threadIdx.x;
    float v0, v1 = 0.f, ss;
    v0 = y[(size_t)row * dinner + t] * siluf(zx[(size_t)row * zstride + t]);
    ss = v0 * v0;
    if (dinner == 512){
        v1 = y[(size_t)row * dinner + t + 256] * siluf(zx[(size_t)row * zstride + t + 256]);
        ss += v1 * v1;
    }
    float tot = blk_sum1(ss, sm);
    float sc = rsqrtf(tot / (float)dinner + 1e-5f);
    out[(size_t)row * dinner + t] = v0 * sc * rw[t];
    if (dinner == 512) out[(size_t)row * dinner + t + 256] = v1 * sc * rw[t + 256];
}

// ---------- center projection + q ----------
__global__ void k_center_q(const float* __restrict__ xs, const float* __restrict__ cw,
                           const float* __restrict__ cb, const float* __restrict__ qw,
                           const float* __restrict__ qb, float* __restrict__ q){
    __shared__ float xr[640];
    __shared__ float cen[128];
    int b = blockIdx.x, t = threadIdx.x; // 128 thr
    for (int idx = t; idx < 640; idx += 128)
        xr[idx] = xs[(size_t)b * 256 * 128 + idx];
    __syncthreads();
    float acc = cb[t];
    for (int c = 0; c < 128; c++){
        const float* wp = cw + (size_t)(t * 128 + c) * 5;
        #pragma unroll
        for (int l = 0; l < 5; l++) acc += xr[l * 128 + c] * wp[l];
    }
    cen[t] = acc;
    __syncthreads();
    float qa = qb[t];
    const float* wr = qw + (size_t)t * 128;
    for (int o = 0; o < 128; o++) qa += cen[o] * wr[o];
    q[b * 128 + t] = qa;
}

// ---------- attention softmax over l ----------
__global__ void k_attn(const float* __restrict__ q, const float* __restrict__ k,
                       float* __restrict__ attn){
    __shared__ float sm[16];
    __shared__ float qh[16];
    int blk = blockIdx.x; int b = blk >> 3, h = blk & 7; int l = threadIdx.x; // 256 thr
    if (l < 16) qh[l] = q[b * 128 + h * 16 + l];
    __syncthreads();
    const float* kp = k + ((size_t)(b * 256 + l)) * 128 + h * 16;
    float s = 0.f;
    #pragma unroll
    for (int d = 0; d < 16; d++) s += qh[d] * kp[d];
    s *= 0.25f;
    float mx = blk_max1(s, sm);
    float e = __expf(s - mx);
    float sum = blk_sum1(e, sm);
    attn[(size_t)blk * 256 + l] = e / sum;
}

// ---------- attention out ----------
__global__ void k_attn_out(const float* __restrict__ v, const float* __restrict__ attn,
                           const float* __restrict__ ow, const float* __restrict__ ob,
                           float* __restrict__ xs){
    __shared__ float vp[128];
    int bl = blockIdx.x; int b = bl >> 8, l = bl & 255; int t = threadIdx.x; // 128 thr
    float a = attn[((size_t)((b << 3) + (t >> 4))) * 256 + l];
    vp[t] = v[(size_t)bl * 128 + t] * a;
    __syncthreads();
    float acc = ob[t];
    const float* wr = ow + (size_t)t * 128;
    for (int j = 0; j < 128; j++) acc += vp[j] * wr[j];
    xs[(size_t)bl * 128 + t] += acc;
}

// ---------- spectral q2/k2/v2 ----------
__global__ __launch_bounds__(256) void k_spe_qkv(const float* __restrict__ xs,
                                                 const float* __restrict__ sqw, const float* __restrict__ sqb,
                                                 const float* __restrict__ skw, const float* __restrict__ skb,
                                                 const float* __restrict__ svw, const float* __restrict__ svb,
                                                 float* __restrict__ q2, float* __restrict__ k2,
                                                 float* __restrict__ v2){
    __shared__ float xt[8][256];
    int blk = blockIdx.x; int b = blk >> 4; int i0 = (blk & 15) << 3;
    int t = threadIdx.x;
    for (int idx = t; idx < 8 * 256; idx += 256){
        int ii = idx >> 8, tt = idx & 255;
        xt[ii][tt] = xs[((size_t)(b * 256 + tt)) * 128 + i0 + ii];
    }
    __syncthreads();
    int j = t;
    float aq[8] = {}, ak_[8] = {}, av_[8] = {};
    const float* wq = sqw + (size_t)j * 256;
    const float* wk = skw + (size_t)j * 256;
    const float* wv = svw + (size_t)j * 256;
    for (int tt = 0; tt < 256; tt++){
        float wqv = wq[tt], wkv = wk[tt], wvv = wv[tt];
        #pragma unroll
        for (int ii = 0; ii < 8; ii++){
            float xv = xt[ii][tt];
            aq[ii] = fmaf(xv, wqv, aq[ii]);
            ak_[ii] = fmaf(xv, wkv, ak_[ii]);
            av_[ii] = fmaf(xv, wvv, av_[ii]);
        }
    }
    float bq = sqb[j], bk = skb[j], bv = svb[j];
    #pragma unroll
    for (int ii = 0; ii < 8; ii++){
        size_t row = (size_t)(b * 128 + i0 + ii) * 256 + j;
        q2[row] = aq[ii] + bq;
        k2[row] = ak_[ii] + bk;
        v2[row] = av_[ii] + bv;
    }
}

// ---------- spectral attention + softmax ----------
__global__ __launch_bounds__(128) void k_attn2(const float* __restrict__ q2,
                                               const float* __restrict__ k2,
                                               float* __restrict__ attn2){
    __shared__ float qs[8][256];
    __shared__ float lg[8][128];
    __shared__ float mxs[8], sms[8];
    int blk = blockIdx.x; int b = blk >> 4; int i0 = (blk & 15) << 3;
    int j = threadIdx.x;
    for (int idx = j; idx < 8 * 256; idx += 128){
        int ii = idx >> 8, d = idx & 255;
        qs[ii][d] = q2[((size_t)(b * 128 + i0 + ii)) * 256 + d];
    }
    __syncthreads();
    const float* kr = k2 + ((size_t)(b * 128 + j)) * 256;
    float acc[8] = {};
    for (int d = 0; d < 256; d++){
        float kv = kr[d];
        #pragma unroll
        for (int ii = 0; ii < 8; ii++) acc[ii] = fmaf(qs[ii][d], kv, acc[ii]);
    }
    #pragma unroll
    for (int ii = 0; ii < 8; ii++) lg[ii][j] = acc[ii] * (1.f / 16.f);
    __syncthreads();
    if (j < 8){
        float mx = -3.4e38f;
        for (int tt = 0; tt < 128; tt++) mx = fmaxf(mx, lg[j][tt]);
        float sm = 0.f;
        for (int tt = 0; tt < 128; tt++) sm += __expf(lg[j][tt] - mx);
        mxs[j] = mx; sms[j] = 1.f / sm;
    }
    __syncthreads();
    #pragma unroll
    for (int ii = 0; ii < 8; ii++)
        attn2[((size_t)(b * 128 + i0 + ii)) * 128 + j] =
            __expf(lg[ii][j] - mxs[ii]) * sms[ii];
}

// ---------- (attn2 @ v2) @ so_w.T + so_b, transposed add ----------
__global__ __launch_bounds__(256) void k_av_so(const float* __restrict__ attn2,
                                               const float* __restrict__ v2,
                                               const float* __restrict__ sow,
                                               const float* __restrict__ sob,
                                               float* __restrict__ xs){
    __shared__ float a2[8][128];
    __shared__ float av[8][256];
    int blk = blockIdx.x; int b = blk >> 4; int i0 = (blk & 15) << 3;
    int t = threadIdx.x;
    for (int idx = t; idx < 8 * 128; idx += 256){
        int ii = idx >> 7, j = idx & 127;
        a2[ii][j] = attn2[((size_t)(b * 128 + i0 + ii)) * 128 + j];
    }
    __syncthreads();
    {
        float acc[8] = {};
        const float* vb = v2 + (size_t)b * 128 * 256 + t;
        for (int j = 0; j < 128; j++){
            float vv = vb[(size_t)j * 256];
            #pragma unroll
            for (int ii = 0; ii < 8; ii++) acc[ii] = fmaf(a2[ii][j], vv, acc[ii]);
        }
        #pragma unroll
        for (int ii = 0; ii < 8; ii++) av[ii][t] = acc[ii];
    }
    __syncthreads();
    float acc[8] = {};
    const float* wr = sow + (size_t)t * 256;
    for (int d = 0; d < 256; d++){
        float wv = wr[d];
        #pragma unroll
        for (int ii = 0; ii < 8; ii++) acc[ii] = fmaf(av[ii][d], wv, acc[ii]);
    }
    float bias = sob[t];
    float* xp = xs + ((size_t)(b * 256 + t)) * 128 + i0;
    #pragma unroll
    for (int ii = 0; ii < 8; ii++) xp[ii] += acc[ii] + bias;
}

// ---------- unsort scatter ----------
__global__ void k_scatter(const float* __restrict__ xs, const int* __restrict__ sidx,
                          float* __restrict__ xr){
    int bl = blockIdx.x; int b = bl >> 8;
    int p = sidx[bl];
    xr[((size_t)(b * 256 + p)) * 128 + threadIdx.x] = xs[(size_t)bl * 128 + threadIdx.x];
}

// ---------- im2col for 3x3/2 conv: col[r][ (kh*3+kw)*128 + c ] ----------
__global__ void k_im2col(const float* __restrict__ xr, float* __restrict__ col){
    int r = blockIdx.x; int t = threadIdx.x; // 128 thr
    int b = r >> 6, oh = (r >> 3) & 7, ow = r & 7;
    float* dst = col + (size_t)r * 1152;
    #pragma unroll
    for (int kh = 0; kh < 3; kh++){
        int ih = oh * 2 - 1 + kh;
        #pragma unroll
        for (int kw = 0; kw < 3; kw++){
            int iw = ow * 2 - 1 + kw;
            float v = 0.f;
            if (ih >= 0 && ih < 16 && iw >= 0 && iw < 16)
                v = xr[((size_t)((b << 8) + (ih << 4) + iw)) * 128 + t];
            dst[(kh * 3 + kw) * 128 + t] = v;
        }
    }
}

// ---------- conv GEMM: part[s][r][j] = sum over K-slice col[r][k]*W2[k][j] ----------
// W2 = ds_conv_w flat [1152][128] (K-major, j contiguous). split-K=4 x 288.
__global__ __launch_bounds__(256) void k_conv_gemm(const float* __restrict__ col,
                                                   const float* __restrict__ W2,
                                                   float* __restrict__ part){
    __shared__ float As[16][68];
    __shared__ float Ws[16][64];
    int j0 = blockIdx.x * 64, r0 = blockIdx.y * 64, s = blockIdx.z;
    int tid = threadIdx.x;
    int cg = tid & 15, rg = tid >> 4;
    float acc[4][4] = {};
    int kbeg = s * 288, kend = kbeg + 288;
    for (int k0 = kbeg; k0 < kend; k0 += 16){
        // A: 64 rows x 16 k, float4-coalesced then transposed into LDS
        {
            int row = tid >> 2, kg = tid & 3;
            float4 a4 = *(const float4*)(col + (size_t)(r0 + row) * 1152 + k0 + kg * 4);
            As[kg * 4 + 0][row] = a4.x; As[kg * 4 + 1][row] = a4.y;
            As[kg * 4 + 2][row] = a4.z; As[kg * 4 + 3][row] = a4.w;
        }
        // W: 16 k x 64 j, naturally coalesced
        #pragma unroll
        for (int it = 0; it < 4; it++){
            int idx = tid + it * 256;
            int jj = idx & 63, kk = idx >> 6;
            Ws[kk][jj] = W2[(size_t)(k0 + kk) * 128 + j0 + jj];
        }
        __syncthreads();
        #pragma unroll
        for (int kk = 0; kk < 16; kk++){
            float4 a4 = *(const float4*)(&As[kk][rg << 2]);
            float4 w4 = *(const float4*)(&Ws[kk][cg << 2]);
            float av_[4] = {a4.x, a4.y, a4.z, a4.w};
            float wv_[4] = {w4.x, w4.y, w4.z, w4.w};
            #pragma unroll
            for (int ri = 0; ri < 4; ri++)
                #pragma unroll
                for (int ci = 0; ci < 4; ci++)
                    acc[ri][ci] = fmaf(av_[ri], wv_[ci], acc[ri][ci]);
        }
        __syncthreads();
    }
    float* pp = part + (size_t)s * 1024 * 128;
    #pragma unroll
    for (int ri = 0; ri < 4; ri++){
        int r = r0 + (rg << 2) + ri;
        #pragma unroll
        for (int ci = 0; ci < 4; ci++){
            int j = j0 + (cg << 2) + ci;
            pp[(size_t)r * 128 + j] = acc[ri][ci];
        }
    }
}

// ---------- reduce split-K partials + LayerNorm ----------
__global__ void k_part_ln(const float* __restrict__ part, const float* __restrict__ lnw,
                          const float* __restrict__ lnb, float* __restrict__ out){
    __shared__ float sm[16];
    int r = blockIdx.x, t = threadIdx.x; // 128 thr
    float v = part[(size_t)r * 128 + t]
            + part[(size_t)(1024 + r) * 128 + t]
            + part[(size_t)(2048 + r) * 128 + t]
            + part[(size_t)(3072 + r) * 128 + t];
    float a = v, q = v * v;
    blk_sum2(a, q, sm);
    float mu = a * (1.f / 128.f);
    float var = q * (1.f / 128.f) - mu * mu;
    float rs = rsqrtf(var + 1e-5f);
    out[(size_t)r * 128 + t] = (v - mu) * rs * lnw[t] + lnb[t];
}

extern "C" void kernel_launch(void* const* d_in, const int* in_sizes, int n_in,
                              void* d_out, int out_size, void* d_ws, size_t ws_size,
                              hipStream_t stream) {
    const float* x          = (const float*)d_in[0];
    const int*   sidx       = (const int*)  d_in[1];
    const float* spa_ln_w   = (const float*)d_in[2];
    const float* spa_ln_b   = (const float*)d_in[3];
    const float* spa_in_w   = (const float*)d_in[4];
    const float* spa_conv_w = (const float*)d_in[5];
    const float* spa_conv_b = (const float*)d_in[6];
    const float* spa_dt_bias= (const float*)d_in[7];
    const float* spa_A_log  = (const float*)d_in[8];
    const float* spa_D      = (const float*)d_in[9];
    const float* spa_rms_w  = (const float*)d_in[10];
    const float* spa_out_w  = (const float*)d_in[11];
    const float* spe_ln_w   = (const float*)d_in[12];
    const float* spe_ln_b   = (const float*)d_in[13];
    const float* spe_in_w   = (const float*)d_in[14];
    const float* spe_conv_w = (const float*)d_in[15];
    const float* spe_conv_b = (const float*)d_in[16];
    const float* spe_dt_bias= (const float*)d_in[17];
    const float* spe_A_log  = (const float*)d_in[18];
    const float* spe_D      = (const float*)d_in[19];
    const float* spe_rms_w  = (const float*)d_in[20];
    const float* spe_out_w  = (const float*)d_in[21];
    const float* norm_w     = (const float*)d_in[22];
    const float* norm_b     = (const float*)d_in[23];
    const float* cprj_w     = (const float*)d_in[24];
    const float* cprj_b     = (const float*)d_in[25];
    const float* aq_w       = (const float*)d_in[26];
    const float* aq_b       = (const float*)d_in[27];
    const float* ak_w       = (const float*)d_in[28];
    const float* ak_b       = (const float*)d_in[29];
    const float* av_w       = (const float*)d_in[30];
    const float* av_b       = (const float*)d_in[31];
    const float* ao_w       = (const float*)d_in[32];
    const float* ao_b       = (const float*)d_in[33];
    const float* sq_w       = (const float*)d_in[34];
    const float* sq_b       = (const float*)d_in[35];
    const float* sk_w       = (const float*)d_in[36];
    const float* sk_b       = (const float*)d_in[37];
    const float* sv_w       = (const float*)d_in[38];
    const float* sv_b       = (const float*)d_in[39];
    const float* so_w       = (const float*)d_in[40];
    const float* so_b       = (const float*)d_in[41];
    const float* ds_conv_w  = (const float*)d_in[42];
    const float* ds_ln_w    = (const float*)d_in[43];
    const float* ds_ln_b    = (const float*)d_in[44];

    float* ws = (float*)d_ws;
    float* xs   = ws + 0;        // 524288
    float* lnb_ = ws + 524288;   // 524288
    float* zx   = ws + 1048576;  // up to 2637824 -> ends 3686400
    float* xc   = ws + 3686400;  // up to 1572864 -> ends 5259264
    float* dtb  = ws + 5259264;  // 32768
    float* dAb  = ws + 5292032;  // 32768
    float* yb   = ws + 5324800;  // 1048576 -> 6373376
    float* gb   = ws + 6373376;  // 1048576 -> 7421952
    float* h1   = ws + 7421952;  // 524288 -> 7946240
    // attention-stage aliases (zx/xc/yb arenas dead)
    float* kb    = ws + 1048576;
    float* vb    = ws + 1572864;
    float* attnb = ws + 2097152;
    float* qb    = ws + 2129920;
    float* q2    = ws + 3686400;
    float* k2    = ws + 4210688;
    float* v2    = ws + 4734976;
    float* attn2 = ws + 5324800; // 262144 -> 5586944
    float* xr    = ws + 5586944; // 524288 -> 6111232
    float* col   = ws + 6111232; // 1179648 -> 7290880
    float* part  = ws + 7290880; // 524288 -> 7815168 (gb/h1 dead by then)

    k_embed<<<4096, 128, 0, stream>>>(x, sidx, xs);

    for (int i = 0; i < 2; i++){
        // ---- spatial mamba ----
        k_ln<<<4096, 128, 0, stream>>>(xs, spa_ln_w + i * 128, spa_ln_b + i * 128, lnb_, 128);
        k_gemm128<<<dim3(6, 32), 256, 0, stream>>>(lnb_, spa_in_w + (size_t)i * 644 * 128,
                                                   zx, 4096, 644, 128);
        k_conv<<<4096, 256, 0, stream>>>(zx, spa_conv_w + (size_t)i * 384 * 4,
                                         spa_conv_b + i * 384, xc,
                                         spa_dt_bias + i * 4, spa_A_log + i * 4, dtb, dAb,
                                         256, 384, 644, 256, 4, 640);
        k_scan<<<64, 256, 0, stream>>>(xc, dtb, dAb, spa_D + i * 4, yb,
                                       256, 4, 384, 256, 320, 256);
        k_gate<<<4096, 256, 0, stream>>>(yb, zx, spa_rms_w + i * 256, gb, 256, 644);
        k_gemm<<<dim3(2, 64), 256, 0, stream>>>(gb, spa_out_w + (size_t)i * 128 * 256,
                                                nullptr, xs, h1, 4096, 128, 256, 1);
        // ---- spectral mamba ----
        k_ln_t<<<2048, 256, 0, stream>>>(h1, spe_ln_w + i * 256, spe_ln_b + i * 256, lnb_);
        k_gemm128<<<dim3(10, 16), 256, 0, stream>>>(lnb_, spe_in_w + (size_t)i * 1160 * 256,
                                                    zx, 2048, 1160, 256);
        k_conv<<<2048, 256, 0, stream>>>(zx, spe_conv_w + (size_t)i * 640 * 4,
                                         spe_conv_b + i * 640, xc,
                                         spe_dt_bias + i * 8, spe_A_log + i * 8, dtb, dAb,
                                         128, 640, 1160, 512, 8, 1152);
        k_scan<<<128, 256, 0, stream>>>(xc, dtb, dAb, spe_D + i * 8, yb,
                                        128, 8, 640, 512, 576, 512);
        k_gate<<<2048, 256, 0, stream>>>(yb, zx, spe_rms_w + i * 512, gb, 512, 1160);
        k_gemm<<<dim3(4, 32), 256, 0, stream>>>(gb, spe_out_w + (size_t)i * 256 * 512,
                                                nullptr, h1, xs, 2048, 256, 512, 2);
    }

    k_ln<<<4096, 128, 0, stream>>>(xs, norm_w, norm_b, xs, 128);
    k_center_q<<<16, 128, 0, stream>>>(xs, cprj_w, cprj_b, aq_w, aq_b, qb);
    k_gemm<<<dim3(2, 64), 256, 0, stream>>>(xs, ak_w, ak_b, nullptr, kb, 4096, 128, 128, 0);
    k_gemm<<<dim3(2, 64), 256, 0, stream>>>(xs, av_w, av_b, nullptr, vb, 4096, 128, 128, 0);
    k_attn<<<128, 256, 0, stream>>>(qb, kb, attnb);
    k_attn_out<<<4096, 128, 0, stream>>>(vb, attnb, ao_w, ao_b, xs);
    k_spe_qkv<<<256, 256, 0, stream>>>(xs, sq_w, sq_b, sk_w, sk_b, sv_w, sv_b, q2, k2, v2);
    k_attn2<<<256, 128, 0, stream>>>(q2, k2, attn2);
    k_av_so<<<256, 256, 0, stream>>>(attn2, v2, so_w, so_b, xs);
    k_scatter<<<4096, 128, 0, stream>>>(xs, sidx, xr);
    k_im2col<<<1024, 128, 0, stream>>>(xr, col);
    k_conv_gemm<<<dim3(2, 16, 4), 256, 0, stream>>>(col, ds_conv_w, part);
    k_part_ln<<<1024, 128, 0, stream>>>(part, ds_ln_w, ds_ln_b, (float*)d_out);
}

// Round 5
// 879.649 us; speedup vs baseline: 1.2104x; 1.1138x over previous
//
#include <hip/hip_runtime.h>
#include <math.h>

#define DEV __device__ __forceinline__

DEV float siluf(float x){ return x / (1.f + __expf(-x)); }
DEV float softplusf(float x){ return (x > 20.f) ? x : log1pf(__expf(x)); }

// ---------- block reduction helpers (wave64) ----------
DEV void blk_sum2(float &a, float &b, float* sm){
    int lane = threadIdx.x & 63, wid = threadIdx.x >> 6, nw = blockDim.x >> 6;
    #pragma unroll
    for (int off = 32; off; off >>= 1){ a += __shfl_down(a, off); b += __shfl_down(b, off); }
    if (lane == 0){ sm[wid] = a; sm[8 + wid] = b; }
    __syncthreads();
    float ra = 0.f, rb = 0.f;
    for (int i = 0; i < nw; i++){ ra += sm[i]; rb += sm[8 + i]; }
    __syncthreads();
    a = ra; b = rb;
}
DEV float blk_sum1(float v, float* sm){
    int lane = threadIdx.x & 63, wid = threadIdx.x >> 6, nw = blockDim.x >> 6;
    #pragma unroll
    for (int off = 32; off; off >>= 1) v += __shfl_down(v, off);
    if (lane == 0) sm[wid] = v;
    __syncthreads();
    float r = 0.f;
    for (int i = 0; i < nw; i++) r += sm[i];
    __syncthreads();
    return r;
}
DEV float blk_max1(float v, float* sm){
    int lane = threadIdx.x & 63, wid = threadIdx.x >> 6, nw = blockDim.x >> 6;
    #pragma unroll
    for (int off = 32; off; off >>= 1) v = fmaxf(v, __shfl_down(v, off));
    if (lane == 0) sm[wid] = v;
    __syncthreads();
    float r = -3.4e38f;
    for (int i = 0; i < nw; i++) r = fmaxf(r, sm[i]);
    __syncthreads();
    return r;
}

// ---------- K1: pos-embed + gather ----------
__global__ void k_embed(const float* __restrict__ x, const int* __restrict__ sidx,
                        float* __restrict__ xs){
    int bl = blockIdx.x; int b = bl >> 8; int c = threadIdx.x;
    int p = sidx[bl];
    int hh = p >> 4, ww = p & 15;
    int pos = (c < 64) ? hh : ww;
    int jm = c & 63;
    float om = __expf(-(float)(jm & 31) * 0.28782313662425574f); // ln(10000)/32
    float ang = (float)pos * om;
    float pe = (jm < 32) ? sinf(ang) : cosf(ang);
    xs[(size_t)bl * 128 + c] = x[((size_t)(b * 128 + c)) * 256 + p] + pe;
}

// ---------- LayerNorm (block per row, blockDim == dim) ----------
__global__ void k_ln(const float* __restrict__ in, const float* __restrict__ w,
                     const float* __restrict__ bb, float* __restrict__ out, int dim){
    __shared__ float sm[16];
    int row = blockIdx.x, t = threadIdx.x;
    float v = in[(size_t)row * dim + t];
    float a = v, q = v * v;
    blk_sum2(a, q, sm);
    float inv = 1.f / (float)dim;
    float mu = a * inv;
    float var = q * inv - mu * mu;
    float rs = rsqrtf(var + 1e-5f);
    out[(size_t)row * dim + t] = (v - mu) * rs * w[t] + bb[t];
}

// ---------- transposed LayerNorm for spectral ----------
__global__ void k_ln_t(const float* __restrict__ h1, const float* __restrict__ w,
                       const float* __restrict__ bb, float* __restrict__ out){
    __shared__ float sm[16];
    int row = blockIdx.x; int b = row >> 7, i = row & 127; int t = threadIdx.x; // 256 thr
    float v = h1[((size_t)(b * 256 + t)) * 128 + i];
    float a = v, q = v * v;
    blk_sum2(a, q, sm);
    float mu = a * (1.f / 256.f);
    float var = q * (1.f / 256.f) - mu * mu;
    float rs = rsqrtf(var + 1e-5f);
    out[(size_t)row * 256 + t] = (v - mu) * rs * w[t] + bb[t];
}

// ---------- 64x64-tile fp32 GEMM: out[r,j] = sum_k A[r,k]*W[j,k] (+epilogue) ----------
__global__ __launch_bounds__(256) void k_gemm(const float* __restrict__ A,
                                              const float* __restrict__ W,
                                              const float* __restrict__ bias,
                                              const float* __restrict__ res,
                                              float* __restrict__ out,
                                              int M, int N, int K, int mode){
    __shared__ float As[16][64];
    __shared__ float Ws[16][64];
    int j0 = blockIdx.x * 64, r0 = blockIdx.y * 64;
    int tid = threadIdx.x;
    int cg = tid & 15, rg = tid >> 4;
    float acc[4][4] = {};
    for (int k0 = 0; k0 < K; k0 += 16){
        #pragma unroll
        for (int it = 0; it < 4; it++){
            int idx = tid + it * 256;
            int rr = idx & 63, kk = idx >> 6;
            As[kk][rr] = A[(size_t)(r0 + rr) * K + k0 + kk];
            Ws[kk][rr] = (j0 + rr < N) ? W[(size_t)(j0 + rr) * K + k0 + kk] : 0.f;
        }
        __syncthreads();
        #pragma unroll
        for (int kk = 0; kk < 16; kk++){
            float4 a4 = *(const float4*)(&As[kk][rg << 2]);
            float4 w4 = *(const float4*)(&Ws[kk][cg << 2]);
            float av_[4] = {a4.x, a4.y, a4.z, a4.w};
            float wv_[4] = {w4.x, w4.y, w4.z, w4.w};
            #pragma unroll
            for (int ri = 0; ri < 4; ri++)
                #pragma unroll
                for (int ci = 0; ci < 4; ci++)
                    acc[ri][ci] = fmaf(av_[ri], wv_[ci], acc[ri][ci]);
        }
        __syncthreads();
    }
    #pragma unroll
    for (int ri = 0; ri < 4; ri++){
        int r = r0 + (rg << 2) + ri;
        #pragma unroll
        for (int ci = 0; ci < 4; ci++){
            int j = j0 + (cg << 2) + ci;
            if (j < N){
                float v = acc[ri][ci];
                if (mode == 0){
                    if (bias) v += bias[j];
                    out[(size_t)r * N + j] = v;
                } else if (mode == 1){
                    out[(size_t)r * N + j] = v + res[(size_t)r * N + j];
                } else {
                    int b2 = r >> 7, ii = r & 127;
                    size_t oi = ((size_t)(b2 * 256 + j)) * 128 + ii;
                    out[oi] = v + res[oi];
                }
            }
        }
    }
}

// ---------- 128x128-tile fp32 GEMM (no bias), coalesced staging ----------
__global__ __launch_bounds__(256) void k_gemm128(const float* __restrict__ A,
                                                 const float* __restrict__ W,
                                                 float* __restrict__ out,
                                                 int M, int N, int K){
    __shared__ float As[16][132];
    __shared__ float Ws[16][132];
    int j0 = blockIdx.x * 128, r0 = blockIdx.y * 128;
    int tid = threadIdx.x;
    int cg = tid & 15, rg = tid >> 4; // 8 cols, 8 rows each
    float acc[8][8] = {};
    for (int k0 = 0; k0 < K; k0 += 16){
        #pragma unroll
        for (int it = 0; it < 2; it++){
            int id = tid + it * 256;
            int row = id >> 2, kg = id & 3;
            float4 a4 = *(const float4*)(A + (size_t)(r0 + row) * K + k0 + kg * 4);
            As[kg * 4 + 0][row] = a4.x; As[kg * 4 + 1][row] = a4.y;
            As[kg * 4 + 2][row] = a4.z; As[kg * 4 + 3][row] = a4.w;
            float4 w4 = make_float4(0.f, 0.f, 0.f, 0.f);
            if (j0 + row < N)
                w4 = *(const float4*)(W + (size_t)(j0 + row) * K + k0 + kg * 4);
            Ws[kg * 4 + 0][row] = w4.x; Ws[kg * 4 + 1][row] = w4.y;
            Ws[kg * 4 + 2][row] = w4.z; Ws[kg * 4 + 3][row] = w4.w;
        }
        __syncthreads();
        #pragma unroll
        for (int kk = 0; kk < 16; kk++){
            float a[8], w[8];
            *(float4*)(a)     = *(const float4*)(&As[kk][rg * 8]);
            *(float4*)(a + 4) = *(const float4*)(&As[kk][rg * 8 + 4]);
            *(float4*)(w)     = *(const float4*)(&Ws[kk][cg * 8]);
            *(float4*)(w + 4) = *(const float4*)(&Ws[kk][cg * 8 + 4]);
            #pragma unroll
            for (int ri = 0; ri < 8; ri++)
                #pragma unroll
                for (int ci = 0; ci < 8; ci++)
                    acc[ri][ci] = fmaf(a[ri], w[ci], acc[ri][ci]);
        }
        __syncthreads();
    }
    #pragma unroll
    for (int ri = 0; ri < 8; ri++){
        int r = r0 + rg * 8 + ri;
        #pragma unroll
        for (int ci = 0; ci < 8; ci++){
            int j = j0 + cg * 8 + ci;
            if (j < N) out[(size_t)r * N + j] = acc[ri][ci];
        }
    }
}

// ---------- causal depthwise conv(4)+bias+silu, fused dt / log-dA ----------
__global__ void k_conv(const float* __restrict__ zx, const float* __restrict__ cw,
                       const float* __restrict__ cb, float* __restrict__ xc,
                       const float* __restrict__ dtbias, const float* __restrict__ Al,
                       float* __restrict__ dt, float* __restrict__ dlA,
                       int L, int D, int stride, int off, int nh, int dtoff){
    int bl = blockIdx.x;
    int l = bl & (L - 1);
    const float* base = zx + (size_t)bl * stride + off;
    for (int d = threadIdx.x; d < D; d += blockDim.x){
        float acc = cb[d];
        #pragma unroll
        for (int k = 0; k < 4; k++){
            int dl = l + k - 3;
            if (dl >= 0) acc += base[(ptrdiff_t)(k - 3) * stride + d] * cw[d * 4 + k];
        }
        xc[(size_t)bl * D + d] = siluf(acc);
    }
    int t = threadIdx.x;
    if (t < nh){
        float xv = zx[(size_t)bl * stride + dtoff + t] + dtbias[t];
        float d = softplusf(xv);
        dt[(size_t)bl * nh + t] = d;
        dlA[(size_t)bl * nh + t] = -d * __expf(Al[t]); // log(dA) <= 0
    }
}

// ---------- chunked SSD, stage A: per (b,h,chunk-of-64) ----------
// y_intra[t][p] = sum_{s<=t} (C_t.B_s) exp(cl[t]-cl[s]) dt_s x_s[p]
// S[p][n]      = sum_s exp(cl[63]-cl[s]) dt_s x_s[p] B_s[n]
// cl = inclusive chunk-local cumsum of log(dA)
// sC is reused to hold the masked G matrix after phase 1.
__global__ __launch_bounds__(256) void k_ssd_chunk(
        const float* __restrict__ xc, const float* __restrict__ dt,
        const float* __restrict__ dlA, float* __restrict__ y,
        float* __restrict__ S, float* __restrict__ clb,
        int L, int nh, int nc, int xcs, int bo, int co, int ys){
    __shared__ float sX[64][68];
    __shared__ float sB[64][68];
    __shared__ float sC[64][68]; // phase1: C ; after: masked G
    __shared__ float cl[64], sdt[64], sw[64];
    int blk = blockIdx.x;
    int c = blk % nc; int bh = blk / nc; int h = bh % nh; int b = bh / nh;
    int l0 = c * 64;
    int tid = threadIdx.x;
    const float* base = xc + ((size_t)(b * L + l0)) * xcs;
    for (int idx = tid; idx < 4096; idx += 256){
        int s = idx >> 6, n = idx & 63;
        const float* row = base + (size_t)s * xcs;
        sX[s][n] = row[h * 64 + n];
        sB[s][n] = row[bo + n];
        sC[s][n] = row[co + n];
    }
    if (tid < 64){
        size_t di = (size_t)(b * L + l0 + tid) * nh + h;
        float dlv = dlA[di];
        sdt[tid] = dt[di];
        #pragma unroll
        for (int off = 1; off < 64; off <<= 1){
            float o = __shfl_up(dlv, off, 64);
            if (tid >= off) dlv += o;
        }
        cl[tid] = dlv;
        clb[(size_t)blk * 64 + tid] = dlv;
    }
    __syncthreads();
    if (tid < 64) sw[tid] = __expf(cl[63] - cl[tid]) * sdt[tid];

    int g1 = tid >> 4, g2 = tid & 15;
    int t0 = g1 * 4, s0 = g2 * 4;
    // ---- phase 1: g = C.B^T (registers) ----
    float g[4][4] = {};
    for (int n = 0; n < 64; n += 4){
        float4 cv[4], bv[4];
        #pragma unroll
        for (int i = 0; i < 4; i++) cv[i] = *(const float4*)&sC[t0 + i][n];
        #pragma unroll
        for (int j = 0; j < 4; j++) bv[j] = *(const float4*)&sB[s0 + j][n];
        #pragma unroll
        for (int i = 0; i < 4; i++)
            #pragma unroll
            for (int j = 0; j < 4; j++){
                g[i][j] = fmaf(cv[i].x, bv[j].x, g[i][j]);
                g[i][j] = fmaf(cv[i].y, bv[j].y, g[i][j]);
                g[i][j] = fmaf(cv[i].z, bv[j].z, g[i][j]);
                g[i][j] = fmaf(cv[i].w, bv[j].w, g[i][j]);
            }
    }
    __syncthreads(); // all reads of sC (as C) complete
    #pragma unroll
    for (int i = 0; i < 4; i++)
        #pragma unroll
        for (int j = 0; j < 4; j++){
            int t = t0 + i, s = s0 + j;
            float v = 0.f;
            if (s <= t) v = g[i][j] * __expf(cl[t] - cl[s]) * sdt[s];
            sC[t][s] = v; // sC now holds masked G
        }
    __syncthreads();
    // ---- phase 2: y_intra = G @ X (t-tile t0, p-tile s0) ----
    {
        float acc[4][4] = {};
        for (int s = 0; s < 64; s++){
            float4 xv = *(const float4*)&sX[s][s0];
            float gv[4];
            #pragma unroll
            for (int i = 0; i < 4; i++) gv[i] = sC[t0 + i][s];
            #pragma unroll
            for (int i = 0; i < 4; i++){
                acc[i][0] = fmaf(gv[i], xv.x, acc[i][0]);
                acc[i][1] = fmaf(gv[i], xv.y, acc[i][1]);
                acc[i][2] = fmaf(gv[i], xv.z, acc[i][2]);
                acc[i][3] = fmaf(gv[i], xv.w, acc[i][3]);
            }
        }
        #pragma unroll
        for (int i = 0; i < 4; i++){
            float4 o = make_float4(acc[i][0], acc[i][1], acc[i][2], acc[i][3]);
            *(float4*)&y[(size_t)(b * L + l0 + t0 + i) * ys + h * 64 + s0] = o;
        }
    }
    // ---- phase 3: S[p][n] (p-tile t0, n-tile s0) ----
    {
        float acc[4][4] = {};
        int p0 = t0, n0 = s0;
        for (int s = 0; s < 64; s++){
            float wv = sw[s];
            float4 bv = *(const float4*)&sB[s][n0];
            float4 xv = *(const float4*)&sX[s][p0];
            float w0 = wv * xv.x, w1 = wv * xv.y, w2 = wv * xv.z, w3 = wv * xv.w;
            acc[0][0] = fmaf(w0, bv.x, acc[0][0]); acc[0][1] = fmaf(w0, bv.y, acc[0][1]);
            acc[0][2] = fmaf(w0, bv.z, acc[0][2]); acc[0][3] = fmaf(w0, bv.w, acc[0][3]);
            acc[1][0] = fmaf(w1, bv.x, acc[1][0]); acc[1][1] = fmaf(w1, bv.y, acc[1][1]);
            acc[1][2] = fmaf(w1, bv.z, acc[1][2]); acc[1][3] = fmaf(w1, bv.w, acc[1][3]);
            acc[2][0] = fmaf(w2, bv.x, acc[2][0]); acc[2][1] = fmaf(w2, bv.y, acc[2][1]);
            acc[2][2] = fmaf(w2, bv.z, acc[2][2]); acc[2][3] = fmaf(w2, bv.w, acc[2][3]);
            acc[3][0] = fmaf(w3, bv.x, acc[3][0]); acc[3][1] = fmaf(w3, bv.y, acc[3][1]);
            acc[3][2] = fmaf(w3, bv.z, acc[3][2]); acc[3][3] = fmaf(w3, bv.w, acc[3][3]);
        }
        float* Sp = S + (size_t)blk * 4096;
        #pragma unroll
        for (int i = 0; i < 4; i++){
            float4 o = make_float4(acc[i][0], acc[i][1], acc[i][2], acc[i][3]);
            *(float4*)&Sp[(p0 + i) * 64 + n0] = o;
        }
    }
}

// ---------- chunked SSD, stage B: sequential chunk-state scan, in-place ----------
// On exit S[row] holds h_init for that chunk (state BEFORE the chunk).
__global__ __launch_bounds__(256) void k_chunk_scan(float* __restrict__ S,
                                                    const float* __restrict__ clb,
                                                    int nc){
    int row0 = blockIdx.x * nc;
    int tid = threadIdx.x;
    float h[16];
    #pragma unroll
    for (int k = 0; k < 16; k++) h[k] = 0.f;
    for (int c = 0; c < nc; c++){
        int row = row0 + c;
        float dec = __expf(clb[(size_t)row * 64 + 63]);
        float* Sp = S + (size_t)row * 4096;
        #pragma unroll
        for (int k = 0; k < 16; k++){
            int e = tid + k * 256;
            float s = Sp[e];
            Sp[e] = h[k];
            h[k] = fmaf(dec, h[k], s);
        }
    }
}

// ---------- chunked SSD, stage C: y += exp(cl[t]) * (C_t . h_init) + D*x ----------
__global__ __launch_bounds__(256) void k_chunk_y(
        const float* __restrict__ xc, const float* __restrict__ Hb,
        const float* __restrict__ clb, const float* __restrict__ Dp,
        float* __restrict__ y,
        int L, int nh, int nc, int xcs, int co, int ys){
    __shared__ float sH[64][68]; // [p][n]
    __shared__ float sC[64][68]; // [t][n]
    __shared__ float scl[64];
    int blk = blockIdx.x;
    int c = blk % nc; int bh = blk / nc; int h = bh % nh; int b = bh / nh;
    int l0 = c * 64;
    int tid = threadIdx.x;
    const float* Hp = Hb + (size_t)blk * 4096;
    const float* base = xc + ((size_t)(b * L + l0)) * xcs;
    for (int idx = tid; idx < 4096; idx += 256){
        int r = idx >> 6, n = idx & 63;
        sH[r][n] = Hp[idx];
        sC[r][n] = base[(size_t)r * xcs + co + n];
    }
    if (tid < 64) scl[tid] = __expf(clb[(size_t)blk * 64 + tid]);
    float Dh = Dp[h];
    __syncthreads();
    int g1 = tid >> 4, g2 = tid & 15;
    int t0 = g1 * 4, p0 = g2 * 4;
    float m[4][4] = {};
    for (int n = 0; n < 64; n += 4){
        float4 cv[4], hv[4];
        #pragma unroll
        for (int i = 0; i < 4; i++) cv[i] = *(const float4*)&sC[t0 + i][n];
        #pragma unroll
        for (int j = 0; j < 4; j++) hv[j] = *(const float4*)&sH[p0 + j][n];
        #pragma unroll
        for (int i = 0; i < 4; i++)
            #pragma unroll
            for (int j = 0; j < 4; j++){
                m[i][j] = fmaf(cv[i].x, hv[j].x, m[i][j]);
                m[i][j] = fmaf(cv[i].y, hv[j].y, m[i][j]);
                m[i][j] = fmaf(cv[i].z, hv[j].z, m[i][j]);
                m[i][j] = fmaf(cv[i].w, hv[j].w, m[i][j]);
            }
    }
    #pragma unroll
    for (int i = 0; i < 4; i++){
        int t = t0 + i;
        size_t yi = (size_t)(b * L + l0 + t) * ys + h * 64 + p0;
        float4 yv = *(float4*)&y[yi];
        float4 xv = *(const float4*)&base[(size_t)t * xcs + h * 64 + p0];
        float e = scl[t];
        yv.x += e * m[i][0] + Dh * xv.x;
        yv.y += e * m[i][1] + Dh * xv.y;
        yv.z += e * m[i][2] + Dh * xv.z;
        yv.w += e * m[i][3] + Dh * xv.w;
        *(float4*)&y[yi] = yv;
    }
}

// ---------- gate (silu(z)) + RMSNorm ----------
__global__ __launch_bounds__(256) void k_gate(const float* __restrict__ y,
                                              const float* __restrict__ zx,
                                              const float* __restrict__ rw,
                                              float* __restrict__ out,
                                              int dinner, int zstride){
    __shared__ float sm[16];
    int row = blockIdx.x, t = threadIdx.x;
    float v0, v1 = 0.f, ss;
    v0 = y[(size_t)row * dinner + t] * siluf(zx[(size_t)row * zstride + t]);
    ss = v0 * v0;
    if (dinner == 512){
        v1 = y[(size_t)row * dinner + t + 256] * siluf(zx[(size_t)row * zstride + t + 256]);
        ss += v1 * v1;
    }
    float tot = blk_sum1(ss, sm);
    float sc = rsqrtf(tot / (float)dinner + 1e-5f);
    out[(size_t)row * dinner + t] = v0 * sc * rw[t];
    if (dinner == 512) out[(size_t)row * dinner + t + 256] = v1 * sc * rw[t + 256];
}

// ---------- center projection + q ----------
__global__ void k_center_q(const float* __restrict__ xs, const float* __restrict__ cw,
                           const float* __restrict__ cb, const float* __restrict__ qw,
                           const float* __restrict__ qb, float* __restrict__ q){
    __shared__ float xr[640];
    __shared__ float cen[128];
    int b = blockIdx.x, t = threadIdx.x; // 128 thr
    for (int idx = t; idx < 640; idx += 128)
        xr[idx] = xs[(size_t)b * 256 * 128 + idx];
    __syncthreads();
    float acc = cb[t];
    for (int c = 0; c < 128; c++){
        const float* wp = cw + (size_t)(t * 128 + c) * 5;
        #pragma unroll
        for (int l = 0; l < 5; l++) acc += xr[l * 128 + c] * wp[l];
    }
    cen[t] = acc;
    __syncthreads();
    float qa = qb[t];
    const float* wr = qw + (size_t)t * 128;
    for (int o = 0; o < 128; o++) qa += cen[o] * wr[o];
    q[b * 128 + t] = qa;
}

// ---------- attention softmax over l ----------
__global__ void k_attn(const float* __restrict__ q, const float* __restrict__ k,
                       float* __restrict__ attn){
    __shared__ float sm[16];
    __shared__ float qh[16];
    int blk = blockIdx.x; int b = blk >> 3, h = blk & 7; int l = threadIdx.x; // 256 thr
    if (l < 16) qh[l] = q[b * 128 + h * 16 + l];
    __syncthreads();
    const float* kp = k + ((size_t)(b * 256 + l)) * 128 + h * 16;
    float s = 0.f;
    #pragma unroll
    for (int d = 0; d < 16; d++) s += qh[d] * kp[d];
    s *= 0.25f;
    float mx = blk_max1(s, sm);
    float e = __expf(s - mx);
    float sum = blk_sum1(e, sm);
    attn[(size_t)blk * 256 + l] = e / sum;
}

// ---------- attention out ----------
__global__ void k_attn_out(const float* __restrict__ v, const float* __restrict__ attn,
                           const float* __restrict__ ow, const float* __restrict__ ob,
                           float* __restrict__ xs){
    __shared__ float vp[128];
    int bl = blockIdx.x; int b = bl >> 8, l = bl & 255; int t = threadIdx.x; // 128 thr
    float a = attn[((size_t)((b << 3) + (t >> 4))) * 256 + l];
    vp[t] = v[(size_t)bl * 128 + t] * a;
    __syncthreads();
    float acc = ob[t];
    const float* wr = ow + (size_t)t * 128;
    for (int j = 0; j < 128; j++) acc += vp[j] * wr[j];
    xs[(size_t)bl * 128 + t] += acc;
}

// ---------- spectral q2/k2/v2 ----------
__global__ __launch_bounds__(256) void k_spe_qkv(const float* __restrict__ xs,
                                                 const float* __restrict__ sqw, const float* __restrict__ sqb,
                                                 const float* __restrict__ skw, const float* __restrict__ skb,
                                                 const float* __restrict__ svw, const float* __restrict__ svb,
                                                 float* __restrict__ q2, float* __restrict__ k2,
                                                 float* __restrict__ v2){
    __shared__ float xt[8][256];
    int blk = blockIdx.x; int b = blk >> 4; int i0 = (blk & 15) << 3;
    int t = threadIdx.x;
    for (int idx = t; idx < 8 * 256; idx += 256){
        int ii = idx >> 8, tt = idx & 255;
        xt[ii][tt] = xs[((size_t)(b * 256 + tt)) * 128 + i0 + ii];
    }
    __syncthreads();
    int j = t;
    float aq[8] = {}, ak_[8] = {}, av_[8] = {};
    const float* wq = sqw + (size_t)j * 256;
    const float* wk = skw + (size_t)j * 256;
    const float* wv = svw + (size_t)j * 256;
    for (int tt = 0; tt < 256; tt++){
        float wqv = wq[tt], wkv = wk[tt], wvv = wv[tt];
        #pragma unroll
        for (int ii = 0; ii < 8; ii++){
            float xv = xt[ii][tt];
            aq[ii] = fmaf(xv, wqv, aq[ii]);
            ak_[ii] = fmaf(xv, wkv, ak_[ii]);
            av_[ii] = fmaf(xv, wvv, av_[ii]);
        }
    }
    float bq = sqb[j], bk = skb[j], bv = svb[j];
    #pragma unroll
    for (int ii = 0; ii < 8; ii++){
        size_t row = (size_t)(b * 128 + i0 + ii) * 256 + j;
        q2[row] = aq[ii] + bq;
        k2[row] = ak_[ii] + bk;
        v2[row] = av_[ii] + bv;
    }
}

// ---------- spectral attention + softmax ----------
__global__ __launch_bounds__(128) void k_attn2(const float* __restrict__ q2,
                                               const float* __restrict__ k2,
                                               float* __restrict__ attn2){
    __shared__ float qs[8][256];
    __shared__ float lg[8][128];
    __shared__ float mxs[8], sms[8];
    int blk = blockIdx.x; int b = blk >> 4; int i0 = (blk & 15) << 3;
    int j = threadIdx.x;
    for (int idx = j; idx < 8 * 256; idx += 128){
        int ii = idx >> 8, d = idx & 255;
        qs[ii][d] = q2[((size_t)(b * 128 + i0 + ii)) * 256 + d];
    }
    __syncthreads();
    const float* kr = k2 + ((size_t)(b * 128 + j)) * 256;
    float acc[8] = {};
    for (int d = 0; d < 256; d++){
        float kv = kr[d];
        #pragma unroll
        for (int ii = 0; ii < 8; ii++) acc[ii] = fmaf(qs[ii][d], kv, acc[ii]);
    }
    #pragma unroll
    for (int ii = 0; ii < 8; ii++) lg[ii][j] = acc[ii] * (1.f / 16.f);
    __syncthreads();
    if (j < 8){
        float mx = -3.4e38f;
        for (int tt = 0; tt < 128; tt++) mx = fmaxf(mx, lg[j][tt]);
        float sm = 0.f;
        for (int tt = 0; tt < 128; tt++) sm += __expf(lg[j][tt] - mx);
        mxs[j] = mx; sms[j] = 1.f / sm;
    }
    __syncthreads();
    #pragma unroll
    for (int ii = 0; ii < 8; ii++)
        attn2[((size_t)(b * 128 + i0 + ii)) * 128 + j] =
            __expf(lg[ii][j] - mxs[ii]) * sms[ii];
}

// ---------- (attn2 @ v2) @ so_w.T + so_b, transposed add ----------
__global__ __launch_bounds__(256) void k_av_so(const float* __restrict__ attn2,
                                               const float* __restrict__ v2,
                                               const float* __restrict__ sow,
                                               const float* __restrict__ sob,
                                               float* __restrict__ xs){
    __shared__ float a2[8][128];
    __shared__ float av[8][256];
    int blk = blockIdx.x; int b = blk >> 4; int i0 = (blk & 15) << 3;
    int t = threadIdx.x;
    for (int idx = t; idx < 8 * 128; idx += 256){
        int ii = idx >> 7, j = idx & 127;
        a2[ii][j] = attn2[((size_t)(b * 128 + i0 + ii)) * 128 + j];
    }
    __syncthreads();
    {
        float acc[8] = {};
        const float* vb = v2 + (size_t)b * 128 * 256 + t;
        for (int j = 0; j < 128; j++){
            float vv = vb[(size_t)j * 256];
            #pragma unroll
            for (int ii = 0; ii < 8; ii++) acc[ii] = fmaf(a2[ii][j], vv, acc[ii]);
        }
        #pragma unroll
        for (int ii = 0; ii < 8; ii++) av[ii][t] = acc[ii];
    }
    __syncthreads();
    float acc[8] = {};
    const float* wr = sow + (size_t)t * 256;
    for (int d = 0; d < 256; d++){
        float wv = wr[d];
        #pragma unroll
        for (int ii = 0; ii < 8; ii++) acc[ii] = fmaf(av[ii][d], wv, acc[ii]);
    }
    float bias = sob[t];
    float* xp = xs + ((size_t)(b * 256 + t)) * 128 + i0;
    #pragma unroll
    for (int ii = 0; ii < 8; ii++) xp[ii] += acc[ii] + bias;
}

// ---------- unsort scatter ----------
__global__ void k_scatter(const float* __restrict__ xs, const int* __restrict__ sidx,
                          float* __restrict__ xr){
    int bl = blockIdx.x; int b = bl >> 8;
    int p = sidx[bl];
    xr[((size_t)(b * 256 + p)) * 128 + threadIdx.x] = xs[(size_t)bl * 128 + threadIdx.x];
}

// ---------- im2col for 3x3/2 conv ----------
__global__ void k_im2col(const float* __restrict__ xr, float* __restrict__ col){
    int r = blockIdx.x; int t = threadIdx.x; // 128 thr
    int b = r >> 6, oh = (r >> 3) & 7, ow = r & 7;
    float* dst = col + (size_t)r * 1152;
    #pragma unroll
    for (int kh = 0; kh < 3; kh++){
        int ih = oh * 2 - 1 + kh;
        #pragma unroll
        for (int kw = 0; kw < 3; kw++){
            int iw = ow * 2 - 1 + kw;
            float v = 0.f;
            if (ih >= 0 && ih < 16 && iw >= 0 && iw < 16)
                v = xr[((size_t)((b << 8) + (ih << 4) + iw)) * 128 + t];
            dst[(kh * 3 + kw) * 128 + t] = v;
        }
    }
}

// ---------- conv GEMM split-K=4 ----------
__global__ __launch_bounds__(256) void k_conv_gemm(const float* __restrict__ col,
                                                   const float* __restrict__ W2,
                                                   float* __restrict__ part){
    __shared__ float As[16][68];
    __shared__ float Ws[16][64];
    int j0 = blockIdx.x * 64, r0 = blockIdx.y * 64, s = blockIdx.z;
    int tid = threadIdx.x;
    int cg = tid & 15, rg = tid >> 4;
    float acc[4][4] = {};
    int kbeg = s * 288, kend = kbeg + 288;
    for (int k0 = kbeg; k0 < kend; k0 += 16){
        {
            int row = tid >> 2, kg = tid & 3;
            float4 a4 = *(const float4*)(col + (size_t)(r0 + row) * 1152 + k0 + kg * 4);
            As[kg * 4 + 0][row] = a4.x; As[kg * 4 + 1][row] = a4.y;
            As[kg * 4 + 2][row] = a4.z; As[kg * 4 + 3][row] = a4.w;
        }
        #pragma unroll
        for (int it = 0; it < 4; it++){
            int idx = tid + it * 256;
            int jj = idx & 63, kk = idx >> 6;
            Ws[kk][jj] = W2[(size_t)(k0 + kk) * 128 + j0 + jj];
        }
        __syncthreads();
        #pragma unroll
        for (int kk = 0; kk < 16; kk++){
            float4 a4 = *(const float4*)(&As[kk][rg << 2]);
            float4 w4 = *(const float4*)(&Ws[kk][cg << 2]);
            float av_[4] = {a4.x, a4.y, a4.z, a4.w};
            float wv_[4] = {w4.x, w4.y, w4.z, w4.w};
            #pragma unroll
            for (int ri = 0; ri < 4; ri++)
                #pragma unroll
                for (int ci = 0; ci < 4; ci++)
                    acc[ri][ci] = fmaf(av_[ri], wv_[ci], acc[ri][ci]);
        }
        __syncthreads();
    }
    float* pp = part + (size_t)s * 1024 * 128;
    #pragma unroll
    for (int ri = 0; ri < 4; ri++){
        int r = r0 + (rg << 2) + ri;
        #pragma unroll
        for (int ci = 0; ci < 4; ci++){
            int j = j0 + (cg << 2) + ci;
            pp[(size_t)r * 128 + j] = acc[ri][ci];
        }
    }
}

// ---------- reduce split-K partials + LayerNorm ----------
__global__ void k_part_ln(const float* __restrict__ part, const float* __restrict__ lnw,
                          const float* __restrict__ lnb, float* __restrict__ out){
    __shared__ float sm[16];
    int r = blockIdx.x, t = threadIdx.x; // 128 thr
    float v = part[(size_t)r * 128 + t]
            + part[(size_t)(1024 + r) * 128 + t]
            + part[(size_t)(2048 + r) * 128 + t]
            + part[(size_t)(3072 + r) * 128 + t];
    float a = v, q = v * v;
    blk_sum2(a, q, sm);
    float mu = a * (1.f / 128.f);
    float var = q * (1.f / 128.f) - mu * mu;
    float rs = rsqrtf(var + 1e-5f);
    out[(size_t)r * 128 + t] = (v - mu) * rs * lnw[t] + lnb[t];
}

extern "C" void kernel_launch(void* const* d_in, const int* in_sizes, int n_in,
                              void* d_out, int out_size, void* d_ws, size_t ws_size,
                              hipStream_t stream) {
    const float* x          = (const float*)d_in[0];
    const int*   sidx       = (const int*)  d_in[1];
    const float* spa_ln_w   = (const float*)d_in[2];
    const float* spa_ln_b   = (const float*)d_in[3];
    const float* spa_in_w   = (const float*)d_in[4];
    const float* spa_conv_w = (const float*)d_in[5];
    const float* spa_conv_b = (const float*)d_in[6];
    const float* spa_dt_bias= (const float*)d_in[7];
    const float* spa_A_log  = (const float*)d_in[8];
    const float* spa_D      = (const float*)d_in[9];
    const float* spa_rms_w  = (const float*)d_in[10];
    const float* spa_out_w  = (const float*)d_in[11];
    const float* spe_ln_w   = (const float*)d_in[12];
    const float* spe_ln_b   = (const float*)d_in[13];
    const float* spe_in_w   = (const float*)d_in[14];
    const float* spe_conv_w = (const float*)d_in[15];
    const float* spe_conv_b = (const float*)d_in[16];
    const float* spe_dt_bias= (const float*)d_in[17];
    const float* spe_A_log  = (const float*)d_in[18];
    const float* spe_D      = (const float*)d_in[19];
    const float* spe_rms_w  = (const float*)d_in[20];
    const float* spe_out_w  = (const float*)d_in[21];
    const float* norm_w     = (const float*)d_in[22];
    const float* norm_b     = (const float*)d_in[23];
    const float* cprj_w     = (const float*)d_in[24];
    const float* cprj_b     = (const float*)d_in[25];
    const float* aq_w       = (const float*)d_in[26];
    const float* aq_b       = (const float*)d_in[27];
    const float* ak_w       = (const float*)d_in[28];
    const float* ak_b       = (const float*)d_in[29];
    const float* av_w       = (const float*)d_in[30];
    const float* av_b       = (const float*)d_in[31];
    const float* ao_w       = (const float*)d_in[32];
    const float* ao_b       = (const float*)d_in[33];
    const float* sq_w       = (const float*)d_in[34];
    const float* sq_b       = (const float*)d_in[35];
    const float* sk_w       = (const float*)d_in[36];
    const float* sk_b       = (const float*)d_in[37];
    const float* sv_w       = (const float*)d_in[38];
    const float* sv_b       = (const float*)d_in[39];
    const float* so_w       = (const float*)d_in[40];
    const float* so_b       = (const float*)d_in[41];
    const float* ds_conv_w  = (const float*)d_in[42];
    const float* ds_ln_w    = (const float*)d_in[43];
    const float* ds_ln_b    = (const float*)d_in[44];

    float* ws = (float*)d_ws;
    float* xs   = ws + 0;        // 524288
    float* lnb_ = ws + 524288;   // 524288 (clbuf lives in its tail when lnb_ is dead)
    float* zx   = ws + 1048576;  // -> 3686400
    float* xc   = ws + 3686400;  // -> 5259264
    float* dtb  = ws + 5259264;  // 32768
    float* dAb  = ws + 5292032;  // 32768 (holds log-dA)
    float* yb   = ws + 5324800;  // 1048576 -> 6373376
    float* gb   = ws + 6373376;  // 1048576 -> 7421952 (scan: S buffer alias)
    float* h1   = ws + 7421952;  // 524288 -> 7946240
    // clbuf: 16384 floats inside lnb_'s region (lnb_ is dead from k_conv until
    // the next k_ln/k_ln_t, which covers clbuf's entire live range).
    float* clbuf = ws + 524288;
    // attention-stage aliases
    float* kb    = ws + 1048576;
    float* vb    = ws + 1572864;
    float* attnb = ws + 2097152;
    float* qb    = ws + 2129920;
    float* q2    = ws + 3686400;
    float* k2    = ws + 4210688;
    float* v2    = ws + 4734976;
    float* attn2 = ws + 5324800;
    float* xr    = ws + 5586944;
    float* col   = ws + 6111232; // -> 7290880
    float* part  = ws + 7290880; // -> 7815168

    k_embed<<<4096, 128, 0, stream>>>(x, sidx, xs);

    for (int i = 0; i < 2; i++){
        // ---- spatial mamba (L=256, nh=4, nc=4) ----
        k_ln<<<4096, 128, 0, stream>>>(xs, spa_ln_w + i * 128, spa_ln_b + i * 128, lnb_, 128);
        k_gemm128<<<dim3(6, 32), 256, 0, stream>>>(lnb_, spa_in_w + (size_t)i * 644 * 128,
                                                   zx, 4096, 644, 128);
        k_conv<<<4096, 256, 0, stream>>>(zx, spa_conv_w + (size_t)i * 384 * 4,
                                         spa_conv_b + i * 384, xc,
                                         spa_dt_bias + i * 4, spa_A_log + i * 4, dtb, dAb,
                                         256, 384, 644, 256, 4, 640);
        k_ssd_chunk<<<256, 256, 0, stream>>>(xc, dtb, dAb, yb, gb, clbuf,
                                             256, 4, 4, 384, 256, 320, 256);
        k_chunk_scan<<<64, 256, 0, stream>>>(gb, clbuf, 4);
        k_chunk_y<<<256, 256, 0, stream>>>(xc, gb, clbuf, spa_D + i * 4, yb,
                                           256, 4, 4, 384, 320, 256);
        k_gate<<<4096, 256, 0, stream>>>(yb, zx, spa_rms_w + i * 256, gb, 256, 644);
        k_gemm<<<dim3(2, 64), 256, 0, stream>>>(gb, spa_out_w + (size_t)i * 128 * 256,
                                                nullptr, xs, h1, 4096, 128, 256, 1);
        // ---- spectral mamba (L=128, nh=8, nc=2) ----
        k_ln_t<<<2048, 256, 0, stream>>>(h1, spe_ln_w + i * 256, spe_ln_b + i * 256, lnb_);
        k_gemm128<<<dim3(10, 16), 256, 0, stream>>>(lnb_, spe_in_w + (size_t)i * 1160 * 256,
                                                    zx, 2048, 1160, 256);
        k_conv<<<2048, 256, 0, stream>>>(zx, spe_conv_w + (size_t)i * 640 * 4,
                                         spe_conv_b + i * 640, xc,
                                         spe_dt_bias + i * 8, spe_A_log + i * 8, dtb, dAb,
                                         128, 640, 1160, 512, 8, 1152);
        k_ssd_chunk<<<256, 256, 0, stream>>>(xc, dtb, dAb, yb, gb, clbuf,
                                             128, 8, 2, 640, 512, 576, 512);
        k_chunk_scan<<<128, 256, 0, stream>>>(gb, clbuf, 2);
        k_chunk_y<<<256, 256, 0, stream>>>(xc, gb, clbuf, spe_D + i * 8, yb,
                                           128, 8, 2, 640, 576, 512);
        k_gate<<<2048, 256, 0, stream>>>(yb, zx, spe_rms_w + i * 512, gb, 512, 1160);
        k_gemm<<<dim3(4, 32), 256, 0, stream>>>(gb, spe_out_w + (size_t)i * 256 * 512,
                                                nullptr, h1, xs, 2048, 256, 512, 2);
    }

    k_ln<<<4096, 128, 0, stream>>>(xs, norm_w, norm_b, xs, 128);
    k_center_q<<<16, 128, 0, stream>>>(xs, cprj_w, cprj_b, aq_w, aq_b, qb);
    k_gemm<<<dim3(2, 64), 256, 0, stream>>>(xs, ak_w, ak_b, nullptr, kb, 4096, 128, 128, 0);
    k_gemm<<<dim3(2, 64), 256, 0, stream>>>(xs, av_w, av_b, nullptr, vb, 4096, 128, 128, 0);
    k_attn<<<128, 256, 0, stream>>>(qb, kb, attnb);
    k_attn_out<<<4096, 128, 0, stream>>>(vb, attnb, ao_w, ao_b, xs);
    k_spe_qkv<<<256, 256, 0, stream>>>(xs, sq_w, sq_b, sk_w, sk_b, sv_w, sv_b, q2, k2, v2);
    k_attn2<<<256, 128, 0, stream>>>(q2, k2, attn2);
    k_av_so<<<256, 256, 0, stream>>>(attn2, v2, so_w, so_b, xs);
    k_scatter<<<4096, 128, 0, stream>>>(xs, sidx, xr);
    k_im2col<<<1024, 128, 0, stream>>>(xr, col);
    k_conv_gemm<<<dim3(2, 16, 4), 256, 0, stream>>>(col, ds_conv_w, part);
    k_part_ln<<<1024, 128, 0, stream>>>(part, ds_ln_w, ds_ln_b, (float*)d_out);
}

// Round 6
// 763.859 us; speedup vs baseline: 1.3939x; 1.1516x over previous
//
#include <hip/hip_runtime.h>
#include <math.h>

#define DEV __device__ __forceinline__

DEV float siluf(float x){ return x / (1.f + __expf(-x)); }
DEV float softplusf(float x){ return (x > 20.f) ? x : log1pf(__expf(x)); }

// ---------- block reduction helpers (wave64) ----------
DEV void blk_sum2(float &a, float &b, float* sm){
    int lane = threadIdx.x & 63, wid = threadIdx.x >> 6, nw = blockDim.x >> 6;
    #pragma unroll
    for (int off = 32; off; off >>= 1){ a += __shfl_down(a, off); b += __shfl_down(b, off); }
    if (lane == 0){ sm[wid] = a; sm[8 + wid] = b; }
    __syncthreads();
    float ra = 0.f, rb = 0.f;
    for (int i = 0; i < nw; i++){ ra += sm[i]; rb += sm[8 + i]; }
    __syncthreads();
    a = ra; b = rb;
}
DEV float blk_sum1(float v, float* sm){
    int lane = threadIdx.x & 63, wid = threadIdx.x >> 6, nw = blockDim.x >> 6;
    #pragma unroll
    for (int off = 32; off; off >>= 1) v += __shfl_down(v, off);
    if (lane == 0) sm[wid] = v;
    __syncthreads();
    float r = 0.f;
    for (int i = 0; i < nw; i++) r += sm[i];
    __syncthreads();
    return r;
}
DEV float blk_max1(float v, float* sm){
    int lane = threadIdx.x & 63, wid = threadIdx.x >> 6, nw = blockDim.x >> 6;
    #pragma unroll
    for (int off = 32; off; off >>= 1) v = fmaxf(v, __shfl_down(v, off));
    if (lane == 0) sm[wid] = v;
    __syncthreads();
    float r = -3.4e38f;
    for (int i = 0; i < nw; i++) r = fmaxf(r, sm[i]);
    __syncthreads();
    return r;
}

// ---------- K1: pos-embed + gather ----------
__global__ void k_embed(const float* __restrict__ x, const int* __restrict__ sidx,
                        float* __restrict__ xs){
    int bl = blockIdx.x; int b = bl >> 8; int c = threadIdx.x;
    int p = sidx[bl];
    int hh = p >> 4, ww = p & 15;
    int pos = (c < 64) ? hh : ww;
    int jm = c & 63;
    float om = __expf(-(float)(jm & 31) * 0.28782313662425574f); // ln(10000)/32
    float ang = (float)pos * om;
    float pe = (jm < 32) ? sinf(ang) : cosf(ang);
    xs[(size_t)bl * 128 + c] = x[((size_t)(b * 128 + c)) * 256 + p] + pe;
}

// ---------- LayerNorm (block per row, blockDim == dim) ----------
__global__ void k_ln(const float* __restrict__ in, const float* __restrict__ w,
                     const float* __restrict__ bb, float* __restrict__ out, int dim){
    __shared__ float sm[16];
    int row = blockIdx.x, t = threadIdx.x;
    float v = in[(size_t)row * dim + t];
    float a = v, q = v * v;
    blk_sum2(a, q, sm);
    float inv = 1.f / (float)dim;
    float mu = a * inv;
    float var = q * inv - mu * mu;
    float rs = rsqrtf(var + 1e-5f);
    out[(size_t)row * dim + t] = (v - mu) * rs * w[t] + bb[t];
}

// ---------- transposed LayerNorm for spectral ----------
__global__ void k_ln_t(const float* __restrict__ h1, const float* __restrict__ w,
                       const float* __restrict__ bb, float* __restrict__ out){
    __shared__ float sm[16];
    int row = blockIdx.x; int b = row >> 7, i = row & 127; int t = threadIdx.x; // 256 thr
    float v = h1[((size_t)(b * 256 + t)) * 128 + i];
    float a = v, q = v * v;
    blk_sum2(a, q, sm);
    float mu = a * (1.f / 256.f);
    float var = q * (1.f / 256.f) - mu * mu;
    float rs = rsqrtf(var + 1e-5f);
    out[(size_t)row * 256 + t] = (v - mu) * rs * w[t] + bb[t];
}

// ---------- 64x64-tile fp32 GEMM v2: coalesced staging, BK=32 ----------
// out[r,j] = sum_k A[r,k]*W[j,k]  (+epilogue)
// mode 0: +bias (may be null). mode 1: + res. mode 2 (N mult of 64, M rows map
// to (b2,ii)): out[((r0>>7)*256 + j)*128 + (r&127)] = acc + res[same] via LDS
// transpose for coalesced writes. Requires: K % 32 == 0, N % 64 == 0.
__global__ __launch_bounds__(256) void k_gemm(const float* __restrict__ A,
                                              const float* __restrict__ W,
                                              const float* __restrict__ bias,
                                              const float* __restrict__ res,
                                              float* __restrict__ out,
                                              int M, int N, int K, int mode){
    __shared__ float lds[2][32][68]; // [0]=A-tile, [1]=W-tile; reused as T[64][68]
    int j0 = blockIdx.x * 64, r0 = blockIdx.y * 64;
    int tid = threadIdx.x;
    int cg = tid & 15, rg = tid >> 4;
    int row = tid >> 2, kg = tid & 3; // staging: 64 rows x (4 lanes x float4 = 16k) x2
    float acc[4][4] = {};
    for (int k0 = 0; k0 < K; k0 += 32){
        const float* Ap = A + (size_t)(r0 + row) * K + k0 + kg * 4;
        float4 a0 = *(const float4*)(Ap);
        float4 a1 = *(const float4*)(Ap + 16);
        const float* Wp = W + (size_t)(j0 + row) * K + k0 + kg * 4;
        float4 w0 = *(const float4*)(Wp);
        float4 w1 = *(const float4*)(Wp + 16);
        __syncthreads(); // previous iteration's LDS reads done
        lds[0][kg * 4 + 0][row] = a0.x; lds[0][kg * 4 + 1][row] = a0.y;
        lds[0][kg * 4 + 2][row] = a0.z; lds[0][kg * 4 + 3][row] = a0.w;
        lds[0][16 + kg * 4 + 0][row] = a1.x; lds[0][16 + kg * 4 + 1][row] = a1.y;
        lds[0][16 + kg * 4 + 2][row] = a1.z; lds[0][16 + kg * 4 + 3][row] = a1.w;
        lds[1][kg * 4 + 0][row] = w0.x; lds[1][kg * 4 + 1][row] = w0.y;
        lds[1][kg * 4 + 2][row] = w0.z; lds[1][kg * 4 + 3][row] = w0.w;
        lds[1][16 + kg * 4 + 0][row] = w1.x; lds[1][16 + kg * 4 + 1][row] = w1.y;
        lds[1][16 + kg * 4 + 2][row] = w1.z; lds[1][16 + kg * 4 + 3][row] = w1.w;
        __syncthreads();
        #pragma unroll
        for (int kk = 0; kk < 32; kk++){
            float4 a4 = *(const float4*)(&lds[0][kk][rg << 2]);
            float4 w4 = *(const float4*)(&lds[1][kk][cg << 2]);
            float av_[4] = {a4.x, a4.y, a4.z, a4.w};
            float wv_[4] = {w4.x, w4.y, w4.z, w4.w};
            #pragma unroll
            for (int ri = 0; ri < 4; ri++)
                #pragma unroll
                for (int ci = 0; ci < 4; ci++)
                    acc[ri][ci] = fmaf(av_[ri], wv_[ci], acc[ri][ci]);
        }
    }
    if (mode == 2){
        // stage output tile transposed: T[j-j0][r-r0], then coalesced writes
        float (*T)[68] = (float (*)[68])lds;
        __syncthreads();
        #pragma unroll
        for (int ri = 0; ri < 4; ri++)
            #pragma unroll
            for (int ci = 0; ci < 4; ci++)
                T[(cg << 2) + ci][(rg << 2) + ri] = acc[ri][ci];
        __syncthreads();
        int b2 = r0 >> 7;
        int ii0 = r0 & 127;
        int jj = tid >> 2, seg = tid & 3;
        size_t base = ((size_t)(b2 * 256 + j0 + jj)) * 128 + ii0 + seg * 16;
        float* op = out + base;
        const float* rp = res + base;
        #pragma unroll
        for (int c = 0; c < 4; c++){
            float4 v = *(const float4*)(&T[jj][seg * 16 + c * 4]);
            float4 rv = *(const float4*)(rp + c * 4);
            v.x += rv.x; v.y += rv.y; v.z += rv.z; v.w += rv.w;
            *(float4*)(op + c * 4) = v;
        }
    } else {
        #pragma unroll
        for (int ri = 0; ri < 4; ri++){
            int r = r0 + (rg << 2) + ri;
            int j = j0 + (cg << 2);
            float4 v = make_float4(acc[ri][0], acc[ri][1], acc[ri][2], acc[ri][3]);
            if (mode == 0){
                if (bias){
                    v.x += bias[j]; v.y += bias[j + 1];
                    v.z += bias[j + 2]; v.w += bias[j + 3];
                }
                *(float4*)(&out[(size_t)r * N + j]) = v;
            } else {
                float4 rv = *(const float4*)(&res[(size_t)r * N + j]);
                v.x += rv.x; v.y += rv.y; v.z += rv.z; v.w += rv.w;
                *(float4*)(&out[(size_t)r * N + j]) = v;
            }
        }
    }
}

// ---------- 128x128-tile fp32 GEMM (no bias), coalesced staging ----------
__global__ __launch_bounds__(256) void k_gemm128(const float* __restrict__ A,
                                                 const float* __restrict__ W,
                                                 float* __restrict__ out,
                                                 int M, int N, int K){
    __shared__ float As[16][132];
    __shared__ float Ws[16][132];
    int j0 = blockIdx.x * 128, r0 = blockIdx.y * 128;
    int tid = threadIdx.x;
    int cg = tid & 15, rg = tid >> 4; // 8 cols, 8 rows each
    float acc[8][8] = {};
    for (int k0 = 0; k0 < K; k0 += 16){
        #pragma unroll
        for (int it = 0; it < 2; it++){
            int id = tid + it * 256;
            int row = id >> 2, kg = id & 3;
            float4 a4 = *(const float4*)(A + (size_t)(r0 + row) * K + k0 + kg * 4);
            As[kg * 4 + 0][row] = a4.x; As[kg * 4 + 1][row] = a4.y;
            As[kg * 4 + 2][row] = a4.z; As[kg * 4 + 3][row] = a4.w;
            float4 w4 = make_float4(0.f, 0.f, 0.f, 0.f);
            if (j0 + row < N)
                w4 = *(const float4*)(W + (size_t)(j0 + row) * K + k0 + kg * 4);
            Ws[kg * 4 + 0][row] = w4.x; Ws[kg * 4 + 1][row] = w4.y;
            Ws[kg * 4 + 2][row] = w4.z; Ws[kg * 4 + 3][row] = w4.w;
        }
        __syncthreads();
        #pragma unroll
        for (int kk = 0; kk < 16; kk++){
            float a[8], w[8];
            *(float4*)(a)     = *(const float4*)(&As[kk][rg * 8]);
            *(float4*)(a + 4) = *(const float4*)(&As[kk][rg * 8 + 4]);
            *(float4*)(w)     = *(const float4*)(&Ws[kk][cg * 8]);
            *(float4*)(w + 4) = *(const float4*)(&Ws[kk][cg * 8 + 4]);
            #pragma unroll
            for (int ri = 0; ri < 8; ri++)
                #pragma unroll
                for (int ci = 0; ci < 8; ci++)
                    acc[ri][ci] = fmaf(a[ri], w[ci], acc[ri][ci]);
        }
        __syncthreads();
    }
    #pragma unroll
    for (int ri = 0; ri < 8; ri++){
        int r = r0 + rg * 8 + ri;
        #pragma unroll
        for (int ci = 0; ci < 8; ci++){
            int j = j0 + cg * 8 + ci;
            if (j < N) out[(size_t)r * N + j] = acc[ri][ci];
        }
    }
}

// ---------- causal depthwise conv(4)+bias+silu, fused dt / log-dA ----------
__global__ void k_conv(const float* __restrict__ zx, const float* __restrict__ cw,
                       const float* __restrict__ cb, float* __restrict__ xc,
                       const float* __restrict__ dtbias, const float* __restrict__ Al,
                       float* __restrict__ dt, float* __restrict__ dlA,
                       int L, int D, int stride, int off, int nh, int dtoff){
    int bl = blockIdx.x;
    int l = bl & (L - 1);
    const float* base = zx + (size_t)bl * stride + off;
    for (int d = threadIdx.x; d < D; d += blockDim.x){
        float acc = cb[d];
        #pragma unroll
        for (int k = 0; k < 4; k++){
            int dl = l + k - 3;
            if (dl >= 0) acc += base[(ptrdiff_t)(k - 3) * stride + d] * cw[d * 4 + k];
        }
        xc[(size_t)bl * D + d] = siluf(acc);
    }
    int t = threadIdx.x;
    if (t < nh){
        float xv = zx[(size_t)bl * stride + dtoff + t] + dtbias[t];
        float d = softplusf(xv);
        dt[(size_t)bl * nh + t] = d;
        dlA[(size_t)bl * nh + t] = -d * __expf(Al[t]); // log(dA) <= 0
    }
}

// ---------- chunked SSD, stage A: per (b,h,chunk-of-64) ----------
__global__ __launch_bounds__(256) void k_ssd_chunk(
        const float* __restrict__ xc, const float* __restrict__ dt,
        const float* __restrict__ dlA, float* __restrict__ y,
        float* __restrict__ S, float* __restrict__ clb,
        int L, int nh, int nc, int xcs, int bo, int co, int ys){
    __shared__ float sX[64][68];
    __shared__ float sB[64][68];
    __shared__ float sC[64][68]; // phase1: C ; after: masked G
    __shared__ float cl[64], sdt[64], sw[64];
    int blk = blockIdx.x;
    int c = blk % nc; int bh = blk / nc; int h = bh % nh; int b = bh / nh;
    int l0 = c * 64;
    int tid = threadIdx.x;
    const float* base = xc + ((size_t)(b * L + l0)) * xcs;
    for (int idx = tid; idx < 4096; idx += 256){
        int s = idx >> 6, n = idx & 63;
        const float* row = base + (size_t)s * xcs;
        sX[s][n] = row[h * 64 + n];
        sB[s][n] = row[bo + n];
        sC[s][n] = row[co + n];
    }
    if (tid < 64){
        size_t di = (size_t)(b * L + l0 + tid) * nh + h;
        float dlv = dlA[di];
        sdt[tid] = dt[di];
        #pragma unroll
        for (int off = 1; off < 64; off <<= 1){
            float o = __shfl_up(dlv, off, 64);
            if (tid >= off) dlv += o;
        }
        cl[tid] = dlv;
        clb[(size_t)blk * 64 + tid] = dlv;
    }
    __syncthreads();
    if (tid < 64) sw[tid] = __expf(cl[63] - cl[tid]) * sdt[tid];

    int g1 = tid >> 4, g2 = tid & 15;
    int t0 = g1 * 4, s0 = g2 * 4;
    // ---- phase 1: g = C.B^T (registers) ----
    float g[4][4] = {};
    for (int n = 0; n < 64; n += 4){
        float4 cv[4], bv[4];
        #pragma unroll
        for (int i = 0; i < 4; i++) cv[i] = *(const float4*)&sC[t0 + i][n];
        #pragma unroll
        for (int j = 0; j < 4; j++) bv[j] = *(const float4*)&sB[s0 + j][n];
        #pragma unroll
        for (int i = 0; i < 4; i++)
            #pragma unroll
            for (int j = 0; j < 4; j++){
                g[i][j] = fmaf(cv[i].x, bv[j].x, g[i][j]);
                g[i][j] = fmaf(cv[i].y, bv[j].y, g[i][j]);
                g[i][j] = fmaf(cv[i].z, bv[j].z, g[i][j]);
                g[i][j] = fmaf(cv[i].w, bv[j].w, g[i][j]);
            }
    }
    __syncthreads(); // all reads of sC (as C) complete
    #pragma unroll
    for (int i = 0; i < 4; i++)
        #pragma unroll
        for (int j = 0; j < 4; j++){
            int t = t0 + i, s = s0 + j;
            float v = 0.f;
            if (s <= t) v = g[i][j] * __expf(cl[t] - cl[s]) * sdt[s];
            sC[t][s] = v; // sC now holds masked G
        }
    __syncthreads();
    // ---- phase 2: y_intra = G @ X ----
    {
        float acc[4][4] = {};
        for (int s = 0; s < 64; s++){
            float4 xv = *(const float4*)&sX[s][s0];
            float gv[4];
            #pragma unroll
            for (int i = 0; i < 4; i++) gv[i] = sC[t0 + i][s];
            #pragma unroll
            for (int i = 0; i < 4; i++){
                acc[i][0] = fmaf(gv[i], xv.x, acc[i][0]);
                acc[i][1] = fmaf(gv[i], xv.y, acc[i][1]);
                acc[i][2] = fmaf(gv[i], xv.z, acc[i][2]);
                acc[i][3] = fmaf(gv[i], xv.w, acc[i][3]);
            }
        }
        #pragma unroll
        for (int i = 0; i < 4; i++){
            float4 o = make_float4(acc[i][0], acc[i][1], acc[i][2], acc[i][3]);
            *(float4*)&y[(size_t)(b * L + l0 + t0 + i) * ys + h * 64 + s0] = o;
        }
    }
    // ---- phase 3: S[p][n] ----
    {
        float acc[4][4] = {};
        int p0 = t0, n0 = s0;
        for (int s = 0; s < 64; s++){
            float wv = sw[s];
            float4 bv = *(const float4*)&sB[s][n0];
            float4 xv = *(const float4*)&sX[s][p0];
            float w0 = wv * xv.x, w1 = wv * xv.y, w2 = wv * xv.z, w3 = wv * xv.w;
            acc[0][0] = fmaf(w0, bv.x, acc[0][0]); acc[0][1] = fmaf(w0, bv.y, acc[0][1]);
            acc[0][2] = fmaf(w0, bv.z, acc[0][2]); acc[0][3] = fmaf(w0, bv.w, acc[0][3]);
            acc[1][0] = fmaf(w1, bv.x, acc[1][0]); acc[1][1] = fmaf(w1, bv.y, acc[1][1]);
            acc[1][2] = fmaf(w1, bv.z, acc[1][2]); acc[1][3] = fmaf(w1, bv.w, acc[1][3]);
            acc[2][0] = fmaf(w2, bv.x, acc[2][0]); acc[2][1] = fmaf(w2, bv.y, acc[2][1]);
            acc[2][2] = fmaf(w2, bv.z, acc[2][2]); acc[2][3] = fmaf(w2, bv.w, acc[2][3]);
            acc[3][0] = fmaf(w3, bv.x, acc[3][0]); acc[3][1] = fmaf(w3, bv.y, acc[3][1]);
            acc[3][2] = fmaf(w3, bv.z, acc[3][2]); acc[3][3] = fmaf(w3, bv.w, acc[3][3]);
        }
        float* Sp = S + (size_t)blk * 4096;
        #pragma unroll
        for (int i = 0; i < 4; i++){
            float4 o = make_float4(acc[i][0], acc[i][1], acc[i][2], acc[i][3]);
            *(float4*)&Sp[(p0 + i) * 64 + n0] = o;
        }
    }
}

// ---------- chunked SSD, stage B: sequential chunk-state scan, in-place ----------
__global__ __launch_bounds__(256) void k_chunk_scan(float* __restrict__ S,
                                                    const float* __restrict__ clb,
                                                    int nc){
    int row0 = blockIdx.x * nc;
    int tid = threadIdx.x;
    float h[16];
    #pragma unroll
    for (int k = 0; k < 16; k++) h[k] = 0.f;
    for (int c = 0; c < nc; c++){
        int row = row0 + c;
        float dec = __expf(clb[(size_t)row * 64 + 63]);
        float* Sp = S + (size_t)row * 4096;
        #pragma unroll
        for (int k = 0; k < 16; k++){
            int e = tid + k * 256;
            float s = Sp[e];
            Sp[e] = h[k];
            h[k] = fmaf(dec, h[k], s);
        }
    }
}

// ---------- chunked SSD, stage C: y += exp(cl[t]) * (C_t . h_init) + D*x ----------
__global__ __launch_bounds__(256) void k_chunk_y(
        const float* __restrict__ xc, const float* __restrict__ Hb,
        const float* __restrict__ clb, const float* __restrict__ Dp,
        float* __restrict__ y,
        int L, int nh, int nc, int xcs, int co, int ys){
    __shared__ float sH[64][68]; // [p][n]
    __shared__ float sC[64][68]; // [t][n]
    __shared__ float scl[64];
    int blk = blockIdx.x;
    int c = blk % nc; int bh = blk / nc; int h = bh % nh; int b = bh / nh;
    int l0 = c * 64;
    int tid = threadIdx.x;
    const float* Hp = Hb + (size_t)blk * 4096;
    const float* base = xc + ((size_t)(b * L + l0)) * xcs;
    for (int idx = tid; idx < 4096; idx += 256){
        int r = idx >> 6, n = idx & 63;
        sH[r][n] = Hp[idx];
        sC[r][n] = base[(size_t)r * xcs + co + n];
    }
    if (tid < 64) scl[tid] = __expf(clb[(size_t)blk * 64 + tid]);
    float Dh = Dp[h];
    __syncthreads();
    int g1 = tid >> 4, g2 = tid & 15;
    int t0 = g1 * 4, p0 = g2 * 4;
    float m[4][4] = {};
    for (int n = 0; n < 64; n += 4){
        float4 cv[4], hv[4];
        #pragma unroll
        for (int i = 0; i < 4; i++) cv[i] = *(const float4*)&sC[t0 + i][n];
        #pragma unroll
        for (int j = 0; j < 4; j++) hv[j] = *(const float4*)&sH[p0 + j][n];
        #pragma unroll
        for (int i = 0; i < 4; i++)
            #pragma unroll
            for (int j = 0; j < 4; j++){
                m[i][j] = fmaf(cv[i].x, hv[j].x, m[i][j]);
                m[i][j] = fmaf(cv[i].y, hv[j].y, m[i][j]);
                m[i][j] = fmaf(cv[i].z, hv[j].z, m[i][j]);
                m[i][j] = fmaf(cv[i].w, hv[j].w, m[i][j]);
            }
    }
    #pragma unroll
    for (int i = 0; i < 4; i++){
        int t = t0 + i;
        size_t yi = (size_t)(b * L + l0 + t) * ys + h * 64 + p0;
        float4 yv = *(float4*)&y[yi];
        float4 xv = *(const float4*)&base[(size_t)t * xcs + h * 64 + p0];
        float e = scl[t];
        yv.x += e * m[i][0] + Dh * xv.x;
        yv.y += e * m[i][1] + Dh * xv.y;
        yv.z += e * m[i][2] + Dh * xv.z;
        yv.w += e * m[i][3] + Dh * xv.w;
        *(float4*)&y[yi] = yv;
    }
}

// ---------- gate (silu(z)) + RMSNorm ----------
__global__ __launch_bounds__(256) void k_gate(const float* __restrict__ y,
                                              const float* __restrict__ zx,
                                              const float* __restrict__ rw,
                                              float* __restrict__ out,
                                              int dinner, int zstride){
    __shared__ float sm[16];
    int row = blockIdx.x, t = threadIdx.x;
    float v0, v1 = 0.f, ss;
    v0 = y[(size_t)row * dinner + t] * siluf(zx[(size_t)row * zstride + t]);
    ss = v0 * v0;
    if (dinner == 512){
        v1 = y[(size_t)row * dinner + t + 256] * siluf(zx[(size_t)row * zstride + t + 256]);
        ss += v1 * v1;
    }
    float tot = blk_sum1(ss, sm);
    float sc = rsqrtf(tot / (float)dinner + 1e-5f);
    out[(size_t)row * dinner + t] = v0 * sc * rw[t];
    if (dinner == 512) out[(size_t)row * dinner + t + 256] = v1 * sc * rw[t + 256];
}

// ---------- center projection + q ----------
__global__ void k_center_q(const float* __restrict__ xs, const float* __restrict__ cw,
                           const float* __restrict__ cb, const float* __restrict__ qw,
                           const float* __restrict__ qb, float* __restrict__ q){
    __shared__ float xr[640];
    __shared__ float cen[128];
    int b = blockIdx.x, t = threadIdx.x; // 128 thr
    for (int idx = t; idx < 640; idx += 128)
        xr[idx] = xs[(size_t)b * 256 * 128 + idx];
    __syncthreads();
    float acc = cb[t];
    for (int c = 0; c < 128; c++){
        const float* wp = cw + (size_t)(t * 128 + c) * 5;
        #pragma unroll
        for (int l = 0; l < 5; l++) acc += xr[l * 128 + c] * wp[l];
    }
    cen[t] = acc;
    __syncthreads();
    float qa = qb[t];
    const float* wr = qw + (size_t)t * 128;
    for (int o = 0; o < 128; o++) qa += cen[o] * wr[o];
    q[b * 128 + t] = qa;
}

// ---------- attention softmax over l ----------
__global__ void k_attn(const float* __restrict__ q, const float* __restrict__ k,
                       float* __restrict__ attn){
    __shared__ float sm[16];
    __shared__ float qh[16];
    int blk = blockIdx.x; int b = blk >> 3, h = blk & 7; int l = threadIdx.x; // 256 thr
    if (l < 16) qh[l] = q[b * 128 + h * 16 + l];
    __syncthreads();
    const float* kp = k + ((size_t)(b * 256 + l)) * 128 + h * 16;
    float s = 0.f;
    #pragma unroll
    for (int d = 0; d < 16; d++) s += qh[d] * kp[d];
    s *= 0.25f;
    float mx = blk_max1(s, sm);
    float e = __expf(s - mx);
    float sum = blk_sum1(e, sm);
    attn[(size_t)blk * 256 + l] = e / sum;
}

// ---------- attention out ----------
__global__ void k_attn_out(const float* __restrict__ v, const float* __restrict__ attn,
                           const float* __restrict__ ow, const float* __restrict__ ob,
                           float* __restrict__ xs){
    __shared__ float vp[128];
    int bl = blockIdx.x; int b = bl >> 8, l = bl & 255; int t = threadIdx.x; // 128 thr
    float a = attn[((size_t)((b << 3) + (t >> 4))) * 256 + l];
    vp[t] = v[(size_t)bl * 128 + t] * a;
    __syncthreads();
    float acc = ob[t];
    const float* wr = ow + (size_t)t * 128;
    for (int j = 0; j < 128; j++) acc += vp[j] * wr[j];
    xs[(size_t)bl * 128 + t] += acc;
}

// ---------- spectral q2/k2/v2 ----------
__global__ __launch_bounds__(256) void k_spe_qkv(const float* __restrict__ xs,
                                                 const float* __restrict__ sqw, const float* __restrict__ sqb,
                                                 const float* __restrict__ skw, const float* __restrict__ skb,
                                                 const float* __restrict__ svw, const float* __restrict__ svb,
                                                 float* __restrict__ q2, float* __restrict__ k2,
                                                 float* __restrict__ v2){
    __shared__ float xt[8][256];
    int blk = blockIdx.x; int b = blk >> 4; int i0 = (blk & 15) << 3;
    int t = threadIdx.x;
    for (int idx = t; idx < 8 * 256; idx += 256){
        int ii = idx >> 8, tt = idx & 255;
        xt[ii][tt] = xs[((size_t)(b * 256 + tt)) * 128 + i0 + ii];
    }
    __syncthreads();
    int j = t;
    float aq[8] = {}, ak_[8] = {}, av_[8] = {};
    const float* wq = sqw + (size_t)j * 256;
    const float* wk = skw + (size_t)j * 256;
    const float* wv = svw + (size_t)j * 256;
    for (int tt = 0; tt < 256; tt++){
        float wqv = wq[tt], wkv = wk[tt], wvv = wv[tt];
        #pragma unroll
        for (int ii = 0; ii < 8; ii++){
            float xv = xt[ii][tt];
            aq[ii] = fmaf(xv, wqv, aq[ii]);
            ak_[ii] = fmaf(xv, wkv, ak_[ii]);
            av_[ii] = fmaf(xv, wvv, av_[ii]);
        }
    }
    float bq = sqb[j], bk = skb[j], bv = svb[j];
    #pragma unroll
    for (int ii = 0; ii < 8; ii++){
        size_t row = (size_t)(b * 128 + i0 + ii) * 256 + j;
        q2[row] = aq[ii] + bq;
        k2[row] = ak_[ii] + bk;
        v2[row] = av_[ii] + bv;
    }
}

// ---------- spectral attention + softmax ----------
__global__ __launch_bounds__(128) void k_attn2(const float* __restrict__ q2,
                                               const float* __restrict__ k2,
                                               float* __restrict__ attn2){
    __shared__ float qs[8][256];
    __shared__ float lg[8][128];
    __shared__ float mxs[8], sms[8];
    int blk = blockIdx.x; int b = blk >> 4; int i0 = (blk & 15) << 3;
    int j = threadIdx.x;
    for (int idx = j; idx < 8 * 256; idx += 128){
        int ii = idx >> 8, d = idx & 255;
        qs[ii][d] = q2[((size_t)(b * 128 + i0 + ii)) * 256 + d];
    }
    __syncthreads();
    const float* kr = k2 + ((size_t)(b * 128 + j)) * 256;
    float acc[8] = {};
    for (int d = 0; d < 256; d++){
        float kv = kr[d];
        #pragma unroll
        for (int ii = 0; ii < 8; ii++) acc[ii] = fmaf(qs[ii][d], kv, acc[ii]);
    }
    #pragma unroll
    for (int ii = 0; ii < 8; ii++) lg[ii][j] = acc[ii] * (1.f / 16.f);
    __syncthreads();
    if (j < 8){
        float mx = -3.4e38f;
        for (int tt = 0; tt < 128; tt++) mx = fmaxf(mx, lg[j][tt]);
        float sm = 0.f;
        for (int tt = 0; tt < 128; tt++) sm += __expf(lg[j][tt] - mx);
        mxs[j] = mx; sms[j] = 1.f / sm;
    }
    __syncthreads();
    #pragma unroll
    for (int ii = 0; ii < 8; ii++)
        attn2[((size_t)(b * 128 + i0 + ii)) * 128 + j] =
            __expf(lg[ii][j] - mxs[ii]) * sms[ii];
}

// ---------- (attn2 @ v2) @ so_w.T + so_b, transposed add ----------
__global__ __launch_bounds__(256) void k_av_so(const float* __restrict__ attn2,
                                               const float* __restrict__ v2,
                                               const float* __restrict__ sow,
                                               const float* __restrict__ sob,
                                               float* __restrict__ xs){
    __shared__ float a2[8][128];
    __shared__ float av[8][256];
    int blk = blockIdx.x; int b = blk >> 4; int i0 = (blk & 15) << 3;
    int t = threadIdx.x;
    for (int idx = t; idx < 8 * 128; idx += 256){
        int ii = idx >> 7, j = idx & 127;
        a2[ii][j] = attn2[((size_t)(b * 128 + i0 + ii)) * 128 + j];
    }
    __syncthreads();
    {
        float acc[8] = {};
        const float* vb = v2 + (size_t)b * 128 * 256 + t;
        for (int j = 0; j < 128; j++){
            float vv = vb[(size_t)j * 256];
            #pragma unroll
            for (int ii = 0; ii < 8; ii++) acc[ii] = fmaf(a2[ii][j], vv, acc[ii]);
        }
        #pragma unroll
        for (int ii = 0; ii < 8; ii++) av[ii][t] = acc[ii];
    }
    __syncthreads();
    float acc[8] = {};
    const float* wr = sow + (size_t)t * 256;
    for (int d = 0; d < 256; d++){
        float wv = wr[d];
        #pragma unroll
        for (int ii = 0; ii < 8; ii++) acc[ii] = fmaf(av[ii][d], wv, acc[ii]);
    }
    float bias = sob[t];
    float* xp = xs + ((size_t)(b * 256 + t)) * 128 + i0;
    #pragma unroll
    for (int ii = 0; ii < 8; ii++) xp[ii] += acc[ii] + bias;
}

// ---------- unsort scatter ----------
__global__ void k_scatter(const float* __restrict__ xs, const int* __restrict__ sidx,
                          float* __restrict__ xr){
    int bl = blockIdx.x; int b = bl >> 8;
    int p = sidx[bl];
    xr[((size_t)(b * 256 + p)) * 128 + threadIdx.x] = xs[(size_t)bl * 128 + threadIdx.x];
}

// ---------- im2col for 3x3/2 conv ----------
__global__ void k_im2col(const float* __restrict__ xr, float* __restrict__ col){
    int r = blockIdx.x; int t = threadIdx.x; // 128 thr
    int b = r >> 6, oh = (r >> 3) & 7, ow = r & 7;
    float* dst = col + (size_t)r * 1152;
    #pragma unroll
    for (int kh = 0; kh < 3; kh++){
        int ih = oh * 2 - 1 + kh;
        #pragma unroll
        for (int kw = 0; kw < 3; kw++){
            int iw = ow * 2 - 1 + kw;
            float v = 0.f;
            if (ih >= 0 && ih < 16 && iw >= 0 && iw < 16)
                v = xr[((size_t)((b << 8) + (ih << 4) + iw)) * 128 + t];
            dst[(kh * 3 + kw) * 128 + t] = v;
        }
    }
}

// ---------- conv GEMM split-K=4 ----------
__global__ __launch_bounds__(256) void k_conv_gemm(const float* __restrict__ col,
                                                   const float* __restrict__ W2,
                                                   float* __restrict__ part){
    __shared__ float As[16][68];
    __shared__ float Ws[16][64];
    int j0 = blockIdx.x * 64, r0 = blockIdx.y * 64, s = blockIdx.z;
    int tid = threadIdx.x;
    int cg = tid & 15, rg = tid >> 4;
    float acc[4][4] = {};
    int kbeg = s * 288, kend = kbeg + 288;
    for (int k0 = kbeg; k0 < kend; k0 += 16){
        {
            int row = tid >> 2, kg = tid & 3;
            float4 a4 = *(const float4*)(col + (size_t)(r0 + row) * 1152 + k0 + kg * 4);
            As[kg * 4 + 0][row] = a4.x; As[kg * 4 + 1][row] = a4.y;
            As[kg * 4 + 2][row] = a4.z; As[kg * 4 + 3][row] = a4.w;
        }
        #pragma unroll
        for (int it = 0; it < 4; it++){
            int idx = tid + it * 256;
            int jj = idx & 63, kk = idx >> 6;
            Ws[kk][jj] = W2[(size_t)(k0 + kk) * 128 + j0 + jj];
        }
        __syncthreads();
        #pragma unroll
        for (int kk = 0; kk < 16; kk++){
            float4 a4 = *(const float4*)(&As[kk][rg << 2]);
            float4 w4 = *(const float4*)(&Ws[kk][cg << 2]);
            float av_[4] = {a4.x, a4.y, a4.z, a4.w};
            float wv_[4] = {w4.x, w4.y, w4.z, w4.w};
            #pragma unroll
            for (int ri = 0; ri < 4; ri++)
                #pragma unroll
                for (int ci = 0; ci < 4; ci++)
                    acc[ri][ci] = fmaf(av_[ri], wv_[ci], acc[ri][ci]);
        }
        __syncthreads();
    }
    float* pp = part + (size_t)s * 1024 * 128;
    #pragma unroll
    for (int ri = 0; ri < 4; ri++){
        int r = r0 + (rg << 2) + ri;
        #pragma unroll
        for (int ci = 0; ci < 4; ci++){
            int j = j0 + (cg << 2) + ci;
            pp[(size_t)r * 128 + j] = acc[ri][ci];
        }
    }
}

// ---------- reduce split-K partials + LayerNorm ----------
__global__ void k_part_ln(const float* __restrict__ part, const float* __restrict__ lnw,
                          const float* __restrict__ lnb, float* __restrict__ out){
    __shared__ float sm[16];
    int r = blockIdx.x, t = threadIdx.x; // 128 thr
    float v = part[(size_t)r * 128 + t]
            + part[(size_t)(1024 + r) * 128 + t]
            + part[(size_t)(2048 + r) * 128 + t]
            + part[(size_t)(3072 + r) * 128 + t];
    float a = v, q = v * v;
    blk_sum2(a, q, sm);
    float mu = a * (1.f / 128.f);
    float var = q * (1.f / 128.f) - mu * mu;
    float rs = rsqrtf(var + 1e-5f);
    out[(size_t)r * 128 + t] = (v - mu) * rs * lnw[t] + lnb[t];
}

extern "C" void kernel_launch(void* const* d_in, const int* in_sizes, int n_in,
                              void* d_out, int out_size, void* d_ws, size_t ws_size,
                              hipStream_t stream) {
    const float* x          = (const float*)d_in[0];
    const int*   sidx       = (const int*)  d_in[1];
    const float* spa_ln_w   = (const float*)d_in[2];
    const float* spa_ln_b   = (const float*)d_in[3];
    const float* spa_in_w   = (const float*)d_in[4];
    const float* spa_conv_w = (const float*)d_in[5];
    const float* spa_conv_b = (const float*)d_in[6];
    const float* spa_dt_bias= (const float*)d_in[7];
    const float* spa_A_log  = (const float*)d_in[8];
    const float* spa_D      = (const float*)d_in[9];
    const float* spa_rms_w  = (const float*)d_in[10];
    const float* spa_out_w  = (const float*)d_in[11];
    const float* spe_ln_w   = (const float*)d_in[12];
    const float* spe_ln_b   = (const float*)d_in[13];
    const float* spe_in_w   = (const float*)d_in[14];
    const float* spe_conv_w = (const float*)d_in[15];
    const float* spe_conv_b = (const float*)d_in[16];
    const float* spe_dt_bias= (const float*)d_in[17];
    const float* spe_A_log  = (const float*)d_in[18];
    const float* spe_D      = (const float*)d_in[19];
    const float* spe_rms_w  = (const float*)d_in[20];
    const float* spe_out_w  = (const float*)d_in[21];
    const float* norm_w     = (const float*)d_in[22];
    const float* norm_b     = (const float*)d_in[23];
    const float* cprj_w     = (const float*)d_in[24];
    const float* cprj_b     = (const float*)d_in[25];
    const float* aq_w       = (const float*)d_in[26];
    const float* aq_b       = (const float*)d_in[27];
    const float* ak_w       = (const float*)d_in[28];
    const float* ak_b       = (const float*)d_in[29];
    const float* av_w       = (const float*)d_in[30];
    const float* av_b       = (const float*)d_in[31];
    const float* ao_w       = (const float*)d_in[32];
    const float* ao_b       = (const float*)d_in[33];
    const float* sq_w       = (const float*)d_in[34];
    const float* sq_b       = (const float*)d_in[35];
    const float* sk_w       = (const float*)d_in[36];
    const float* sk_b       = (const float*)d_in[37];
    const float* sv_w       = (const float*)d_in[38];
    const float* sv_b       = (const float*)d_in[39];
    const float* so_w       = (const float*)d_in[40];
    const float* so_b       = (const float*)d_in[41];
    const float* ds_conv_w  = (const float*)d_in[42];
    const float* ds_ln_w    = (const float*)d_in[43];
    const float* ds_ln_b    = (const float*)d_in[44];

    float* ws = (float*)d_ws;
    float* xs   = ws + 0;        // 524288
    float* lnb_ = ws + 524288;   // 524288 (clbuf lives here when lnb_ is dead)
    float* zx   = ws + 1048576;  // -> 3686400
    float* xc   = ws + 3686400;  // -> 5259264
    float* dtb  = ws + 5259264;  // 32768
    float* dAb  = ws + 5292032;  // 32768 (holds log-dA)
    float* yb   = ws + 5324800;  // 1048576 -> 6373376
    float* gb   = ws + 6373376;  // 1048576 -> 7421952 (scan: S buffer alias)
    float* h1   = ws + 7421952;  // 524288 -> 7946240
    float* clbuf = ws + 524288;  // 16384, inside dead lnb_ during scan stages
    // attention-stage aliases
    float* kb    = ws + 1048576;
    float* vb    = ws + 1572864;
    float* attnb = ws + 2097152;
    float* qb    = ws + 2129920;
    float* q2    = ws + 3686400;
    float* k2    = ws + 4210688;
    float* v2    = ws + 4734976;
    float* attn2 = ws + 5324800;
    float* xr    = ws + 5586944;
    float* col   = ws + 6111232; // -> 7290880
    float* part  = ws + 7290880; // -> 7815168

    k_embed<<<4096, 128, 0, stream>>>(x, sidx, xs);

    for (int i = 0; i < 2; i++){
        // ---- spatial mamba (L=256, nh=4, nc=4) ----
        k_ln<<<4096, 128, 0, stream>>>(xs, spa_ln_w + i * 128, spa_ln_b + i * 128, lnb_, 128);
        k_gemm128<<<dim3(6, 32), 256, 0, stream>>>(lnb_, spa_in_w + (size_t)i * 644 * 128,
                                                   zx, 4096, 644, 128);
        k_conv<<<4096, 256, 0, stream>>>(zx, spa_conv_w + (size_t)i * 384 * 4,
                                         spa_conv_b + i * 384, xc,
                                         spa_dt_bias + i * 4, spa_A_log + i * 4, dtb, dAb,
                                         256, 384, 644, 256, 4, 640);
        k_ssd_chunk<<<256, 256, 0, stream>>>(xc, dtb, dAb, yb, gb, clbuf,
                                             256, 4, 4, 384, 256, 320, 256);
        k_chunk_scan<<<64, 256, 0, stream>>>(gb, clbuf, 4);
        k_chunk_y<<<256, 256, 0, stream>>>(xc, gb, clbuf, spa_D + i * 4, yb,
                                           256, 4, 4, 384, 320, 256);
        k_gate<<<4096, 256, 0, stream>>>(yb, zx, spa_rms_w + i * 256, gb, 256, 644);
        k_gemm<<<dim3(2, 64), 256, 0, stream>>>(gb, spa_out_w + (size_t)i * 128 * 256,
                                                nullptr, xs, h1, 4096, 128, 256, 1);
        // ---- spectral mamba (L=128, nh=8, nc=2) ----
        k_ln_t<<<2048, 256, 0, stream>>>(h1, spe_ln_w + i * 256, spe_ln_b + i * 256, lnb_);
        k_gemm128<<<dim3(10, 16), 256, 0, stream>>>(lnb_, spe_in_w + (size_t)i * 1160 * 256,
                                                    zx, 2048, 1160, 256);
        k_conv<<<2048, 256, 0, stream>>>(zx, spe_conv_w + (size_t)i * 640 * 4,
                                         spe_conv_b + i * 640, xc,
                                         spe_dt_bias + i * 8, spe_A_log + i * 8, dtb, dAb,
                                         128, 640, 1160, 512, 8, 1152);
        k_ssd_chunk<<<256, 256, 0, stream>>>(xc, dtb, dAb, yb, gb, clbuf,
                                             128, 8, 2, 640, 512, 576, 512);
        k_chunk_scan<<<128, 256, 0, stream>>>(gb, clbuf, 2);
        k_chunk_y<<<256, 256, 0, stream>>>(xc, gb, clbuf, spe_D + i * 8, yb,
                                           128, 8, 2, 640, 576, 512);
        k_gate<<<2048, 256, 0, stream>>>(yb, zx, spe_rms_w + i * 512, gb, 512, 1160);
        k_gemm<<<dim3(4, 32), 256, 0, stream>>>(gb, spe_out_w + (size_t)i * 256 * 512,
                                                nullptr, h1, xs, 2048, 256, 512, 2);
    }

    k_ln<<<4096, 128, 0, stream>>>(xs, norm_w, norm_b, xs, 128);
    k_center_q<<<16, 128, 0, stream>>>(xs, cprj_w, cprj_b, aq_w, aq_b, qb);
    k_gemm<<<dim3(2, 64), 256, 0, stream>>>(xs, ak_w, ak_b, nullptr, kb, 4096, 128, 128, 0);
    k_gemm<<<dim3(2, 64), 256, 0, stream>>>(xs, av_w, av_b, nullptr, vb, 4096, 128, 128, 0);
    k_attn<<<128, 256, 0, stream>>>(qb, kb, attnb);
    k_attn_out<<<4096, 128, 0, stream>>>(vb, attnb, ao_w, ao_b, xs);
    k_spe_qkv<<<256, 256, 0, stream>>>(xs, sq_w, sq_b, sk_w, sk_b, sv_w, sv_b, q2, k2, v2);
    k_attn2<<<256, 128, 0, stream>>>(q2, k2, attn2);
    k_av_so<<<256, 256, 0, stream>>>(attn2, v2, so_w, so_b, xs);
    k_scatter<<<4096, 128, 0, stream>>>(xs, sidx, xr);
    k_im2col<<<1024, 128, 0, stream>>>(xr, col);
    k_conv_gemm<<<dim3(2, 16, 4), 256, 0, stream>>>(col, ds_conv_w, part);
    k_part_ln<<<1024, 128, 0, stream>>>(part, ds_ln_w, ds_ln_b, (float*)d_out);
}

// Round 7
// 681.797 us; speedup vs baseline: 1.5617x; 1.1204x over previous
//
#include <hip/hip_runtime.h>
#include <math.h>

#define DEV __device__ __forceinline__

DEV float siluf(float x){ return x / (1.f + __expf(-x)); }
DEV float softplusf(float x){ return (x > 20.f) ? x : log1pf(__expf(x)); }

// ---------- block reduction helpers (wave64) ----------
DEV void blk_sum2(float &a, float &b, float* sm){
    int lane = threadIdx.x & 63, wid = threadIdx.x >> 6, nw = blockDim.x >> 6;
    #pragma unroll
    for (int off = 32; off; off >>= 1){ a += __shfl_down(a, off); b += __shfl_down(b, off); }
    if (lane == 0){ sm[wid] = a; sm[8 + wid] = b; }
    __syncthreads();
    float ra = 0.f, rb = 0.f;
    for (int i = 0; i < nw; i++){ ra += sm[i]; rb += sm[8 + i]; }
    __syncthreads();
    a = ra; b = rb;
}
DEV float blk_sum1(float v, float* sm){
    int lane = threadIdx.x & 63, wid = threadIdx.x >> 6, nw = blockDim.x >> 6;
    #pragma unroll
    for (int off = 32; off; off >>= 1) v += __shfl_down(v, off);
    if (lane == 0) sm[wid] = v;
    __syncthreads();
    float r = 0.f;
    for (int i = 0; i < nw; i++) r += sm[i];
    __syncthreads();
    return r;
}
DEV float blk_max1(float v, float* sm){
    int lane = threadIdx.x & 63, wid = threadIdx.x >> 6, nw = blockDim.x >> 6;
    #pragma unroll
    for (int off = 32; off; off >>= 1) v = fmaxf(v, __shfl_down(v, off));
    if (lane == 0) sm[wid] = v;
    __syncthreads();
    float r = -3.4e38f;
    for (int i = 0; i < nw; i++) r = fmaxf(r, sm[i]);
    __syncthreads();
    return r;
}

// ---------- K1: pos-embed + gather ----------
__global__ void k_embed(const float* __restrict__ x, const int* __restrict__ sidx,
                        float* __restrict__ xs){
    int bl = blockIdx.x; int b = bl >> 8; int c = threadIdx.x;
    int p = sidx[bl];
    int hh = p >> 4, ww = p & 15;
    int pos = (c < 64) ? hh : ww;
    int jm = c & 63;
    float om = __expf(-(float)(jm & 31) * 0.28782313662425574f); // ln(10000)/32
    float ang = (float)pos * om;
    float pe = (jm < 32) ? sinf(ang) : cosf(ang);
    xs[(size_t)bl * 128 + c] = x[((size_t)(b * 128 + c)) * 256 + p] + pe;
}

// ---------- LayerNorm (block per row, blockDim == dim) ----------
__global__ void k_ln(const float* __restrict__ in, const float* __restrict__ w,
                     const float* __restrict__ bb, float* __restrict__ out, int dim){
    __shared__ float sm[16];
    int row = blockIdx.x, t = threadIdx.x;
    float v = in[(size_t)row * dim + t];
    float a = v, q = v * v;
    blk_sum2(a, q, sm);
    float inv = 1.f / (float)dim;
    float mu = a * inv;
    float var = q * inv - mu * mu;
    float rs = rsqrtf(var + 1e-5f);
    out[(size_t)row * dim + t] = (v - mu) * rs * w[t] + bb[t];
}

// ---------- transposed LayerNorm for spectral ----------
__global__ void k_ln_t(const float* __restrict__ h1, const float* __restrict__ w,
                       const float* __restrict__ bb, float* __restrict__ out){
    __shared__ float sm[16];
    int row = blockIdx.x; int b = row >> 7, i = row & 127; int t = threadIdx.x; // 256 thr
    float v = h1[((size_t)(b * 256 + t)) * 128 + i];
    float a = v, q = v * v;
    blk_sum2(a, q, sm);
    float mu = a * (1.f / 256.f);
    float var = q * (1.f / 256.f) - mu * mu;
    float rs = rsqrtf(var + 1e-5f);
    out[(size_t)row * 256 + t] = (v - mu) * rs * w[t] + bb[t];
}

// ---------- batched LDS-tiled transpose: out[c*R+r] = in[r*C+c] ----------
// grid (C/32, R/32, batch), 256 thr
__global__ __launch_bounds__(256) void k_tr(const float* __restrict__ in,
                                            float* __restrict__ out, int R, int C){
    __shared__ float tile[32][33];
    const float* ip = in + (size_t)blockIdx.z * R * C;
    float* op = out + (size_t)blockIdx.z * R * C;
    int c0 = blockIdx.x * 32, r0 = blockIdx.y * 32;
    int tx = threadIdx.x & 31, ty = threadIdx.x >> 5;
    #pragma unroll
    for (int rr = ty; rr < 32; rr += 8)
        tile[rr][tx] = ip[(size_t)(r0 + rr) * C + c0 + tx];
    __syncthreads();
    #pragma unroll
    for (int rr = ty; rr < 32; rr += 8)
        op[(size_t)(c0 + rr) * R + r0 + tx] = tile[tx][rr];
}

// ---------- 64x64-tile fp32 GEMM: coalesced staging, BK=32 ----------
// out[r,j] = sum_k A[r,k]*W[j,k]  (+epilogue). Requires K%32==0, N%4==0.
// mode 0: +bias (may be null)      mode 1: + res[r*N+j]
// mode 2: transposed scatter (N==256): out[((r0>>7)*256+j)*128+(r&127)] += res
// mode 3: transposed scatter + bias (N==256), no residual
__global__ __launch_bounds__(256) void k_gemm(const float* __restrict__ A,
                                              const float* __restrict__ W,
                                              const float* __restrict__ bias,
                                              const float* __restrict__ res,
                                              float* __restrict__ out,
                                              int M, int N, int K, int mode){
    __shared__ float lds[2][32][68]; // [0]=A-tile, [1]=W-tile; reused as T[64][68]
    int j0 = blockIdx.x * 64, r0 = blockIdx.y * 64;
    int tid = threadIdx.x;
    int cg = tid & 15, rg = tid >> 4;
    int row = tid >> 2, kg = tid & 3;
    int wrow = j0 + row; if (wrow > N - 1) wrow = N - 1; // clamp (guarded stores)
    float acc[4][4] = {};
    for (int k0 = 0; k0 < K; k0 += 32){
        const float* Ap = A + (size_t)(r0 + row) * K + k0 + kg * 4;
        float4 a0 = *(const float4*)(Ap);
        float4 a1 = *(const float4*)(Ap + 16);
        const float* Wp = W + (size_t)wrow * K + k0 + kg * 4;
        float4 w0 = *(const float4*)(Wp);
        float4 w1 = *(const float4*)(Wp + 16);
        __syncthreads(); // previous iteration's LDS reads done
        lds[0][kg * 4 + 0][row] = a0.x; lds[0][kg * 4 + 1][row] = a0.y;
        lds[0][kg * 4 + 2][row] = a0.z; lds[0][kg * 4 + 3][row] = a0.w;
        lds[0][16 + kg * 4 + 0][row] = a1.x; lds[0][16 + kg * 4 + 1][row] = a1.y;
        lds[0][16 + kg * 4 + 2][row] = a1.z; lds[0][16 + kg * 4 + 3][row] = a1.w;
        lds[1][kg * 4 + 0][row] = w0.x; lds[1][kg * 4 + 1][row] = w0.y;
        lds[1][kg * 4 + 2][row] = w0.z; lds[1][kg * 4 + 3][row] = w0.w;
        lds[1][16 + kg * 4 + 0][row] = w1.x; lds[1][16 + kg * 4 + 1][row] = w1.y;
        lds[1][16 + kg * 4 + 2][row] = w1.z; lds[1][16 + kg * 4 + 3][row] = w1.w;
        __syncthreads();
        #pragma unroll
        for (int kk = 0; kk < 32; kk++){
            float4 a4 = *(const float4*)(&lds[0][kk][rg << 2]);
            float4 w4 = *(const float4*)(&lds[1][kk][cg << 2]);
            float av_[4] = {a4.x, a4.y, a4.z, a4.w};
            float wv_[4] = {w4.x, w4.y, w4.z, w4.w};
            #pragma unroll
            for (int ri = 0; ri < 4; ri++)
                #pragma unroll
                for (int ci = 0; ci < 4; ci++)
                    acc[ri][ci] = fmaf(av_[ri], wv_[ci], acc[ri][ci]);
        }
    }
    if (mode >= 2){
        // stage output tile transposed: T[j-j0][r-r0], then coalesced writes
        float (*T)[68] = (float (*)[68])lds;
        __syncthreads();
        #pragma unroll
        for (int ri = 0; ri < 4; ri++)
            #pragma unroll
            for (int ci = 0; ci < 4; ci++)
                T[(cg << 2) + ci][(rg << 2) + ri] = acc[ri][ci];
        __syncthreads();
        int b2 = r0 >> 7;
        int ii0 = r0 & 127;
        int jj = tid >> 2, seg = tid & 3;
        size_t base = ((size_t)(b2 * 256 + j0 + jj)) * 128 + ii0 + seg * 16;
        float* op = out + base;
        if (mode == 2){
            const float* rp = res + base;
            #pragma unroll
            for (int c = 0; c < 4; c++){
                float4 v = *(const float4*)(&T[jj][seg * 16 + c * 4]);
                float4 rv = *(const float4*)(rp + c * 4);
                v.x += rv.x; v.y += rv.y; v.z += rv.z; v.w += rv.w;
                *(float4*)(op + c * 4) = v;
            }
        } else {
            float bj = bias[j0 + jj];
            #pragma unroll
            for (int c = 0; c < 4; c++){
                float4 v = *(const float4*)(&T[jj][seg * 16 + c * 4]);
                v.x += bj; v.y += bj; v.z += bj; v.w += bj;
                *(float4*)(op + c * 4) = v;
            }
        }
    } else {
        #pragma unroll
        for (int ri = 0; ri < 4; ri++){
            int r = r0 + (rg << 2) + ri;
            int j = j0 + (cg << 2);
            if (j < N){
                float4 v = make_float4(acc[ri][0], acc[ri][1], acc[ri][2], acc[ri][3]);
                if (mode == 0){
                    if (bias){
                        v.x += bias[j]; v.y += bias[j + 1];
                        v.z += bias[j + 2]; v.w += bias[j + 3];
                    }
                    *(float4*)(&out[(size_t)r * N + j]) = v;
                } else {
                    float4 rv = *(const float4*)(&res[(size_t)r * N + j]);
                    v.x += rv.x; v.y += rv.y; v.z += rv.z; v.w += rv.w;
                    *(float4*)(&out[(size_t)r * N + j]) = v;
                }
            }
        }
    }
}

// ---------- causal depthwise conv(4)+bias+silu, fused dt / log-dA ----------
__global__ void k_conv(const float* __restrict__ zx, const float* __restrict__ cw,
                       const float* __restrict__ cb, float* __restrict__ xc,
                       const float* __restrict__ dtbias, const float* __restrict__ Al,
                       float* __restrict__ dt, float* __restrict__ dlA,
                       int L, int D, int stride, int off, int nh, int dtoff){
    int bl = blockIdx.x;
    int l = bl & (L - 1);
    const float* base = zx + (size_t)bl * stride + off;
    for (int d = threadIdx.x; d < D; d += blockDim.x){
        float acc = cb[d];
        #pragma unroll
        for (int k = 0; k < 4; k++){
            int dl = l + k - 3;
            if (dl >= 0) acc += base[(ptrdiff_t)(k - 3) * stride + d] * cw[d * 4 + k];
        }
        xc[(size_t)bl * D + d] = siluf(acc);
    }
    int t = threadIdx.x;
    if (t < nh){
        float xv = zx[(size_t)bl * stride + dtoff + t] + dtbias[t];
        float d = softplusf(xv);
        dt[(size_t)bl * nh + t] = d;
        dlA[(size_t)bl * nh + t] = -d * __expf(Al[t]); // log(dA) <= 0
    }
}

// ---------- chunked SSD, stage A: per (b,h,chunk-of-64) ----------
__global__ __launch_bounds__(256) void k_ssd_chunk(
        const float* __restrict__ xc, const float* __restrict__ dt,
        const float* __restrict__ dlA, float* __restrict__ y,
        float* __restrict__ S, float* __restrict__ clb,
        int L, int nh, int nc, int xcs, int bo, int co, int ys){
    __shared__ float sX[64][68];
    __shared__ float sB[64][68];
    __shared__ float sC[64][68]; // phase1: C ; after: masked G
    __shared__ float cl[64], sdt[64], sw[64];
    int blk = blockIdx.x;
    int c = blk % nc; int bh = blk / nc; int h = bh % nh; int b = bh / nh;
    int l0 = c * 64;
    int tid = threadIdx.x;
    const float* base = xc + ((size_t)(b * L + l0)) * xcs;
    for (int idx = tid; idx < 4096; idx += 256){
        int s = idx >> 6, n = idx & 63;
        const float* row = base + (size_t)s * xcs;
        sX[s][n] = row[h * 64 + n];
        sB[s][n] = row[bo + n];
        sC[s][n] = row[co + n];
    }
    if (tid < 64){
        size_t di = (size_t)(b * L + l0 + tid) * nh + h;
        float dlv = dlA[di];
        sdt[tid] = dt[di];
        #pragma unroll
        for (int off = 1; off < 64; off <<= 1){
            float o = __shfl_up(dlv, off, 64);
            if (tid >= off) dlv += o;
        }
        cl[tid] = dlv;
        clb[(size_t)blk * 64 + tid] = dlv;
    }
    __syncthreads();
    if (tid < 64) sw[tid] = __expf(cl[63] - cl[tid]) * sdt[tid];

    int g1 = tid >> 4, g2 = tid & 15;
    int t0 = g1 * 4, s0 = g2 * 4;
    // ---- phase 1: g = C.B^T (registers) ----
    float g[4][4] = {};
    for (int n = 0; n < 64; n += 4){
        float4 cv[4], bv[4];
        #pragma unroll
        for (int i = 0; i < 4; i++) cv[i] = *(const float4*)&sC[t0 + i][n];
        #pragma unroll
        for (int j = 0; j < 4; j++) bv[j] = *(const float4*)&sB[s0 + j][n];
        #pragma unroll
        for (int i = 0; i < 4; i++)
            #pragma unroll
            for (int j = 0; j < 4; j++){
                g[i][j] = fmaf(cv[i].x, bv[j].x, g[i][j]);
                g[i][j] = fmaf(cv[i].y, bv[j].y, g[i][j]);
                g[i][j] = fmaf(cv[i].z, bv[j].z, g[i][j]);
                g[i][j] = fmaf(cv[i].w, bv[j].w, g[i][j]);
            }
    }
    __syncthreads(); // all reads of sC (as C) complete
    #pragma unroll
    for (int i = 0; i < 4; i++)
        #pragma unroll
        for (int j = 0; j < 4; j++){
            int t = t0 + i, s = s0 + j;
            float v = 0.f;
            if (s <= t) v = g[i][j] * __expf(cl[t] - cl[s]) * sdt[s];
            sC[t][s] = v; // sC now holds masked G
        }
    __syncthreads();
    // ---- phase 2: y_intra = G @ X ----
    {
        float acc[4][4] = {};
        for (int s = 0; s < 64; s++){
            float4 xv = *(const float4*)&sX[s][s0];
            float gv[4];
            #pragma unroll
            for (int i = 0; i < 4; i++) gv[i] = sC[t0 + i][s];
            #pragma unroll
            for (int i = 0; i < 4; i++){
                acc[i][0] = fmaf(gv[i], xv.x, acc[i][0]);
                acc[i][1] = fmaf(gv[i], xv.y, acc[i][1]);
                acc[i][2] = fmaf(gv[i], xv.z, acc[i][2]);
                acc[i][3] = fmaf(gv[i], xv.w, acc[i][3]);
            }
        }
        #pragma unroll
        for (int i = 0; i < 4; i++){
            float4 o = make_float4(acc[i][0], acc[i][1], acc[i][2], acc[i][3]);
            *(float4*)&y[(size_t)(b * L + l0 + t0 + i) * ys + h * 64 + s0] = o;
        }
    }
    // ---- phase 3: S[p][n] ----
    {
        float acc[4][4] = {};
        int p0 = t0, n0 = s0;
        for (int s = 0; s < 64; s++){
            float wv = sw[s];
            float4 bv = *(const float4*)&sB[s][n0];
            float4 xv = *(const float4*)&sX[s][p0];
            float w0 = wv * xv.x, w1 = wv * xv.y, w2 = wv * xv.z, w3 = wv * xv.w;
            acc[0][0] = fmaf(w0, bv.x, acc[0][0]); acc[0][1] = fmaf(w0, bv.y, acc[0][1]);
            acc[0][2] = fmaf(w0, bv.z, acc[0][2]); acc[0][3] = fmaf(w0, bv.w, acc[0][3]);
            acc[1][0] = fmaf(w1, bv.x, acc[1][0]); acc[1][1] = fmaf(w1, bv.y, acc[1][1]);
            acc[1][2] = fmaf(w1, bv.z, acc[1][2]); acc[1][3] = fmaf(w1, bv.w, acc[1][3]);
            acc[2][0] = fmaf(w2, bv.x, acc[2][0]); acc[2][1] = fmaf(w2, bv.y, acc[2][1]);
            acc[2][2] = fmaf(w2, bv.z, acc[2][2]); acc[2][3] = fmaf(w2, bv.w, acc[2][3]);
            acc[3][0] = fmaf(w3, bv.x, acc[3][0]); acc[3][1] = fmaf(w3, bv.y, acc[3][1]);
            acc[3][2] = fmaf(w3, bv.z, acc[3][2]); acc[3][3] = fmaf(w3, bv.w, acc[3][3]);
        }
        float* Sp = S + (size_t)blk * 4096;
        #pragma unroll
        for (int i = 0; i < 4; i++){
            float4 o = make_float4(acc[i][0], acc[i][1], acc[i][2], acc[i][3]);
            *(float4*)&Sp[(p0 + i) * 64 + n0] = o;
        }
    }
}

// ---------- chunked SSD, stage B: sequential chunk-state scan, in-place ----------
__global__ __launch_bounds__(256) void k_chunk_scan(float* __restrict__ S,
                                                    const float* __restrict__ clb,
                                                    int nc){
    int row0 = blockIdx.x * nc;
    int tid = threadIdx.x;
    float h[16];
    #pragma unroll
    for (int k = 0; k < 16; k++) h[k] = 0.f;
    for (int c = 0; c < nc; c++){
        int row = row0 + c;
        float dec = __expf(clb[(size_t)row * 64 + 63]);
        float* Sp = S + (size_t)row * 4096;
        #pragma unroll
        for (int k = 0; k < 16; k++){
            int e = tid + k * 256;
            float s = Sp[e];
            Sp[e] = h[k];
            h[k] = fmaf(dec, h[k], s);
        }
    }
}

// ---------- chunked SSD, stage C: y += exp(cl[t]) * (C_t . h_init) + D*x ----------
__global__ __launch_bounds__(256) void k_chunk_y(
        const float* __restrict__ xc, const float* __restrict__ Hb,
        const float* __restrict__ clb, const float* __restrict__ Dp,
        float* __restrict__ y,
        int L, int nh, int nc, int xcs, int co, int ys){
    __shared__ float sH[64][68]; // [p][n]
    __shared__ float sC[64][68]; // [t][n]
    __shared__ float scl[64];
    int blk = blockIdx.x;
    int c = blk % nc; int bh = blk / nc; int h = bh % nh; int b = bh / nh;
    int l0 = c * 64;
    int tid = threadIdx.x;
    const float* Hp = Hb + (size_t)blk * 4096;
    const float* base = xc + ((size_t)(b * L + l0)) * xcs;
    for (int idx = tid; idx < 4096; idx += 256){
        int r = idx >> 6, n = idx & 63;
        sH[r][n] = Hp[idx];
        sC[r][n] = base[(size_t)r * xcs + co + n];
    }
    if (tid < 64) scl[tid] = __expf(clb[(size_t)blk * 64 + tid]);
    float Dh = Dp[h];
    __syncthreads();
    int g1 = tid >> 4, g2 = tid & 15;
    int t0 = g1 * 4, p0 = g2 * 4;
    float m[4][4] = {};
    for (int n = 0; n < 64; n += 4){
        float4 cv[4], hv[4];
        #pragma unroll
        for (int i = 0; i < 4; i++) cv[i] = *(const float4*)&sC[t0 + i][n];
        #pragma unroll
        for (int j = 0; j < 4; j++) hv[j] = *(const float4*)&sH[p0 + j][n];
        #pragma unroll
        for (int i = 0; i < 4; i++)
            #pragma unroll
            for (int j = 0; j < 4; j++){
                m[i][j] = fmaf(cv[i].x, hv[j].x, m[i][j]);
                m[i][j] = fmaf(cv[i].y, hv[j].y, m[i][j]);
                m[i][j] = fmaf(cv[i].z, hv[j].z, m[i][j]);
                m[i][j] = fmaf(cv[i].w, hv[j].w, m[i][j]);
            }
    }
    #pragma unroll
    for (int i = 0; i < 4; i++){
        int t = t0 + i;
        size_t yi = (size_t)(b * L + l0 + t) * ys + h * 64 + p0;
        float4 yv = *(float4*)&y[yi];
        float4 xv = *(const float4*)&base[(size_t)t * xcs + h * 64 + p0];
        float e = scl[t];
        yv.x += e * m[i][0] + Dh * xv.x;
        yv.y += e * m[i][1] + Dh * xv.y;
        yv.z += e * m[i][2] + Dh * xv.z;
        yv.w += e * m[i][3] + Dh * xv.w;
        *(float4*)&y[yi] = yv;
    }
}

// ---------- gate (silu(z)) + RMSNorm ----------
__global__ __launch_bounds__(256) void k_gate(const float* __restrict__ y,
                                              const float* __restrict__ zx,
                                              const float* __restrict__ rw,
                                              float* __restrict__ out,
                                              int dinner, int zstride){
    __shared__ float sm[16];
    int row = blockIdx.x, t = threadIdx.x;
    float v0, v1 = 0.f, ss;
    v0 = y[(size_t)row * dinner + t] * siluf(zx[(size_t)row * zstride + t]);
    ss = v0 * v0;
    if (dinner == 512){
        v1 = y[(size_t)row * dinner + t + 256] * siluf(zx[(size_t)row * zstride + t + 256]);
        ss += v1 * v1;
    }
    float tot = blk_sum1(ss, sm);
    float sc = rsqrtf(tot / (float)dinner + 1e-5f);
    out[(size_t)row * dinner + t] = v0 * sc * rw[t];
    if (dinner == 512) out[(size_t)row * dinner + t + 256] = v1 * sc * rw[t + 256];
}

// ---------- center projection + q ----------
__global__ void k_center_q(const float* __restrict__ xs, const float* __restrict__ cw,
                           const float* __restrict__ cb, const float* __restrict__ qw,
                           const float* __restrict__ qb, float* __restrict__ q){
    __shared__ float xr[640];
    __shared__ float cen[128];
    int b = blockIdx.x, t = threadIdx.x; // 128 thr
    for (int idx = t; idx < 640; idx += 128)
        xr[idx] = xs[(size_t)b * 256 * 128 + idx];
    __syncthreads();
    float acc = cb[t];
    for (int c = 0; c < 128; c++){
        const float* wp = cw + (size_t)(t * 128 + c) * 5;
        #pragma unroll
        for (int l = 0; l < 5; l++) acc += xr[l * 128 + c] * wp[l];
    }
    cen[t] = acc;
    __syncthreads();
    float qa = qb[t];
    const float* wr = qw + (size_t)t * 128;
    for (int o = 0; o < 128; o++) qa += cen[o] * wr[o];
    q[b * 128 + t] = qa;
}

// ---------- attention softmax over l ----------
__global__ void k_attn(const float* __restrict__ q, const float* __restrict__ k,
                       float* __restrict__ attn){
    __shared__ float sm[16];
    __shared__ float qh[16];
    int blk = blockIdx.x; int b = blk >> 3, h = blk & 7; int l = threadIdx.x; // 256 thr
    if (l < 16) qh[l] = q[b * 128 + h * 16 + l];
    __syncthreads();
    const float* kp = k + ((size_t)(b * 256 + l)) * 128 + h * 16;
    float s = 0.f;
    #pragma unroll
    for (int d = 0; d < 16; d++) s += qh[d] * kp[d];
    s *= 0.25f;
    float mx = blk_max1(s, sm);
    float e = __expf(s - mx);
    float sum = blk_sum1(e, sm);
    attn[(size_t)blk * 256 + l] = e / sum;
}

// ---------- attention out (owt = ao_w transposed) ----------
__global__ void k_attn_out(const float* __restrict__ v, const float* __restrict__ attn,
                           const float* __restrict__ owt, const float* __restrict__ ob,
                           float* __restrict__ xs){
    __shared__ float vp[128];
    int bl = blockIdx.x; int b = bl >> 8, l = bl & 255; int t = threadIdx.x; // 128 thr
    float a = attn[((size_t)((b << 3) + (t >> 4))) * 256 + l];
    vp[t] = v[(size_t)bl * 128 + t] * a;
    __syncthreads();
    float acc = ob[t];
    for (int j = 0; j < 128; j++) acc += vp[j] * owt[j * 128 + t];
    xs[(size_t)bl * 128 + t] += acc;
}

// ---------- spectral attention + softmax (k2t = [b][d][i], coalesced) ----------
__global__ __launch_bounds__(128) void k_attn2(const float* __restrict__ q2,
                                               const float* __restrict__ k2t,
                                               float* __restrict__ attn2){
    __shared__ float qs[8][256];
    __shared__ float lg[8][128];
    __shared__ float mxs[8], sms[8];
    int blk = blockIdx.x; int b = blk >> 4; int i0 = (blk & 15) << 3;
    int j = threadIdx.x;
    for (int idx = j; idx < 8 * 256; idx += 128){
        int ii = idx >> 8, d = idx & 255;
        qs[ii][d] = q2[((size_t)(b * 128 + i0 + ii)) * 256 + d];
    }
    __syncthreads();
    const float* kt = k2t + (size_t)b * 32768;
    float acc[8] = {};
    for (int d = 0; d < 256; d++){
        float kv = kt[d * 128 + j];
        #pragma unroll
        for (int ii = 0; ii < 8; ii++) acc[ii] = fmaf(qs[ii][d], kv, acc[ii]);
    }
    #pragma unroll
    for (int ii = 0; ii < 8; ii++) lg[ii][j] = acc[ii] * (1.f / 16.f);
    __syncthreads();
    if (j < 8){
        float mx = -3.4e38f;
        for (int tt = 0; tt < 128; tt++) mx = fmaxf(mx, lg[j][tt]);
        float sm = 0.f;
        for (int tt = 0; tt < 128; tt++) sm += __expf(lg[j][tt] - mx);
        mxs[j] = mx; sms[j] = 1.f / sm;
    }
    __syncthreads();
    #pragma unroll
    for (int ii = 0; ii < 8; ii++)
        attn2[((size_t)(b * 128 + i0 + ii)) * 128 + j] =
            __expf(lg[ii][j] - mxs[ii]) * sms[ii];
}

// ---------- (attn2 @ v2) @ so_w.T + so_b (sowt transposed), transposed add ----------
__global__ __launch_bounds__(256) void k_av_so(const float* __restrict__ attn2,
                                               const float* __restrict__ v2,
                                               const float* __restrict__ sowt,
                                               const float* __restrict__ sob,
                                               float* __restrict__ xs){
    __shared__ float a2[8][128];
    __shared__ float av[8][256];
    int blk = blockIdx.x; int b = blk >> 4; int i0 = (blk & 15) << 3;
    int t = threadIdx.x;
    for (int idx = t; idx < 8 * 128; idx += 256){
        int ii = idx >> 7, j = idx & 127;
        a2[ii][j] = attn2[((size_t)(b * 128 + i0 + ii)) * 128 + j];
    }
    __syncthreads();
    {
        float acc[8] = {};
        const float* vb = v2 + (size_t)b * 128 * 256 + t;
        for (int j = 0; j < 128; j++){
            float vv = vb[(size_t)j * 256];
            #pragma unroll
            for (int ii = 0; ii < 8; ii++) acc[ii] = fmaf(a2[ii][j], vv, acc[ii]);
        }
        #pragma unroll
        for (int ii = 0; ii < 8; ii++) av[ii][t] = acc[ii];
    }
    __syncthreads();
    float acc[8] = {};
    for (int d = 0; d < 256; d++){
        float wv = sowt[d * 256 + t];
        #pragma unroll
        for (int ii = 0; ii < 8; ii++) acc[ii] = fmaf(av[ii][d], wv, acc[ii]);
    }
    float bias = sob[t];
    float* xp = xs + ((size_t)(b * 256 + t)) * 128 + i0;
    #pragma unroll
    for (int ii = 0; ii < 8; ii++) xp[ii] += acc[ii] + bias;
}

// ---------- unsort scatter ----------
__global__ void k_scatter(const float* __restrict__ xs, const int* __restrict__ sidx,
                          float* __restrict__ xr){
    int bl = blockIdx.x; int b = bl >> 8;
    int p = sidx[bl];
    xr[((size_t)(b * 256 + p)) * 128 + threadIdx.x] = xs[(size_t)bl * 128 + threadIdx.x];
}

// ---------- im2col for 3x3/2 conv ----------
__global__ void k_im2col(const float* __restrict__ xr, float* __restrict__ col){
    int r = blockIdx.x; int t = threadIdx.x; // 128 thr
    int b = r >> 6, oh = (r >> 3) & 7, ow = r & 7;
    float* dst = col + (size_t)r * 1152;
    #pragma unroll
    for (int kh = 0; kh < 3; kh++){
        int ih = oh * 2 - 1 + kh;
        #pragma unroll
        for (int kw = 0; kw < 3; kw++){
            int iw = ow * 2 - 1 + kw;
            float v = 0.f;
            if (ih >= 0 && ih < 16 && iw >= 0 && iw < 16)
                v = xr[((size_t)((b << 8) + (ih << 4) + iw)) * 128 + t];
            dst[(kh * 3 + kw) * 128 + t] = v;
        }
    }
}

// ---------- conv GEMM split-K=4 ----------
__global__ __launch_bounds__(256) void k_conv_gemm(const float* __restrict__ col,
                                                   const float* __restrict__ W2,
                                                   float* __restrict__ part){
    __shared__ float As[16][68];
    __shared__ float Ws[16][64];
    int j0 = blockIdx.x * 64, r0 = blockIdx.y * 64, s = blockIdx.z;
    int tid = threadIdx.x;
    int cg = tid & 15, rg = tid >> 4;
    float acc[4][4] = {};
    int kbeg = s * 288, kend = kbeg + 288;
    for (int k0 = kbeg; k0 < kend; k0 += 16){
        {
            int row = tid >> 2, kg = tid & 3;
            float4 a4 = *(const float4*)(col + (size_t)(r0 + row) * 1152 + k0 + kg * 4);
            As[kg * 4 + 0][row] = a4.x; As[kg * 4 + 1][row] = a4.y;
            As[kg * 4 + 2][row] = a4.z; As[kg * 4 + 3][row] = a4.w;
        }
        #pragma unroll
        for (int it = 0; it < 4; it++){
            int idx = tid + it * 256;
            int jj = idx & 63, kk = idx >> 6;
            Ws[kk][jj] = W2[(size_t)(k0 + kk) * 128 + j0 + jj];
        }
        __syncthreads();
        #pragma unroll
        for (int kk = 0; kk < 16; kk++){
            float4 a4 = *(const float4*)(&As[kk][rg << 2]);
            float4 w4 = *(const float4*)(&Ws[kk][cg << 2]);
            float av_[4] = {a4.x, a4.y, a4.z, a4.w};
            float wv_[4] = {w4.x, w4.y, w4.z, w4.w};
            #pragma unroll
            for (int ri = 0; ri < 4; ri++)
                #pragma unroll
                for (int ci = 0; ci < 4; ci++)
                    acc[ri][ci] = fmaf(av_[ri], wv_[ci], acc[ri][ci]);
        }
        __syncthreads();
    }
    float* pp = part + (size_t)s * 1024 * 128;
    #pragma unroll
    for (int ri = 0; ri < 4; ri++){
        int r = r0 + (rg << 2) + ri;
        #pragma unroll
        for (int ci = 0; ci < 4; ci++){
            int j = j0 + (cg << 2) + ci;
            pp[(size_t)r * 128 + j] = acc[ri][ci];
        }
    }
}

// ---------- reduce split-K partials + LayerNorm ----------
__global__ void k_part_ln(const float* __restrict__ part, const float* __restrict__ lnw,
                          const float* __restrict__ lnb, float* __restrict__ out){
    __shared__ float sm[16];
    int r = blockIdx.x, t = threadIdx.x; // 128 thr
    float v = part[(size_t)r * 128 + t]
            + part[(size_t)(1024 + r) * 128 + t]
            + part[(size_t)(2048 + r) * 128 + t]
            + part[(size_t)(3072 + r) * 128 + t];
    float a = v, q = v * v;
    blk_sum2(a, q, sm);
    float mu = a * (1.f / 128.f);
    float var = q * (1.f / 128.f) - mu * mu;
    float rs = rsqrtf(var + 1e-5f);
    out[(size_t)r * 128 + t] = (v - mu) * rs * lnw[t] + lnb[t];
}

extern "C" void kernel_launch(void* const* d_in, const int* in_sizes, int n_in,
                              void* d_out, int out_size, void* d_ws, size_t ws_size,
                              hipStream_t stream) {
    const float* x          = (const float*)d_in[0];
    const int*   sidx       = (const int*)  d_in[1];
    const float* spa_ln_w   = (const float*)d_in[2];
    const float* spa_ln_b   = (const float*)d_in[3];
    const float* spa_in_w   = (const float*)d_in[4];
    const float* spa_conv_w = (const float*)d_in[5];
    const float* spa_conv_b = (const float*)d_in[6];
    const float* spa_dt_bias= (const float*)d_in[7];
    const float* spa_A_log  = (const float*)d_in[8];
    const float* spa_D      = (const float*)d_in[9];
    const float* spa_rms_w  = (const float*)d_in[10];
    const float* spa_out_w  = (const float*)d_in[11];
    const float* spe_ln_w   = (const float*)d_in[12];
    const float* spe_ln_b   = (const float*)d_in[13];
    const float* spe_in_w   = (const float*)d_in[14];
    const float* spe_conv_w = (const float*)d_in[15];
    const float* spe_conv_b = (const float*)d_in[16];
    const float* spe_dt_bias= (const float*)d_in[17];
    const float* spe_A_log  = (const float*)d_in[18];
    const float* spe_D      = (const float*)d_in[19];
    const float* spe_rms_w  = (const float*)d_in[20];
    const float* spe_out_w  = (const float*)d_in[21];
    const float* norm_w     = (const float*)d_in[22];
    const float* norm_b     = (const float*)d_in[23];
    const float* cprj_w     = (const float*)d_in[24];
    const float* cprj_b     = (const float*)d_in[25];
    const float* aq_w       = (const float*)d_in[26];
    const float* aq_b       = (const float*)d_in[27];
    const float* ak_w       = (const float*)d_in[28];
    const float* ak_b       = (const float*)d_in[29];
    const float* av_w       = (const float*)d_in[30];
    const float* av_b       = (const float*)d_in[31];
    const float* ao_w       = (const float*)d_in[32];
    const float* ao_b       = (const float*)d_in[33];
    const float* sq_w       = (const float*)d_in[34];
    const float* sq_b       = (const float*)d_in[35];
    const float* sk_w       = (const float*)d_in[36];
    const float* sk_b       = (const float*)d_in[37];
    const float* sv_w       = (const float*)d_in[38];
    const float* sv_b       = (const float*)d_in[39];
    const float* so_w       = (const float*)d_in[40];
    const float* so_b       = (const float*)d_in[41];
    const float* ds_conv_w  = (const float*)d_in[42];
    const float* ds_ln_w    = (const float*)d_in[43];
    const float* ds_ln_b    = (const float*)d_in[44];

    float* ws = (float*)d_ws;
    float* xs   = ws + 0;        // 524288
    float* lnb_ = ws + 524288;   // 524288 (clbuf/xt live here when lnb_ dead)
    float* zx   = ws + 1048576;  // -> 3686400
    float* xc   = ws + 3686400;  // -> 5259264
    float* dtb  = ws + 5259264;  // 32768
    float* dAb  = ws + 5292032;  // 32768 (holds log-dA)
    float* yb   = ws + 5324800;  // 1048576 -> 6373376
    float* gb   = ws + 6373376;  // 1048576 -> 7421952 (scan: S buffer alias)
    float* h1   = ws + 7421952;  // 524288 -> 7946240
    float* clbuf = ws + 524288;  // 16384, inside dead lnb_ during scan stages
    // attention-stage aliases (all host regions dead post-loop)
    float* kb    = ws + 1048576;
    float* vb    = ws + 1572864;
    float* attnb = ws + 2097152;
    float* qb    = ws + 2129920;
    float* xt    = ws + 524288;  // 524288 (lnb_ region, dead post-loop)
    float* q2    = ws + 3686400;
    float* k2t   = ws + 4210688;
    float* v2    = ws + 4734976;
    float* attn2 = ws + 5324800;
    float* xr    = ws + 5586944;
    float* owt   = ws + 7421952; // 16384 (h1 region, dead post-loop)
    float* sowt  = ws + 7438336; // 65536 -> 7503872
    float* col   = ws + 6111232; // -> 7290880
    float* part  = ws + 7290880; // -> 7815168 (written after owt/sowt last use)

    k_embed<<<4096, 128, 0, stream>>>(x, sidx, xs);

    for (int i = 0; i < 2; i++){
        // ---- spatial mamba (L=256, nh=4, nc=4) ----
        k_ln<<<4096, 128, 0, stream>>>(xs, spa_ln_w + i * 128, spa_ln_b + i * 128, lnb_, 128);
        k_gemm<<<dim3(11, 64), 256, 0, stream>>>(lnb_, spa_in_w + (size_t)i * 644 * 128,
                                                 nullptr, nullptr, zx, 4096, 644, 128, 0);
        k_conv<<<4096, 256, 0, stream>>>(zx, spa_conv_w + (size_t)i * 384 * 4,
                                         spa_conv_b + i * 384, xc,
                                         spa_dt_bias + i * 4, spa_A_log + i * 4, dtb, dAb,
                                         256, 384, 644, 256, 4, 640);
        k_ssd_chunk<<<256, 256, 0, stream>>>(xc, dtb, dAb, yb, gb, clbuf,
                                             256, 4, 4, 384, 256, 320, 256);
        k_chunk_scan<<<64, 256, 0, stream>>>(gb, clbuf, 4);
        k_chunk_y<<<256, 256, 0, stream>>>(xc, gb, clbuf, spa_D + i * 4, yb,
                                           256, 4, 4, 384, 320, 256);
        k_gate<<<4096, 256, 0, stream>>>(yb, zx, spa_rms_w + i * 256, gb, 256, 644);
        k_gemm<<<dim3(2, 64), 256, 0, stream>>>(gb, spa_out_w + (size_t)i * 128 * 256,
                                                nullptr, xs, h1, 4096, 128, 256, 1);
        // ---- spectral mamba (L=128, nh=8, nc=2) ----
        k_ln_t<<<2048, 256, 0, stream>>>(h1, spe_ln_w + i * 256, spe_ln_b + i * 256, lnb_);
        k_gemm<<<dim3(19, 32), 256, 0, stream>>>(lnb_, spe_in_w + (size_t)i * 1160 * 256,
                                                 nullptr, nullptr, zx, 2048, 1160, 256, 0);
        k_conv<<<2048, 256, 0, stream>>>(zx, spe_conv_w + (size_t)i * 640 * 4,
                                         spe_conv_b + i * 640, xc,
                                         spe_dt_bias + i * 8, spe_A_log + i * 8, dtb, dAb,
                                         128, 640, 1160, 512, 8, 1152);
        k_ssd_chunk<<<256, 256, 0, stream>>>(xc, dtb, dAb, yb, gb, clbuf,
                                             128, 8, 2, 640, 512, 576, 512);
        k_chunk_scan<<<128, 256, 0, stream>>>(gb, clbuf, 2);
        k_chunk_y<<<256, 256, 0, stream>>>(xc, gb, clbuf, spe_D + i * 8, yb,
                                           128, 8, 2, 640, 576, 512);
        k_gate<<<2048, 256, 0, stream>>>(yb, zx, spe_rms_w + i * 512, gb, 512, 1160);
        k_gemm<<<dim3(4, 32), 256, 0, stream>>>(gb, spe_out_w + (size_t)i * 256 * 512,
                                                nullptr, h1, xs, 2048, 256, 512, 2);
    }

    // weight transposes for coalesced attention epilogues (h1 region now dead)
    k_tr<<<dim3(4, 4, 1), 256, 0, stream>>>(ao_w, owt, 128, 128);
    k_tr<<<dim3(8, 8, 1), 256, 0, stream>>>(so_w, sowt, 256, 256);

    k_ln<<<4096, 128, 0, stream>>>(xs, norm_w, norm_b, xs, 128);
    k_center_q<<<16, 128, 0, stream>>>(xs, cprj_w, cprj_b, aq_w, aq_b, qb);
    k_gemm<<<dim3(2, 64), 256, 0, stream>>>(xs, ak_w, ak_b, nullptr, kb, 4096, 128, 128, 0);
    k_gemm<<<dim3(2, 64), 256, 0, stream>>>(xs, av_w, av_b, nullptr, vb, 4096, 128, 128, 0);
    k_attn<<<128, 256, 0, stream>>>(qb, kb, attnb);
    k_attn_out<<<4096, 128, 0, stream>>>(vb, attnb, owt, ao_b, xs);
    // ---- spectral attention: transpose xs, then 3 tiled GEMMs ----
    k_tr<<<dim3(4, 8, 16), 256, 0, stream>>>(xs, xt, 256, 128);
    k_gemm<<<dim3(4, 32), 256, 0, stream>>>(xt, sq_w, sq_b, nullptr, q2, 2048, 256, 256, 0);
    k_gemm<<<dim3(4, 32), 256, 0, stream>>>(xt, sk_w, sk_b, nullptr, k2t, 2048, 256, 256, 3);
    k_gemm<<<dim3(4, 32), 256, 0, stream>>>(xt, sv_w, sv_b, nullptr, v2, 2048, 256, 256, 0);
    k_attn2<<<256, 128, 0, stream>>>(q2, k2t, attn2);
    k_av_so<<<256, 256, 0, stream>>>(attn2, v2, sowt, so_b, xs);
    k_scatter<<<4096, 128, 0, stream>>>(xs, sidx, xr);
    k_im2col<<<1024, 128, 0, stream>>>(xr, col);
    k_conv_gemm<<<dim3(2, 16, 4), 256, 0, stream>>>(col, ds_conv_w, part);
    k_part_ln<<<1024, 128, 0, stream>>>(part, ds_ln_w, ds_ln_b, (float*)d_out);
}

// Round 8
// 661.234 us; speedup vs baseline: 1.6102x; 1.0311x over previous
//
#include <hip/hip_runtime.h>
#include <math.h>

#define DEV __device__ __forceinline__

DEV float siluf(float x){ return x / (1.f + __expf(-x)); }
DEV float softplusf(float x){ return (x > 20.f) ? x : log1pf(__expf(x)); }

// ---------- block reduction helpers (wave64) ----------
DEV void blk_sum2(float &a, float &b, float* sm){
    int lane = threadIdx.x & 63, wid = threadIdx.x >> 6, nw = blockDim.x >> 6;
    #pragma unroll
    for (int off = 32; off; off >>= 1){ a += __shfl_down(a, off); b += __shfl_down(b, off); }
    if (lane == 0){ sm[wid] = a; sm[8 + wid] = b; }
    __syncthreads();
    float ra = 0.f, rb = 0.f;
    for (int i = 0; i < nw; i++){ ra += sm[i]; rb += sm[8 + i]; }
    __syncthreads();
    a = ra; b = rb;
}
DEV float blk_sum1(float v, float* sm){
    int lane = threadIdx.x & 63, wid = threadIdx.x >> 6, nw = blockDim.x >> 6;
    #pragma unroll
    for (int off = 32; off; off >>= 1) v += __shfl_down(v, off);
    if (lane == 0) sm[wid] = v;
    __syncthreads();
    float r = 0.f;
    for (int i = 0; i < nw; i++) r += sm[i];
    __syncthreads();
    return r;
}
DEV float blk_max1(float v, float* sm){
    int lane = threadIdx.x & 63, wid = threadIdx.x >> 6, nw = blockDim.x >> 6;
    #pragma unroll
    for (int off = 32; off; off >>= 1) v = fmaxf(v, __shfl_down(v, off));
    if (lane == 0) sm[wid] = v;
    __syncthreads();
    float r = -3.4e38f;
    for (int i = 0; i < nw; i++) r = fmaxf(r, sm[i]);
    __syncthreads();
    return r;
}

// ---------- batched LDS-tiled transpose: out[z][c*R+r] = in[z][r*C+c] ----------
// grid (C/32, R/32, batch), 256 thr
__global__ __launch_bounds__(256) void k_tr(const float* __restrict__ in,
                                            float* __restrict__ out, int R, int C){
    __shared__ float tile[32][33];
    const float* ip = in + (size_t)blockIdx.z * R * C;
    float* op = out + (size_t)blockIdx.z * R * C;
    int c0 = blockIdx.x * 32, r0 = blockIdx.y * 32;
    int tx = threadIdx.x & 31, ty = threadIdx.x >> 5;
    #pragma unroll
    for (int rr = ty; rr < 32; rr += 8)
        tile[rr][tx] = ip[(size_t)(r0 + rr) * C + c0 + tx];
    __syncthreads();
    #pragma unroll
    for (int rr = ty; rr < 32; rr += 8)
        op[(size_t)(c0 + rr) * R + r0 + tx] = tile[tx][rr];
}

// ---------- K1: pos-embed + gather (xT = x pre-transposed to [b][p][c]) ----------
__global__ void k_embed(const float* __restrict__ xT, const int* __restrict__ sidx,
                        float* __restrict__ xs){
    int bl = blockIdx.x; int b = bl >> 8; int c = threadIdx.x;
    int p = sidx[bl];
    int hh = p >> 4, ww = p & 15;
    int pos = (c < 64) ? hh : ww;
    int jm = c & 63;
    float om = __expf(-(float)(jm & 31) * 0.28782313662425574f); // ln(10000)/32
    float ang = (float)pos * om;
    float pe = (jm < 32) ? sinf(ang) : cosf(ang);
    xs[(size_t)bl * 128 + c] = xT[((size_t)(b * 256 + p)) * 128 + c] + pe;
}

// ---------- LayerNorm (block per row, blockDim == dim) ----------
__global__ void k_ln(const float* __restrict__ in, const float* __restrict__ w,
                     const float* __restrict__ bb, float* __restrict__ out, int dim){
    __shared__ float sm[16];
    int row = blockIdx.x, t = threadIdx.x;
    float v = in[(size_t)row * dim + t];
    float a = v, q = v * v;
    blk_sum2(a, q, sm);
    float inv = 1.f / (float)dim;
    float mu = a * inv;
    float var = q * inv - mu * mu;
    float rs = rsqrtf(var + 1e-5f);
    out[(size_t)row * dim + t] = (v - mu) * rs * w[t] + bb[t];
}

// ---------- 64x64-tile fp32 GEMM core: coalesced staging, BK=32 ----------
// out[r,j] = sum_k A[r,k]*W[j,k]. Requires K%32==0, N%4==0.
// mode 0: +bias (may be null)      mode 1: + res[r*N+j]
// mode 2: transposed scatter (N==256): out[((r0>>7)*256+j)*128+(r&127)] += res
// mode 3: transposed scatter + bias (N==256), no residual
DEV void gemm_core(const float* __restrict__ A, const float* __restrict__ W,
                   const float* __restrict__ bias, const float* __restrict__ res,
                   float* __restrict__ out, int N, int K, int mode,
                   int j0, int r0){
    __shared__ float lds[2][32][68]; // [0]=A-tile, [1]=W-tile; reused as T[64][68]
    int tid = threadIdx.x;
    int cg = tid & 15, rg = tid >> 4;
    int row = tid >> 2, kg = tid & 3;
    int wrow = j0 + row; if (wrow > N - 1) wrow = N - 1; // clamp (guarded stores)
    float acc[4][4] = {};
    for (int k0 = 0; k0 < K; k0 += 32){
        const float* Ap = A + (size_t)(r0 + row) * K + k0 + kg * 4;
        float4 a0 = *(const float4*)(Ap);
        float4 a1 = *(const float4*)(Ap + 16);
        const float* Wp = W + (size_t)wrow * K + k0 + kg * 4;
        float4 w0 = *(const float4*)(Wp);
        float4 w1 = *(const float4*)(Wp + 16);
        __syncthreads(); // previous iteration's LDS reads done
        lds[0][kg * 4 + 0][row] = a0.x; lds[0][kg * 4 + 1][row] = a0.y;
        lds[0][kg * 4 + 2][row] = a0.z; lds[0][kg * 4 + 3][row] = a0.w;
        lds[0][16 + kg * 4 + 0][row] = a1.x; lds[0][16 + kg * 4 + 1][row] = a1.y;
        lds[0][16 + kg * 4 + 2][row] = a1.z; lds[0][16 + kg * 4 + 3][row] = a1.w;
        lds[1][kg * 4 + 0][row] = w0.x; lds[1][kg * 4 + 1][row] = w0.y;
        lds[1][kg * 4 + 2][row] = w0.z; lds[1][kg * 4 + 3][row] = w0.w;
        lds[1][16 + kg * 4 + 0][row] = w1.x; lds[1][16 + kg * 4 + 1][row] = w1.y;
        lds[1][16 + kg * 4 + 2][row] = w1.z; lds[1][16 + kg * 4 + 3][row] = w1.w;
        __syncthreads();
        #pragma unroll
        for (int kk = 0; kk < 32; kk++){
            float4 a4 = *(const float4*)(&lds[0][kk][rg << 2]);
            float4 w4 = *(const float4*)(&lds[1][kk][cg << 2]);
            float av_[4] = {a4.x, a4.y, a4.z, a4.w};
            float wv_[4] = {w4.x, w4.y, w4.z, w4.w};
            #pragma unroll
            for (int ri = 0; ri < 4; ri++)
                #pragma unroll
                for (int ci = 0; ci < 4; ci++)
                    acc[ri][ci] = fmaf(av_[ri], wv_[ci], acc[ri][ci]);
        }
    }
    if (mode >= 2){
        // stage output tile transposed: T[j-j0][r-r0], then coalesced writes
        float (*T)[68] = (float (*)[68])lds;
        __syncthreads();
        #pragma unroll
        for (int ri = 0; ri < 4; ri++)
            #pragma unroll
            for (int ci = 0; ci < 4; ci++)
                T[(cg << 2) + ci][(rg << 2) + ri] = acc[ri][ci];
        __syncthreads();
        int b2 = r0 >> 7;
        int ii0 = r0 & 127;
        int jj = tid >> 2, seg = tid & 3;
        size_t base = ((size_t)(b2 * 256 + j0 + jj)) * 128 + ii0 + seg * 16;
        float* op = out + base;
        if (mode == 2){
            const float* rp = res + base;
            #pragma unroll
            for (int c = 0; c < 4; c++){
                float4 v = *(const float4*)(&T[jj][seg * 16 + c * 4]);
                float4 rv = *(const float4*)(rp + c * 4);
                v.x += rv.x; v.y += rv.y; v.z += rv.z; v.w += rv.w;
                *(float4*)(op + c * 4) = v;
            }
        } else {
            float bj = bias[j0 + jj];
            #pragma unroll
            for (int c = 0; c < 4; c++){
                float4 v = *(const float4*)(&T[jj][seg * 16 + c * 4]);
                v.x += bj; v.y += bj; v.z += bj; v.w += bj;
                *(float4*)(op + c * 4) = v;
            }
        }
    } else {
        #pragma unroll
        for (int ri = 0; ri < 4; ri++){
            int r = r0 + (rg << 2) + ri;
            int j = j0 + (cg << 2);
            if (j < N){
                float4 v = make_float4(acc[ri][0], acc[ri][1], acc[ri][2], acc[ri][3]);
                if (mode == 0){
                    if (bias){
                        v.x += bias[j]; v.y += bias[j + 1];
                        v.z += bias[j + 2]; v.w += bias[j + 3];
                    }
                    *(float4*)(&out[(size_t)r * N + j]) = v;
                } else {
                    float4 rv = *(const float4*)(&res[(size_t)r * N + j]);
                    v.x += rv.x; v.y += rv.y; v.z += rv.z; v.w += rv.w;
                    *(float4*)(&out[(size_t)r * N + j]) = v;
                }
            }
        }
    }
}

__global__ __launch_bounds__(256) void k_gemm(const float* __restrict__ A,
                                              const float* __restrict__ W,
                                              const float* __restrict__ bias,
                                              const float* __restrict__ res,
                                              float* __restrict__ out,
                                              int M, int N, int K, int mode){
    gemm_core(A, W, bias, res, out, N, K, mode, blockIdx.x * 64, blockIdx.y * 64);
}

struct GJob { const float* W; const float* bias; float* out; int mode; };

// multi-output GEMM: blockIdx.z selects job (same A, N, K)
__global__ __launch_bounds__(256) void k_gemm3(const float* __restrict__ A,
                                               GJob ja, GJob jb, GJob jc,
                                               int N, int K){
    GJob j = (blockIdx.z == 0) ? ja : ((blockIdx.z == 1) ? jb : jc);
    gemm_core(A, j.W, j.bias, nullptr, j.out, N, K, j.mode,
              blockIdx.x * 64, blockIdx.y * 64);
}

// ---------- causal depthwise conv(4)+bias+silu, fused dt / log-dA ----------
__global__ void k_conv(const float* __restrict__ zx, const float* __restrict__ cw,
                       const float* __restrict__ cb, float* __restrict__ xc,
                       const float* __restrict__ dtbias, const float* __restrict__ Al,
                       float* __restrict__ dt, float* __restrict__ dlA,
                       int L, int D, int stride, int off, int nh, int dtoff){
    int bl = blockIdx.x;
    int l = bl & (L - 1);
    const float* base = zx + (size_t)bl * stride + off;
    for (int d = threadIdx.x; d < D; d += blockDim.x){
        float acc = cb[d];
        #pragma unroll
        for (int k = 0; k < 4; k++){
            int dl = l + k - 3;
            if (dl >= 0) acc += base[(ptrdiff_t)(k - 3) * stride + d] * cw[d * 4 + k];
        }
        xc[(size_t)bl * D + d] = siluf(acc);
    }
    int t = threadIdx.x;
    if (t < nh){
        float xv = zx[(size_t)bl * stride + dtoff + t] + dtbias[t];
        float d = softplusf(xv);
        dt[(size_t)bl * nh + t] = d;
        dlA[(size_t)bl * nh + t] = -d * __expf(Al[t]); // log(dA) <= 0
    }
}

// ---------- chunked SSD, stage A: per (b,h,chunk-of-64) ----------
__global__ __launch_bounds__(256) void k_ssd_chunk(
        const float* __restrict__ xc, const float* __restrict__ dt,
        const float* __restrict__ dlA, float* __restrict__ y,
        float* __restrict__ S, float* __restrict__ clb,
        int L, int nh, int nc, int xcs, int bo, int co, int ys){
    __shared__ float sX[64][68];
    __shared__ float sB[64][68];
    __shared__ float sC[64][68]; // phase1: C ; after: masked G
    __shared__ float cl[64], sdt[64], sw[64];
    int blk = blockIdx.x;
    int c = blk % nc; int bh = blk / nc; int h = bh % nh; int b = bh / nh;
    int l0 = c * 64;
    int tid = threadIdx.x;
    const float* base = xc + ((size_t)(b * L + l0)) * xcs;
    for (int idx = tid; idx < 4096; idx += 256){
        int s = idx >> 6, n = idx & 63;
        const float* row = base + (size_t)s * xcs;
        sX[s][n] = row[h * 64 + n];
        sB[s][n] = row[bo + n];
        sC[s][n] = row[co + n];
    }
    if (tid < 64){
        size_t di = (size_t)(b * L + l0 + tid) * nh + h;
        float dlv = dlA[di];
        sdt[tid] = dt[di];
        #pragma unroll
        for (int off = 1; off < 64; off <<= 1){
            float o = __shfl_up(dlv, off, 64);
            if (tid >= off) dlv += o;
        }
        cl[tid] = dlv;
        clb[(size_t)blk * 64 + tid] = dlv;
    }
    __syncthreads();
    if (tid < 64) sw[tid] = __expf(cl[63] - cl[tid]) * sdt[tid];

    int g1 = tid >> 4, g2 = tid & 15;
    int t0 = g1 * 4, s0 = g2 * 4;
    // ---- phase 1: g = C.B^T (registers) ----
    float g[4][4] = {};
    for (int n = 0; n < 64; n += 4){
        float4 cv[4], bv[4];
        #pragma unroll
        for (int i = 0; i < 4; i++) cv[i] = *(const float4*)&sC[t0 + i][n];
        #pragma unroll
        for (int j = 0; j < 4; j++) bv[j] = *(const float4*)&sB[s0 + j][n];
        #pragma unroll
        for (int i = 0; i < 4; i++)
            #pragma unroll
            for (int j = 0; j < 4; j++){
                g[i][j] = fmaf(cv[i].x, bv[j].x, g[i][j]);
                g[i][j] = fmaf(cv[i].y, bv[j].y, g[i][j]);
                g[i][j] = fmaf(cv[i].z, bv[j].z, g[i][j]);
                g[i][j] = fmaf(cv[i].w, bv[j].w, g[i][j]);
            }
    }
    __syncthreads(); // all reads of sC (as C) complete
    #pragma unroll
    for (int i = 0; i < 4; i++)
        #pragma unroll
        for (int j = 0; j < 4; j++){
            int t = t0 + i, s = s0 + j;
            float v = 0.f;
            if (s <= t) v = g[i][j] * __expf(cl[t] - cl[s]) * sdt[s];
            sC[t][s] = v; // sC now holds masked G
        }
    __syncthreads();
    // ---- phase 2: y_intra = G @ X ----
    {
        float acc[4][4] = {};
        for (int s = 0; s < 64; s++){
            float4 xv = *(const float4*)&sX[s][s0];
            float gv[4];
            #pragma unroll
            for (int i = 0; i < 4; i++) gv[i] = sC[t0 + i][s];
            #pragma unroll
            for (int i = 0; i < 4; i++){
                acc[i][0] = fmaf(gv[i], xv.x, acc[i][0]);
                acc[i][1] = fmaf(gv[i], xv.y, acc[i][1]);
                acc[i][2] = fmaf(gv[i], xv.z, acc[i][2]);
                acc[i][3] = fmaf(gv[i], xv.w, acc[i][3]);
            }
        }
        #pragma unroll
        for (int i = 0; i < 4; i++){
            float4 o = make_float4(acc[i][0], acc[i][1], acc[i][2], acc[i][3]);
            *(float4*)&y[(size_t)(b * L + l0 + t0 + i) * ys + h * 64 + s0] = o;
        }
    }
    // ---- phase 3: S[p][n] ----
    {
        float acc[4][4] = {};
        int p0 = t0, n0 = s0;
        for (int s = 0; s < 64; s++){
            float wv = sw[s];
            float4 bv = *(const float4*)&sB[s][n0];
            float4 xv = *(const float4*)&sX[s][p0];
            float w0 = wv * xv.x, w1 = wv * xv.y, w2 = wv * xv.z, w3 = wv * xv.w;
            acc[0][0] = fmaf(w0, bv.x, acc[0][0]); acc[0][1] = fmaf(w0, bv.y, acc[0][1]);
            acc[0][2] = fmaf(w0, bv.z, acc[0][2]); acc[0][3] = fmaf(w0, bv.w, acc[0][3]);
            acc[1][0] = fmaf(w1, bv.x, acc[1][0]); acc[1][1] = fmaf(w1, bv.y, acc[1][1]);
            acc[1][2] = fmaf(w1, bv.z, acc[1][2]); acc[1][3] = fmaf(w1, bv.w, acc[1][3]);
            acc[2][0] = fmaf(w2, bv.x, acc[2][0]); acc[2][1] = fmaf(w2, bv.y, acc[2][1]);
            acc[2][2] = fmaf(w2, bv.z, acc[2][2]); acc[2][3] = fmaf(w2, bv.w, acc[2][3]);
            acc[3][0] = fmaf(w3, bv.x, acc[3][0]); acc[3][1] = fmaf(w3, bv.y, acc[3][1]);
            acc[3][2] = fmaf(w3, bv.z, acc[3][2]); acc[3][3] = fmaf(w3, bv.w, acc[3][3]);
        }
        float* Sp = S + (size_t)blk * 4096;
        #pragma unroll
        for (int i = 0; i < 4; i++){
            float4 o = make_float4(acc[i][0], acc[i][1], acc[i][2], acc[i][3]);
            *(float4*)&Sp[(p0 + i) * 64 + n0] = o;
        }
    }
}

// ---------- chunked SSD, stage B+C fused ----------
// h_init(c) = sum_{c'<c} S_{c'} * prod_{m=c'+1}^{c-1} dec_m  (nc <= 4)
// y += exp(cl[t]) * (C_t . h_init) + D*x
__global__ __launch_bounds__(256) void k_chunk_y(
        const float* __restrict__ xc, const float* __restrict__ S,
        const float* __restrict__ clb, const float* __restrict__ Dp,
        float* __restrict__ y,
        int L, int nh, int nc, int xcs, int co, int ys){
    __shared__ float sH[64][68]; // [p][n]
    __shared__ float sC[64][68]; // [t][n]
    __shared__ float scl[64];
    int blk = blockIdx.x;
    int c = blk % nc; int bh = blk / nc; int h = bh % nh; int b = bh / nh;
    int l0 = c * 64;
    int tid = threadIdx.x;
    // chunk weights
    float wch[4];
    {
        float w = 1.f;
        for (int cp = c - 1; cp >= 0; cp--){
            wch[cp] = w;
            w *= __expf(clb[((size_t)(bh * nc + cp)) * 64 + 63]);
        }
    }
    const float* Sb = S + (size_t)(bh * nc) * 4096;
    const float* base = xc + ((size_t)(b * L + l0)) * xcs;
    for (int idx = tid; idx < 4096; idx += 256){
        int r = idx >> 6, n = idx & 63;
        float hv = 0.f;
        for (int cp = 0; cp < c; cp++)
            hv = fmaf(wch[cp], Sb[(size_t)cp * 4096 + idx], hv);
        sH[r][n] = hv;
        sC[r][n] = base[(size_t)r * xcs + co + n];
    }
    if (tid < 64) scl[tid] = __expf(clb[(size_t)blk * 64 + tid]);
    float Dh = Dp[h];
    __syncthreads();
    int g1 = tid >> 4, g2 = tid & 15;
    int t0 = g1 * 4, p0 = g2 * 4;
    float m[4][4] = {};
    for (int n = 0; n < 64; n += 4){
        float4 cv[4], hv[4];
        #pragma unroll
        for (int i = 0; i < 4; i++) cv[i] = *(const float4*)&sC[t0 + i][n];
        #pragma unroll
        for (int j = 0; j < 4; j++) hv[j] = *(const float4*)&sH[p0 + j][n];
        #pragma unroll
        for (int i = 0; i < 4; i++)
            #pragma unroll
            for (int j = 0; j < 4; j++){
                m[i][j] = fmaf(cv[i].x, hv[j].x, m[i][j]);
                m[i][j] = fmaf(cv[i].y, hv[j].y, m[i][j]);
                m[i][j] = fmaf(cv[i].z, hv[j].z, m[i][j]);
                m[i][j] = fmaf(cv[i].w, hv[j].w, m[i][j]);
            }
    }
    #pragma unroll
    for (int i = 0; i < 4; i++){
        int t = t0 + i;
        size_t yi = (size_t)(b * L + l0 + t) * ys + h * 64 + p0;
        float4 yv = *(float4*)&y[yi];
        float4 xv = *(const float4*)&base[(size_t)t * xcs + h * 64 + p0];
        float e = scl[t];
        yv.x += e * m[i][0] + Dh * xv.x;
        yv.y += e * m[i][1] + Dh * xv.y;
        yv.z += e * m[i][2] + Dh * xv.z;
        yv.w += e * m[i][3] + Dh * xv.w;
        *(float4*)&y[yi] = yv;
    }
}

// ---------- gate (silu(z)) + RMSNorm ----------
__global__ __launch_bounds__(256) void k_gate(const float* __restrict__ y,
                                              const float* __restrict__ zx,
                                              const float* __restrict__ rw,
                                              float* __restrict__ out,
                                              int dinner, int zstride){
    __shared__ float sm[16];
    int row = blockIdx.x, t = threadIdx.x;
    float v0, v1 = 0.f, ss;
    v0 = y[(size_t)row * dinner + t] * siluf(zx[(size_t)row * zstride + t]);
    ss = v0 * v0;
    if (dinner == 512){
        v1 = y[(size_t)row * dinner + t + 256] * siluf(zx[(size_t)row * zstride + t + 256]);
        ss += v1 * v1;
    }
    float tot = blk_sum1(ss, sm);
    float sc = rsqrtf(tot / (float)dinner + 1e-5f);
    out[(size_t)row * dinner + t] = v0 * sc * rw[t];
    if (dinner == 512) out[(size_t)row * dinner + t + 256] = v1 * sc * rw[t + 256];
}

// ---------- center projection + q ----------
__global__ void k_center_q(const float* __restrict__ xs, const float* __restrict__ cw,
                           const float* __restrict__ cb, const float* __restrict__ qw,
                           const float* __restrict__ qb, float* __restrict__ q){
    __shared__ float xr[640];
    __shared__ float cen[128];
    int b = blockIdx.x, t = threadIdx.x; // 128 thr
    for (int idx = t; idx < 640; idx += 128)
        xr[idx] = xs[(size_t)b * 256 * 128 + idx];
    __syncthreads();
    float acc = cb[t];
    for (int c = 0; c < 128; c++){
        const float* wp = cw + (size_t)(t * 128 + c) * 5;
        #pragma unroll
        for (int l = 0; l < 5; l++) acc += xr[l * 128 + c] * wp[l];
    }
    cen[t] = acc;
    __syncthreads();
    float qa = qb[t];
    const float* wr = qw + (size_t)t * 128;
    for (int o = 0; o < 128; o++) qa += cen[o] * wr[o];
    q[b * 128 + t] = qa;
}

// ---------- attention softmax over l ----------
__global__ void k_attn(const float* __restrict__ q, const float* __restrict__ k,
                       float* __restrict__ attn){
    __shared__ float sm[16];
    __shared__ float qh[16];
    int blk = blockIdx.x; int b = blk >> 3, h = blk & 7; int l = threadIdx.x; // 256 thr
    if (l < 16) qh[l] = q[b * 128 + h * 16 + l];
    __syncthreads();
    const float* kp = k + ((size_t)(b * 256 + l)) * 128 + h * 16;
    float s = 0.f;
    #pragma unroll
    for (int d = 0; d < 16; d++) s += qh[d] * kp[d];
    s *= 0.25f;
    float mx = blk_max1(s, sm);
    float e = __expf(s - mx);
    float sum = blk_sum1(e, sm);
    attn[(size_t)blk * 256 + l] = e / sum;
}

// ---------- attention out, 8 l-rows per block (owt = ao_w transposed) ----------
__global__ __launch_bounds__(128) void k_attn_out(const float* __restrict__ v,
                                                  const float* __restrict__ attn,
                                                  const float* __restrict__ owt,
                                                  const float* __restrict__ ob,
                                                  float* __restrict__ xs){
    __shared__ float vp[8][128];
    int blk = blockIdx.x; int b = blk >> 5, l0 = (blk & 31) << 3;
    int t = threadIdx.x; // 128 thr
    int h = t >> 4;
    float a[8];
    #pragma unroll
    for (int r = 0; r < 8; r++)
        a[r] = attn[((size_t)(b * 8 + h)) * 256 + l0 + r];
    #pragma unroll
    for (int r = 0; r < 8; r++)
        vp[r][t] = v[((size_t)(b * 256 + l0 + r)) * 128 + t] * a[r];
    __syncthreads();
    float acc[8];
    float bv = ob[t];
    #pragma unroll
    for (int r = 0; r < 8; r++) acc[r] = bv;
    for (int j = 0; j < 128; j++){
        float w = owt[j * 128 + t];
        #pragma unroll
        for (int r = 0; r < 8; r++) acc[r] = fmaf(vp[r][j], w, acc[r]);
    }
    #pragma unroll
    for (int r = 0; r < 8; r++)
        xs[((size_t)(b * 256 + l0 + r)) * 128 + t] += acc[r];
}

// ---------- spectral attention + softmax (k2t = [b][d][i], coalesced) ----------
__global__ __launch_bounds__(128) void k_attn2(const float* __restrict__ q2,
                                               const float* __restrict__ k2t,
                                               float* __restrict__ attn2){
    __shared__ float qs[8][256];
    __shared__ float lg[8][128];
    __shared__ float mxs[8], sms[8];
    int blk = blockIdx.x; int b = blk >> 4; int i0 = (blk & 15) << 3;
    int j = threadIdx.x;
    for (int idx = j; idx < 8 * 256; idx += 128){
        int ii = idx >> 8, d = idx & 255;
        qs[ii][d] = q2[((size_t)(b * 128 + i0 + ii)) * 256 + d];
    }
    __syncthreads();
    const float* kt = k2t + (size_t)b * 32768;
    float acc[8] = {};
    for (int d = 0; d < 256; d++){
        float kv = kt[d * 128 + j];
        #pragma unroll
        for (int ii = 0; ii < 8; ii++) acc[ii] = fmaf(qs[ii][d], kv, acc[ii]);
    }
    #pragma unroll
    for (int ii = 0; ii < 8; ii++) lg[ii][j] = acc[ii] * (1.f / 16.f);
    __syncthreads();
    if (j < 8){
        float mx = -3.4e38f;
        for (int tt = 0; tt < 128; tt++) mx = fmaxf(mx, lg[j][tt]);
        float sm = 0.f;
        for (int tt = 0; tt < 128; tt++) sm += __expf(lg[j][tt] - mx);
        mxs[j] = mx; sms[j] = 1.f / sm;
    }
    __syncthreads();
    #pragma unroll
    for (int ii = 0; ii < 8; ii++)
        attn2[((size_t)(b * 128 + i0 + ii)) * 128 + j] =
            __expf(lg[ii][j] - mxs[ii]) * sms[ii];
}

// ---------- (attn2 @ v2) @ so_w.T + so_b, transposed add + unsort scatter ----------
// writes final result directly to xr[(b, sidx[b][l]), :] = xs + attn-out
__global__ __launch_bounds__(256) void k_av_so(const float* __restrict__ attn2,
                                               const float* __restrict__ v2,
                                               const float* __restrict__ sowt,
                                               const float* __restrict__ sob,
                                               const float* __restrict__ xs,
                                               const int* __restrict__ sidx,
                                               float* __restrict__ xr){
    __shared__ float a2[8][128];
    __shared__ float av[8][256];
    int blk = blockIdx.x; int b = blk >> 4; int i0 = (blk & 15) << 3;
    int t = threadIdx.x;
    for (int idx = t; idx < 8 * 128; idx += 256){
        int ii = idx >> 7, j = idx & 127;
        a2[ii][j] = attn2[((size_t)(b * 128 + i0 + ii)) * 128 + j];
    }
    __syncthreads();
    {
        float acc[8] = {};
        const float* vb = v2 + (size_t)b * 128 * 256 + t;
        for (int j = 0; j < 128; j++){
            float vv = vb[(size_t)j * 256];
            #pragma unroll
            for (int ii = 0; ii < 8; ii++) acc[ii] = fmaf(a2[ii][j], vv, acc[ii]);
        }
        #pragma unroll
        for (int ii = 0; ii < 8; ii++) av[ii][t] = acc[ii];
    }
    __syncthreads();
    float acc[8] = {};
    for (int d = 0; d < 256; d++){
        float wv = sowt[d * 256 + t];
        #pragma unroll
        for (int ii = 0; ii < 8; ii++) acc[ii] = fmaf(av[ii][d], wv, acc[ii]);
    }
    float bias = sob[t];
    int p = sidx[b * 256 + t];
    const float* xin = xs + ((size_t)(b * 256 + t)) * 128 + i0;
    float* xout = xr + ((size_t)(b * 256 + p)) * 128 + i0;
    #pragma unroll
    for (int ii = 0; ii < 8; ii++) xout[ii] = xin[ii] + acc[ii] + bias;
}

// ---------- im2col for 3x3/2 conv ----------
__global__ void k_im2col(const float* __restrict__ xr, float* __restrict__ col){
    int r = blockIdx.x; int t = threadIdx.x; // 128 thr
    int b = r >> 6, oh = (r >> 3) & 7, ow = r & 7;
    float* dst = col + (size_t)r * 1152;
    #pragma unroll
    for (int kh = 0; kh < 3; kh++){
        int ih = oh * 2 - 1 + kh;
        #pragma unroll
        for (int kw = 0; kw < 3; kw++){
            int iw = ow * 2 - 1 + kw;
            float v = 0.f;
            if (ih >= 0 && ih < 16 && iw >= 0 && iw < 16)
                v = xr[((size_t)((b << 8) + (ih << 4) + iw)) * 128 + t];
            dst[(kh * 3 + kw) * 128 + t] = v;
        }
    }
}

// ---------- conv GEMM split-K=4 ----------
__global__ __launch_bounds__(256) void k_conv_gemm(const float* __restrict__ col,
                                                   const float* __restrict__ W2,
                                                   float* __restrict__ part){
    __shared__ float As[16][68];
    __shared__ float Ws[16][64];
    int j0 = blockIdx.x * 64, r0 = blockIdx.y * 64, s = blockIdx.z;
    int tid = threadIdx.x;
    int cg = tid & 15, rg = tid >> 4;
    float acc[4][4] = {};
    int kbeg = s * 288, kend = kbeg + 288;
    for (int k0 = kbeg; k0 < kend; k0 += 16){
        {
            int row = tid >> 2, kg = tid & 3;
            float4 a4 = *(const float4*)(col + (size_t)(r0 + row) * 1152 + k0 + kg * 4);
            As[kg * 4 + 0][row] = a4.x; As[kg * 4 + 1][row] = a4.y;
            As[kg * 4 + 2][row] = a4.z; As[kg * 4 + 3][row] = a4.w;
        }
        #pragma unroll
        for (int it = 0; it < 4; it++){
            int idx = tid + it * 256;
            int jj = idx & 63, kk = idx >> 6;
            Ws[kk][jj] = W2[(size_t)(k0 + kk) * 128 + j0 + jj];
        }
        __syncthreads();
        #pragma unroll
        for (int kk = 0; kk < 16; kk++){
            float4 a4 = *(const float4*)(&As[kk][rg << 2]);
            float4 w4 = *(const float4*)(&Ws[kk][cg << 2]);
            float av_[4] = {a4.x, a4.y, a4.z, a4.w};
            float wv_[4] = {w4.x, w4.y, w4.z, w4.w};
            #pragma unroll
            for (int ri = 0; ri < 4; ri++)
                #pragma unroll
                for (int ci = 0; ci < 4; ci++)
                    acc[ri][ci] = fmaf(av_[ri], wv_[ci], acc[ri][ci]);
        }
        __syncthreads();
    }
    float* pp = part + (size_t)s * 1024 * 128;
    #pragma unroll
    for (int ri = 0; ri < 4; ri++){
        int r = r0 + (rg << 2) + ri;
        #pragma unroll
        for (int ci = 0; ci < 4; ci++){
            int j = j0 + (cg << 2) + ci;
            pp[(size_t)r * 128 + j] = acc[ri][ci];
        }
    }
}

// ---------- reduce split-K partials + LayerNorm ----------
__global__ void k_part_ln(const float* __restrict__ part, const float* __restrict__ lnw,
                          const float* __restrict__ lnb, float* __restrict__ out){
    __shared__ float sm[16];
    int r = blockIdx.x, t = threadIdx.x; // 128 thr
    float v = part[(size_t)r * 128 + t]
            + part[(size_t)(1024 + r) * 128 + t]
            + part[(size_t)(2048 + r) * 128 + t]
            + part[(size_t)(3072 + r) * 128 + t];
    float a = v, q = v * v;
    blk_sum2(a, q, sm);
    float mu = a * (1.f / 128.f);
    float var = q * (1.f / 128.f) - mu * mu;
    float rs = rsqrtf(var + 1e-5f);
    out[(size_t)r * 128 + t] = (v - mu) * rs * lnw[t] + lnb[t];
}

extern "C" void kernel_launch(void* const* d_in, const int* in_sizes, int n_in,
                              void* d_out, int out_size, void* d_ws, size_t ws_size,
                              hipStream_t stream) {
    const float* x          = (const float*)d_in[0];
    const int*   sidx       = (const int*)  d_in[1];
    const float* spa_ln_w   = (const float*)d_in[2];
    const float* spa_ln_b   = (const float*)d_in[3];
    const float* spa_in_w   = (const float*)d_in[4];
    const float* spa_conv_w = (const float*)d_in[5];
    const float* spa_conv_b = (const float*)d_in[6];
    const float* spa_dt_bias= (const float*)d_in[7];
    const float* spa_A_log  = (const float*)d_in[8];
    const float* spa_D      = (const float*)d_in[9];
    const float* spa_rms_w  = (const float*)d_in[10];
    const float* spa_out_w  = (const float*)d_in[11];
    const float* spe_ln_w   = (const float*)d_in[12];
    const float* spe_ln_b   = (const float*)d_in[13];
    const float* spe_in_w   = (const float*)d_in[14];
    const float* spe_conv_w = (const float*)d_in[15];
    const float* spe_conv_b = (const float*)d_in[16];
    const float* spe_dt_bias= (const float*)d_in[17];
    const float* spe_A_log  = (const float*)d_in[18];
    const float* spe_D      = (const float*)d_in[19];
    const float* spe_rms_w  = (const float*)d_in[20];
    const float* spe_out_w  = (const float*)d_in[21];
    const float* norm_w     = (const float*)d_in[22];
    const float* norm_b     = (const float*)d_in[23];
    const float* cprj_w     = (const float*)d_in[24];
    const float* cprj_b     = (const float*)d_in[25];
    const float* aq_w       = (const float*)d_in[26];
    const float* aq_b       = (const float*)d_in[27];
    const float* ak_w       = (const float*)d_in[28];
    const float* ak_b       = (const float*)d_in[29];
    const float* av_w       = (const float*)d_in[30];
    const float* av_b       = (const float*)d_in[31];
    const float* ao_w       = (const float*)d_in[32];
    const float* ao_b       = (const float*)d_in[33];
    const float* sq_w       = (const float*)d_in[34];
    const float* sq_b       = (const float*)d_in[35];
    const float* sk_w       = (const float*)d_in[36];
    const float* sk_b       = (const float*)d_in[37];
    const float* sv_w       = (const float*)d_in[38];
    const float* sv_b       = (const float*)d_in[39];
    const float* so_w       = (const float*)d_in[40];
    const float* so_b       = (const float*)d_in[41];
    const float* ds_conv_w  = (const float*)d_in[42];
    const float* ds_ln_w    = (const float*)d_in[43];
    const float* ds_ln_b    = (const float*)d_in[44];

    float* ws = (float*)d_ws;
    float* xs   = ws + 0;        // 524288
    float* lnb_ = ws + 524288;   // 524288 (xT/clbuf/xt live here when lnb_ dead)
    float* zx   = ws + 1048576;  // -> 3686400
    float* xc   = ws + 3686400;  // -> 5259264
    float* dtb  = ws + 5259264;  // 32768
    float* dAb  = ws + 5292032;  // 32768 (holds log-dA)
    float* yb   = ws + 5324800;  // 1048576 -> 6373376
    float* gb   = ws + 6373376;  // 1048576 -> 7421952 (S buffer / h1t alias)
    float* h1   = ws + 7421952;  // 524288 -> 7946240
    float* clbuf = ws + 524288;  // 16384, inside dead lnb_ during scan stages
    float* xT    = ws + 524288;  // 524288, inside lnb_ (dead until first k_ln)
    float* h1t   = ws + 6373376; // 524288, inside gb (dead between gate & ssd)
    // attention-stage aliases (host regions dead post-loop)
    float* kb    = ws + 1048576;
    float* vb    = ws + 1572864;
    float* attnb = ws + 2097152;
    float* qb    = ws + 2129920;
    float* xt    = ws + 524288;  // lnb_ region, dead post-loop
    float* q2    = ws + 3686400;
    float* k2t   = ws + 4210688;
    float* v2    = ws + 4734976;
    float* attn2 = ws + 5324800;
    float* xr    = ws + 5586944;
    float* owt   = ws + 7421952; // h1 region, dead post-loop
    float* sowt  = ws + 7438336; // 65536 -> 7503872
    float* col   = ws + 6111232; // -> 7290880
    float* part  = ws + 7290880; // -> 7815168

    // coalesce the embed gather: xT[b][p][c] = x[b][c][p]
    k_tr<<<dim3(8, 4, 16), 256, 0, stream>>>(x, xT, 128, 256);
    k_embed<<<4096, 128, 0, stream>>>(xT, sidx, xs);

    for (int i = 0; i < 2; i++){
        // ---- spatial mamba (L=256, nh=4, nc=4) ----
        k_ln<<<4096, 128, 0, stream>>>(xs, spa_ln_w + i * 128, spa_ln_b + i * 128, lnb_, 128);
        k_gemm<<<dim3(11, 64), 256, 0, stream>>>(lnb_, spa_in_w + (size_t)i * 644 * 128,
                                                 nullptr, nullptr, zx, 4096, 644, 128, 0);
        k_conv<<<4096, 256, 0, stream>>>(zx, spa_conv_w + (size_t)i * 384 * 4,
                                         spa_conv_b + i * 384, xc,
                                         spa_dt_bias + i * 4, spa_A_log + i * 4, dtb, dAb,
                                         256, 384, 644, 256, 4, 640);
        k_ssd_chunk<<<256, 256, 0, stream>>>(xc, dtb, dAb, yb, gb, clbuf,
                                             256, 4, 4, 384, 256, 320, 256);
        k_chunk_y<<<256, 256, 0, stream>>>(xc, gb, clbuf, spa_D + i * 4, yb,
                                           256, 4, 4, 384, 320, 256);
        k_gate<<<4096, 256, 0, stream>>>(yb, zx, spa_rms_w + i * 256, gb, 256, 644);
        k_gemm<<<dim3(2, 64), 256, 0, stream>>>(gb, spa_out_w + (size_t)i * 128 * 256,
                                                nullptr, xs, h1, 4096, 128, 256, 1);
        // ---- spectral mamba (L=128, nh=8, nc=2) ----
        k_tr<<<dim3(4, 8, 16), 256, 0, stream>>>(h1, h1t, 256, 128);
        k_ln<<<2048, 256, 0, stream>>>(h1t, spe_ln_w + i * 256, spe_ln_b + i * 256,
                                       lnb_, 256);
        k_gemm<<<dim3(19, 32), 256, 0, stream>>>(lnb_, spe_in_w + (size_t)i * 1160 * 256,
                                                 nullptr, nullptr, zx, 2048, 1160, 256, 0);
        k_conv<<<2048, 256, 0, stream>>>(zx, spe_conv_w + (size_t)i * 640 * 4,
                                         spe_conv_b + i * 640, xc,
                                         spe_dt_bias + i * 8, spe_A_log + i * 8, dtb, dAb,
                                         128, 640, 1160, 512, 8, 1152);
        k_ssd_chunk<<<256, 256, 0, stream>>>(xc, dtb, dAb, yb, gb, clbuf,
                                             128, 8, 2, 640, 512, 576, 512);
        k_chunk_y<<<256, 256, 0, stream>>>(xc, gb, clbuf, spe_D + i * 8, yb,
                                           128, 8, 2, 640, 576, 512);
        k_gate<<<2048, 256, 0, stream>>>(yb, zx, spe_rms_w + i * 512, gb, 512, 1160);
        k_gemm<<<dim3(4, 32), 256, 0, stream>>>(gb, spe_out_w + (size_t)i * 256 * 512,
                                                nullptr, h1, xs, 2048, 256, 512, 2);
    }

    // weight transposes for coalesced attention epilogues (h1 region now dead)
    k_tr<<<dim3(4, 4, 1), 256, 0, stream>>>(ao_w, owt, 128, 128);
    k_tr<<<dim3(8, 8, 1), 256, 0, stream>>>(so_w, sowt, 256, 256);

    k_ln<<<4096, 128, 0, stream>>>(xs, norm_w, norm_b, xs, 128);
    k_center_q<<<16, 128, 0, stream>>>(xs, cprj_w, cprj_b, aq_w, aq_b, qb);
    {
        GJob jk = {ak_w, ak_b, kb, 0};
        GJob jv = {av_w, av_b, vb, 0};
        k_gemm3<<<dim3(2, 64, 2), 256, 0, stream>>>(xs, jk, jv, jk, 128, 128);
    }
    k_attn<<<128, 256, 0, stream>>>(qb, kb, attnb);
    k_attn_out<<<512, 128, 0, stream>>>(vb, attnb, owt, ao_b, xs);
    // ---- spectral attention: transpose xs, one 3-output GEMM ----
    k_tr<<<dim3(4, 8, 16), 256, 0, stream>>>(xs, xt, 256, 128);
    {
        GJob jq = {sq_w, sq_b, q2, 0};
        GJob jk = {sk_w, sk_b, k2t, 3};
        GJob jv = {sv_w, sv_b, v2, 0};
        k_gemm3<<<dim3(4, 32, 3), 256, 0, stream>>>(xt, jq, jk, jv, 256, 256);
    }
    k_attn2<<<256, 128, 0, stream>>>(q2, k2t, attn2);
    k_av_so<<<256, 256, 0, stream>>>(attn2, v2, sowt, so_b, xs, sidx, xr);
    k_im2col<<<1024, 128, 0, stream>>>(xr, col);
    k_conv_gemm<<<dim3(2, 16, 4), 256, 0, stream>>>(col, ds_conv_w, part);
    k_part_ln<<<1024, 128, 0, stream>>>(part, ds_ln_w, ds_ln_b, (float*)d_out);
}

// Round 10
// 639.385 us; speedup vs baseline: 1.6653x; 1.0342x over previous
//
#include <hip/hip_runtime.h>
#include <math.h>

#define DEV __device__ __forceinline__

DEV float siluf(float x){ return x / (1.f + __expf(-x)); }
DEV float softplusf(float x){ return (x > 20.f) ? x : log1pf(__expf(x)); }

// ---------- block reduction helpers (wave64) ----------
DEV void blk_sum2(float &a, float &b, float* sm){
    int lane = threadIdx.x & 63, wid = threadIdx.x >> 6, nw = blockDim.x >> 6;
    #pragma unroll
    for (int off = 32; off; off >>= 1){ a += __shfl_down(a, off); b += __shfl_down(b, off); }
    if (lane == 0){ sm[wid] = a; sm[8 + wid] = b; }
    __syncthreads();
    float ra = 0.f, rb = 0.f;
    for (int i = 0; i < nw; i++){ ra += sm[i]; rb += sm[8 + i]; }
    __syncthreads();
    a = ra; b = rb;
}
DEV float blk_sum1(float v, float* sm){
    int lane = threadIdx.x & 63, wid = threadIdx.x >> 6, nw = blockDim.x >> 6;
    #pragma unroll
    for (int off = 32; off; off >>= 1) v += __shfl_down(v, off);
    if (lane == 0) sm[wid] = v;
    __syncthreads();
    float r = 0.f;
    for (int i = 0; i < nw; i++) r += sm[i];
    __syncthreads();
    return r;
}
DEV float blk_max1(float v, float* sm){
    int lane = threadIdx.x & 63, wid = threadIdx.x >> 6, nw = blockDim.x >> 6;
    #pragma unroll
    for (int off = 32; off; off >>= 1) v = fmaxf(v, __shfl_down(v, off));
    if (lane == 0) sm[wid] = v;
    __syncthreads();
    float r = -3.4e38f;
    for (int i = 0; i < nw; i++) r = fmaxf(r, sm[i]);
    __syncthreads();
    return r;
}

// ---------- transpose body ----------
DEV void tr_body(const float* __restrict__ ip, float* __restrict__ op,
                 int R, int C, int c0, int r0){
    __shared__ float tile[32][33];
    int tx = threadIdx.x & 31, ty = threadIdx.x >> 5;
    #pragma unroll
    for (int rr = ty; rr < 32; rr += 8)
        tile[rr][tx] = ip[(size_t)(r0 + rr) * C + c0 + tx];
    __syncthreads();
    #pragma unroll
    for (int rr = ty; rr < 32; rr += 8)
        op[(size_t)(c0 + rr) * R + r0 + tx] = tile[tx][rr];
}

// batched transpose: out[z][c*R+r] = in[z][r*C+c]; grid (C/32, R/32, batch)
__global__ __launch_bounds__(256) void k_tr(const float* __restrict__ in,
                                            float* __restrict__ out, int R, int C){
    tr_body(in + (size_t)blockIdx.z * R * C, out + (size_t)blockIdx.z * R * C,
            R, C, blockIdx.x * 32, blockIdx.y * 32);
}

// packed: job0 x->xT (128x256, batch16, 512 blks), job1 ao_w (16), job2 so_w (64)
__global__ __launch_bounds__(256) void k_tr_multi(const float* __restrict__ x,
        float* __restrict__ xT, const float* __restrict__ aow, float* __restrict__ owt,
        const float* __restrict__ sow, float* __restrict__ sowt){
    int idx = blockIdx.x;
    if (idx < 512){
        int bx = idx & 7, by = (idx >> 3) & 3, bz = idx >> 5;
        tr_body(x + (size_t)bz * 32768, xT + (size_t)bz * 32768, 128, 256, bx * 32, by * 32);
    } else if (idx < 528){
        int l = idx - 512;
        tr_body(aow, owt, 128, 128, (l & 3) * 32, (l >> 2) * 32);
    } else {
        int l = idx - 528;
        tr_body(sow, sowt, 256, 256, (l & 7) * 32, (l >> 3) * 32);
    }
}

// ---------- K1: pos-embed + gather (xT = x pre-transposed to [b][p][c]) ----------
__global__ void k_embed(const float* __restrict__ xT, const int* __restrict__ sidx,
                        float* __restrict__ xs){
    int bl = blockIdx.x; int b = bl >> 8; int c = threadIdx.x;
    int p = sidx[bl];
    int hh = p >> 4, ww = p & 15;
    int pos = (c < 64) ? hh : ww;
    int jm = c & 63;
    float om = __expf(-(float)(jm & 31) * 0.28782313662425574f); // ln(10000)/32
    float ang = (float)pos * om;
    float pe = (jm < 32) ? sinf(ang) : cosf(ang);
    xs[(size_t)bl * 128 + c] = xT[((size_t)(b * 256 + p)) * 128 + c] + pe;
}

// ---------- LayerNorm (block per row) ----------
__global__ void k_ln(const float* __restrict__ in, const float* __restrict__ w,
                     const float* __restrict__ bb, float* __restrict__ out, int dim){
    __shared__ float sm[16];
    int row = blockIdx.x, t = threadIdx.x;
    float v = in[(size_t)row * dim + t];
    float a = v, q = v * v;
    blk_sum2(a, q, sm);
    float inv = 1.f / (float)dim;
    float mu = a * inv;
    float var = q * inv - mu * mu;
    float rs = rsqrtf(var + 1e-5f);
    out[(size_t)row * dim + t] = (v - mu) * rs * w[t] + bb[t];
}

// ---------- in-projection GEMM with fused LayerNorm over K ----------
// out[r,j] = sum_k LN(A)[r,k] * W[j,k].  K%32==0.
__global__ __launch_bounds__(256) void k_gemm_ln(const float* __restrict__ A,
        const float* __restrict__ W, const float* __restrict__ lw,
        const float* __restrict__ lb, float* __restrict__ out, int N, int K){
    __shared__ float lds[2][32][68];
    int j0 = blockIdx.x * 64, r0 = blockIdx.y * 64;
    int tid = threadIdx.x;
    int cg = tid & 15, rg = tid >> 4;
    int row = tid >> 2, kg = tid & 3;
    int wrow = j0 + row; if (wrow > N - 1) wrow = N - 1;
    const float* Ar = A + (size_t)(r0 + row) * K;
    // phase 0: LN stats (each thread covers disjoint k of its row; 4 lanes/row)
    float s = 0.f, ss = 0.f;
    for (int k0 = 0; k0 < K; k0 += 32){
        float4 a0 = *(const float4*)(Ar + k0 + kg * 4);
        float4 a1 = *(const float4*)(Ar + k0 + 16 + kg * 4);
        s  += a0.x + a0.y + a0.z + a0.w + a1.x + a1.y + a1.z + a1.w;
        ss += a0.x*a0.x + a0.y*a0.y + a0.z*a0.z + a0.w*a0.w
            + a1.x*a1.x + a1.y*a1.y + a1.z*a1.z + a1.w*a1.w;
    }
    s  += __shfl_xor(s, 1);  ss += __shfl_xor(ss, 1);
    s  += __shfl_xor(s, 2);  ss += __shfl_xor(ss, 2);
    float inv = 1.f / (float)K;
    float mu = s * inv;
    float rs = rsqrtf(ss * inv - mu * mu + 1e-5f);
    float acc[4][4] = {};
    for (int k0 = 0; k0 < K; k0 += 32){
        float4 a0 = *(const float4*)(Ar + k0 + kg * 4);
        float4 a1 = *(const float4*)(Ar + k0 + 16 + kg * 4);
        float4 w0 = *(const float4*)(lw + k0 + kg * 4);
        float4 w1 = *(const float4*)(lw + k0 + 16 + kg * 4);
        float4 b0 = *(const float4*)(lb + k0 + kg * 4);
        float4 b1 = *(const float4*)(lb + k0 + 16 + kg * 4);
        const float* Wp = W + (size_t)wrow * K + k0 + kg * 4;
        float4 v0 = *(const float4*)(Wp);
        float4 v1 = *(const float4*)(Wp + 16);
        a0.x = (a0.x - mu) * rs * w0.x + b0.x; a0.y = (a0.y - mu) * rs * w0.y + b0.y;
        a0.z = (a0.z - mu) * rs * w0.z + b0.z; a0.w = (a0.w - mu) * rs * w0.w + b0.w;
        a1.x = (a1.x - mu) * rs * w1.x + b1.x; a1.y = (a1.y - mu) * rs * w1.y + b1.y;
        a1.z = (a1.z - mu) * rs * w1.z + b1.z; a1.w = (a1.w - mu) * rs * w1.w + b1.w;
        __syncthreads();
        lds[0][kg * 4 + 0][row] = a0.x; lds[0][kg * 4 + 1][row] = a0.y;
        lds[0][kg * 4 + 2][row] = a0.z; lds[0][kg * 4 + 3][row] = a0.w;
        lds[0][16 + kg * 4 + 0][row] = a1.x; lds[0][16 + kg * 4 + 1][row] = a1.y;
        lds[0][16 + kg * 4 + 2][row] = a1.z; lds[0][16 + kg * 4 + 3][row] = a1.w;
        lds[1][kg * 4 + 0][row] = v0.x; lds[1][kg * 4 + 1][row] = v0.y;
        lds[1][kg * 4 + 2][row] = v0.z; lds[1][kg * 4 + 3][row] = v0.w;
        lds[1][16 + kg * 4 + 0][row] = v1.x; lds[1][16 + kg * 4 + 1][row] = v1.y;
        lds[1][16 + kg * 4 + 2][row] = v1.z; lds[1][16 + kg * 4 + 3][row] = v1.w;
        __syncthreads();
        #pragma unroll
        for (int kk = 0; kk < 32; kk++){
            float4 a4 = *(const float4*)(&lds[0][kk][rg << 2]);
            float4 w4 = *(const float4*)(&lds[1][kk][cg << 2]);
            float av_[4] = {a4.x, a4.y, a4.z, a4.w};
            float wv_[4] = {w4.x, w4.y, w4.z, w4.w};
            #pragma unroll
            for (int ri = 0; ri < 4; ri++)
                #pragma unroll
                for (int ci = 0; ci < 4; ci++)
                    acc[ri][ci] = fmaf(av_[ri], wv_[ci], acc[ri][ci]);
        }
    }
    #pragma unroll
    for (int ri = 0; ri < 4; ri++){
        int r = r0 + (rg << 2) + ri;
        int j = j0 + (cg << 2);
        if (j < N){
            float4 v = make_float4(acc[ri][0], acc[ri][1], acc[ri][2], acc[ri][3]);
            *(float4*)(&out[(size_t)r * N + j]) = v;
        }
    }
}

// ---------- out-projection GEMM with fused gate (silu) + RMSNorm ----------
// v[r,k] = y[r,k]*silu(z[r,k]); scale[r] = rsqrt(mean_k v^2 + 1e-5)
// out = scale[r] * sum_k (v[r,k]*rw[k]) * W[j,k]  (+res epilogue)
// mode 1: out[r*N+j] = . + res[r*N+j]
// mode 2: transposed scatter (N==256): out[((r0>>7)*256+j)*128+(r&127)] = . + res[same]
__global__ __launch_bounds__(256) void k_gemm_gate(const float* __restrict__ Y,
        const float* __restrict__ Z, const float* __restrict__ rw,
        const float* __restrict__ W, const float* __restrict__ res,
        float* __restrict__ out, int N, int K, int zs, int mode){
    __shared__ float lds[2][32][68];
    __shared__ float sscale[64];
    int j0 = blockIdx.x * 64, r0 = blockIdx.y * 64;
    int tid = threadIdx.x;
    int cg = tid & 15, rg = tid >> 4;
    int row = tid >> 2, kg = tid & 3;
    const float* Yr = Y + (size_t)(r0 + row) * K;
    const float* Zr = Z + (size_t)(r0 + row) * zs;
    float ssq = 0.f;
    float acc[4][4] = {};
    for (int k0 = 0; k0 < K; k0 += 32){
        float4 y0 = *(const float4*)(Yr + k0 + kg * 4);
        float4 y1 = *(const float4*)(Yr + k0 + 16 + kg * 4);
        float4 z0 = *(const float4*)(Zr + k0 + kg * 4);
        float4 z1 = *(const float4*)(Zr + k0 + 16 + kg * 4);
        float4 g0 = *(const float4*)(rw + k0 + kg * 4);
        float4 g1 = *(const float4*)(rw + k0 + 16 + kg * 4);
        const float* Wp = W + (size_t)(j0 + row) * K + k0 + kg * 4;
        float4 v0 = *(const float4*)(Wp);
        float4 v1 = *(const float4*)(Wp + 16);
        y0.x *= siluf(z0.x); y0.y *= siluf(z0.y); y0.z *= siluf(z0.z); y0.w *= siluf(z0.w);
        y1.x *= siluf(z1.x); y1.y *= siluf(z1.y); y1.z *= siluf(z1.z); y1.w *= siluf(z1.w);
        ssq += y0.x*y0.x + y0.y*y0.y + y0.z*y0.z + y0.w*y0.w
             + y1.x*y1.x + y1.y*y1.y + y1.z*y1.z + y1.w*y1.w;
        y0.x *= g0.x; y0.y *= g0.y; y0.z *= g0.z; y0.w *= g0.w;
        y1.x *= g1.x; y1.y *= g1.y; y1.z *= g1.z; y1.w *= g1.w;
        __syncthreads();
        lds[0][kg * 4 + 0][row] = y0.x; lds[0][kg * 4 + 1][row] = y0.y;
        lds[0][kg * 4 + 2][row] = y0.z; lds[0][kg * 4 + 3][row] = y0.w;
        lds[0][16 + kg * 4 + 0][row] = y1.x; lds[0][16 + kg * 4 + 1][row] = y1.y;
        lds[0][16 + kg * 4 + 2][row] = y1.z; lds[0][16 + kg * 4 + 3][row] = y1.w;
        lds[1][kg * 4 + 0][row] = v0.x; lds[1][kg * 4 + 1][row] = v0.y;
        lds[1][kg * 4 + 2][row] = v0.z; lds[1][kg * 4 + 3][row] = v0.w;
        lds[1][16 + kg * 4 + 0][row] = v1.x; lds[1][16 + kg * 4 + 1][row] = v1.y;
        lds[1][16 + kg * 4 + 2][row] = v1.z; lds[1][16 + kg * 4 + 3][row] = v1.w;
        __syncthreads();
        #pragma unroll
        for (int kk = 0; kk < 32; kk++){
            float4 a4 = *(const float4*)(&lds[0][kk][rg << 2]);
            float4 w4 = *(const float4*)(&lds[1][kk][cg << 2]);
            float av_[4] = {a4.x, a4.y, a4.z, a4.w};
            float wv_[4] = {w4.x, w4.y, w4.z, w4.w};
            #pragma unroll
            for (int ri = 0; ri < 4; ri++)
                #pragma unroll
                for (int ci = 0; ci < 4; ci++)
                    acc[ri][ci] = fmaf(av_[ri], wv_[ci], acc[ri][ci]);
        }
    }
    ssq += __shfl_xor(ssq, 1);
    ssq += __shfl_xor(ssq, 2);
    if ((tid & 3) == 0) sscale[row] = rsqrtf(ssq / (float)K + 1e-5f);
    __syncthreads();
    if (mode == 2){
        float (*T)[68] = (float (*)[68])lds;
        #pragma unroll
        for (int ri = 0; ri < 4; ri++){
            float sc = sscale[(rg << 2) + ri];
            #pragma unroll
            for (int ci = 0; ci < 4; ci++)
                T[(cg << 2) + ci][(rg << 2) + ri] = acc[ri][ci] * sc;
        }
        __syncthreads();
        int b2 = r0 >> 7, ii0 = r0 & 127;
        int jj = tid >> 2, seg = tid & 3;
        size_t base = ((size_t)(b2 * 256 + j0 + jj)) * 128 + ii0 + seg * 16;
        float* op = out + base;
        const float* rp = res + base;
        #pragma unroll
        for (int c = 0; c < 4; c++){
            float4 v = *(const float4*)(&T[jj][seg * 16 + c * 4]);
            float4 rv = *(const float4*)(rp + c * 4);
            v.x += rv.x; v.y += rv.y; v.z += rv.z; v.w += rv.w;
            *(float4*)(op + c * 4) = v;
        }
    } else {
        #pragma unroll
        for (int ri = 0; ri < 4; ri++){
            int r = r0 + (rg << 2) + ri;
            int j = j0 + (cg << 2);
            float sc = sscale[(rg << 2) + ri];
            float4 v = make_float4(acc[ri][0] * sc, acc[ri][1] * sc,
                                   acc[ri][2] * sc, acc[ri][3] * sc);
            float4 rv = *(const float4*)(&res[(size_t)r * N + j]);
            v.x += rv.x; v.y += rv.y; v.z += rv.z; v.w += rv.w;
            *(float4*)(&out[(size_t)r * N + j]) = v;
        }
    }
}

// ---------- generic 64x64 GEMM core (for qkv batch) ----------
DEV void gemm_core(const float* __restrict__ A, const float* __restrict__ W,
                   const float* __restrict__ bias, float* __restrict__ out,
                   int N, int K, int mode, int j0, int r0){
    __shared__ float lds[2][32][68];
    int tid = threadIdx.x;
    int cg = tid & 15, rg = tid >> 4;
    int row = tid >> 2, kg = tid & 3;
    int wrow = j0 + row; if (wrow > N - 1) wrow = N - 1;
    float acc[4][4] = {};
    for (int k0 = 0; k0 < K; k0 += 32){
        const float* Ap = A + (size_t)(r0 + row) * K + k0 + kg * 4;
        float4 a0 = *(const float4*)(Ap);
        float4 a1 = *(const float4*)(Ap + 16);
        const float* Wp = W + (size_t)wrow * K + k0 + kg * 4;
        float4 w0 = *(const float4*)(Wp);
        float4 w1 = *(const float4*)(Wp + 16);
        __syncthreads();
        lds[0][kg * 4 + 0][row] = a0.x; lds[0][kg * 4 + 1][row] = a0.y;
        lds[0][kg * 4 + 2][row] = a0.z; lds[0][kg * 4 + 3][row] = a0.w;
        lds[0][16 + kg * 4 + 0][row] = a1.x; lds[0][16 + kg * 4 + 1][row] = a1.y;
        lds[0][16 + kg * 4 + 2][row] = a1.z; lds[0][16 + kg * 4 + 3][row] = a1.w;
        lds[1][kg * 4 + 0][row] = w0.x; lds[1][kg * 4 + 1][row] = w0.y;
        lds[1][kg * 4 + 2][row] = w0.z; lds[1][kg * 4 + 3][row] = w0.w;
        lds[1][16 + kg * 4 + 0][row] = w1.x; lds[1][16 + kg * 4 + 1][row] = w1.y;
        lds[1][16 + kg * 4 + 2][row] = w1.z; lds[1][16 + kg * 4 + 3][row] = w1.w;
        __syncthreads();
        #pragma unroll
        for (int kk = 0; kk < 32; kk++){
            float4 a4 = *(const float4*)(&lds[0][kk][rg << 2]);
            float4 w4 = *(const float4*)(&lds[1][kk][cg << 2]);
            float av_[4] = {a4.x, a4.y, a4.z, a4.w};
            float wv_[4] = {w4.x, w4.y, w4.z, w4.w};
            #pragma unroll
            for (int ri = 0; ri < 4; ri++)
                #pragma unroll
                for (int ci = 0; ci < 4; ci++)
                    acc[ri][ci] = fmaf(av_[ri], wv_[ci], acc[ri][ci]);
        }
    }
    if (mode == 3){
        float (*T)[68] = (float (*)[68])lds;
        __syncthreads();
        #pragma unroll
        for (int ri = 0; ri < 4; ri++)
            #pragma unroll
            for (int ci = 0; ci < 4; ci++)
                T[(cg << 2) + ci][(rg << 2) + ri] = acc[ri][ci];
        __syncthreads();
        int b2 = r0 >> 7, ii0 = r0 & 127;
        int jj = tid >> 2, seg = tid & 3;
        size_t base = ((size_t)(b2 * 256 + j0 + jj)) * 128 + ii0 + seg * 16;
        float* op = out + base;
        float bj = bias[j0 + jj];
        #pragma unroll
        for (int c = 0; c < 4; c++){
            float4 v = *(const float4*)(&T[jj][seg * 16 + c * 4]);
            v.x += bj; v.y += bj; v.z += bj; v.w += bj;
            *(float4*)(op + c * 4) = v;
        }
    } else {
        #pragma unroll
        for (int ri = 0; ri < 4; ri++){
            int r = r0 + (rg << 2) + ri;
            int j = j0 + (cg << 2);
            float4 v = make_float4(acc[ri][0], acc[ri][1], acc[ri][2], acc[ri][3]);
            v.x += bias[j]; v.y += bias[j + 1]; v.z += bias[j + 2]; v.w += bias[j + 3];
            *(float4*)(&out[(size_t)r * N + j]) = v;
        }
    }
}

struct GJob { const float* W; const float* bias; float* out; int mode; };

__global__ __launch_bounds__(256) void k_gemm3(const float* __restrict__ A,
                                               GJob ja, GJob jb, GJob jc,
                                               int N, int K){
    GJob j = (blockIdx.z == 0) ? ja : ((blockIdx.z == 1) ? jb : jc);
    gemm_core(A, j.W, j.bias, j.out, N, K, j.mode, blockIdx.x * 64, blockIdx.y * 64);
}

// ---------- causal depthwise conv(4)+bias+silu, fused dt / log-dA ----------
__global__ void k_conv(const float* __restrict__ zx, const float* __restrict__ cw,
                       const float* __restrict__ cb, float* __restrict__ xc,
                       const float* __restrict__ dtbias, const float* __restrict__ Al,
                       float* __restrict__ dt, float* __restrict__ dlA,
                       int L, int D, int stride, int off, int nh, int dtoff){
    int bl = blockIdx.x;
    int l = bl & (L - 1);
    const float* base = zx + (size_t)bl * stride + off;
    for (int d = threadIdx.x; d < D; d += blockDim.x){
        float acc = cb[d];
        #pragma unroll
        for (int k = 0; k < 4; k++){
            int dl = l + k - 3;
            if (dl >= 0) acc += base[(ptrdiff_t)(k - 3) * stride + d] * cw[d * 4 + k];
        }
        xc[(size_t)bl * D + d] = siluf(acc);
    }
    int t = threadIdx.x;
    if (t < nh){
        float xv = zx[(size_t)bl * stride + dtoff + t] + dtbias[t];
        float d = softplusf(xv);
        dt[(size_t)bl * nh + t] = d;
        dlA[(size_t)bl * nh + t] = -d * __expf(Al[t]); // log(dA) <= 0
    }
}

// ---------- chunked SSD, stage A ----------
__global__ __launch_bounds__(256) void k_ssd_chunk(
        const float* __restrict__ xc, const float* __restrict__ dt,
        const float* __restrict__ dlA, float* __restrict__ y,
        float* __restrict__ S, float* __restrict__ clb,
        int L, int nh, int nc, int xcs, int bo, int co, int ys){
    __shared__ float sX[64][68];
    __shared__ float sB[64][68];
    __shared__ float sC[64][68]; // phase1: C ; after: masked G
    __shared__ float cl[64], sdt[64], sw[64];
    int blk = blockIdx.x;
    int c = blk % nc; int bh = blk / nc; int h = bh % nh; int b = bh / nh;
    int l0 = c * 64;
    int tid = threadIdx.x;
    const float* base = xc + ((size_t)(b * L + l0)) * xcs;
    for (int idx = tid; idx < 4096; idx += 256){
        int s = idx >> 6, n = idx & 63;
        const float* row = base + (size_t)s * xcs;
        sX[s][n] = row[h * 64 + n];
        sB[s][n] = row[bo + n];
        sC[s][n] = row[co + n];
    }
    if (tid < 64){
        size_t di = (size_t)(b * L + l0 + tid) * nh + h;
        float dlv = dlA[di];
        sdt[tid] = dt[di];
        #pragma unroll
        for (int off = 1; off < 64; off <<= 1){
            float o = __shfl_up(dlv, off, 64);
            if (tid >= off) dlv += o;
        }
        cl[tid] = dlv;
        clb[(size_t)blk * 64 + tid] = dlv;
    }
    __syncthreads();
    if (tid < 64) sw[tid] = __expf(cl[63] - cl[tid]) * sdt[tid];

    int g1 = tid >> 4, g2 = tid & 15;
    int t0 = g1 * 4, s0 = g2 * 4;
    float g[4][4] = {};
    for (int n = 0; n < 64; n += 4){
        float4 cv[4], bv[4];
        #pragma unroll
        for (int i = 0; i < 4; i++) cv[i] = *(const float4*)&sC[t0 + i][n];
        #pragma unroll
        for (int j = 0; j < 4; j++) bv[j] = *(const float4*)&sB[s0 + j][n];
        #pragma unroll
        for (int i = 0; i < 4; i++)
            #pragma unroll
            for (int j = 0; j < 4; j++){
                g[i][j] = fmaf(cv[i].x, bv[j].x, g[i][j]);
                g[i][j] = fmaf(cv[i].y, bv[j].y, g[i][j]);
                g[i][j] = fmaf(cv[i].z, bv[j].z, g[i][j]);
                g[i][j] = fmaf(cv[i].w, bv[j].w, g[i][j]);
            }
    }
    __syncthreads();
    #pragma unroll
    for (int i = 0; i < 4; i++)
        #pragma unroll
        for (int j = 0; j < 4; j++){
            int t = t0 + i, s = s0 + j;
            float v = 0.f;
            if (s <= t) v = g[i][j] * __expf(cl[t] - cl[s]) * sdt[s];
            sC[t][s] = v;
        }
    __syncthreads();
    {
        float acc[4][4] = {};
        for (int s = 0; s < 64; s++){
            float4 xv = *(const float4*)&sX[s][s0];
            float gv[4];
            #pragma unroll
            for (int i = 0; i < 4; i++) gv[i] = sC[t0 + i][s];
            #pragma unroll
            for (int i = 0; i < 4; i++){
                acc[i][0] = fmaf(gv[i], xv.x, acc[i][0]);
                acc[i][1] = fmaf(gv[i], xv.y, acc[i][1]);
                acc[i][2] = fmaf(gv[i], xv.z, acc[i][2]);
                acc[i][3] = fmaf(gv[i], xv.w, acc[i][3]);
            }
        }
        #pragma unroll
        for (int i = 0; i < 4; i++){
            float4 o = make_float4(acc[i][0], acc[i][1], acc[i][2], acc[i][3]);
            *(float4*)&y[(size_t)(b * L + l0 + t0 + i) * ys + h * 64 + s0] = o;
        }
    }
    {
        float acc[4][4] = {};
        int p0 = t0, n0 = s0;
        for (int s = 0; s < 64; s++){
            float wv = sw[s];
            float4 bv = *(const float4*)&sB[s][n0];
            float4 xv = *(const float4*)&sX[s][p0];
            float w0 = wv * xv.x, w1 = wv * xv.y, w2 = wv * xv.z, w3 = wv * xv.w;
            acc[0][0] = fmaf(w0, bv.x, acc[0][0]); acc[0][1] = fmaf(w0, bv.y, acc[0][1]);
            acc[0][2] = fmaf(w0, bv.z, acc[0][2]); acc[0][3] = fmaf(w0, bv.w, acc[0][3]);
            acc[1][0] = fmaf(w1, bv.x, acc[1][0]); acc[1][1] = fmaf(w1, bv.y, acc[1][1]);
            acc[1][2] = fmaf(w1, bv.z, acc[1][2]); acc[1][3] = fmaf(w1, bv.w, acc[1][3]);
            acc[2][0] = fmaf(w2, bv.x, acc[2][0]); acc[2][1] = fmaf(w2, bv.y, acc[2][1]);
            acc[2][2] = fmaf(w2, bv.z, acc[2][2]); acc[2][3] = fmaf(w2, bv.w, acc[2][3]);
            acc[3][0] = fmaf(w3, bv.x, acc[3][0]); acc[3][1] = fmaf(w3, bv.y, acc[3][1]);
            acc[3][2] = fmaf(w3, bv.z, acc[3][2]); acc[3][3] = fmaf(w3, bv.w, acc[3][3]);
        }
        float* Sp = S + (size_t)blk * 4096;
        #pragma unroll
        for (int i = 0; i < 4; i++){
            float4 o = make_float4(acc[i][0], acc[i][1], acc[i][2], acc[i][3]);
            *(float4*)&Sp[(p0 + i) * 64 + n0] = o;
        }
    }
}

// ---------- chunked SSD, stage B+C fused ----------
// h_init(c) = sum_{c'<c} S_{c'} * prod_{m=c'+1}^{c-1} dec_m  (nc <= 4)
// y += exp(cl[t]) * (C_t . h_init) + D*x
__global__ __launch_bounds__(256) void k_chunk_y(
        const float* __restrict__ xc, const float* __restrict__ S,
        const float* __restrict__ clb, const float* __restrict__ Dp,
        float* __restrict__ y,
        int L, int nh, int nc, int xcs, int co, int ys){
    __shared__ float sH[64][68];
    __shared__ float sC[64][68];
    __shared__ float scl[64];
    int blk = blockIdx.x;
    int c = blk % nc; int bh = blk / nc; int h = bh % nh; int b = bh / nh;
    int l0 = c * 64;
    int tid = threadIdx.x;
    float wch[4];
    {
        float w = 1.f;
        for (int cp = c - 1; cp >= 0; cp--){
            wch[cp] = w;
            w *= __expf(clb[((size_t)(bh * nc + cp)) * 64 + 63]);
        }
    }
    const float* Sb = S + (size_t)(bh * nc) * 4096;
    const float* base = xc + ((size_t)(b * L + l0)) * xcs;
    for (int idx = tid; idx < 4096; idx += 256){
        int r = idx >> 6, n = idx & 63;
        float hv = 0.f;
        for (int cp = 0; cp < c; cp++)
            hv = fmaf(wch[cp], Sb[(size_t)cp * 4096 + idx], hv);
        sH[r][n] = hv;
        sC[r][n] = base[(size_t)r * xcs + co + n];
    }
    if (tid < 64) scl[tid] = __expf(clb[(size_t)blk * 64 + tid]);
    float Dh = Dp[h];
    __syncthreads();
    int g1 = tid >> 4, g2 = tid & 15;
    int t0 = g1 * 4, p0 = g2 * 4;
    float m[4][4] = {};
    for (int n = 0; n < 64; n += 4){
        float4 cv[4], hv[4];
        #pragma unroll
        for (int i = 0; i < 4; i++) cv[i] = *(const float4*)&sC[t0 + i][n];
        #pragma unroll
        for (int j = 0; j < 4; j++) hv[j] = *(const float4*)&sH[p0 + j][n];
        #pragma unroll
        for (int i = 0; i < 4; i++)
            #pragma unroll
            for (int j = 0; j < 4; j++){
                m[i][j] = fmaf(cv[i].x, hv[j].x, m[i][j]);
                m[i][j] = fmaf(cv[i].y, hv[j].y, m[i][j]);
                m[i][j] = fmaf(cv[i].z, hv[j].z, m[i][j]);
                m[i][j] = fmaf(cv[i].w, hv[j].w, m[i][j]);
            }
    }
    #pragma unroll
    for (int i = 0; i < 4; i++){
        int t = t0 + i;
        size_t yi = (size_t)(b * L + l0 + t) * ys + h * 64 + p0;
        float4 yv = *(float4*)&y[yi];
        float4 xv = *(const float4*)&base[(size_t)t * xcs + h * 64 + p0];
        float e = scl[t];
        yv.x += e * m[i][0] + Dh * xv.x;
        yv.y += e * m[i][1] + Dh * xv.y;
        yv.z += e * m[i][2] + Dh * xv.z;
        yv.w += e * m[i][3] + Dh * xv.w;
        *(float4*)&y[yi] = yv;
    }
}

// ---------- center projection + q ----------
__global__ void k_center_q(const float* __restrict__ xs, const float* __restrict__ cw,
                           const float* __restrict__ cb, const float* __restrict__ qw,
                           const float* __restrict__ qb, float* __restrict__ q){
    __shared__ float xr[640];
    __shared__ float cen[128];
    int b = blockIdx.x, t = threadIdx.x; // 128 thr
    for (int idx = t; idx < 640; idx += 128)
        xr[idx] = xs[(size_t)b * 256 * 128 + idx];
    __syncthreads();
    float acc = cb[t];
    for (int c = 0; c < 128; c++){
        const float* wp = cw + (size_t)(t * 128 + c) * 5;
        #pragma unroll
        for (int l = 0; l < 5; l++) acc += xr[l * 128 + c] * wp[l];
    }
    cen[t] = acc;
    __syncthreads();
    float qa = qb[t];
    const float* wr = qw + (size_t)t * 128;
    for (int o = 0; o < 128; o++) qa += cen[o] * wr[o];
    q[b * 128 + t] = qa;
}

// ---------- attention softmax over l ----------
__global__ void k_attn(const float* __restrict__ q, const float* __restrict__ k,
                       float* __restrict__ attn){
    __shared__ float sm[16];
    __shared__ float qh[16];
    int blk = blockIdx.x; int b = blk >> 3, h = blk & 7; int l = threadIdx.x; // 256 thr
    if (l < 16) qh[l] = q[b * 128 + h * 16 + l];
    __syncthreads();
    const float* kp = k + ((size_t)(b * 256 + l)) * 128 + h * 16;
    float s = 0.f;
    #pragma unroll
    for (int d = 0; d < 16; d++) s += qh[d] * kp[d];
    s *= 0.25f;
    float mx = blk_max1(s, sm);
    float e = __expf(s - mx);
    float sum = blk_sum1(e, sm);
    attn[(size_t)blk * 256 + l] = e / sum;
}

// ---------- attention out, 8 l-rows per block ----------
__global__ __launch_bounds__(128) void k_attn_out(const float* __restrict__ v,
                                                  const float* __restrict__ attn,
                                                  const float* __restrict__ owt,
                                                  const float* __restrict__ ob,
                                                  float* __restrict__ xs){
    __shared__ float vp[8][128];
    int blk = blockIdx.x; int b = blk >> 5, l0 = (blk & 31) << 3;
    int t = threadIdx.x; // 128 thr
    int h = t >> 4;
    float a[8];
    #pragma unroll
    for (int r = 0; r < 8; r++)
        a[r] = attn[((size_t)(b * 8 + h)) * 256 + l0 + r];
    #pragma unroll
    for (int r = 0; r < 8; r++)
        vp[r][t] = v[((size_t)(b * 256 + l0 + r)) * 128 + t] * a[r];
    __syncthreads();
    float acc[8];
    float bv = ob[t];
    #pragma unroll
    for (int r = 0; r < 8; r++) acc[r] = bv;
    for (int j = 0; j < 128; j++){
        float w = owt[j * 128 + t];
        #pragma unroll
        for (int r = 0; r < 8; r++) acc[r] = fmaf(vp[r][j], w, acc[r]);
    }
    #pragma unroll
    for (int r = 0; r < 8; r++)
        xs[((size_t)(b * 256 + l0 + r)) * 128 + t] += acc[r];
}

// ---------- fused spectral attention: QK+softmax+AV+SO+residual+unsort ----------
__global__ __launch_bounds__(256) void k_spe_attn(const float* __restrict__ q2,
        const float* __restrict__ k2t, const float* __restrict__ v2,
        const float* __restrict__ sowt, const float* __restrict__ sob,
        const float* __restrict__ xs, const int* __restrict__ sidx,
        float* __restrict__ xr){
    __shared__ float qs[8][256];
    __shared__ float lgp[2][8][128];
    __shared__ float sa[8][132];
    __shared__ float av[8][256];
    __shared__ float mxs[8], sms[8];
    int blk = blockIdx.x; int b = blk >> 4; int i0 = (blk & 15) << 3;
    int t = threadIdx.x;
    for (int idx = t; idx < 2048; idx += 256){
        int ii = idx >> 8, d = idx & 255;
        qs[ii][d] = q2[((size_t)(b * 128 + i0 + ii)) * 256 + d];
    }
    __syncthreads();
    {
        int j = t & 127, dh = t >> 7;
        const float* kt = k2t + (size_t)b * 32768 + dh * 16384;
        float acc[8] = {};
        for (int dd = 0; dd < 128; dd++){
            float kv = kt[dd * 128 + j];
            int d = dh * 128 + dd;
            #pragma unroll
            for (int ii = 0; ii < 8; ii++) acc[ii] = fmaf(qs[ii][d], kv, acc[ii]);
        }
        #pragma unroll
        for (int ii = 0; ii < 8; ii++) lgp[dh][ii][j] = acc[ii];
    }
    __syncthreads();
    if (t < 128){
        #pragma unroll
        for (int ii = 0; ii < 8; ii++)
            sa[ii][t] = (lgp[0][ii][t] + lgp[1][ii][t]) * (1.f / 16.f);
    }
    __syncthreads();
    if (t < 8){
        float mx = -3.4e38f;
        for (int j = 0; j < 128; j++) mx = fmaxf(mx, sa[t][j]);
        float sm = 0.f;
        for (int j = 0; j < 128; j++) sm += __expf(sa[t][j] - mx);
        mxs[t] = mx; sms[t] = 1.f / sm;
    }
    __syncthreads();
    if (t < 128){
        #pragma unroll
        for (int ii = 0; ii < 8; ii++)
            sa[ii][t] = __expf(sa[ii][t] - mxs[ii]) * sms[ii];
    }
    __syncthreads();
    {
        float acc[8] = {};
        const float* vb = v2 + (size_t)b * 32768 + t;
        for (int j = 0; j < 128; j++){
            float vv = vb[(size_t)j * 256];
            #pragma unroll
            for (int ii = 0; ii < 8; ii++) acc[ii] = fmaf(sa[ii][j], vv, acc[ii]);
        }
        #pragma unroll
        for (int ii = 0; ii < 8; ii++) av[ii][t] = acc[ii];
    }
    __syncthreads();
    float acc[8] = {};
    for (int d = 0; d < 256; d++){
        float wv = sowt[d * 256 + t];
        #pragma unroll
        for (int ii = 0; ii < 8; ii++) acc[ii] = fmaf(av[ii][d], wv, acc[ii]);
    }
    float bias = sob[t];
    int p = sidx[b * 256 + t];
    const float* xin = xs + ((size_t)(b * 256 + t)) * 128 + i0;
    float* xout = xr + ((size_t)(b * 256 + p)) * 128 + i0;
    #pragma unroll
    for (int ii = 0; ii < 8; ii++) xout[ii] = xin[ii] + acc[ii] + bias;
}

// ---------- conv GEMM split-K=4 with fused im2col ----------
__global__ __launch_bounds__(256) void k_conv_gemm(const float* __restrict__ xr,
                                                   const float* __restrict__ W2,
                                                   float* __restrict__ part){
    __shared__ float As[16][68];
    __shared__ float Ws[16][64];
    int j0 = blockIdx.x * 64, r0 = blockIdx.y * 64, s = blockIdx.z;
    int tid = threadIdx.x;
    int cg = tid & 15, rg = tid >> 4;
    int arow = tid >> 2, akg = tid & 3;
    int r = r0 + arow; int b = r >> 6, oh = (r >> 3) & 7, ow = r & 7;
    float acc[4][4] = {};
    int kbeg = s * 288, kend = kbeg + 288;
    for (int k0 = kbeg; k0 < kend; k0 += 16){
        {
            int k = k0 + akg * 4;
            int khw = k >> 7, c = k & 127;
            int kh = khw / 3, kw = khw - kh * 3;
            int ih = oh * 2 - 1 + kh, iw = ow * 2 - 1 + kw;
            float4 a4 = make_float4(0.f, 0.f, 0.f, 0.f);
            if (ih >= 0 && ih < 16 && iw >= 0 && iw < 16)
                a4 = *(const float4*)(xr + ((size_t)((b << 8) + (ih << 4) + iw)) * 128 + c);
            As[akg * 4 + 0][arow] = a4.x; As[akg * 4 + 1][arow] = a4.y;
            As[akg * 4 + 2][arow] = a4.z; As[akg * 4 + 3][arow] = a4.w;
        }
        #pragma unroll
        for (int it = 0; it < 4; it++){
            int idx = tid + it * 256;
            int jj = idx & 63, kk = idx >> 6;
            Ws[kk][jj] = W2[(size_t)(k0 + kk) * 128 + j0 + jj];
        }
        __syncthreads();
        #pragma unroll
        for (int kk = 0; kk < 16; kk++){
            float4 a4 = *(const float4*)(&As[kk][rg << 2]);
            float4 w4 = *(const float4*)(&Ws[kk][cg << 2]);
            float av_[4] = {a4.x, a4.y, a4.z, a4.w};
            float wv_[4] = {w4.x, w4.y, w4.z, w4.w};
            #pragma unroll
            for (int ri = 0; ri < 4; ri++)
                #pragma unroll
                for (int ci = 0; ci < 4; ci++)
                    acc[ri][ci] = fmaf(av_[ri], wv_[ci], acc[ri][ci]);
        }
        __syncthreads();
    }
    float* pp = part + (size_t)s * 1024 * 128;
    #pragma unroll
    for (int ri = 0; ri < 4; ri++){
        int rr = r0 + (rg << 2) + ri;
        #pragma unroll
        for (int ci = 0; ci < 4; ci++){
            int j = j0 + (cg << 2) + ci;
            pp[(size_t)rr * 128 + j] = acc[ri][ci];
        }
    }
}

// ---------- reduce split-K partials + LayerNorm ----------
__global__ void k_part_ln(const float* __restrict__ part, const float* __restrict__ lnw,
                          const float* __restrict__ lnb, float* __restrict__ out){
    __shared__ float sm[16];
    int r = blockIdx.x, t = threadIdx.x; // 128 thr
    float v = part[(size_t)r * 128 + t]
            + part[(size_t)(1024 + r) * 128 + t]
            + part[(size_t)(2048 + r) * 128 + t]
            + part[(size_t)(3072 + r) * 128 + t];
    float a = v, q = v * v;
    blk_sum2(a, q, sm);
    float mu = a * (1.f / 128.f);
    float var = q * (1.f / 128.f) - mu * mu;
    float rs = rsqrtf(var + 1e-5f);
    out[(size_t)r * 128 + t] = (v - mu) * rs * lnw[t] + lnb[t];
}

extern "C" void kernel_launch(void* const* d_in, const int* in_sizes, int n_in,
                              void* d_out, int out_size, void* d_ws, size_t ws_size,
                              hipStream_t stream) {
    const float* x          = (const float*)d_in[0];
    const int*   sidx       = (const int*)  d_in[1];
    const float* spa_ln_w   = (const float*)d_in[2];
    const float* spa_ln_b   = (const float*)d_in[3];
    const float* spa_in_w   = (const float*)d_in[4];
    const float* spa_conv_w = (const float*)d_in[5];
    const float* spa_conv_b = (const float*)d_in[6];
    const float* spa_dt_bias= (const float*)d_in[7];
    const float* spa_A_log  = (const float*)d_in[8];
    const float* spa_D      = (const float*)d_in[9];
    const float* spa_rms_w  = (const float*)d_in[10];
    const float* spa_out_w  = (const float*)d_in[11];
    const float* spe_ln_w   = (const float*)d_in[12];
    const float* spe_ln_b   = (const float*)d_in[13];
    const float* spe_in_w   = (const float*)d_in[14];
    const float* spe_conv_w = (const float*)d_in[15];
    const float* spe_conv_b = (const float*)d_in[16];
    const float* spe_dt_bias= (const float*)d_in[17];
    const float* spe_A_log  = (const float*)d_in[18];
    const float* spe_D      = (const float*)d_in[19];
    const float* spe_rms_w  = (const float*)d_in[20];
    const float* spe_out_w  = (const float*)d_in[21];
    const float* norm_w     = (const float*)d_in[22];
    const float* norm_b     = (const float*)d_in[23];
    const float* cprj_w     = (const float*)d_in[24];
    const float* cprj_b     = (const float*)d_in[25];
    const float* aq_w       = (const float*)d_in[26];
    const float* aq_b       = (const float*)d_in[27];
    const float* ak_w       = (const float*)d_in[28];
    const float* ak_b       = (const float*)d_in[29];
    const float* av_w       = (const float*)d_in[30];
    const float* av_b       = (const float*)d_in[31];
    const float* ao_w       = (const float*)d_in[32];
    const float* ao_b       = (const float*)d_in[33];
    const float* sq_w       = (const float*)d_in[34];
    const float* sq_b       = (const float*)d_in[35];
    const float* sk_w       = (const float*)d_in[36];
    const float* sk_b       = (const float*)d_in[37];
    const float* sv_w       = (const float*)d_in[38];
    const float* sv_b       = (const float*)d_in[39];
    const float* so_w       = (const float*)d_in[40];
    const float* so_b       = (const float*)d_in[41];
    const float* ds_conv_w  = (const float*)d_in[42];
    const float* ds_ln_w    = (const float*)d_in[43];
    const float* ds_ln_b    = (const float*)d_in[44];

    float* ws = (float*)d_ws;
    // loop-live arena: 0 .. 7946240
    float* xs   = ws + 0;        // 524288
    float* zx   = ws + 1048576;  // -> 3686400
    float* xc   = ws + 3686400;  // -> 5259264
    float* dtb  = ws + 5259264;  // 32768
    float* dAb  = ws + 5292032;  // 32768 (log-dA)
    float* yb   = ws + 5324800;  // -> 6373376
    float* Sbuf = ws + 6373376;  // -> 7421952
    float* h1   = ws + 7421952;  // -> 7946240
    float* clbuf = ws + 524288;  // in scratch region (dead between uses)
    float* xT    = ws + 524288;  // scratch (dead after k_embed)
    float* h1t   = ws + 6373376; // in Sbuf (dead before S writes)
    // weight transposes: PAST the loop-live arena (h1 writes clobbered them in R9!)
    float* owt   = ws + 7946240; // 16384 -> 7962624
    float* sowt  = ws + 7962624; // 65536 -> 8028160
    // attention-stage aliases (host regions dead post-loop)
    float* kb    = ws + 1048576;
    float* vb    = ws + 1572864;
    float* attnb = ws + 2097152;
    float* qb    = ws + 2129920;
    float* xt    = ws + 524288;
    float* q2    = ws + 3686400;
    float* k2t   = ws + 4210688;
    float* v2    = ws + 4734976;
    float* xr    = ws + 5586944; // -> 6111232
    float* part  = ws + 1048576; // 524288 -> 1572864 (kb/vb dead by conv_gemm)

    k_tr_multi<<<592, 256, 0, stream>>>(x, xT, ao_w, owt, so_w, sowt);
    k_embed<<<4096, 128, 0, stream>>>(xT, sidx, xs);

    for (int i = 0; i < 2; i++){
        // ---- spatial mamba (L=256, nh=4, nc=4) ----
        k_gemm_ln<<<dim3(11, 64), 256, 0, stream>>>(xs, spa_in_w + (size_t)i * 644 * 128,
                                                    spa_ln_w + i * 128, spa_ln_b + i * 128,
                                                    zx, 644, 128);
        k_conv<<<4096, 256, 0, stream>>>(zx, spa_conv_w + (size_t)i * 384 * 4,
                                         spa_conv_b + i * 384, xc,
                                         spa_dt_bias + i * 4, spa_A_log + i * 4, dtb, dAb,
                                         256, 384, 644, 256, 4, 640);
        k_ssd_chunk<<<256, 256, 0, stream>>>(xc, dtb, dAb, yb, Sbuf, clbuf,
                                             256, 4, 4, 384, 256, 320, 256);
        k_chunk_y<<<256, 256, 0, stream>>>(xc, Sbuf, clbuf, spa_D + i * 4, yb,
                                           256, 4, 4, 384, 320, 256);
        k_gemm_gate<<<dim3(2, 64), 256, 0, stream>>>(yb, zx, spa_rms_w + i * 256,
                                                     spa_out_w + (size_t)i * 128 * 256,
                                                     xs, h1, 128, 256, 644, 1);
        // ---- spectral mamba (L=128, nh=8, nc=2) ----
        k_tr<<<dim3(4, 8, 16), 256, 0, stream>>>(h1, h1t, 256, 128);
        k_gemm_ln<<<dim3(19, 32), 256, 0, stream>>>(h1t, spe_in_w + (size_t)i * 1160 * 256,
                                                    spe_ln_w + i * 256, spe_ln_b + i * 256,
                                                    zx, 1160, 256);
        k_conv<<<2048, 256, 0, stream>>>(zx, spe_conv_w + (size_t)i * 640 * 4,
                                         spe_conv_b + i * 640, xc,
                                         spe_dt_bias + i * 8, spe_A_log + i * 8, dtb, dAb,
                                         128, 640, 1160, 512, 8, 1152);
        k_ssd_chunk<<<256, 256, 0, stream>>>(xc, dtb, dAb, yb, Sbuf, clbuf,
                                             128, 8, 2, 640, 512, 576, 512);
        k_chunk_y<<<256, 256, 0, stream>>>(xc, Sbuf, clbuf, spe_D + i * 8, yb,
                                           128, 8, 2, 640, 576, 512);
        k_gemm_gate<<<dim3(4, 32), 256, 0, stream>>>(yb, zx, spe_rms_w + i * 512,
                                                     spe_out_w + (size_t)i * 256 * 512,
                                                     h1, xs, 256, 512, 1160, 2);
    }

    k_ln<<<4096, 128, 0, stream>>>(xs, norm_w, norm_b, xs, 128);
    k_center_q<<<16, 128, 0, stream>>>(xs, cprj_w, cprj_b, aq_w, aq_b, qb);
    {
        GJob jk = {ak_w, ak_b, kb, 0};
        GJob jv = {av_w, av_b, vb, 0};
        k_gemm3<<<dim3(2, 64, 2), 256, 0, stream>>>(xs, jk, jv, jk, 128, 128);
    }
    k_attn<<<128, 256, 0, stream>>>(qb, kb, attnb);
    k_attn_out<<<512, 128, 0, stream>>>(vb, attnb, owt, ao_b, xs);
    k_tr<<<dim3(4, 8, 16), 256, 0, stream>>>(xs, xt, 256, 128);
    {
        GJob jq = {sq_w, sq_b, q2, 0};
        GJob jk = {sk_w, sk_b, k2t, 3};
        GJob jv = {sv_w, sv_b, v2, 0};
        k_gemm3<<<dim3(4, 32, 3), 256, 0, stream>>>(xt, jq, jk, jv, 256, 256);
    }
    k_spe_attn<<<256, 256, 0, stream>>>(q2, k2t, v2, sowt, so_b, xs, sidx, xr);
    k_conv_gemm<<<dim3(2, 16, 4), 256, 0, stream>>>(xr, ds_conv_w, part);
    k_part_ln<<<1024, 128, 0, stream>>>(part, ds_ln_w, ds_ln_b, (float*)d_out);
}

// Round 11
// 611.598 us; speedup vs baseline: 1.7409x; 1.0454x over previous
//
#include <hip/hip_runtime.h>
#include <math.h>

#define DEV __device__ __forceinline__

DEV float siluf(float x){ return x / (1.f + __expf(-x)); }
DEV float softplusf(float x){ return (x > 20.f) ? x : log1pf(__expf(x)); }

// ---------- block reduction helpers (wave64) ----------
DEV void blk_sum2(float &a, float &b, float* sm){
    int lane = threadIdx.x & 63, wid = threadIdx.x >> 6, nw = blockDim.x >> 6;
    #pragma unroll
    for (int off = 32; off; off >>= 1){ a += __shfl_down(a, off); b += __shfl_down(b, off); }
    if (lane == 0){ sm[wid] = a; sm[8 + wid] = b; }
    __syncthreads();
    float ra = 0.f, rb = 0.f;
    for (int i = 0; i < nw; i++){ ra += sm[i]; rb += sm[8 + i]; }
    __syncthreads();
    a = ra; b = rb;
}
DEV float blk_sum1(float v, float* sm){
    int lane = threadIdx.x & 63, wid = threadIdx.x >> 6, nw = blockDim.x >> 6;
    #pragma unroll
    for (int off = 32; off; off >>= 1) v += __shfl_down(v, off);
    if (lane == 0) sm[wid] = v;
    __syncthreads();
    float r = 0.f;
    for (int i = 0; i < nw; i++) r += sm[i];
    __syncthreads();
    return r;
}
DEV float blk_max1(float v, float* sm){
    int lane = threadIdx.x & 63, wid = threadIdx.x >> 6, nw = blockDim.x >> 6;
    #pragma unroll
    for (int off = 32; off; off >>= 1) v = fmaxf(v, __shfl_down(v, off));
    if (lane == 0) sm[wid] = v;
    __syncthreads();
    float r = -3.4e38f;
    for (int i = 0; i < nw; i++) r = fmaxf(r, sm[i]);
    __syncthreads();
    return r;
}

// ---------- transpose body ----------
DEV void tr_body(const float* __restrict__ ip, float* __restrict__ op,
                 int R, int C, int c0, int r0){
    __shared__ float tile[32][33];
    int tx = threadIdx.x & 31, ty = threadIdx.x >> 5;
    #pragma unroll
    for (int rr = ty; rr < 32; rr += 8)
        tile[rr][tx] = ip[(size_t)(r0 + rr) * C + c0 + tx];
    __syncthreads();
    #pragma unroll
    for (int rr = ty; rr < 32; rr += 8)
        op[(size_t)(c0 + rr) * R + r0 + tx] = tile[tx][rr];
}

// batched transpose: out[z][c*R+r] = in[z][r*C+c]; grid (C/32, R/32, batch)
__global__ __launch_bounds__(256) void k_tr(const float* __restrict__ in,
                                            float* __restrict__ out, int R, int C){
    tr_body(in + (size_t)blockIdx.z * R * C, out + (size_t)blockIdx.z * R * C,
            R, C, blockIdx.x * 32, blockIdx.y * 32);
}

// packed: job0 x->xT (128x256, batch16, 512 blks), job1 ao_w (16), job2 so_w (64)
__global__ __launch_bounds__(256) void k_tr_multi(const float* __restrict__ x,
        float* __restrict__ xT, const float* __restrict__ aow, float* __restrict__ owt,
        const float* __restrict__ sow, float* __restrict__ sowt){
    int idx = blockIdx.x;
    if (idx < 512){
        int bx = idx & 7, by = (idx >> 3) & 3, bz = idx >> 5;
        tr_body(x + (size_t)bz * 32768, xT + (size_t)bz * 32768, 128, 256, bx * 32, by * 32);
    } else if (idx < 528){
        int l = idx - 512;
        tr_body(aow, owt, 128, 128, (l & 3) * 32, (l >> 2) * 32);
    } else {
        int l = idx - 528;
        tr_body(sow, sowt, 256, 256, (l & 7) * 32, (l >> 3) * 32);
    }
}

// ---------- K1: pos-embed + gather (xT = x pre-transposed to [b][p][c]) ----------
__global__ void k_embed(const float* __restrict__ xT, const int* __restrict__ sidx,
                        float* __restrict__ xs){
    int bl = blockIdx.x; int b = bl >> 8; int c = threadIdx.x;
    int p = sidx[bl];
    int hh = p >> 4, ww = p & 15;
    int pos = (c < 64) ? hh : ww;
    int jm = c & 63;
    float om = __expf(-(float)(jm & 31) * 0.28782313662425574f); // ln(10000)/32
    float ang = (float)pos * om;
    float pe = (jm < 32) ? sinf(ang) : cosf(ang);
    xs[(size_t)bl * 128 + c] = xT[((size_t)(b * 256 + p)) * 128 + c] + pe;
}

// ---------- LayerNorm (block per row) ----------
__global__ void k_ln(const float* __restrict__ in, const float* __restrict__ w,
                     const float* __restrict__ bb, float* __restrict__ out, int dim){
    __shared__ float sm[16];
    int row = blockIdx.x, t = threadIdx.x;
    float v = in[(size_t)row * dim + t];
    float a = v, q = v * v;
    blk_sum2(a, q, sm);
    float inv = 1.f / (float)dim;
    float mu = a * inv;
    float var = q * inv - mu * mu;
    float rs = rsqrtf(var + 1e-5f);
    out[(size_t)row * dim + t] = (v - mu) * rs * w[t] + bb[t];
}

// ---------- in-projection GEMM with fused LayerNorm over K (pipelined) ----------
// out[r,j] = sum_k LN(A)[r,k] * W[j,k].  K%32==0.
__global__ __launch_bounds__(256) void k_gemm_ln(const float* __restrict__ A,
        const float* __restrict__ W, const float* __restrict__ lw,
        const float* __restrict__ lb, float* __restrict__ out, int N, int K){
    __shared__ float lds[2][32][68];
    int j0 = blockIdx.x * 64, r0 = blockIdx.y * 64;
    int tid = threadIdx.x;
    int cg = tid & 15, rg = tid >> 4;
    int row = tid >> 2, kg = tid & 3;
    int wrow = j0 + row; if (wrow > N - 1) wrow = N - 1;
    const float* Ar  = A + (size_t)(r0 + row) * K + kg * 4;
    const float* Wr  = W + (size_t)wrow * K + kg * 4;
    const float* lwr = lw + kg * 4;
    const float* lbr = lb + kg * 4;
    // phase 0: LN stats (each thread covers disjoint k of its row; 4 lanes/row)
    float s = 0.f, ss = 0.f;
    for (int k0 = 0; k0 < K; k0 += 32){
        float4 a0 = *(const float4*)(Ar + k0);
        float4 a1 = *(const float4*)(Ar + k0 + 16);
        s  += a0.x + a0.y + a0.z + a0.w + a1.x + a1.y + a1.z + a1.w;
        ss += a0.x*a0.x + a0.y*a0.y + a0.z*a0.z + a0.w*a0.w
            + a1.x*a1.x + a1.y*a1.y + a1.z*a1.z + a1.w*a1.w;
    }
    s  += __shfl_xor(s, 1);  ss += __shfl_xor(ss, 1);
    s  += __shfl_xor(s, 2);  ss += __shfl_xor(ss, 2);
    float inv = 1.f / (float)K;
    float mu = s * inv;
    float rs = rsqrtf(ss * inv - mu * mu + 1e-5f);
    // prologue loads
    float4 a0 = *(const float4*)(Ar);
    float4 a1 = *(const float4*)(Ar + 16);
    float4 w0 = *(const float4*)(lwr);
    float4 w1 = *(const float4*)(lwr + 16);
    float4 b0 = *(const float4*)(lbr);
    float4 b1 = *(const float4*)(lbr + 16);
    float4 v0 = *(const float4*)(Wr);
    float4 v1 = *(const float4*)(Wr + 16);
    float acc[4][4] = {};
    for (int k0 = 0; k0 < K; k0 += 32){
        a0.x = (a0.x - mu) * rs * w0.x + b0.x; a0.y = (a0.y - mu) * rs * w0.y + b0.y;
        a0.z = (a0.z - mu) * rs * w0.z + b0.z; a0.w = (a0.w - mu) * rs * w0.w + b0.w;
        a1.x = (a1.x - mu) * rs * w1.x + b1.x; a1.y = (a1.y - mu) * rs * w1.y + b1.y;
        a1.z = (a1.z - mu) * rs * w1.z + b1.z; a1.w = (a1.w - mu) * rs * w1.w + b1.w;
        __syncthreads();
        lds[0][kg * 4 + 0][row] = a0.x; lds[0][kg * 4 + 1][row] = a0.y;
        lds[0][kg * 4 + 2][row] = a0.z; lds[0][kg * 4 + 3][row] = a0.w;
        lds[0][16 + kg * 4 + 0][row] = a1.x; lds[0][16 + kg * 4 + 1][row] = a1.y;
        lds[0][16 + kg * 4 + 2][row] = a1.z; lds[0][16 + kg * 4 + 3][row] = a1.w;
        lds[1][kg * 4 + 0][row] = v0.x; lds[1][kg * 4 + 1][row] = v0.y;
        lds[1][kg * 4 + 2][row] = v0.z; lds[1][kg * 4 + 3][row] = v0.w;
        lds[1][16 + kg * 4 + 0][row] = v1.x; lds[1][16 + kg * 4 + 1][row] = v1.y;
        lds[1][16 + kg * 4 + 2][row] = v1.z; lds[1][16 + kg * 4 + 3][row] = v1.w;
        __syncthreads();
        // prefetch next k-tile BEFORE the FMA burst (overlap latency w/ compute)
        bool more = (k0 + 32 < K);
        float4 na0, na1, nw0, nw1, nb0, nb1, nv0, nv1;
        if (more){
            na0 = *(const float4*)(Ar + k0 + 32);
            na1 = *(const float4*)(Ar + k0 + 48);
            nw0 = *(const float4*)(lwr + k0 + 32);
            nw1 = *(const float4*)(lwr + k0 + 48);
            nb0 = *(const float4*)(lbr + k0 + 32);
            nb1 = *(const float4*)(lbr + k0 + 48);
            nv0 = *(const float4*)(Wr + k0 + 32);
            nv1 = *(const float4*)(Wr + k0 + 48);
        }
        #pragma unroll
        for (int kk = 0; kk < 32; kk++){
            float4 a4 = *(const float4*)(&lds[0][kk][rg << 2]);
            float4 w4 = *(const float4*)(&lds[1][kk][cg << 2]);
            float av_[4] = {a4.x, a4.y, a4.z, a4.w};
            float wv_[4] = {w4.x, w4.y, w4.z, w4.w};
            #pragma unroll
            for (int ri = 0; ri < 4; ri++)
                #pragma unroll
                for (int ci = 0; ci < 4; ci++)
                    acc[ri][ci] = fmaf(av_[ri], wv_[ci], acc[ri][ci]);
        }
        if (more){
            a0 = na0; a1 = na1; w0 = nw0; w1 = nw1;
            b0 = nb0; b1 = nb1; v0 = nv0; v1 = nv1;
        }
    }
    #pragma unroll
    for (int ri = 0; ri < 4; ri++){
        int r = r0 + (rg << 2) + ri;
        int j = j0 + (cg << 2);
        if (j < N){
            float4 v = make_float4(acc[ri][0], acc[ri][1], acc[ri][2], acc[ri][3]);
            *(float4*)(&out[(size_t)r * N + j]) = v;
        }
    }
}

// ---------- out-projection GEMM with fused gate (silu) + RMSNorm (pipelined) ----------
// v[r,k] = y[r,k]*silu(z[r,k]); scale[r] = rsqrt(mean_k v^2 + 1e-5)
// out = scale[r] * sum_k (v[r,k]*rw[k]) * W[j,k]  (+res epilogue)
// mode 1: out[r*N+j] = . + res[r*N+j]
// mode 2: transposed scatter (N==256): out[((r0>>7)*256+j)*128+(r&127)] = . + res[same]
__global__ __launch_bounds__(256) void k_gemm_gate(const float* __restrict__ Y,
        const float* __restrict__ Z, const float* __restrict__ rw,
        const float* __restrict__ W, const float* __restrict__ res,
        float* __restrict__ out, int N, int K, int zs, int mode){
    __shared__ float lds[2][32][68];
    __shared__ float sscale[64];
    int j0 = blockIdx.x * 64, r0 = blockIdx.y * 64;
    int tid = threadIdx.x;
    int cg = tid & 15, rg = tid >> 4;
    int row = tid >> 2, kg = tid & 3;
    const float* Yr = Y + (size_t)(r0 + row) * K + kg * 4;
    const float* Zr = Z + (size_t)(r0 + row) * zs + kg * 4;
    const float* Gr = rw + kg * 4;
    const float* Wr = W + (size_t)(j0 + row) * K + kg * 4;
    float ssq = 0.f;
    float acc[4][4] = {};
    // prologue
    float4 y0 = *(const float4*)(Yr);
    float4 y1 = *(const float4*)(Yr + 16);
    float4 z0 = *(const float4*)(Zr);
    float4 z1 = *(const float4*)(Zr + 16);
    float4 g0 = *(const float4*)(Gr);
    float4 g1 = *(const float4*)(Gr + 16);
    float4 v0 = *(const float4*)(Wr);
    float4 v1 = *(const float4*)(Wr + 16);
    for (int k0 = 0; k0 < K; k0 += 32){
        y0.x *= siluf(z0.x); y0.y *= siluf(z0.y); y0.z *= siluf(z0.z); y0.w *= siluf(z0.w);
        y1.x *= siluf(z1.x); y1.y *= siluf(z1.y); y1.z *= siluf(z1.z); y1.w *= siluf(z1.w);
        ssq += y0.x*y0.x + y0.y*y0.y + y0.z*y0.z + y0.w*y0.w
             + y1.x*y1.x + y1.y*y1.y + y1.z*y1.z + y1.w*y1.w;
        y0.x *= g0.x; y0.y *= g0.y; y0.z *= g0.z; y0.w *= g0.w;
        y1.x *= g1.x; y1.y *= g1.y; y1.z *= g1.z; y1.w *= g1.w;
        __syncthreads();
        lds[0][kg * 4 + 0][row] = y0.x; lds[0][kg * 4 + 1][row] = y0.y;
        lds[0][kg * 4 + 2][row] = y0.z; lds[0][kg * 4 + 3][row] = y0.w;
        lds[0][16 + kg * 4 + 0][row] = y1.x; lds[0][16 + kg * 4 + 1][row] = y1.y;
        lds[0][16 + kg * 4 + 2][row] = y1.z; lds[0][16 + kg * 4 + 3][row] = y1.w;
        lds[1][kg * 4 + 0][row] = v0.x; lds[1][kg * 4 + 1][row] = v0.y;
        lds[1][kg * 4 + 2][row] = v0.z; lds[1][kg * 4 + 3][row] = v0.w;
        lds[1][16 + kg * 4 + 0][row] = v1.x; lds[1][16 + kg * 4 + 1][row] = v1.y;
        lds[1][16 + kg * 4 + 2][row] = v1.z; lds[1][16 + kg * 4 + 3][row] = v1.w;
        __syncthreads();
        bool more = (k0 + 32 < K);
        float4 ny0, ny1, nz0, nz1, ng0, ng1, nv0, nv1;
        if (more){
            ny0 = *(const float4*)(Yr + k0 + 32);
            ny1 = *(const float4*)(Yr + k0 + 48);
            nz0 = *(const float4*)(Zr + k0 + 32);
            nz1 = *(const float4*)(Zr + k0 + 48);
            ng0 = *(const float4*)(Gr + k0 + 32);
            ng1 = *(const float4*)(Gr + k0 + 48);
            nv0 = *(const float4*)(Wr + k0 + 32);
            nv1 = *(const float4*)(Wr + k0 + 48);
        }
        #pragma unroll
        for (int kk = 0; kk < 32; kk++){
            float4 a4 = *(const float4*)(&lds[0][kk][rg << 2]);
            float4 w4 = *(const float4*)(&lds[1][kk][cg << 2]);
            float av_[4] = {a4.x, a4.y, a4.z, a4.w};
            float wv_[4] = {w4.x, w4.y, w4.z, w4.w};
            #pragma unroll
            for (int ri = 0; ri < 4; ri++)
                #pragma unroll
                for (int ci = 0; ci < 4; ci++)
                    acc[ri][ci] = fmaf(av_[ri], wv_[ci], acc[ri][ci]);
        }
        if (more){
            y0 = ny0; y1 = ny1; z0 = nz0; z1 = nz1;
            g0 = ng0; g1 = ng1; v0 = nv0; v1 = nv1;
        }
    }
    ssq += __shfl_xor(ssq, 1);
    ssq += __shfl_xor(ssq, 2);
    if ((tid & 3) == 0) sscale[row] = rsqrtf(ssq / (float)K + 1e-5f);
    __syncthreads();
    if (mode == 2){
        float (*T)[68] = (float (*)[68])lds;
        #pragma unroll
        for (int ri = 0; ri < 4; ri++){
            float sc = sscale[(rg << 2) + ri];
            #pragma unroll
            for (int ci = 0; ci < 4; ci++)
                T[(cg << 2) + ci][(rg << 2) + ri] = acc[ri][ci] * sc;
        }
        __syncthreads();
        int b2 = r0 >> 7, ii0 = r0 & 127;
        int jj = tid >> 2, seg = tid & 3;
        size_t base = ((size_t)(b2 * 256 + j0 + jj)) * 128 + ii0 + seg * 16;
        float* op = out + base;
        const float* rp = res + base;
        #pragma unroll
        for (int c = 0; c < 4; c++){
            float4 v = *(const float4*)(&T[jj][seg * 16 + c * 4]);
            float4 rv = *(const float4*)(rp + c * 4);
            v.x += rv.x; v.y += rv.y; v.z += rv.z; v.w += rv.w;
            *(float4*)(op + c * 4) = v;
        }
    } else {
        #pragma unroll
        for (int ri = 0; ri < 4; ri++){
            int r = r0 + (rg << 2) + ri;
            int j = j0 + (cg << 2);
            float sc = sscale[(rg << 2) + ri];
            float4 v = make_float4(acc[ri][0] * sc, acc[ri][1] * sc,
                                   acc[ri][2] * sc, acc[ri][3] * sc);
            float4 rv = *(const float4*)(&res[(size_t)r * N + j]);
            v.x += rv.x; v.y += rv.y; v.z += rv.z; v.w += rv.w;
            *(float4*)(&out[(size_t)r * N + j]) = v;
        }
    }
}

// ---------- generic 64x64 GEMM core (for qkv batch), pipelined ----------
DEV void gemm_core(const float* __restrict__ A, const float* __restrict__ W,
                   const float* __restrict__ bias, float* __restrict__ out,
                   int N, int K, int mode, int j0, int r0){
    __shared__ float lds[2][32][68];
    int tid = threadIdx.x;
    int cg = tid & 15, rg = tid >> 4;
    int row = tid >> 2, kg = tid & 3;
    int wrow = j0 + row; if (wrow > N - 1) wrow = N - 1;
    const float* Ap = A + (size_t)(r0 + row) * K + kg * 4;
    const float* Wp = W + (size_t)wrow * K + kg * 4;
    float4 a0 = *(const float4*)(Ap);
    float4 a1 = *(const float4*)(Ap + 16);
    float4 w0 = *(const float4*)(Wp);
    float4 w1 = *(const float4*)(Wp + 16);
    float acc[4][4] = {};
    for (int k0 = 0; k0 < K; k0 += 32){
        __syncthreads();
        lds[0][kg * 4 + 0][row] = a0.x; lds[0][kg * 4 + 1][row] = a0.y;
        lds[0][kg * 4 + 2][row] = a0.z; lds[0][kg * 4 + 3][row] = a0.w;
        lds[0][16 + kg * 4 + 0][row] = a1.x; lds[0][16 + kg * 4 + 1][row] = a1.y;
        lds[0][16 + kg * 4 + 2][row] = a1.z; lds[0][16 + kg * 4 + 3][row] = a1.w;
        lds[1][kg * 4 + 0][row] = w0.x; lds[1][kg * 4 + 1][row] = w0.y;
        lds[1][kg * 4 + 2][row] = w0.z; lds[1][kg * 4 + 3][row] = w0.w;
        lds[1][16 + kg * 4 + 0][row] = w1.x; lds[1][16 + kg * 4 + 1][row] = w1.y;
        lds[1][16 + kg * 4 + 2][row] = w1.z; lds[1][16 + kg * 4 + 3][row] = w1.w;
        __syncthreads();
        bool more = (k0 + 32 < K);
        float4 na0, na1, nw0, nw1;
        if (more){
            na0 = *(const float4*)(Ap + k0 + 32);
            na1 = *(const float4*)(Ap + k0 + 48);
            nw0 = *(const float4*)(Wp + k0 + 32);
            nw1 = *(const float4*)(Wp + k0 + 48);
        }
        #pragma unroll
        for (int kk = 0; kk < 32; kk++){
            float4 a4 = *(const float4*)(&lds[0][kk][rg << 2]);
            float4 w4 = *(const float4*)(&lds[1][kk][cg << 2]);
            float av_[4] = {a4.x, a4.y, a4.z, a4.w};
            float wv_[4] = {w4.x, w4.y, w4.z, w4.w};
            #pragma unroll
            for (int ri = 0; ri < 4; ri++)
                #pragma unroll
                for (int ci = 0; ci < 4; ci++)
                    acc[ri][ci] = fmaf(av_[ri], wv_[ci], acc[ri][ci]);
        }
        if (more){ a0 = na0; a1 = na1; w0 = nw0; w1 = nw1; }
    }
    if (mode == 3){
        float (*T)[68] = (float (*)[68])lds;
        __syncthreads();
        #pragma unroll
        for (int ri = 0; ri < 4; ri++)
            #pragma unroll
            for (int ci = 0; ci < 4; ci++)
                T[(cg << 2) + ci][(rg << 2) + ri] = acc[ri][ci];
        __syncthreads();
        int b2 = r0 >> 7, ii0 = r0 & 127;
        int jj = tid >> 2, seg = tid & 3;
        size_t base = ((size_t)(b2 * 256 + j0 + jj)) * 128 + ii0 + seg * 16;
        float* op = out + base;
        float bj = bias[j0 + jj];
        #pragma unroll
        for (int c = 0; c < 4; c++){
            float4 v = *(const float4*)(&T[jj][seg * 16 + c * 4]);
            v.x += bj; v.y += bj; v.z += bj; v.w += bj;
            *(float4*)(op + c * 4) = v;
        }
    } else {
        #pragma unroll
        for (int ri = 0; ri < 4; ri++){
            int r = r0 + (rg << 2) + ri;
            int j = j0 + (cg << 2);
            float4 v = make_float4(acc[ri][0], acc[ri][1], acc[ri][2], acc[ri][3]);
            v.x += bias[j]; v.y += bias[j + 1]; v.z += bias[j + 2]; v.w += bias[j + 3];
            *(float4*)(&out[(size_t)r * N + j]) = v;
        }
    }
}

struct GJob { const float* W; const float* bias; float* out; int mode; };

__global__ __launch_bounds__(256) void k_gemm3(const float* __restrict__ A,
                                               GJob ja, GJob jb, GJob jc,
                                               int N, int K){
    GJob j = (blockIdx.z == 0) ? ja : ((blockIdx.z == 1) ? jb : jc);
    gemm_core(A, j.W, j.bias, j.out, N, K, j.mode, blockIdx.x * 64, blockIdx.y * 64);
}

// ---------- causal depthwise conv(4)+bias+silu, fused dt / log-dA ----------
__global__ void k_conv(const float* __restrict__ zx, const float* __restrict__ cw,
                       const float* __restrict__ cb, float* __restrict__ xc,
                       const float* __restrict__ dtbias, const float* __restrict__ Al,
                       float* __restrict__ dt, float* __restrict__ dlA,
                       int L, int D, int stride, int off, int nh, int dtoff){
    int bl = blockIdx.x;
    int l = bl & (L - 1);
    const float* base = zx + (size_t)bl * stride + off;
    for (int d = threadIdx.x; d < D; d += blockDim.x){
        float acc = cb[d];
        #pragma unroll
        for (int k = 0; k < 4; k++){
            int dl = l + k - 3;
            if (dl >= 0) acc += base[(ptrdiff_t)(k - 3) * stride + d] * cw[d * 4 + k];
        }
        xc[(size_t)bl * D + d] = siluf(acc);
    }
    int t = threadIdx.x;
    if (t < nh){
        float xv = zx[(size_t)bl * stride + dtoff + t] + dtbias[t];
        float d = softplusf(xv);
        dt[(size_t)bl * nh + t] = d;
        dlA[(size_t)bl * nh + t] = -d * __expf(Al[t]); // log(dA) <= 0
    }
}

// ---------- chunked SSD, stage A ----------
__global__ __launch_bounds__(256) void k_ssd_chunk(
        const float* __restrict__ xc, const float* __restrict__ dt,
        const float* __restrict__ dlA, float* __restrict__ y,
        float* __restrict__ S, float* __restrict__ clb,
        int L, int nh, int nc, int xcs, int bo, int co, int ys){
    __shared__ float sX[64][68];
    __shared__ float sB[64][68];
    __shared__ float sC[64][68]; // phase1: C ; after: masked G
    __shared__ float cl[64], sdt[64], sw[64];
    int blk = blockIdx.x;
    int c = blk % nc; int bh = blk / nc; int h = bh % nh; int b = bh / nh;
    int l0 = c * 64;
    int tid = threadIdx.x;
    const float* base = xc + ((size_t)(b * L + l0)) * xcs;
    for (int idx = tid; idx < 4096; idx += 256){
        int s = idx >> 6, n = idx & 63;
        const float* row = base + (size_t)s * xcs;
        sX[s][n] = row[h * 64 + n];
        sB[s][n] = row[bo + n];
        sC[s][n] = row[co + n];
    }
    if (tid < 64){
        size_t di = (size_t)(b * L + l0 + tid) * nh + h;
        float dlv = dlA[di];
        sdt[tid] = dt[di];
        #pragma unroll
        for (int off = 1; off < 64; off <<= 1){
            float o = __shfl_up(dlv, off, 64);
            if (tid >= off) dlv += o;
        }
        cl[tid] = dlv;
        clb[(size_t)blk * 64 + tid] = dlv;
    }
    __syncthreads();
    if (tid < 64) sw[tid] = __expf(cl[63] - cl[tid]) * sdt[tid];

    int g1 = tid >> 4, g2 = tid & 15;
    int t0 = g1 * 4, s0 = g2 * 4;
    float g[4][4] = {};
    for (int n = 0; n < 64; n += 4){
        float4 cv[4], bv[4];
        #pragma unroll
        for (int i = 0; i < 4; i++) cv[i] = *(const float4*)&sC[t0 + i][n];
        #pragma unroll
        for (int j = 0; j < 4; j++) bv[j] = *(const float4*)&sB[s0 + j][n];
        #pragma unroll
        for (int i = 0; i < 4; i++)
            #pragma unroll
            for (int j = 0; j < 4; j++){
                g[i][j] = fmaf(cv[i].x, bv[j].x, g[i][j]);
                g[i][j] = fmaf(cv[i].y, bv[j].y, g[i][j]);
                g[i][j] = fmaf(cv[i].z, bv[j].z, g[i][j]);
                g[i][j] = fmaf(cv[i].w, bv[j].w, g[i][j]);
            }
    }
    __syncthreads();
    #pragma unroll
    for (int i = 0; i < 4; i++)
        #pragma unroll
        for (int j = 0; j < 4; j++){
            int t = t0 + i, s = s0 + j;
            float v = 0.f;
            if (s <= t) v = g[i][j] * __expf(cl[t] - cl[s]) * sdt[s];
            sC[t][s] = v;
        }
    __syncthreads();
    {
        float acc[4][4] = {};
        for (int s = 0; s < 64; s++){
            float4 xv = *(const float4*)&sX[s][s0];
            float gv[4];
            #pragma unroll
            for (int i = 0; i < 4; i++) gv[i] = sC[t0 + i][s];
            #pragma unroll
            for (int i = 0; i < 4; i++){
                acc[i][0] = fmaf(gv[i], xv.x, acc[i][0]);
                acc[i][1] = fmaf(gv[i], xv.y, acc[i][1]);
                acc[i][2] = fmaf(gv[i], xv.z, acc[i][2]);
                acc[i][3] = fmaf(gv[i], xv.w, acc[i][3]);
            }
        }
        #pragma unroll
        for (int i = 0; i < 4; i++){
            float4 o = make_float4(acc[i][0], acc[i][1], acc[i][2], acc[i][3]);
            *(float4*)&y[(size_t)(b * L + l0 + t0 + i) * ys + h * 64 + s0] = o;
        }
    }
    {
        float acc[4][4] = {};
        int p0 = t0, n0 = s0;
        for (int s = 0; s < 64; s++){
            float wv = sw[s];
            float4 bv = *(const float4*)&sB[s][n0];
            float4 xv = *(const float4*)&sX[s][p0];
            float w0 = wv * xv.x, w1 = wv * xv.y, w2 = wv * xv.z, w3 = wv * xv.w;
            acc[0][0] = fmaf(w0, bv.x, acc[0][0]); acc[0][1] = fmaf(w0, bv.y, acc[0][1]);
            acc[0][2] = fmaf(w0, bv.z, acc[0][2]); acc[0][3] = fmaf(w0, bv.w, acc[0][3]);
            acc[1][0] = fmaf(w1, bv.x, acc[1][0]); acc[1][1] = fmaf(w1, bv.y, acc[1][1]);
            acc[1][2] = fmaf(w1, bv.z, acc[1][2]); acc[1][3] = fmaf(w1, bv.w, acc[1][3]);
            acc[2][0] = fmaf(w2, bv.x, acc[2][0]); acc[2][1] = fmaf(w2, bv.y, acc[2][1]);
            acc[2][2] = fmaf(w2, bv.z, acc[2][2]); acc[2][3] = fmaf(w2, bv.w, acc[2][3]);
            acc[3][0] = fmaf(w3, bv.x, acc[3][0]); acc[3][1] = fmaf(w3, bv.y, acc[3][1]);
            acc[3][2] = fmaf(w3, bv.z, acc[3][2]); acc[3][3] = fmaf(w3, bv.w, acc[3][3]);
        }
        float* Sp = S + (size_t)blk * 4096;
        #pragma unroll
        for (int i = 0; i < 4; i++){
            float4 o = make_float4(acc[i][0], acc[i][1], acc[i][2], acc[i][3]);
            *(float4*)&Sp[(p0 + i) * 64 + n0] = o;
        }
    }
}

// ---------- chunked SSD, stage B+C fused ----------
// h_init(c) = sum_{c'<c} S_{c'} * prod_{m=c'+1}^{c-1} dec_m  (nc <= 4)
// y += exp(cl[t]) * (C_t . h_init) + D*x
__global__ __launch_bounds__(256) void k_chunk_y(
        const float* __restrict__ xc, const float* __restrict__ S,
        const float* __restrict__ clb, const float* __restrict__ Dp,
        float* __restrict__ y,
        int L, int nh, int nc, int xcs, int co, int ys){
    __shared__ float sH[64][68];
    __shared__ float sC[64][68];
    __shared__ float scl[64];
    int blk = blockIdx.x;
    int c = blk % nc; int bh = blk / nc; int h = bh % nh; int b = bh / nh;
    int l0 = c * 64;
    int tid = threadIdx.x;
    float wch[4];
    {
        float w = 1.f;
        for (int cp = c - 1; cp >= 0; cp--){
            wch[cp] = w;
            w *= __expf(clb[((size_t)(bh * nc + cp)) * 64 + 63]);
        }
    }
    const float* Sb = S + (size_t)(bh * nc) * 4096;
    const float* base = xc + ((size_t)(b * L + l0)) * xcs;
    for (int idx = tid; idx < 4096; idx += 256){
        int r = idx >> 6, n = idx & 63;
        float hv = 0.f;
        for (int cp = 0; cp < c; cp++)
            hv = fmaf(wch[cp], Sb[(size_t)cp * 4096 + idx], hv);
        sH[r][n] = hv;
        sC[r][n] = base[(size_t)r * xcs + co + n];
    }
    if (tid < 64) scl[tid] = __expf(clb[(size_t)blk * 64 + tid]);
    float Dh = Dp[h];
    __syncthreads();
    int g1 = tid >> 4, g2 = tid & 15;
    int t0 = g1 * 4, p0 = g2 * 4;
    float m[4][4] = {};
    for (int n = 0; n < 64; n += 4){
        float4 cv[4], hv[4];
        #pragma unroll
        for (int i = 0; i < 4; i++) cv[i] = *(const float4*)&sC[t0 + i][n];
        #pragma unroll
        for (int j = 0; j < 4; j++) hv[j] = *(const float4*)&sH[p0 + j][n];
        #pragma unroll
        for (int i = 0; i < 4; i++)
            #pragma unroll
            for (int j = 0; j < 4; j++){
                m[i][j] = fmaf(cv[i].x, hv[j].x, m[i][j]);
                m[i][j] = fmaf(cv[i].y, hv[j].y, m[i][j]);
                m[i][j] = fmaf(cv[i].z, hv[j].z, m[i][j]);
                m[i][j] = fmaf(cv[i].w, hv[j].w, m[i][j]);
            }
    }
    #pragma unroll
    for (int i = 0; i < 4; i++){
        int t = t0 + i;
        size_t yi = (size_t)(b * L + l0 + t) * ys + h * 64 + p0;
        float4 yv = *(float4*)&y[yi];
        float4 xv = *(const float4*)&base[(size_t)t * xcs + h * 64 + p0];
        float e = scl[t];
        yv.x += e * m[i][0] + Dh * xv.x;
        yv.y += e * m[i][1] + Dh * xv.y;
        yv.z += e * m[i][2] + Dh * xv.z;
        yv.w += e * m[i][3] + Dh * xv.w;
        *(float4*)&y[yi] = yv;
    }
}

// ---------- center projection + q ----------
__global__ void k_center_q(const float* __restrict__ xs, const float* __restrict__ cw,
                           const float* __restrict__ cb, const float* __restrict__ qw,
                           const float* __restrict__ qb, float* __restrict__ q){
    __shared__ float xr[640];
    __shared__ float cen[128];
    int b = blockIdx.x, t = threadIdx.x; // 128 thr
    for (int idx = t; idx < 640; idx += 128)
        xr[idx] = xs[(size_t)b * 256 * 128 + idx];
    __syncthreads();
    float acc = cb[t];
    for (int c = 0; c < 128; c++){
        const float* wp = cw + (size_t)(t * 128 + c) * 5;
        #pragma unroll
        for (int l = 0; l < 5; l++) acc += xr[l * 128 + c] * wp[l];
    }
    cen[t] = acc;
    __syncthreads();
    float qa = qb[t];
    const float* wr = qw + (size_t)t * 128;
    for (int o = 0; o < 128; o++) qa += cen[o] * wr[o];
    q[b * 128 + t] = qa;
}

// ---------- attention softmax over l ----------
__global__ void k_attn(const float* __restrict__ q, const float* __restrict__ k,
                       float* __restrict__ attn){
    __shared__ float sm[16];
    __shared__ float qh[16];
    int blk = blockIdx.x; int b = blk >> 3, h = blk & 7; int l = threadIdx.x; // 256 thr
    if (l < 16) qh[l] = q[b * 128 + h * 16 + l];
    __syncthreads();
    const float* kp = k + ((size_t)(b * 256 + l)) * 128 + h * 16;
    float s = 0.f;
    #pragma unroll
    for (int d = 0; d < 16; d++) s += qh[d] * kp[d];
    s *= 0.25f;
    float mx = blk_max1(s, sm);
    float e = __expf(s - mx);
    float sum = blk_sum1(e, sm);
    attn[(size_t)blk * 256 + l] = e / sum;
}

// ---------- attention out, 8 l-rows per block ----------
__global__ __launch_bounds__(128) void k_attn_out(const float* __restrict__ v,
                                                  const float* __restrict__ attn,
                                                  const float* __restrict__ owt,
                                                  const float* __restrict__ ob,
                                                  float* __restrict__ xs){
    __shared__ float vp[8][128];
    int blk = blockIdx.x; int b = blk >> 5, l0 = (blk & 31) << 3;
    int t = threadIdx.x; // 128 thr
    int h = t >> 4;
    float a[8];
    #pragma unroll
    for (int r = 0; r < 8; r++)
        a[r] = attn[((size_t)(b * 8 + h)) * 256 + l0 + r];
    #pragma unroll
    for (int r = 0; r < 8; r++)
        vp[r][t] = v[((size_t)(b * 256 + l0 + r)) * 128 + t] * a[r];
    __syncthreads();
    float acc[8];
    float bv = ob[t];
    #pragma unroll
    for (int r = 0; r < 8; r++) acc[r] = bv;
    for (int j = 0; j < 128; j++){
        float w = owt[j * 128 + t];
        #pragma unroll
        for (int r = 0; r < 8; r++) acc[r] = fmaf(vp[r][j], w, acc[r]);
    }
    #pragma unroll
    for (int r = 0; r < 8; r++)
        xs[((size_t)(b * 256 + l0 + r)) * 128 + t] += acc[r];
}

// ---------- fused spectral attention: QK+softmax+AV+SO+residual+unsort ----------
__global__ __launch_bounds__(256) void k_spe_attn(const float* __restrict__ q2,
        const float* __restrict__ k2t, const float* __restrict__ v2,
        const float* __restrict__ sowt, const float* __restrict__ sob,
        const float* __restrict__ xs, const int* __restrict__ sidx,
        float* __restrict__ xr){
    __shared__ float qs[8][256];
    __shared__ float lgp[2][8][128];
    __shared__ float sa[8][132];
    __shared__ float av[8][256];
    __shared__ float mxs[8], sms[8];
    int blk = blockIdx.x; int b = blk >> 4; int i0 = (blk & 15) << 3;
    int t = threadIdx.x;
    for (int idx = t; idx < 2048; idx += 256){
        int ii = idx >> 8, d = idx & 255;
        qs[ii][d] = q2[((size_t)(b * 128 + i0 + ii)) * 256 + d];
    }
    __syncthreads();
    {
        int j = t & 127, dh = t >> 7;
        const float* kt = k2t + (size_t)b * 32768 + dh * 16384;
        float acc[8] = {};
        for (int dd = 0; dd < 128; dd++){
            float kv = kt[dd * 128 + j];
            int d = dh * 128 + dd;
            #pragma unroll
            for (int ii = 0; ii < 8; ii++) acc[ii] = fmaf(qs[ii][d], kv, acc[ii]);
        }
        #pragma unroll
        for (int ii = 0; ii < 8; ii++) lgp[dh][ii][j] = acc[ii];
    }
    __syncthreads();
    if (t < 128){
        #pragma unroll
        for (int ii = 0; ii < 8; ii++)
            sa[ii][t] = (lgp[0][ii][t] + lgp[1][ii][t]) * (1.f / 16.f);
    }
    __syncthreads();
    if (t < 8){
        float mx = -3.4e38f;
        for (int j = 0; j < 128; j++) mx = fmaxf(mx, sa[t][j]);
        float sm = 0.f;
        for (int j = 0; j < 128; j++) sm += __expf(sa[t][j] - mx);
        mxs[t] = mx; sms[t] = 1.f / sm;
    }
    __syncthreads();
    if (t < 128){
        #pragma unroll
        for (int ii = 0; ii < 8; ii++)
            sa[ii][t] = __expf(sa[ii][t] - mxs[ii]) * sms[ii];
    }
    __syncthreads();
    {
        float acc[8] = {};
        const float* vb = v2 + (size_t)b * 32768 + t;
        for (int j = 0; j < 128; j++){
            float vv = vb[(size_t)j * 256];
            #pragma unroll
            for (int ii = 0; ii < 8; ii++) acc[ii] = fmaf(sa[ii][j], vv, acc[ii]);
        }
        #pragma unroll
        for (int ii = 0; ii < 8; ii++) av[ii][t] = acc[ii];
    }
    __syncthreads();
    float acc[8] = {};
    for (int d = 0; d < 256; d++){
        float wv = sowt[d * 256 + t];
        #pragma unroll
        for (int ii = 0; ii < 8; ii++) acc[ii] = fmaf(av[ii][d], wv, acc[ii]);
    }
    float bias = sob[t];
    int p = sidx[b * 256 + t];
    const float* xin = xs + ((size_t)(b * 256 + t)) * 128 + i0;
    float* xout = xr + ((size_t)(b * 256 + p)) * 128 + i0;
    #pragma unroll
    for (int ii = 0; ii < 8; ii++) xout[ii] = xin[ii] + acc[ii] + bias;
}

// ---------- conv GEMM split-K=4 with fused im2col (pipelined) ----------
__global__ __launch_bounds__(256) void k_conv_gemm(const float* __restrict__ xr,
                                                   const float* __restrict__ W2,
                                                   float* __restrict__ part){
    __shared__ float As[16][68];
    __shared__ float Ws[16][64];
    int j0 = blockIdx.x * 64, r0 = blockIdx.y * 64, s = blockIdx.z;
    int tid = threadIdx.x;
    int cg = tid & 15, rg = tid >> 4;
    int arow = tid >> 2, akg = tid & 3;
    int wkk = tid >> 4, wseg = tid & 15; // Ws staging: float4 per thread
    int r = r0 + arow; int b = r >> 6, oh = (r >> 3) & 7, ow = r & 7;
    float acc[4][4] = {};
    int kbeg = s * 288, kend = kbeg + 288;
    // prologue: gather first A chunk + load first W chunk
    float4 a4, w4;
    {
        int k = kbeg + akg * 4;
        int khw = k >> 7, c = k & 127;
        int kh = khw / 3, kw = khw - kh * 3;
        int ih = oh * 2 - 1 + kh, iw = ow * 2 - 1 + kw;
        a4 = make_float4(0.f, 0.f, 0.f, 0.f);
        if (ih >= 0 && ih < 16 && iw >= 0 && iw < 16)
            a4 = *(const float4*)(xr + ((size_t)((b << 8) + (ih << 4) + iw)) * 128 + c);
        w4 = *(const float4*)(W2 + (size_t)(kbeg + wkk) * 128 + j0 + wseg * 4);
    }
    for (int k0 = kbeg; k0 < kend; k0 += 16){
        __syncthreads();
        As[akg * 4 + 0][arow] = a4.x; As[akg * 4 + 1][arow] = a4.y;
        As[akg * 4 + 2][arow] = a4.z; As[akg * 4 + 3][arow] = a4.w;
        Ws[wkk][wseg * 4 + 0] = w4.x; Ws[wkk][wseg * 4 + 1] = w4.y;
        Ws[wkk][wseg * 4 + 2] = w4.z; Ws[wkk][wseg * 4 + 3] = w4.w;
        __syncthreads();
        bool more = (k0 + 16 < kend);
        float4 na4, nw4;
        if (more){
            int k = k0 + 16 + akg * 4;
            int khw = k >> 7, c = k & 127;
            int kh = khw / 3, kw = khw - kh * 3;
            int ih = oh * 2 - 1 + kh, iw = ow * 2 - 1 + kw;
            na4 = make_float4(0.f, 0.f, 0.f, 0.f);
            if (ih >= 0 && ih < 16 && iw >= 0 && iw < 16)
                na4 = *(const float4*)(xr + ((size_t)((b << 8) + (ih << 4) + iw)) * 128 + c);
            nw4 = *(const float4*)(W2 + (size_t)(k0 + 16 + wkk) * 128 + j0 + wseg * 4);
        }
        #pragma unroll
        for (int kk = 0; kk < 16; kk++){
            float4 av4 = *(const float4*)(&As[kk][rg << 2]);
            float4 wv4 = *(const float4*)(&Ws[kk][cg << 2]);
            float av_[4] = {av4.x, av4.y, av4.z, av4.w};
            float wv_[4] = {wv4.x, wv4.y, wv4.z, wv4.w};
            #pragma unroll
            for (int ri = 0; ri < 4; ri++)
                #pragma unroll
                for (int ci = 0; ci < 4; ci++)
                    acc[ri][ci] = fmaf(av_[ri], wv_[ci], acc[ri][ci]);
        }
        if (more){ a4 = na4; w4 = nw4; }
    }
    float* pp = part + (size_t)s * 1024 * 128;
    #pragma unroll
    for (int ri = 0; ri < 4; ri++){
        int rr = r0 + (rg << 2) + ri;
        #pragma unroll
        for (int ci = 0; ci < 4; ci++){
            int j = j0 + (cg << 2) + ci;
            pp[(size_t)rr * 128 + j] = acc[ri][ci];
        }
    }
}

// ---------- reduce split-K partials + LayerNorm ----------
__global__ void k_part_ln(const float* __restrict__ part, const float* __restrict__ lnw,
                          const float* __restrict__ lnb, float* __restrict__ out){
    __shared__ float sm[16];
    int r = blockIdx.x, t = threadIdx.x; // 128 thr
    float v = part[(size_t)r * 128 + t]
            + part[(size_t)(1024 + r) * 128 + t]
            + part[(size_t)(2048 + r) * 128 + t]
            + part[(size_t)(3072 + r) * 128 + t];
    float a = v, q = v * v;
    blk_sum2(a, q, sm);
    float mu = a * (1.f / 128.f);
    float var = q * (1.f / 128.f) - mu * mu;
    float rs = rsqrtf(var + 1e-5f);
    out[(size_t)r * 128 + t] = (v - mu) * rs * lnw[t] + lnb[t];
}

extern "C" void kernel_launch(void* const* d_in, const int* in_sizes, int n_in,
                              void* d_out, int out_size, void* d_ws, size_t ws_size,
                              hipStream_t stream) {
    const float* x          = (const float*)d_in[0];
    const int*   sidx       = (const int*)  d_in[1];
    const float* spa_ln_w   = (const float*)d_in[2];
    const float* spa_ln_b   = (const float*)d_in[3];
    const float* spa_in_w   = (const float*)d_in[4];
    const float* spa_conv_w = (const float*)d_in[5];
    const float* spa_conv_b = (const float*)d_in[6];
    const float* spa_dt_bias= (const float*)d_in[7];
    const float* spa_A_log  = (const float*)d_in[8];
    const float* spa_D      = (const float*)d_in[9];
    const float* spa_rms_w  = (const float*)d_in[10];
    const float* spa_out_w  = (const float*)d_in[11];
    const float* spe_ln_w   = (const float*)d_in[12];
    const float* spe_ln_b   = (const float*)d_in[13];
    const float* spe_in_w   = (const float*)d_in[14];
    const float* spe_conv_w = (const float*)d_in[15];
    const float* spe_conv_b = (const float*)d_in[16];
    const float* spe_dt_bias= (const float*)d_in[17];
    const float* spe_A_log  = (const float*)d_in[18];
    const float* spe_D      = (const float*)d_in[19];
    const float* spe_rms_w  = (const float*)d_in[20];
    const float* spe_out_w  = (const float*)d_in[21];
    const float* norm_w     = (const float*)d_in[22];
    const float* norm_b     = (const float*)d_in[23];
    const float* cprj_w     = (const float*)d_in[24];
    const float* cprj_b     = (const float*)d_in[25];
    const float* aq_w       = (const float*)d_in[26];
    const float* aq_b       = (const float*)d_in[27];
    const float* ak_w       = (const float*)d_in[28];
    const float* ak_b       = (const float*)d_in[29];
    const float* av_w       = (const float*)d_in[30];
    const float* av_b       = (const float*)d_in[31];
    const float* ao_w       = (const float*)d_in[32];
    const float* ao_b       = (const float*)d_in[33];
    const float* sq_w       = (const float*)d_in[34];
    const float* sq_b       = (const float*)d_in[35];
    const float* sk_w       = (const float*)d_in[36];
    const float* sk_b       = (const float*)d_in[37];
    const float* sv_w       = (const float*)d_in[38];
    const float* sv_b       = (const float*)d_in[39];
    const float* so_w       = (const float*)d_in[40];
    const float* so_b       = (const float*)d_in[41];
    const float* ds_conv_w  = (const float*)d_in[42];
    const float* ds_ln_w    = (const float*)d_in[43];
    const float* ds_ln_b    = (const float*)d_in[44];

    float* ws = (float*)d_ws;
    // loop-live arena: 0 .. 7946240
    float* xs   = ws + 0;        // 524288
    float* zx   = ws + 1048576;  // -> 3686400
    float* xc   = ws + 3686400;  // -> 5259264
    float* dtb  = ws + 5259264;  // 32768
    float* dAb  = ws + 5292032;  // 32768 (log-dA)
    float* yb   = ws + 5324800;  // -> 6373376
    float* Sbuf = ws + 6373376;  // -> 7421952
    float* h1   = ws + 7421952;  // -> 7946240
    float* clbuf = ws + 524288;  // in scratch region (dead between uses)
    float* xT    = ws + 524288;  // scratch (dead after k_embed)
    float* h1t   = ws + 6373376; // in Sbuf (dead before S writes)
    // weight transposes: PAST the loop-live arena
    float* owt   = ws + 7946240; // 16384 -> 7962624
    float* sowt  = ws + 7962624; // 65536 -> 8028160
    // attention-stage aliases (host regions dead post-loop)
    float* kb    = ws + 1048576;
    float* vb    = ws + 1572864;
    float* attnb = ws + 2097152;
    float* qb    = ws + 2129920;
    float* xt    = ws + 524288;
    float* q2    = ws + 3686400;
    float* k2t   = ws + 4210688;
    float* v2    = ws + 4734976;
    float* xr    = ws + 5586944; // -> 6111232
    float* part  = ws + 1048576; // 524288 -> 1572864 (kb/vb dead by conv_gemm)

    k_tr_multi<<<592, 256, 0, stream>>>(x, xT, ao_w, owt, so_w, sowt);
    k_embed<<<4096, 128, 0, stream>>>(xT, sidx, xs);

    for (int i = 0; i < 2; i++){
        // ---- spatial mamba (L=256, nh=4, nc=4) ----
        k_gemm_ln<<<dim3(11, 64), 256, 0, stream>>>(xs, spa_in_w + (size_t)i * 644 * 128,
                                                    spa_ln_w + i * 128, spa_ln_b + i * 128,
                                                    zx, 644, 128);
        k_conv<<<4096, 256, 0, stream>>>(zx, spa_conv_w + (size_t)i * 384 * 4,
                                         spa_conv_b + i * 384, xc,
                                         spa_dt_bias + i * 4, spa_A_log + i * 4, dtb, dAb,
                                         256, 384, 644, 256, 4, 640);
        k_ssd_chunk<<<256, 256, 0, stream>>>(xc, dtb, dAb, yb, Sbuf, clbuf,
                                             256, 4, 4, 384, 256, 320, 256);
        k_chunk_y<<<256, 256, 0, stream>>>(xc, Sbuf, clbuf, spa_D + i * 4, yb,
                                           256, 4, 4, 384, 320, 256);
        k_gemm_gate<<<dim3(2, 64), 256, 0, stream>>>(yb, zx, spa_rms_w + i * 256,
                                                     spa_out_w + (size_t)i * 128 * 256,
                                                     xs, h1, 128, 256, 644, 1);
        // ---- spectral mamba (L=128, nh=8, nc=2) ----
        k_tr<<<dim3(4, 8, 16), 256, 0, stream>>>(h1, h1t, 256, 128);
        k_gemm_ln<<<dim3(19, 32), 256, 0, stream>>>(h1t, spe_in_w + (size_t)i * 1160 * 256,
                                                    spe_ln_w + i * 256, spe_ln_b + i * 256,
                                                    zx, 1160, 256);
        k_conv<<<2048, 256, 0, stream>>>(zx, spe_conv_w + (size_t)i * 640 * 4,
                                         spe_conv_b + i * 640, xc,
                                         spe_dt_bias + i * 8, spe_A_log + i * 8, dtb, dAb,
                                         128, 640, 1160, 512, 8, 1152);
        k_ssd_chunk<<<256, 256, 0, stream>>>(xc, dtb, dAb, yb, Sbuf, clbuf,
                                             128, 8, 2, 640, 512, 576, 512);
        k_chunk_y<<<256, 256, 0, stream>>>(xc, Sbuf, clbuf, spe_D + i * 8, yb,
                                           128, 8, 2, 640, 576, 512);
        k_gemm_gate<<<dim3(4, 32), 256, 0, stream>>>(yb, zx, spe_rms_w + i * 512,
                                                     spe_out_w + (size_t)i * 256 * 512,
                                                     h1, xs, 256, 512, 1160, 2);
    }

    k_ln<<<4096, 128, 0, stream>>>(xs, norm_w, norm_b, xs, 128);
    k_center_q<<<16, 128, 0, stream>>>(xs, cprj_w, cprj_b, aq_w, aq_b, qb);
    {
        GJob jk = {ak_w, ak_b, kb, 0};
        GJob jv = {av_w, av_b, vb, 0};
        k_gemm3<<<dim3(2, 64, 2), 256, 0, stream>>>(xs, jk, jv, jk, 128, 128);
    }
    k_attn<<<128, 256, 0, stream>>>(qb, kb, attnb);
    k_attn_out<<<512, 128, 0, stream>>>(vb, attnb, owt, ao_b, xs);
    k_tr<<<dim3(4, 8, 16), 256, 0, stream>>>(xs, xt, 256, 128);
    {
        GJob jq = {sq_w, sq_b, q2, 0};
        GJob jk = {sk_w, sk_b, k2t, 3};
        GJob jv = {sv_w, sv_b, v2, 0};
        k_gemm3<<<dim3(4, 32, 3), 256, 0, stream>>>(xt, jq, jk, jv, 256, 256);
    }
    k_spe_attn<<<256, 256, 0, stream>>>(q2, k2t, v2, sowt, so_b, xs, sidx, xr);
    k_conv_gemm<<<dim3(2, 16, 4), 256, 0, stream>>>(xr, ds_conv_w, part);
    k_part_ln<<<1024, 128, 0, stream>>>(part, ds_ln_w, ds_ln_b, (float*)d_out);
}

// Round 12
// 601.006 us; speedup vs baseline: 1.7716x; 1.0176x over previous
//
#include <hip/hip_runtime.h>
#include <math.h>

#define DEV __device__ __forceinline__

DEV float siluf(float x){ return x / (1.f + __expf(-x)); }
DEV float softplusf(float x){ return (x > 20.f) ? x : log1pf(__expf(x)); }

// ---------- block reduction helpers (wave64) ----------
DEV void blk_sum2(float &a, float &b, float* sm){
    int lane = threadIdx.x & 63, wid = threadIdx.x >> 6, nw = blockDim.x >> 6;
    #pragma unroll
    for (int off = 32; off; off >>= 1){ a += __shfl_down(a, off); b += __shfl_down(b, off); }
    if (lane == 0){ sm[wid] = a; sm[8 + wid] = b; }
    __syncthreads();
    float ra = 0.f, rb = 0.f;
    for (int i = 0; i < nw; i++){ ra += sm[i]; rb += sm[8 + i]; }
    __syncthreads();
    a = ra; b = rb;
}
DEV float blk_sum1(float v, float* sm){
    int lane = threadIdx.x & 63, wid = threadIdx.x >> 6, nw = blockDim.x >> 6;
    #pragma unroll
    for (int off = 32; off; off >>= 1) v += __shfl_down(v, off);
    if (lane == 0) sm[wid] = v;
    __syncthreads();
    float r = 0.f;
    for (int i = 0; i < nw; i++) r += sm[i];
    __syncthreads();
    return r;
}
DEV float blk_max1(float v, float* sm){
    int lane = threadIdx.x & 63, wid = threadIdx.x >> 6, nw = blockDim.x >> 6;
    #pragma unroll
    for (int off = 32; off; off >>= 1) v = fmaxf(v, __shfl_down(v, off));
    if (lane == 0) sm[wid] = v;
    __syncthreads();
    float r = -3.4e38f;
    for (int i = 0; i < nw; i++) r = fmaxf(r, sm[i]);
    __syncthreads();
    return r;
}

// ---------- transpose body ----------
DEV void tr_body(const float* __restrict__ ip, float* __restrict__ op,
                 int R, int C, int c0, int r0){
    __shared__ float tile[32][33];
    int tx = threadIdx.x & 31, ty = threadIdx.x >> 5;
    #pragma unroll
    for (int rr = ty; rr < 32; rr += 8)
        tile[rr][tx] = ip[(size_t)(r0 + rr) * C + c0 + tx];
    __syncthreads();
    #pragma unroll
    for (int rr = ty; rr < 32; rr += 8)
        op[(size_t)(c0 + rr) * R + r0 + tx] = tile[tx][rr];
}

__global__ __launch_bounds__(256) void k_tr(const float* __restrict__ in,
                                            float* __restrict__ out, int R, int C){
    tr_body(in + (size_t)blockIdx.z * R * C, out + (size_t)blockIdx.z * R * C,
            R, C, blockIdx.x * 32, blockIdx.y * 32);
}

// packed: job0 x->xT (512 blks), job1 ao_w (16), job2 so_w (64)
__global__ __launch_bounds__(256) void k_tr_multi(const float* __restrict__ x,
        float* __restrict__ xT, const float* __restrict__ aow, float* __restrict__ owt,
        const float* __restrict__ sow, float* __restrict__ sowt){
    int idx = blockIdx.x;
    if (idx < 512){
        int bx = idx & 7, by = (idx >> 3) & 3, bz = idx >> 5;
        tr_body(x + (size_t)bz * 32768, xT + (size_t)bz * 32768, 128, 256, bx * 32, by * 32);
    } else if (idx < 528){
        int l = idx - 512;
        tr_body(aow, owt, 128, 128, (l & 3) * 32, (l >> 2) * 32);
    } else {
        int l = idx - 528;
        tr_body(sow, sowt, 256, 256, (l & 7) * 32, (l >> 3) * 32);
    }
}

// ---------- K1: pos-embed + gather (xT = x pre-transposed to [b][p][c]) ----------
__global__ void k_embed(const float* __restrict__ xT, const int* __restrict__ sidx,
                        float* __restrict__ xs){
    int bl = blockIdx.x; int b = bl >> 8; int c = threadIdx.x;
    int p = sidx[bl];
    int hh = p >> 4, ww = p & 15;
    int pos = (c < 64) ? hh : ww;
    int jm = c & 63;
    float om = __expf(-(float)(jm & 31) * 0.28782313662425574f); // ln(10000)/32
    float ang = (float)pos * om;
    float pe = (jm < 32) ? sinf(ang) : cosf(ang);
    xs[(size_t)bl * 128 + c] = xT[((size_t)(b * 256 + p)) * 128 + c] + pe;
}

// ---------- LayerNorm (block per row) ----------
__global__ void k_ln(const float* __restrict__ in, const float* __restrict__ w,
                     const float* __restrict__ bb, float* __restrict__ out, int dim){
    __shared__ float sm[16];
    int row = blockIdx.x, t = threadIdx.x;
    float v = in[(size_t)row * dim + t];
    float a = v, q = v * v;
    blk_sum2(a, q, sm);
    float inv = 1.f / (float)dim;
    float mu = a * inv;
    float var = q * inv - mu * mu;
    float rs = rsqrtf(var + 1e-5f);
    out[(size_t)row * dim + t] = (v - mu) * rs * w[t] + bb[t];
}

// ---------- in-projection GEMM with fused LayerNorm over K (64-tile, pipelined) ----------
__global__ __launch_bounds__(256) void k_gemm_ln(const float* __restrict__ A,
        const float* __restrict__ W, const float* __restrict__ lw,
        const float* __restrict__ lb, float* __restrict__ out, int N, int K){
    __shared__ float lds[2][32][68];
    int j0 = blockIdx.x * 64, r0 = blockIdx.y * 64;
    int tid = threadIdx.x;
    int cg = tid & 15, rg = tid >> 4;
    int row = tid >> 2, kg = tid & 3;
    int wrow = j0 + row; if (wrow > N - 1) wrow = N - 1;
    const float* Ar  = A + (size_t)(r0 + row) * K + kg * 4;
    const float* Wr  = W + (size_t)wrow * K + kg * 4;
    const float* lwr = lw + kg * 4;
    const float* lbr = lb + kg * 4;
    float s = 0.f, ss = 0.f;
    for (int k0 = 0; k0 < K; k0 += 32){
        float4 a0 = *(const float4*)(Ar + k0);
        float4 a1 = *(const float4*)(Ar + k0 + 16);
        s  += a0.x + a0.y + a0.z + a0.w + a1.x + a1.y + a1.z + a1.w;
        ss += a0.x*a0.x + a0.y*a0.y + a0.z*a0.z + a0.w*a0.w
            + a1.x*a1.x + a1.y*a1.y + a1.z*a1.z + a1.w*a1.w;
    }
    s  += __shfl_xor(s, 1);  ss += __shfl_xor(ss, 1);
    s  += __shfl_xor(s, 2);  ss += __shfl_xor(ss, 2);
    float inv = 1.f / (float)K;
    float mu = s * inv;
    float rs = rsqrtf(ss * inv - mu * mu + 1e-5f);
    float4 a0 = *(const float4*)(Ar);
    float4 a1 = *(const float4*)(Ar + 16);
    float4 w0 = *(const float4*)(lwr);
    float4 w1 = *(const float4*)(lwr + 16);
    float4 b0 = *(const float4*)(lbr);
    float4 b1 = *(const float4*)(lbr + 16);
    float4 v0 = *(const float4*)(Wr);
    float4 v1 = *(const float4*)(Wr + 16);
    float acc[4][4] = {};
    for (int k0 = 0; k0 < K; k0 += 32){
        a0.x = (a0.x - mu) * rs * w0.x + b0.x; a0.y = (a0.y - mu) * rs * w0.y + b0.y;
        a0.z = (a0.z - mu) * rs * w0.z + b0.z; a0.w = (a0.w - mu) * rs * w0.w + b0.w;
        a1.x = (a1.x - mu) * rs * w1.x + b1.x; a1.y = (a1.y - mu) * rs * w1.y + b1.y;
        a1.z = (a1.z - mu) * rs * w1.z + b1.z; a1.w = (a1.w - mu) * rs * w1.w + b1.w;
        __syncthreads();
        lds[0][kg * 4 + 0][row] = a0.x; lds[0][kg * 4 + 1][row] = a0.y;
        lds[0][kg * 4 + 2][row] = a0.z; lds[0][kg * 4 + 3][row] = a0.w;
        lds[0][16 + kg * 4 + 0][row] = a1.x; lds[0][16 + kg * 4 + 1][row] = a1.y;
        lds[0][16 + kg * 4 + 2][row] = a1.z; lds[0][16 + kg * 4 + 3][row] = a1.w;
        lds[1][kg * 4 + 0][row] = v0.x; lds[1][kg * 4 + 1][row] = v0.y;
        lds[1][kg * 4 + 2][row] = v0.z; lds[1][kg * 4 + 3][row] = v0.w;
        lds[1][16 + kg * 4 + 0][row] = v1.x; lds[1][16 + kg * 4 + 1][row] = v1.y;
        lds[1][16 + kg * 4 + 2][row] = v1.z; lds[1][16 + kg * 4 + 3][row] = v1.w;
        __syncthreads();
        bool more = (k0 + 32 < K);
        float4 na0, na1, nw0, nw1, nb0, nb1, nv0, nv1;
        if (more){
            na0 = *(const float4*)(Ar + k0 + 32);
            na1 = *(const float4*)(Ar + k0 + 48);
            nw0 = *(const float4*)(lwr + k0 + 32);
            nw1 = *(const float4*)(lwr + k0 + 48);
            nb0 = *(const float4*)(lbr + k0 + 32);
            nb1 = *(const float4*)(lbr + k0 + 48);
            nv0 = *(const float4*)(Wr + k0 + 32);
            nv1 = *(const float4*)(Wr + k0 + 48);
        }
        #pragma unroll
        for (int kk = 0; kk < 32; kk++){
            float4 a4 = *(const float4*)(&lds[0][kk][rg << 2]);
            float4 w4 = *(const float4*)(&lds[1][kk][cg << 2]);
            float av_[4] = {a4.x, a4.y, a4.z, a4.w};
            float wv_[4] = {w4.x, w4.y, w4.z, w4.w};
            #pragma unroll
            for (int ri = 0; ri < 4; ri++)
                #pragma unroll
                for (int ci = 0; ci < 4; ci++)
                    acc[ri][ci] = fmaf(av_[ri], wv_[ci], acc[ri][ci]);
        }
        if (more){
            a0 = na0; a1 = na1; w0 = nw0; w1 = nw1;
            b0 = nb0; b1 = nb1; v0 = nv0; v1 = nv1;
        }
    }
    #pragma unroll
    for (int ri = 0; ri < 4; ri++){
        int r = r0 + (rg << 2) + ri;
        int j = j0 + (cg << 2);
        if (j < N){
            float4 v = make_float4(acc[ri][0], acc[ri][1], acc[ri][2], acc[ri][3]);
            *(float4*)(&out[(size_t)r * N + j]) = v;
        }
    }
}

// ---------- out-projection GEMM, 32x32 tiles, fused gate+RMS (pipelined) ----------
// Grid (N/32, M/32), 256 thr, 4 outputs/thread (row rg, cols cg*4..+3).
// mode 1: out[r*N+j] = .*scale + res   mode 2: transposed scatter (N==256)
__global__ __launch_bounds__(256) void k_gemm_gate(const float* __restrict__ Y,
        const float* __restrict__ Z, const float* __restrict__ rw,
        const float* __restrict__ W, const float* __restrict__ res,
        float* __restrict__ out, int N, int K, int zs, int mode){
    __shared__ float lA[32][36];
    __shared__ float lW[32][36];
    __shared__ float sscale[32];
    int j0 = blockIdx.x * 32, r0 = blockIdx.y * 32;
    int tid = threadIdx.x;
    int srow = tid >> 3, kseg = tid & 7; // staging + ssq: row, k-seg (8 lanes/row)
    int rg = tid >> 3, cg = tid & 7;     // compute: row rg, col group cg
    const float* Yr = Y + (size_t)(r0 + srow) * K + kseg * 4;
    const float* Zr = Z + (size_t)(r0 + srow) * zs + kseg * 4;
    const float* Gr = rw + kseg * 4;
    const float* Wr = W + (size_t)(j0 + srow) * K + kseg * 4;
    float ssq = 0.f;
    float acc[4] = {};
    float4 y4 = *(const float4*)(Yr);
    float4 z4 = *(const float4*)(Zr);
    float4 g4 = *(const float4*)(Gr);
    float4 w4 = *(const float4*)(Wr);
    for (int k0 = 0; k0 < K; k0 += 32){
        y4.x *= siluf(z4.x); y4.y *= siluf(z4.y);
        y4.z *= siluf(z4.z); y4.w *= siluf(z4.w);
        ssq += y4.x*y4.x + y4.y*y4.y + y4.z*y4.z + y4.w*y4.w;
        y4.x *= g4.x; y4.y *= g4.y; y4.z *= g4.z; y4.w *= g4.w;
        __syncthreads();
        lA[kseg * 4 + 0][srow] = y4.x; lA[kseg * 4 + 1][srow] = y4.y;
        lA[kseg * 4 + 2][srow] = y4.z; lA[kseg * 4 + 3][srow] = y4.w;
        lW[kseg * 4 + 0][srow] = w4.x; lW[kseg * 4 + 1][srow] = w4.y;
        lW[kseg * 4 + 2][srow] = w4.z; lW[kseg * 4 + 3][srow] = w4.w;
        __syncthreads();
        bool more = (k0 + 32 < K);
        float4 ny4, nz4, ng4, nw4;
        if (more){
            ny4 = *(const float4*)(Yr + k0 + 32);
            nz4 = *(const float4*)(Zr + k0 + 32);
            ng4 = *(const float4*)(Gr + k0 + 32);
            nw4 = *(const float4*)(Wr + k0 + 32);
        }
        #pragma unroll
        for (int kk = 0; kk < 32; kk++){
            float a = lA[kk][rg];
            float4 wv = *(const float4*)(&lW[kk][cg << 2]);
            acc[0] = fmaf(a, wv.x, acc[0]);
            acc[1] = fmaf(a, wv.y, acc[1]);
            acc[2] = fmaf(a, wv.z, acc[2]);
            acc[3] = fmaf(a, wv.w, acc[3]);
        }
        if (more){ y4 = ny4; z4 = nz4; g4 = ng4; w4 = nw4; }
    }
    ssq += __shfl_xor(ssq, 1);
    ssq += __shfl_xor(ssq, 2);
    ssq += __shfl_xor(ssq, 4);
    if (kseg == 0) sscale[srow] = rsqrtf(ssq / (float)K + 1e-5f);
    __syncthreads(); // sscale visible AND all lA/lW reads complete
    float sc = sscale[rg];
    if (mode == 2){
        float (*T)[36] = lA; // reuse
        #pragma unroll
        for (int c = 0; c < 4; c++) T[(cg << 2) + c][rg] = acc[c] * sc;
        __syncthreads();
        int b2 = r0 >> 7, ii0 = r0 & 127;
        int jj = tid >> 3, seg = tid & 7;
        size_t base = ((size_t)(b2 * 256 + j0 + jj)) * 128 + ii0 + seg * 4;
        float4 v = make_float4(T[jj][seg * 4 + 0], T[jj][seg * 4 + 1],
                               T[jj][seg * 4 + 2], T[jj][seg * 4 + 3]);
        float4 rv = *(const float4*)(res + base);
        v.x += rv.x; v.y += rv.y; v.z += rv.z; v.w += rv.w;
        *(float4*)(out + base) = v;
    } else {
        int r = r0 + rg, j = j0 + (cg << 2);
        float4 rv = *(const float4*)(&res[(size_t)r * N + j]);
        float4 v = make_float4(acc[0] * sc + rv.x, acc[1] * sc + rv.y,
                               acc[2] * sc + rv.z, acc[3] * sc + rv.w);
        *(float4*)(&out[(size_t)r * N + j]) = v;
    }
}

// ---------- generic 32x32 GEMM core (qkv batch), pipelined ----------
// mode 0: +bias, normal store.  mode 3: transposed scatter (N==256) + bias.
DEV void gemm_core32(const float* __restrict__ A, const float* __restrict__ W,
                     const float* __restrict__ bias, float* __restrict__ out,
                     int N, int K, int mode, int j0, int r0){
    __shared__ float lA[32][36];
    __shared__ float lW[32][36];
    int tid = threadIdx.x;
    int srow = tid >> 3, kseg = tid & 7;
    int rg = tid >> 3, cg = tid & 7;
    const float* Ap = A + (size_t)(r0 + srow) * K + kseg * 4;
    const float* Wp = W + (size_t)(j0 + srow) * K + kseg * 4;
    float4 a4 = *(const float4*)(Ap);
    float4 w4 = *(const float4*)(Wp);
    float acc[4] = {};
    for (int k0 = 0; k0 < K; k0 += 32){
        __syncthreads();
        lA[kseg * 4 + 0][srow] = a4.x; lA[kseg * 4 + 1][srow] = a4.y;
        lA[kseg * 4 + 2][srow] = a4.z; lA[kseg * 4 + 3][srow] = a4.w;
        lW[kseg * 4 + 0][srow] = w4.x; lW[kseg * 4 + 1][srow] = w4.y;
        lW[kseg * 4 + 2][srow] = w4.z; lW[kseg * 4 + 3][srow] = w4.w;
        __syncthreads();
        bool more = (k0 + 32 < K);
        float4 na4, nw4;
        if (more){
            na4 = *(const float4*)(Ap + k0 + 32);
            nw4 = *(const float4*)(Wp + k0 + 32);
        }
        #pragma unroll
        for (int kk = 0; kk < 32; kk++){
            float a = lA[kk][rg];
            float4 wv = *(const float4*)(&lW[kk][cg << 2]);
            acc[0] = fmaf(a, wv.x, acc[0]);
            acc[1] = fmaf(a, wv.y, acc[1]);
            acc[2] = fmaf(a, wv.z, acc[2]);
            acc[3] = fmaf(a, wv.w, acc[3]);
        }
        if (more){ a4 = na4; w4 = nw4; }
    }
    if (mode == 3){
        __syncthreads();
        float (*T)[36] = lA;
        #pragma unroll
        for (int c = 0; c < 4; c++) T[(cg << 2) + c][rg] = acc[c];
        __syncthreads();
        int b2 = r0 >> 7, ii0 = r0 & 127;
        int jj = tid >> 3, seg = tid & 7;
        size_t base = ((size_t)(b2 * 256 + j0 + jj)) * 128 + ii0 + seg * 4;
        float bj = bias[j0 + jj];
        float4 v = make_float4(T[jj][seg * 4 + 0] + bj, T[jj][seg * 4 + 1] + bj,
                               T[jj][seg * 4 + 2] + bj, T[jj][seg * 4 + 3] + bj);
        *(float4*)(out + base) = v;
    } else {
        int r = r0 + rg, j = j0 + (cg << 2);
        float4 bv = *(const float4*)(bias + j);
        float4 v = make_float4(acc[0] + bv.x, acc[1] + bv.y,
                               acc[2] + bv.z, acc[3] + bv.w);
        *(float4*)(&out[(size_t)r * N + j]) = v;
    }
}

struct GJob { const float* W; const float* bias; float* out; int mode; };

__global__ __launch_bounds__(256) void k_gemm3(const float* __restrict__ A,
                                               GJob ja, GJob jb, GJob jc,
                                               int N, int K){
    GJob j = (blockIdx.z == 0) ? ja : ((blockIdx.z == 1) ? jb : jc);
    gemm_core32(A, j.W, j.bias, j.out, N, K, j.mode, blockIdx.x * 32, blockIdx.y * 32);
}

// ---------- causal depthwise conv(4)+bias+silu, fused dt / log-dA ----------
__global__ void k_conv(const float* __restrict__ zx, const float* __restrict__ cw,
                       const float* __restrict__ cb, float* __restrict__ xc,
                       const float* __restrict__ dtbias, const float* __restrict__ Al,
                       float* __restrict__ dt, float* __restrict__ dlA,
                       int L, int D, int stride, int off, int nh, int dtoff){
    int bl = blockIdx.x;
    int l = bl & (L - 1);
    const float* base = zx + (size_t)bl * stride + off;
    for (int d = threadIdx.x; d < D; d += blockDim.x){
        float acc = cb[d];
        #pragma unroll
        for (int k = 0; k < 4; k++){
            int dl = l + k - 3;
            if (dl >= 0) acc += base[(ptrdiff_t)(k - 3) * stride + d] * cw[d * 4 + k];
        }
        xc[(size_t)bl * D + d] = siluf(acc);
    }
    int t = threadIdx.x;
    if (t < nh){
        float xv = zx[(size_t)bl * stride + dtoff + t] + dtbias[t];
        float d = softplusf(xv);
        dt[(size_t)bl * nh + t] = d;
        dlA[(size_t)bl * nh + t] = -d * __expf(Al[t]); // log(dA) <= 0
    }
}

// ---------- chunked SSD, stage A ----------
__global__ __launch_bounds__(256) void k_ssd_chunk(
        const float* __restrict__ xc, const float* __restrict__ dt,
        const float* __restrict__ dlA, float* __restrict__ y,
        float* __restrict__ S, float* __restrict__ clb,
        int L, int nh, int nc, int xcs, int bo, int co, int ys){
    __shared__ float sX[64][68];
    __shared__ float sB[64][68];
    __shared__ float sC[64][68]; // phase1: C ; after: masked G
    __shared__ float cl[64], sdt[64], sw[64];
    int blk = blockIdx.x;
    int c = blk % nc; int bh = blk / nc; int h = bh % nh; int b = bh / nh;
    int l0 = c * 64;
    int tid = threadIdx.x;
    const float* base = xc + ((size_t)(b * L + l0)) * xcs;
    for (int idx = tid; idx < 4096; idx += 256){
        int s = idx >> 6, n = idx & 63;
        const float* row = base + (size_t)s * xcs;
        sX[s][n] = row[h * 64 + n];
        sB[s][n] = row[bo + n];
        sC[s][n] = row[co + n];
    }
    if (tid < 64){
        size_t di = (size_t)(b * L + l0 + tid) * nh + h;
        float dlv = dlA[di];
        sdt[tid] = dt[di];
        #pragma unroll
        for (int off = 1; off < 64; off <<= 1){
            float o = __shfl_up(dlv, off, 64);
            if (tid >= off) dlv += o;
        }
        cl[tid] = dlv;
        clb[(size_t)blk * 64 + tid] = dlv;
    }
    __syncthreads();
    if (tid < 64) sw[tid] = __expf(cl[63] - cl[tid]) * sdt[tid];

    int g1 = tid >> 4, g2 = tid & 15;
    int t0 = g1 * 4, s0 = g2 * 4;
    float g[4][4] = {};
    for (int n = 0; n < 64; n += 4){
        float4 cv[4], bv[4];
        #pragma unroll
        for (int i = 0; i < 4; i++) cv[i] = *(const float4*)&sC[t0 + i][n];
        #pragma unroll
        for (int j = 0; j < 4; j++) bv[j] = *(const float4*)&sB[s0 + j][n];
        #pragma unroll
        for (int i = 0; i < 4; i++)
            #pragma unroll
            for (int j = 0; j < 4; j++){
                g[i][j] = fmaf(cv[i].x, bv[j].x, g[i][j]);
                g[i][j] = fmaf(cv[i].y, bv[j].y, g[i][j]);
                g[i][j] = fmaf(cv[i].z, bv[j].z, g[i][j]);
                g[i][j] = fmaf(cv[i].w, bv[j].w, g[i][j]);
            }
    }
    __syncthreads();
    #pragma unroll
    for (int i = 0; i < 4; i++)
        #pragma unroll
        for (int j = 0; j < 4; j++){
            int t = t0 + i, s = s0 + j;
            float v = 0.f;
            if (s <= t) v = g[i][j] * __expf(cl[t] - cl[s]) * sdt[s];
            sC[t][s] = v;
        }
    __syncthreads();
    {
        float acc[4][4] = {};
        for (int s = 0; s < 64; s++){
            float4 xv = *(const float4*)&sX[s][s0];
            float gv[4];
            #pragma unroll
            for (int i = 0; i < 4; i++) gv[i] = sC[t0 + i][s];
            #pragma unroll
            for (int i = 0; i < 4; i++){
                acc[i][0] = fmaf(gv[i], xv.x, acc[i][0]);
                acc[i][1] = fmaf(gv[i], xv.y, acc[i][1]);
                acc[i][2] = fmaf(gv[i], xv.z, acc[i][2]);
                acc[i][3] = fmaf(gv[i], xv.w, acc[i][3]);
            }
        }
        #pragma unroll
        for (int i = 0; i < 4; i++){
            float4 o = make_float4(acc[i][0], acc[i][1], acc[i][2], acc[i][3]);
            *(float4*)&y[(size_t)(b * L + l0 + t0 + i) * ys + h * 64 + s0] = o;
        }
    }
    {
        float acc[4][4] = {};
        int p0 = t0, n0 = s0;
        for (int s = 0; s < 64; s++){
            float wv = sw[s];
            float4 bv = *(const float4*)&sB[s][n0];
            float4 xv = *(const float4*)&sX[s][p0];
            float w0 = wv * xv.x, w1 = wv * xv.y, w2 = wv * xv.z, w3 = wv * xv.w;
            acc[0][0] = fmaf(w0, bv.x, acc[0][0]); acc[0][1] = fmaf(w0, bv.y, acc[0][1]);
            acc[0][2] = fmaf(w0, bv.z, acc[0][2]); acc[0][3] = fmaf(w0, bv.w, acc[0][3]);
            acc[1][0] = fmaf(w1, bv.x, acc[1][0]); acc[1][1] = fmaf(w1, bv.y, acc[1][1]);
            acc[1][2] = fmaf(w1, bv.z, acc[1][2]); acc[1][3] = fmaf(w1, bv.w, acc[1][3]);
            acc[2][0] = fmaf(w2, bv.x, acc[2][0]); acc[2][1] = fmaf(w2, bv.y, acc[2][1]);
            acc[2][2] = fmaf(w2, bv.z, acc[2][2]); acc[2][3] = fmaf(w2, bv.w, acc[2][3]);
            acc[3][0] = fmaf(w3, bv.x, acc[3][0]); acc[3][1] = fmaf(w3, bv.y, acc[3][1]);
            acc[3][2] = fmaf(w3, bv.z, acc[3][2]); acc[3][3] = fmaf(w3, bv.w, acc[3][3]);
        }
        float* Sp = S + (size_t)blk * 4096;
        #pragma unroll
        for (int i = 0; i < 4; i++){
            float4 o = make_float4(acc[i][0], acc[i][1], acc[i][2], acc[i][3]);
            *(float4*)&Sp[(p0 + i) * 64 + n0] = o;
        }
    }
}

// ---------- chunked SSD, stage B+C fused ----------
__global__ __launch_bounds__(256) void k_chunk_y(
        const float* __restrict__ xc, const float* __restrict__ S,
        const float* __restrict__ clb, const float* __restrict__ Dp,
        float* __restrict__ y,
        int L, int nh, int nc, int xcs, int co, int ys){
    __shared__ float sH[64][68];
    __shared__ float sC[64][68];
    __shared__ float scl[64];
    int blk = blockIdx.x;
    int c = blk % nc; int bh = blk / nc; int h = bh % nh; int b = bh / nh;
    int l0 = c * 64;
    int tid = threadIdx.x;
    float wch[4];
    {
        float w = 1.f;
        for (int cp = c - 1; cp >= 0; cp--){
            wch[cp] = w;
            w *= __expf(clb[((size_t)(bh * nc + cp)) * 64 + 63]);
        }
    }
    const float* Sb = S + (size_t)(bh * nc) * 4096;
    const float* base = xc + ((size_t)(b * L + l0)) * xcs;
    for (int idx = tid; idx < 4096; idx += 256){
        int r = idx >> 6, n = idx & 63;
        float hv = 0.f;
        for (int cp = 0; cp < c; cp++)
            hv = fmaf(wch[cp], Sb[(size_t)cp * 4096 + idx], hv);
        sH[r][n] = hv;
        sC[r][n] = base[(size_t)r * xcs + co + n];
    }
    if (tid < 64) scl[tid] = __expf(clb[(size_t)blk * 64 + tid]);
    float Dh = Dp[h];
    __syncthreads();
    int g1 = tid >> 4, g2 = tid & 15;
    int t0 = g1 * 4, p0 = g2 * 4;
    float m[4][4] = {};
    for (int n = 0; n < 64; n += 4){
        float4 cv[4], hv[4];
        #pragma unroll
        for (int i = 0; i < 4; i++) cv[i] = *(const float4*)&sC[t0 + i][n];
        #pragma unroll
        for (int j = 0; j < 4; j++) hv[j] = *(const float4*)&sH[p0 + j][n];
        #pragma unroll
        for (int i = 0; i < 4; i++)
            #pragma unroll
            for (int j = 0; j < 4; j++){
                m[i][j] = fmaf(cv[i].x, hv[j].x, m[i][j]);
                m[i][j] = fmaf(cv[i].y, hv[j].y, m[i][j]);
                m[i][j] = fmaf(cv[i].z, hv[j].z, m[i][j]);
                m[i][j] = fmaf(cv[i].w, hv[j].w, m[i][j]);
            }
    }
    #pragma unroll
    for (int i = 0; i < 4; i++){
        int t = t0 + i;
        size_t yi = (size_t)(b * L + l0 + t) * ys + h * 64 + p0;
        float4 yv = *(float4*)&y[yi];
        float4 xv = *(const float4*)&base[(size_t)t * xcs + h * 64 + p0];
        float e = scl[t];
        yv.x += e * m[i][0] + Dh * xv.x;
        yv.y += e * m[i][1] + Dh * xv.y;
        yv.z += e * m[i][2] + Dh * xv.z;
        yv.w += e * m[i][3] + Dh * xv.w;
        *(float4*)&y[yi] = yv;
    }
}

// ---------- center projection + q ----------
__global__ void k_center_q(const float* __restrict__ xs, const float* __restrict__ cw,
                           const float* __restrict__ cb, const float* __restrict__ qw,
                           const float* __restrict__ qb, float* __restrict__ q){
    __shared__ float xr[640];
    __shared__ float cen[128];
    int b = blockIdx.x, t = threadIdx.x; // 128 thr
    for (int idx = t; idx < 640; idx += 128)
        xr[idx] = xs[(size_t)b * 256 * 128 + idx];
    __syncthreads();
    float acc = cb[t];
    for (int c = 0; c < 128; c++){
        const float* wp = cw + (size_t)(t * 128 + c) * 5;
        #pragma unroll
        for (int l = 0; l < 5; l++) acc += xr[l * 128 + c] * wp[l];
    }
    cen[t] = acc;
    __syncthreads();
    float qa = qb[t];
    const float* wr = qw + (size_t)t * 128;
    for (int o = 0; o < 128; o++) qa += cen[o] * wr[o];
    q[b * 128 + t] = qa;
}

// ---------- attention softmax over l ----------
__global__ void k_attn(const float* __restrict__ q, const float* __restrict__ k,
                       float* __restrict__ attn){
    __shared__ float sm[16];
    __shared__ float qh[16];
    int blk = blockIdx.x; int b = blk >> 3, h = blk & 7; int l = threadIdx.x; // 256 thr
    if (l < 16) qh[l] = q[b * 128 + h * 16 + l];
    __syncthreads();
    const float* kp = k + ((size_t)(b * 256 + l)) * 128 + h * 16;
    float s = 0.f;
    #pragma unroll
    for (int d = 0; d < 16; d++) s += qh[d] * kp[d];
    s *= 0.25f;
    float mx = blk_max1(s, sm);
    float e = __expf(s - mx);
    float sum = blk_sum1(e, sm);
    attn[(size_t)blk * 256 + l] = e / sum;
}

// ---------- attention out, 8 l-rows per block ----------
__global__ __launch_bounds__(128) void k_attn_out(const float* __restrict__ v,
                                                  const float* __restrict__ attn,
                                                  const float* __restrict__ owt,
                                                  const float* __restrict__ ob,
                                                  float* __restrict__ xs){
    __shared__ float vp[8][128];
    int blk = blockIdx.x; int b = blk >> 5, l0 = (blk & 31) << 3;
    int t = threadIdx.x; // 128 thr
    int h = t >> 4;
    float a[8];
    #pragma unroll
    for (int r = 0; r < 8; r++)
        a[r] = attn[((size_t)(b * 8 + h)) * 256 + l0 + r];
    #pragma unroll
    for (int r = 0; r < 8; r++)
        vp[r][t] = v[((size_t)(b * 256 + l0 + r)) * 128 + t] * a[r];
    __syncthreads();
    float acc[8];
    float bv = ob[t];
    #pragma unroll
    for (int r = 0; r < 8; r++) acc[r] = bv;
    for (int j = 0; j < 128; j++){
        float w = owt[j * 128 + t];
        #pragma unroll
        for (int r = 0; r < 8; r++) acc[r] = fmaf(vp[r][j], w, acc[r]);
    }
    #pragma unroll
    for (int r = 0; r < 8; r++)
        xs[((size_t)(b * 256 + l0 + r)) * 128 + t] += acc[r];
}

// ---------- fused spectral attention: QK+softmax+AV+SO+residual+unsort ----------
__global__ __launch_bounds__(256) void k_spe_attn(const float* __restrict__ q2,
        const float* __restrict__ k2t, const float* __restrict__ v2,
        const float* __restrict__ sowt, const float* __restrict__ sob,
        const float* __restrict__ xs, const int* __restrict__ sidx,
        float* __restrict__ xr){
    __shared__ float qs[8][256];
    __shared__ float lgp[2][8][128];
    __shared__ float sa[8][132];
    __shared__ float av[8][256];
    __shared__ float mxs[8], sms[8];
    int blk = blockIdx.x; int b = blk >> 4; int i0 = (blk & 15) << 3;
    int t = threadIdx.x;
    for (int idx = t; idx < 2048; idx += 256){
        int ii = idx >> 8, d = idx & 255;
        qs[ii][d] = q2[((size_t)(b * 128 + i0 + ii)) * 256 + d];
    }
    __syncthreads();
    {
        int j = t & 127, dh = t >> 7;
        const float* kt = k2t + (size_t)b * 32768 + dh * 16384;
        float acc[8] = {};
        for (int dd = 0; dd < 128; dd++){
            float kv = kt[dd * 128 + j];
            int d = dh * 128 + dd;
            #pragma unroll
            for (int ii = 0; ii < 8; ii++) acc[ii] = fmaf(qs[ii][d], kv, acc[ii]);
        }
        #pragma unroll
        for (int ii = 0; ii < 8; ii++) lgp[dh][ii][j] = acc[ii];
    }
    __syncthreads();
    if (t < 128){
        #pragma unroll
        for (int ii = 0; ii < 8; ii++)
            sa[ii][t] = (lgp[0][ii][t] + lgp[1][ii][t]) * (1.f / 16.f);
    }
    __syncthreads();
    if (t < 8){
        float mx = -3.4e38f;
        for (int j = 0; j < 128; j++) mx = fmaxf(mx, sa[t][j]);
        float sm = 0.f;
        for (int j = 0; j < 128; j++) sm += __expf(sa[t][j] - mx);
        mxs[t] = mx; sms[t] = 1.f / sm;
    }
    __syncthreads();
    if (t < 128){
        #pragma unroll
        for (int ii = 0; ii < 8; ii++)
            sa[ii][t] = __expf(sa[ii][t] - mxs[ii]) * sms[ii];
    }
    __syncthreads();
    {
        float acc[8] = {};
        const float* vb = v2 + (size_t)b * 32768 + t;
        for (int j = 0; j < 128; j++){
            float vv = vb[(size_t)j * 256];
            #pragma unroll
            for (int ii = 0; ii < 8; ii++) acc[ii] = fmaf(sa[ii][j], vv, acc[ii]);
        }
        #pragma unroll
        for (int ii = 0; ii < 8; ii++) av[ii][t] = acc[ii];
    }
    __syncthreads();
    float acc[8] = {};
    for (int d = 0; d < 256; d++){
        float wv = sowt[d * 256 + t];
        #pragma unroll
        for (int ii = 0; ii < 8; ii++) acc[ii] = fmaf(av[ii][d], wv, acc[ii]);
    }
    float bias = sob[t];
    int p = sidx[b * 256 + t];
    const float* xin = xs + ((size_t)(b * 256 + t)) * 128 + i0;
    float* xout = xr + ((size_t)(b * 256 + p)) * 128 + i0;
    #pragma unroll
    for (int ii = 0; ii < 8; ii++) xout[ii] = xin[ii] + acc[ii] + bias;
}

// ---------- conv GEMM split-K=4 with fused im2col (pipelined) ----------
__global__ __launch_bounds__(256) void k_conv_gemm(const float* __restrict__ xr,
                                                   const float* __restrict__ W2,
                                                   float* __restrict__ part){
    __shared__ float As[16][68];
    __shared__ float Ws[16][64];
    int j0 = blockIdx.x * 64, r0 = blockIdx.y * 64, s = blockIdx.z;
    int tid = threadIdx.x;
    int cg = tid & 15, rg = tid >> 4;
    int arow = tid >> 2, akg = tid & 3;
    int wkk = tid >> 4, wseg = tid & 15;
    int r = r0 + arow; int b = r >> 6, oh = (r >> 3) & 7, ow = r & 7;
    float acc[4][4] = {};
    int kbeg = s * 288, kend = kbeg + 288;
    float4 a4, w4;
    {
        int k = kbeg + akg * 4;
        int khw = k >> 7, c = k & 127;
        int kh = khw / 3, kw = khw - kh * 3;
        int ih = oh * 2 - 1 + kh, iw = ow * 2 - 1 + kw;
        a4 = make_float4(0.f, 0.f, 0.f, 0.f);
        if (ih >= 0 && ih < 16 && iw >= 0 && iw < 16)
            a4 = *(const float4*)(xr + ((size_t)((b << 8) + (ih << 4) + iw)) * 128 + c);
        w4 = *(const float4*)(W2 + (size_t)(kbeg + wkk) * 128 + j0 + wseg * 4);
    }
    for (int k0 = kbeg; k0 < kend; k0 += 16){
        __syncthreads();
        As[akg * 4 + 0][arow] = a4.x; As[akg * 4 + 1][arow] = a4.y;
        As[akg * 4 + 2][arow] = a4.z; As[akg * 4 + 3][arow] = a4.w;
        Ws[wkk][wseg * 4 + 0] = w4.x; Ws[wkk][wseg * 4 + 1] = w4.y;
        Ws[wkk][wseg * 4 + 2] = w4.z; Ws[wkk][wseg * 4 + 3] = w4.w;
        __syncthreads();
        bool more = (k0 + 16 < kend);
        float4 na4, nw4;
        if (more){
            int k = k0 + 16 + akg * 4;
            int khw = k >> 7, c = k & 127;
            int kh = khw / 3, kw = khw - kh * 3;
            int ih = oh * 2 - 1 + kh, iw = ow * 2 - 1 + kw;
            na4 = make_float4(0.f, 0.f, 0.f, 0.f);
            if (ih >= 0 && ih < 16 && iw >= 0 && iw < 16)
                na4 = *(const float4*)(xr + ((size_t)((b << 8) + (ih << 4) + iw)) * 128 + c);
            nw4 = *(const float4*)(W2 + (size_t)(k0 + 16 + wkk) * 128 + j0 + wseg * 4);
        }
        #pragma unroll
        for (int kk = 0; kk < 16; kk++){
            float4 av4 = *(const float4*)(&As[kk][rg << 2]);
            float4 wv4 = *(const float4*)(&Ws[kk][cg << 2]);
            float av_[4] = {av4.x, av4.y, av4.z, av4.w};
            float wv_[4] = {wv4.x, wv4.y, wv4.z, wv4.w};
            #pragma unroll
            for (int ri = 0; ri < 4; ri++)
                #pragma unroll
                for (int ci = 0; ci < 4; ci++)
                    acc[ri][ci] = fmaf(av_[ri], wv_[ci], acc[ri][ci]);
        }
        if (more){ a4 = na4; w4 = nw4; }
    }
    float* pp = part + (size_t)s * 1024 * 128;
    #pragma unroll
    for (int ri = 0; ri < 4; ri++){
        int rr = r0 + (rg << 2) + ri;
        #pragma unroll
        for (int ci = 0; ci < 4; ci++){
            int j = j0 + (cg << 2) + ci;
            pp[(size_t)rr * 128 + j] = acc[ri][ci];
        }
    }
}

// ---------- reduce split-K partials + LayerNorm ----------
__global__ void k_part_ln(const float* __restrict__ part, const float* __restrict__ lnw,
                          const float* __restrict__ lnb, float* __restrict__ out){
    __shared__ float sm[16];
    int r = blockIdx.x, t = threadIdx.x; // 128 thr
    float v = part[(size_t)r * 128 + t]
            + part[(size_t)(1024 + r) * 128 + t]
            + part[(size_t)(2048 + r) * 128 + t]
            + part[(size_t)(3072 + r) * 128 + t];
    float a = v, q = v * v;
    blk_sum2(a, q, sm);
    float mu = a * (1.f / 128.f);
    float var = q * (1.f / 128.f) - mu * mu;
    float rs = rsqrtf(var + 1e-5f);
    out[(size_t)r * 128 + t] = (v - mu) * rs * lnw[t] + lnb[t];
}

extern "C" void kernel_launch(void* const* d_in, const int* in_sizes, int n_in,
                              void* d_out, int out_size, void* d_ws, size_t ws_size,
                              hipStream_t stream) {
    const float* x          = (const float*)d_in[0];
    const int*   sidx       = (const int*)  d_in[1];
    const float* spa_ln_w   = (const float*)d_in[2];
    const float* spa_ln_b   = (const float*)d_in[3];
    const float* spa_in_w   = (const float*)d_in[4];
    const float* spa_conv_w = (const float*)d_in[5];
    const float* spa_conv_b = (const float*)d_in[6];
    const float* spa_dt_bias= (const float*)d_in[7];
    const float* spa_A_log  = (const float*)d_in[8];
    const float* spa_D      = (const float*)d_in[9];
    const float* spa_rms_w  = (const float*)d_in[10];
    const float* spa_out_w  = (const float*)d_in[11];
    const float* spe_ln_w   = (const float*)d_in[12];
    const float* spe_ln_b   = (const float*)d_in[13];
    const float* spe_in_w   = (const float*)d_in[14];
    const float* spe_conv_w = (const float*)d_in[15];
    const float* spe_conv_b = (const float*)d_in[16];
    const float* spe_dt_bias= (const float*)d_in[17];
    const float* spe_A_log  = (const float*)d_in[18];
    const float* spe_D      = (const float*)d_in[19];
    const float* spe_rms_w  = (const float*)d_in[20];
    const float* spe_out_w  = (const float*)d_in[21];
    const float* norm_w     = (const float*)d_in[22];
    const float* norm_b     = (const float*)d_in[23];
    const float* cprj_w     = (const float*)d_in[24];
    const float* cprj_b     = (const float*)d_in[25];
    const float* aq_w       = (const float*)d_in[26];
    const float* aq_b       = (const float*)d_in[27];
    const float* ak_w       = (const float*)d_in[28];
    const float* ak_b       = (const float*)d_in[29];
    const float* av_w       = (const float*)d_in[30];
    const float* av_b       = (const float*)d_in[31];
    const float* ao_w       = (const float*)d_in[32];
    const float* ao_b       = (const float*)d_in[33];
    const float* sq_w       = (const float*)d_in[34];
    const float* sq_b       = (const float*)d_in[35];
    const float* sk_w       = (const float*)d_in[36];
    const float* sk_b       = (const float*)d_in[37];
    const float* sv_w       = (const float*)d_in[38];
    const float* sv_b       = (const float*)d_in[39];
    const float* so_w       = (const float*)d_in[40];
    const float* so_b       = (const float*)d_in[41];
    const float* ds_conv_w  = (const float*)d_in[42];
    const float* ds_ln_w    = (const float*)d_in[43];
    const float* ds_ln_b    = (const float*)d_in[44];

    float* ws = (float*)d_ws;
    // loop-live arena: 0 .. 7946240
    float* xs   = ws + 0;        // 524288
    float* zx   = ws + 1048576;  // -> 3686400
    float* xc   = ws + 3686400;  // -> 5259264
    float* dtb  = ws + 5259264;  // 32768
    float* dAb  = ws + 5292032;  // 32768 (log-dA)
    float* yb   = ws + 5324800;  // -> 6373376
    float* Sbuf = ws + 6373376;  // -> 7421952
    float* h1   = ws + 7421952;  // -> 7946240
    float* clbuf = ws + 524288;  // scratch (dead between uses)
    float* xT    = ws + 524288;  // scratch (dead after k_embed)
    float* h1t   = ws + 6373376; // in Sbuf (dead before S writes)
    // weight transposes: PAST the loop-live arena
    float* owt   = ws + 7946240; // 16384 -> 7962624
    float* sowt  = ws + 7962624; // 65536 -> 8028160
    // attention-stage aliases (host regions dead post-loop)
    float* kb    = ws + 1048576;
    float* vb    = ws + 1572864;
    float* attnb = ws + 2097152;
    float* qb    = ws + 2129920;
    float* xt    = ws + 524288;
    float* q2    = ws + 3686400;
    float* k2t   = ws + 4210688;
    float* v2    = ws + 4734976;
    float* xr    = ws + 5586944; // -> 6111232
    float* part  = ws + 1048576; // kb/vb region, dead by conv_gemm

    k_tr_multi<<<592, 256, 0, stream>>>(x, xT, ao_w, owt, so_w, sowt);
    k_embed<<<4096, 128, 0, stream>>>(xT, sidx, xs);

    for (int i = 0; i < 2; i++){
        // ---- spatial mamba (L=256, nh=4, nc=4) ----
        k_gemm_ln<<<dim3(11, 64), 256, 0, stream>>>(xs, spa_in_w + (size_t)i * 644 * 128,
                                                    spa_ln_w + i * 128, spa_ln_b + i * 128,
                                                    zx, 644, 128);
        k_conv<<<4096, 256, 0, stream>>>(zx, spa_conv_w + (size_t)i * 384 * 4,
                                         spa_conv_b + i * 384, xc,
                                         spa_dt_bias + i * 4, spa_A_log + i * 4, dtb, dAb,
                                         256, 384, 644, 256, 4, 640);
        k_ssd_chunk<<<256, 256, 0, stream>>>(xc, dtb, dAb, yb, Sbuf, clbuf,
                                             256, 4, 4, 384, 256, 320, 256);
        k_chunk_y<<<256, 256, 0, stream>>>(xc, Sbuf, clbuf, spa_D + i * 4, yb,
                                           256, 4, 4, 384, 320, 256);
        k_gemm_gate<<<dim3(4, 128), 256, 0, stream>>>(yb, zx, spa_rms_w + i * 256,
                                                      spa_out_w + (size_t)i * 128 * 256,
                                                      xs, h1, 128, 256, 644, 1);
        // ---- spectral mamba (L=128, nh=8, nc=2) ----
        k_tr<<<dim3(4, 8, 16), 256, 0, stream>>>(h1, h1t, 256, 128);
        k_gemm_ln<<<dim3(19, 32), 256, 0, stream>>>(h1t, spe_in_w + (size_t)i * 1160 * 256,
                                                    spe_ln_w + i * 256, spe_ln_b + i * 256,
                                                    zx, 1160, 256);
        k_conv<<<2048, 256, 0, stream>>>(zx, spe_conv_w + (size_t)i * 640 * 4,
                                         spe_conv_b + i * 640, xc,
                                         spe_dt_bias + i * 8, spe_A_log + i * 8, dtb, dAb,
                                         128, 640, 1160, 512, 8, 1152);
        k_ssd_chunk<<<256, 256, 0, stream>>>(xc, dtb, dAb, yb, Sbuf, clbuf,
                                             128, 8, 2, 640, 512, 576, 512);
        k_chunk_y<<<256, 256, 0, stream>>>(xc, Sbuf, clbuf, spe_D + i * 8, yb,
                                           128, 8, 2, 640, 576, 512);
        k_gemm_gate<<<dim3(8, 64), 256, 0, stream>>>(yb, zx, spe_rms_w + i * 512,
                                                     spe_out_w + (size_t)i * 256 * 512,
                                                     h1, xs, 256, 512, 1160, 2);
    }

    k_ln<<<4096, 128, 0, stream>>>(xs, norm_w, norm_b, xs, 128);
    k_center_q<<<16, 128, 0, stream>>>(xs, cprj_w, cprj_b, aq_w, aq_b, qb);
    {
        GJob jk = {ak_w, ak_b, kb, 0};
        GJob jv = {av_w, av_b, vb, 0};
        k_gemm3<<<dim3(4, 128, 2), 256, 0, stream>>>(xs, jk, jv, jk, 128, 128);
    }
    k_attn<<<128, 256, 0, stream>>>(qb, kb, attnb);
    k_attn_out<<<512, 128, 0, stream>>>(vb, attnb, owt, ao_b, xs);
    k_tr<<<dim3(4, 8, 16), 256, 0, stream>>>(xs, xt, 256, 128);
    {
        GJob jq = {sq_w, sq_b, q2, 0};
        GJob jk = {sk_w, sk_b, k2t, 3};
        GJob jv = {sv_w, sv_b, v2, 0};
        k_gemm3<<<dim3(8, 64, 3), 256, 0, stream>>>(xt, jq, jk, jv, 256, 256);
    }
    k_spe_attn<<<256, 256, 0, stream>>>(q2, k2t, v2, sowt, so_b, xs, sidx, xr);
    k_conv_gemm<<<dim3(2, 16, 4), 256, 0, stream>>>(xr, ds_conv_w, part);
    k_part_ln<<<1024, 128, 0, stream>>>(part, ds_ln_w, ds_ln_b, (float*)d_out);
}

// Round 13
// 549.004 us; speedup vs baseline: 1.9394x; 1.0947x over previous
//
#include <hip/hip_runtime.h>
#include <math.h>

#define DEV __device__ __forceinline__

typedef __attribute__((ext_vector_type(8))) short short8;
typedef __attribute__((ext_vector_type(4))) float f32x4;
typedef unsigned short ushort_t;
typedef unsigned int uint_t;

DEV float siluf(float x){ return x / (1.f + __expf(-x)); }
DEV float softplusf(float x){ return (x > 20.f) ? x : log1pf(__expf(x)); }

DEV ushort_t bf16r(float f){
    uint_t u = __float_as_uint(f);
    return (ushort_t)((u + 0x7fffu + ((u >> 16) & 1u)) >> 16);
}
DEV uint_t pack2(float a, float b){
    return (uint_t)bf16r(a) | ((uint_t)bf16r(b) << 16);
}

// ---------- block reduction helpers (wave64) ----------
DEV void blk_sum2(float &a, float &b, float* sm){
    int lane = threadIdx.x & 63, wid = threadIdx.x >> 6, nw = blockDim.x >> 6;
    #pragma unroll
    for (int off = 32; off; off >>= 1){ a += __shfl_down(a, off); b += __shfl_down(b, off); }
    if (lane == 0){ sm[wid] = a; sm[8 + wid] = b; }
    __syncthreads();
    float ra = 0.f, rb = 0.f;
    for (int i = 0; i < nw; i++){ ra += sm[i]; rb += sm[8 + i]; }
    __syncthreads();
    a = ra; b = rb;
}
DEV float blk_sum1(float v, float* sm){
    int lane = threadIdx.x & 63, wid = threadIdx.x >> 6, nw = blockDim.x >> 6;
    #pragma unroll
    for (int off = 32; off; off >>= 1) v += __shfl_down(v, off);
    if (lane == 0) sm[wid] = v;
    __syncthreads();
    float r = 0.f;
    for (int i = 0; i < nw; i++) r += sm[i];
    __syncthreads();
    return r;
}
DEV float blk_max1(float v, float* sm){
    int lane = threadIdx.x & 63, wid = threadIdx.x >> 6, nw = blockDim.x >> 6;
    #pragma unroll
    for (int off = 32; off; off >>= 1) v = fmaxf(v, __shfl_down(v, off));
    if (lane == 0) sm[wid] = v;
    __syncthreads();
    float r = -3.4e38f;
    for (int i = 0; i < nw; i++) r = fmaxf(r, sm[i]);
    __syncthreads();
    return r;
}

// ---------- transpose body ----------
DEV void tr_body(const float* __restrict__ ip, float* __restrict__ op,
                 int R, int C, int c0, int r0){
    __shared__ float tile[32][33];
    int tx = threadIdx.x & 31, ty = threadIdx.x >> 5;
    #pragma unroll
    for (int rr = ty; rr < 32; rr += 8)
        tile[rr][tx] = ip[(size_t)(r0 + rr) * C + c0 + tx];
    __syncthreads();
    #pragma unroll
    for (int rr = ty; rr < 32; rr += 8)
        op[(size_t)(c0 + rr) * R + r0 + tx] = tile[tx][rr];
}

__global__ __launch_bounds__(256) void k_tr(const float* __restrict__ in,
                                            float* __restrict__ out, int R, int C){
    tr_body(in + (size_t)blockIdx.z * R * C, out + (size_t)blockIdx.z * R * C,
            R, C, blockIdx.x * 32, blockIdx.y * 32);
}

// packed: job0 x->xT (512 blks), job1 ao_w (16), job2 so_w (64)
__global__ __launch_bounds__(256) void k_tr_multi(const float* __restrict__ x,
        float* __restrict__ xT, const float* __restrict__ aow, float* __restrict__ owt,
        const float* __restrict__ sow, float* __restrict__ sowt){
    int idx = blockIdx.x;
    if (idx < 512){
        int bx = idx & 7, by = (idx >> 3) & 3, bz = idx >> 5;
        tr_body(x + (size_t)bz * 32768, xT + (size_t)bz * 32768, 128, 256, bx * 32, by * 32);
    } else if (idx < 528){
        int l = idx - 512;
        tr_body(aow, owt, 128, 128, (l & 3) * 32, (l >> 2) * 32);
    } else {
        int l = idx - 528;
        tr_body(sow, sowt, 256, 256, (l & 7) * 32, (l >> 3) * 32);
    }
}

// ---------- K1: pos-embed + gather ----------
__global__ void k_embed(const float* __restrict__ xT, const int* __restrict__ sidx,
                        float* __restrict__ xs){
    int bl = blockIdx.x; int b = bl >> 8; int c = threadIdx.x;
    int p = sidx[bl];
    int hh = p >> 4, ww = p & 15;
    int pos = (c < 64) ? hh : ww;
    int jm = c & 63;
    float om = __expf(-(float)(jm & 31) * 0.28782313662425574f); // ln(10000)/32
    float ang = (float)pos * om;
    float pe = (jm < 32) ? sinf(ang) : cosf(ang);
    xs[(size_t)bl * 128 + c] = xT[((size_t)(b * 256 + p)) * 128 + c] + pe;
}

// ---------- LayerNorm (block per row) ----------
__global__ void k_ln(const float* __restrict__ in, const float* __restrict__ w,
                     const float* __restrict__ bb, float* __restrict__ out, int dim){
    __shared__ float sm[16];
    int row = blockIdx.x, t = threadIdx.x;
    float v = in[(size_t)row * dim + t];
    float a = v, q = v * v;
    blk_sum2(a, q, sm);
    float inv = 1.f / (float)dim;
    float mu = a * inv;
    float var = q * inv - mu * mu;
    float rs = rsqrtf(var + 1e-5f);
    out[(size_t)row * dim + t] = (v - mu) * rs * w[t] + bb[t];
}

// ======================================================================
// bf16 MFMA GEMM family: 64x64 tile, 256 thr = 4 waves, each wave owns a
// 16-row stripe x 4 col-subtiles. Fragments per guide (verified layouts):
// A/B frag: elem [lane&15][quad*8+j]; C/D: col=lane&15, row=quad*4+reg.
// LDS: bf16 tiles [64][72] (pad->2-way aliasing only, free per m136).
// ======================================================================

// ---------- in-projection GEMM with fused LayerNorm (bf16 MFMA) ----------
// out[r,j] = sum_k LN(A)[r,k] * W[j,k].  K%64==0.
__global__ __launch_bounds__(256) void k_gemm_ln(const float* __restrict__ A,
        const float* __restrict__ W, const float* __restrict__ lw,
        const float* __restrict__ lb, float* __restrict__ out, int N, int K){
    __shared__ __align__(16) ushort_t smem[2 * 64 * 72];
    ushort_t (*Abf)[72] = (ushort_t (*)[72])smem;
    ushort_t (*Wbf)[72] = (ushort_t (*)[72])(smem + 64 * 72);
    int j0 = blockIdx.x * 64, r0 = blockIdx.y * 64;
    int tid = threadIdx.x;
    int row = tid >> 2, kg = tid & 3;
    int wrow = j0 + row; if (wrow > N - 1) wrow = N - 1;
    const float* Ar = A + (size_t)(r0 + row) * K;
    const float* Wr = W + (size_t)wrow * K;
    // LN stats (4 lanes per row cover disjoint k)
    float s = 0.f, ss = 0.f;
    for (int k0 = 0; k0 < K; k0 += 32){
        float4 a0 = *(const float4*)(Ar + k0 + kg * 4);
        float4 a1 = *(const float4*)(Ar + k0 + 16 + kg * 4);
        s  += a0.x + a0.y + a0.z + a0.w + a1.x + a1.y + a1.z + a1.w;
        ss += a0.x*a0.x + a0.y*a0.y + a0.z*a0.z + a0.w*a0.w
            + a1.x*a1.x + a1.y*a1.y + a1.z*a1.z + a1.w*a1.w;
    }
    s  += __shfl_xor(s, 1);  ss += __shfl_xor(ss, 1);
    s  += __shfl_xor(s, 2);  ss += __shfl_xor(ss, 2);
    float inv = 1.f / (float)K;
    float mu = s * inv;
    float rs = rsqrtf(ss * inv - mu * mu + 1e-5f);
    int wv = tid >> 6, lane = tid & 63, lm = lane & 15, quad = lane >> 4;
    f32x4 zero4 = {0.f, 0.f, 0.f, 0.f};
    f32x4 acc[4] = {zero4, zero4, zero4, zero4};
    for (int kc0 = 0; kc0 < K; kc0 += 64){
        int kb = kc0 + kg * 16;
        float4 q[4], g[4], b[4], p[4];
        #pragma unroll
        for (int i = 0; i < 4; i++){
            q[i] = *(const float4*)(Ar + kb + i * 4);
            g[i] = *(const float4*)(lw + kb + i * 4);
            b[i] = *(const float4*)(lb + kb + i * 4);
            p[i] = *(const float4*)(Wr + kb + i * 4);
        }
        #pragma unroll
        for (int i = 0; i < 4; i++){
            q[i].x = (q[i].x - mu) * rs * g[i].x + b[i].x;
            q[i].y = (q[i].y - mu) * rs * g[i].y + b[i].y;
            q[i].z = (q[i].z - mu) * rs * g[i].z + b[i].z;
            q[i].w = (q[i].w - mu) * rs * g[i].w + b[i].w;
        }
        __syncthreads(); // previous chunk's fragment reads complete
        {
            uint4 u0, u1;
            u0.x = pack2(q[0].x, q[0].y); u0.y = pack2(q[0].z, q[0].w);
            u0.z = pack2(q[1].x, q[1].y); u0.w = pack2(q[1].z, q[1].w);
            u1.x = pack2(q[2].x, q[2].y); u1.y = pack2(q[2].z, q[2].w);
            u1.z = pack2(q[3].x, q[3].y); u1.w = pack2(q[3].z, q[3].w);
            *(uint4*)&Abf[row][kg * 16] = u0;
            *(uint4*)&Abf[row][kg * 16 + 8] = u1;
            u0.x = pack2(p[0].x, p[0].y); u0.y = pack2(p[0].z, p[0].w);
            u0.z = pack2(p[1].x, p[1].y); u0.w = pack2(p[1].z, p[1].w);
            u1.x = pack2(p[2].x, p[2].y); u1.y = pack2(p[2].z, p[2].w);
            u1.z = pack2(p[3].x, p[3].y); u1.w = pack2(p[3].z, p[3].w);
            *(uint4*)&Wbf[row][kg * 16] = u0;
            *(uint4*)&Wbf[row][kg * 16 + 8] = u1;
        }
        __syncthreads();
        #pragma unroll
        for (int kk = 0; kk < 64; kk += 32){
            short8 af = *(const short8*)&Abf[wv * 16 + lm][kk + quad * 8];
            #pragma unroll
            for (int c = 0; c < 4; c++){
                short8 bfv = *(const short8*)&Wbf[c * 16 + lm][kk + quad * 8];
                acc[c] = __builtin_amdgcn_mfma_f32_16x16x32_bf16(af, bfv, acc[c], 0, 0, 0);
            }
        }
    }
    int rbase = r0 + wv * 16 + quad * 4;
    #pragma unroll
    for (int c = 0; c < 4; c++){
        int j = j0 + c * 16 + lm;
        if (j < N){
            #pragma unroll
            for (int reg = 0; reg < 4; reg++)
                out[(size_t)(rbase + reg) * N + j] = acc[c][reg];
        }
    }
}

// ---------- out-projection GEMM, fused gate(silu)+RMS (bf16 MFMA) ----------
// v = y*silu(z); scale[r] = rsqrt(mean v^2 + 1e-5); out = scale*sum (v*rw)*W + res
// mode 1: out[r*N+j]   mode 2: transposed scatter (N==256)
__global__ __launch_bounds__(256) void k_gemm_gate(const float* __restrict__ Y,
        const float* __restrict__ Z, const float* __restrict__ rw,
        const float* __restrict__ W, const float* __restrict__ res,
        float* __restrict__ out, int N, int K, int zs, int mode){
    __shared__ __align__(16) ushort_t smem[2 * 64 * 72];
    ushort_t (*Abf)[72] = (ushort_t (*)[72])smem;
    ushort_t (*Wbf)[72] = (ushort_t (*)[72])(smem + 64 * 72);
    __shared__ float sscale[64];
    int j0 = blockIdx.x * 64, r0 = blockIdx.y * 64;
    int tid = threadIdx.x;
    int row = tid >> 2, kg = tid & 3;
    const float* Yr = Y + (size_t)(r0 + row) * K;
    const float* Zr = Z + (size_t)(r0 + row) * zs;
    const float* Wr = W + (size_t)(j0 + row) * K;
    int wv = tid >> 6, lane = tid & 63, lm = lane & 15, quad = lane >> 4;
    float ssq = 0.f;
    f32x4 zero4 = {0.f, 0.f, 0.f, 0.f};
    f32x4 acc[4] = {zero4, zero4, zero4, zero4};
    for (int kc0 = 0; kc0 < K; kc0 += 64){
        int kb = kc0 + kg * 16;
        float4 y[4], z[4], g[4], p[4];
        #pragma unroll
        for (int i = 0; i < 4; i++){
            y[i] = *(const float4*)(Yr + kb + i * 4);
            z[i] = *(const float4*)(Zr + kb + i * 4);
            g[i] = *(const float4*)(rw + kb + i * 4);
            p[i] = *(const float4*)(Wr + kb + i * 4);
        }
        #pragma unroll
        for (int i = 0; i < 4; i++){
            y[i].x *= siluf(z[i].x); y[i].y *= siluf(z[i].y);
            y[i].z *= siluf(z[i].z); y[i].w *= siluf(z[i].w);
            ssq += y[i].x*y[i].x + y[i].y*y[i].y + y[i].z*y[i].z + y[i].w*y[i].w;
            y[i].x *= g[i].x; y[i].y *= g[i].y; y[i].z *= g[i].z; y[i].w *= g[i].w;
        }
        __syncthreads();
        {
            uint4 u0, u1;
            u0.x = pack2(y[0].x, y[0].y); u0.y = pack2(y[0].z, y[0].w);
            u0.z = pack2(y[1].x, y[1].y); u0.w = pack2(y[1].z, y[1].w);
            u1.x = pack2(y[2].x, y[2].y); u1.y = pack2(y[2].z, y[2].w);
            u1.z = pack2(y[3].x, y[3].y); u1.w = pack2(y[3].z, y[3].w);
            *(uint4*)&Abf[row][kg * 16] = u0;
            *(uint4*)&Abf[row][kg * 16 + 8] = u1;
            u0.x = pack2(p[0].x, p[0].y); u0.y = pack2(p[0].z, p[0].w);
            u0.z = pack2(p[1].x, p[1].y); u0.w = pack2(p[1].z, p[1].w);
            u1.x = pack2(p[2].x, p[2].y); u1.y = pack2(p[2].z, p[2].w);
            u1.z = pack2(p[3].x, p[3].y); u1.w = pack2(p[3].z, p[3].w);
            *(uint4*)&Wbf[row][kg * 16] = u0;
            *(uint4*)&Wbf[row][kg * 16 + 8] = u1;
        }
        __syncthreads();
        #pragma unroll
        for (int kk = 0; kk < 64; kk += 32){
            short8 af = *(const short8*)&Abf[wv * 16 + lm][kk + quad * 8];
            #pragma unroll
            for (int c = 0; c < 4; c++){
                short8 bfv = *(const short8*)&Wbf[c * 16 + lm][kk + quad * 8];
                acc[c] = __builtin_amdgcn_mfma_f32_16x16x32_bf16(af, bfv, acc[c], 0, 0, 0);
            }
        }
    }
    ssq += __shfl_xor(ssq, 1);
    ssq += __shfl_xor(ssq, 2);
    if (kg == 0) sscale[row] = rsqrtf(ssq / (float)K + 1e-5f);
    __syncthreads(); // sscale visible; all LDS fragment reads done
    int lr0 = wv * 16 + quad * 4; // local row base of this lane's accumulators
    float scr[4];
    #pragma unroll
    for (int reg = 0; reg < 4; reg++) scr[reg] = sscale[lr0 + reg];
    if (mode == 2){
        float (*T)[68] = (float (*)[68])smem; // 17408 B <= 18432 B
        #pragma unroll
        for (int c = 0; c < 4; c++)
            #pragma unroll
            for (int reg = 0; reg < 4; reg++)
                T[c * 16 + lm][lr0 + reg] = acc[c][reg] * scr[reg];
        __syncthreads();
        int b2 = r0 >> 7, ii0 = r0 & 127;
        int jj = tid >> 2, seg = tid & 3;
        size_t base = ((size_t)(b2 * 256 + j0 + jj)) * 128 + ii0 + seg * 16;
        float* op = out + base;
        const float* rp = res + base;
        #pragma unroll
        for (int c = 0; c < 4; c++){
            float4 v = *(const float4*)(&T[jj][seg * 16 + c * 4]);
            float4 rv = *(const float4*)(rp + c * 4);
            v.x += rv.x; v.y += rv.y; v.z += rv.z; v.w += rv.w;
            *(float4*)(op + c * 4) = v;
        }
    } else {
        int rbase = r0 + lr0;
        #pragma unroll
        for (int c = 0; c < 4; c++){
            int j = j0 + c * 16 + lm;
            #pragma unroll
            for (int reg = 0; reg < 4; reg++){
                size_t oi = (size_t)(rbase + reg) * N + j;
                out[oi] = acc[c][reg] * scr[reg] + res[oi];
            }
        }
    }
}

// ---------- qkv GEMM (bf16 MFMA), mode 0: +bias; mode 3: transposed+bias ----------
struct GJob { const float* W; const float* bias; float* out; int mode; };

__global__ __launch_bounds__(256) void k_gemm3(const float* __restrict__ A,
                                               GJob ja, GJob jb, GJob jc,
                                               int N, int K){
    GJob job = (blockIdx.z == 0) ? ja : ((blockIdx.z == 1) ? jb : jc);
    const float* W = job.W;
    const float* bias = job.bias;
    float* out = job.out;
    int mode = job.mode;
    __shared__ __align__(16) ushort_t smem[2 * 64 * 72];
    ushort_t (*Abf)[72] = (ushort_t (*)[72])smem;
    ushort_t (*Wbf)[72] = (ushort_t (*)[72])(smem + 64 * 72);
    int j0 = blockIdx.x * 64, r0 = blockIdx.y * 64;
    int tid = threadIdx.x;
    int row = tid >> 2, kg = tid & 3;
    const float* Ar = A + (size_t)(r0 + row) * K;
    const float* Wr = W + (size_t)(j0 + row) * K;
    int wv = tid >> 6, lane = tid & 63, lm = lane & 15, quad = lane >> 4;
    f32x4 zero4 = {0.f, 0.f, 0.f, 0.f};
    f32x4 acc[4] = {zero4, zero4, zero4, zero4};
    for (int kc0 = 0; kc0 < K; kc0 += 64){
        int kb = kc0 + kg * 16;
        float4 q[4], p[4];
        #pragma unroll
        for (int i = 0; i < 4; i++){
            q[i] = *(const float4*)(Ar + kb + i * 4);
            p[i] = *(const float4*)(Wr + kb + i * 4);
        }
        __syncthreads();
        {
            uint4 u0, u1;
            u0.x = pack2(q[0].x, q[0].y); u0.y = pack2(q[0].z, q[0].w);
            u0.z = pack2(q[1].x, q[1].y); u0.w = pack2(q[1].z, q[1].w);
            u1.x = pack2(q[2].x, q[2].y); u1.y = pack2(q[2].z, q[2].w);
            u1.z = pack2(q[3].x, q[3].y); u1.w = pack2(q[3].z, q[3].w);
            *(uint4*)&Abf[row][kg * 16] = u0;
            *(uint4*)&Abf[row][kg * 16 + 8] = u1;
            u0.x = pack2(p[0].x, p[0].y); u0.y = pack2(p[0].z, p[0].w);
            u0.z = pack2(p[1].x, p[1].y); u0.w = pack2(p[1].z, p[1].w);
            u1.x = pack2(p[2].x, p[2].y); u1.y = pack2(p[2].z, p[2].w);
            u1.z = pack2(p[3].x, p[3].y); u1.w = pack2(p[3].z, p[3].w);
            *(uint4*)&Wbf[row][kg * 16] = u0;
            *(uint4*)&Wbf[row][kg * 16 + 8] = u1;
        }
        __syncthreads();
        #pragma unroll
        for (int kk = 0; kk < 64; kk += 32){
            short8 af = *(const short8*)&Abf[wv * 16 + lm][kk + quad * 8];
            #pragma unroll
            for (int c = 0; c < 4; c++){
                short8 bfv = *(const short8*)&Wbf[c * 16 + lm][kk + quad * 8];
                acc[c] = __builtin_amdgcn_mfma_f32_16x16x32_bf16(af, bfv, acc[c], 0, 0, 0);
            }
        }
    }
    int lr0 = wv * 16 + quad * 4;
    if (mode == 3){
        __syncthreads();
        float (*T)[68] = (float (*)[68])smem;
        #pragma unroll
        for (int c = 0; c < 4; c++)
            #pragma unroll
            for (int reg = 0; reg < 4; reg++)
                T[c * 16 + lm][lr0 + reg] = acc[c][reg];
        __syncthreads();
        int b2 = r0 >> 7, ii0 = r0 & 127;
        int jj = tid >> 2, seg = tid & 3;
        size_t base = ((size_t)(b2 * 256 + j0 + jj)) * 128 + ii0 + seg * 16;
        float* op = out + base;
        float bj = bias[j0 + jj];
        #pragma unroll
        for (int c = 0; c < 4; c++){
            float4 v = *(const float4*)(&T[jj][seg * 16 + c * 4]);
            v.x += bj; v.y += bj; v.z += bj; v.w += bj;
            *(float4*)(op + c * 4) = v;
        }
    } else {
        int rbase = r0 + lr0;
        #pragma unroll
        for (int c = 0; c < 4; c++){
            int j = j0 + c * 16 + lm;
            float bj = bias[j];
            #pragma unroll
            for (int reg = 0; reg < 4; reg++)
                out[(size_t)(rbase + reg) * N + j] = acc[c][reg] + bj;
        }
    }
}

// ---------- causal depthwise conv(4)+bias+silu, fused dt / log-dA ----------
__global__ void k_conv(const float* __restrict__ zx, const float* __restrict__ cw,
                       const float* __restrict__ cb, float* __restrict__ xc,
                       const float* __restrict__ dtbias, const float* __restrict__ Al,
                       float* __restrict__ dt, float* __restrict__ dlA,
                       int L, int D, int stride, int off, int nh, int dtoff){
    int bl = blockIdx.x;
    int l = bl & (L - 1);
    const float* base = zx + (size_t)bl * stride + off;
    for (int d = threadIdx.x; d < D; d += blockDim.x){
        float acc = cb[d];
        #pragma unroll
        for (int k = 0; k < 4; k++){
            int dl = l + k - 3;
            if (dl >= 0) acc += base[(ptrdiff_t)(k - 3) * stride + d] * cw[d * 4 + k];
        }
        xc[(size_t)bl * D + d] = siluf(acc);
    }
    int t = threadIdx.x;
    if (t < nh){
        float xv = zx[(size_t)bl * stride + dtoff + t] + dtbias[t];
        float d = softplusf(xv);
        dt[(size_t)bl * nh + t] = d;
        dlA[(size_t)bl * nh + t] = -d * __expf(Al[t]); // log(dA) <= 0
    }
}

// ---------- chunked SSD, stage A ----------
__global__ __launch_bounds__(256) void k_ssd_chunk(
        const float* __restrict__ xc, const float* __restrict__ dt,
        const float* __restrict__ dlA, float* __restrict__ y,
        float* __restrict__ S, float* __restrict__ clb,
        int L, int nh, int nc, int xcs, int bo, int co, int ys){
    __shared__ float sX[64][68];
    __shared__ float sB[64][68];
    __shared__ float sC[64][68]; // phase1: C ; after: masked G
    __shared__ float cl[64], sdt[64], sw[64];
    int blk = blockIdx.x;
    int c = blk % nc; int bh = blk / nc; int h = bh % nh; int b = bh / nh;
    int l0 = c * 64;
    int tid = threadIdx.x;
    const float* base = xc + ((size_t)(b * L + l0)) * xcs;
    for (int idx = tid; idx < 4096; idx += 256){
        int s = idx >> 6, n = idx & 63;
        const float* row = base + (size_t)s * xcs;
        sX[s][n] = row[h * 64 + n];
        sB[s][n] = row[bo + n];
        sC[s][n] = row[co + n];
    }
    if (tid < 64){
        size_t di = (size_t)(b * L + l0 + tid) * nh + h;
        float dlv = dlA[di];
        sdt[tid] = dt[di];
        #pragma unroll
        for (int off = 1; off < 64; off <<= 1){
            float o = __shfl_up(dlv, off, 64);
            if (tid >= off) dlv += o;
        }
        cl[tid] = dlv;
        clb[(size_t)blk * 64 + tid] = dlv;
    }
    __syncthreads();
    if (tid < 64) sw[tid] = __expf(cl[63] - cl[tid]) * sdt[tid];

    int g1 = tid >> 4, g2 = tid & 15;
    int t0 = g1 * 4, s0 = g2 * 4;
    float g[4][4] = {};
    for (int n = 0; n < 64; n += 4){
        float4 cv[4], bv[4];
        #pragma unroll
        for (int i = 0; i < 4; i++) cv[i] = *(const float4*)&sC[t0 + i][n];
        #pragma unroll
        for (int j = 0; j < 4; j++) bv[j] = *(const float4*)&sB[s0 + j][n];
        #pragma unroll
        for (int i = 0; i < 4; i++)
            #pragma unroll
            for (int j = 0; j < 4; j++){
                g[i][j] = fmaf(cv[i].x, bv[j].x, g[i][j]);
                g[i][j] = fmaf(cv[i].y, bv[j].y, g[i][j]);
                g[i][j] = fmaf(cv[i].z, bv[j].z, g[i][j]);
                g[i][j] = fmaf(cv[i].w, bv[j].w, g[i][j]);
            }
    }
    __syncthreads();
    #pragma unroll
    for (int i = 0; i < 4; i++)
        #pragma unroll
        for (int j = 0; j < 4; j++){
            int t = t0 + i, s = s0 + j;
            float v = 0.f;
            if (s <= t) v = g[i][j] * __expf(cl[t] - cl[s]) * sdt[s];
            sC[t][s] = v;
        }
    __syncthreads();
    {
        float acc[4][4] = {};
        for (int s = 0; s < 64; s++){
            float4 xv = *(const float4*)&sX[s][s0];
            float gv[4];
            #pragma unroll
            for (int i = 0; i < 4; i++) gv[i] = sC[t0 + i][s];
            #pragma unroll
            for (int i = 0; i < 4; i++){
                acc[i][0] = fmaf(gv[i], xv.x, acc[i][0]);
                acc[i][1] = fmaf(gv[i], xv.y, acc[i][1]);
                acc[i][2] = fmaf(gv[i], xv.z, acc[i][2]);
                acc[i][3] = fmaf(gv[i], xv.w, acc[i][3]);
            }
        }
        #pragma unroll
        for (int i = 0; i < 4; i++){
            float4 o = make_float4(acc[i][0], acc[i][1], acc[i][2], acc[i][3]);
            *(float4*)&y[(size_t)(b * L + l0 + t0 + i) * ys + h * 64 + s0] = o;
        }
    }
    {
        float acc[4][4] = {};
        int p0 = t0, n0 = s0;
        for (int s = 0; s < 64; s++){
            float wv = sw[s];
            float4 bv = *(const float4*)&sB[s][n0];
            float4 xv = *(const float4*)&sX[s][p0];
            float w0 = wv * xv.x, w1 = wv * xv.y, w2 = wv * xv.z, w3 = wv * xv.w;
            acc[0][0] = fmaf(w0, bv.x, acc[0][0]); acc[0][1] = fmaf(w0, bv.y, acc[0][1]);
            acc[0][2] = fmaf(w0, bv.z, acc[0][2]); acc[0][3] = fmaf(w0, bv.w, acc[0][3]);
            acc[1][0] = fmaf(w1, bv.x, acc[1][0]); acc[1][1] = fmaf(w1, bv.y, acc[1][1]);
            acc[1][2] = fmaf(w1, bv.z, acc[1][2]); acc[1][3] = fmaf(w1, bv.w, acc[1][3]);
            acc[2][0] = fmaf(w2, bv.x, acc[2][0]); acc[2][1] = fmaf(w2, bv.y, acc[2][1]);
            acc[2][2] = fmaf(w2, bv.z, acc[2][2]); acc[2][3] = fmaf(w2, bv.w, acc[2][3]);
            acc[3][0] = fmaf(w3, bv.x, acc[3][0]); acc[3][1] = fmaf(w3, bv.y, acc[3][1]);
            acc[3][2] = fmaf(w3, bv.z, acc[3][2]); acc[3][3] = fmaf(w3, bv.w, acc[3][3]);
        }
        float* Sp = S + (size_t)blk * 4096;
        #pragma unroll
        for (int i = 0; i < 4; i++){
            float4 o = make_float4(acc[i][0], acc[i][1], acc[i][2], acc[i][3]);
            *(float4*)&Sp[(p0 + i) * 64 + n0] = o;
        }
    }
}

// ---------- chunked SSD, stage B+C fused ----------
__global__ __launch_bounds__(256) void k_chunk_y(
        const float* __restrict__ xc, const float* __restrict__ S,
        const float* __restrict__ clb, const float* __restrict__ Dp,
        float* __restrict__ y,
        int L, int nh, int nc, int xcs, int co, int ys){
    __shared__ float sH[64][68];
    __shared__ float sC[64][68];
    __shared__ float scl[64];
    int blk = blockIdx.x;
    int c = blk % nc; int bh = blk / nc; int h = bh % nh; int b = bh / nh;
    int l0 = c * 64;
    int tid = threadIdx.x;
    float wch[4];
    {
        float w = 1.f;
        for (int cp = c - 1; cp >= 0; cp--){
            wch[cp] = w;
            w *= __expf(clb[((size_t)(bh * nc + cp)) * 64 + 63]);
        }
    }
    const float* Sb = S + (size_t)(bh * nc) * 4096;
    const float* base = xc + ((size_t)(b * L + l0)) * xcs;
    for (int idx = tid; idx < 4096; idx += 256){
        int r = idx >> 6, n = idx & 63;
        float hv = 0.f;
        for (int cp = 0; cp < c; cp++)
            hv = fmaf(wch[cp], Sb[(size_t)cp * 4096 + idx], hv);
        sH[r][n] = hv;
        sC[r][n] = base[(size_t)r * xcs + co + n];
    }
    if (tid < 64) scl[tid] = __expf(clb[(size_t)blk * 64 + tid]);
    float Dh = Dp[h];
    __syncthreads();
    int g1 = tid >> 4, g2 = tid & 15;
    int t0 = g1 * 4, p0 = g2 * 4;
    float m[4][4] = {};
    for (int n = 0; n < 64; n += 4){
        float4 cv[4], hv[4];
        #pragma unroll
        for (int i = 0; i < 4; i++) cv[i] = *(const float4*)&sC[t0 + i][n];
        #pragma unroll
        for (int j = 0; j < 4; j++) hv[j] = *(const float4*)&sH[p0 + j][n];
        #pragma unroll
        for (int i = 0; i < 4; i++)
            #pragma unroll
            for (int j = 0; j < 4; j++){
                m[i][j] = fmaf(cv[i].x, hv[j].x, m[i][j]);
                m[i][j] = fmaf(cv[i].y, hv[j].y, m[i][j]);
                m[i][j] = fmaf(cv[i].z, hv[j].z, m[i][j]);
                m[i][j] = fmaf(cv[i].w, hv[j].w, m[i][j]);
            }
    }
    #pragma unroll
    for (int i = 0; i < 4; i++){
        int t = t0 + i;
        size_t yi = (size_t)(b * L + l0 + t) * ys + h * 64 + p0;
        float4 yv = *(float4*)&y[yi];
        float4 xv = *(const float4*)&base[(size_t)t * xcs + h * 64 + p0];
        float e = scl[t];
        yv.x += e * m[i][0] + Dh * xv.x;
        yv.y += e * m[i][1] + Dh * xv.y;
        yv.z += e * m[i][2] + Dh * xv.z;
        yv.w += e * m[i][3] + Dh * xv.w;
        *(float4*)&y[yi] = yv;
    }
}

// ---------- center projection + q ----------
__global__ void k_center_q(const float* __restrict__ xs, const float* __restrict__ cw,
                           const float* __restrict__ cb, const float* __restrict__ qw,
                           const float* __restrict__ qb, float* __restrict__ q){
    __shared__ float xr[640];
    __shared__ float cen[128];
    int b = blockIdx.x, t = threadIdx.x; // 128 thr
    for (int idx = t; idx < 640; idx += 128)
        xr[idx] = xs[(size_t)b * 256 * 128 + idx];
    __syncthreads();
    float acc = cb[t];
    for (int c = 0; c < 128; c++){
        const float* wp = cw + (size_t)(t * 128 + c) * 5;
        #pragma unroll
        for (int l = 0; l < 5; l++) acc += xr[l * 128 + c] * wp[l];
    }
    cen[t] = acc;
    __syncthreads();
    float qa = qb[t];
    const float* wr = qw + (size_t)t * 128;
    for (int o = 0; o < 128; o++) qa += cen[o] * wr[o];
    q[b * 128 + t] = qa;
}

// ---------- attention softmax over l ----------
__global__ void k_attn(const float* __restrict__ q, const float* __restrict__ k,
                       float* __restrict__ attn){
    __shared__ float sm[16];
    __shared__ float qh[16];
    int blk = blockIdx.x; int b = blk >> 3, h = blk & 7; int l = threadIdx.x; // 256 thr
    if (l < 16) qh[l] = q[b * 128 + h * 16 + l];
    __syncthreads();
    const float* kp = k + ((size_t)(b * 256 + l)) * 128 + h * 16;
    float s = 0.f;
    #pragma unroll
    for (int d = 0; d < 16; d++) s += qh[d] * kp[d];
    s *= 0.25f;
    float mx = blk_max1(s, sm);
    float e = __expf(s - mx);
    float sum = blk_sum1(e, sm);
    attn[(size_t)blk * 256 + l] = e / sum;
}

// ---------- attention out, 8 l-rows per block ----------
__global__ __launch_bounds__(128) void k_attn_out(const float* __restrict__ v,
                                                  const float* __restrict__ attn,
                                                  const float* __restrict__ owt,
                                                  const float* __restrict__ ob,
                                                  float* __restrict__ xs){
    __shared__ float vp[8][128];
    int blk = blockIdx.x; int b = blk >> 5, l0 = (blk & 31) << 3;
    int t = threadIdx.x; // 128 thr
    int h = t >> 4;
    float a[8];
    #pragma unroll
    for (int r = 0; r < 8; r++)
        a[r] = attn[((size_t)(b * 8 + h)) * 256 + l0 + r];
    #pragma unroll
    for (int r = 0; r < 8; r++)
        vp[r][t] = v[((size_t)(b * 256 + l0 + r)) * 128 + t] * a[r];
    __syncthreads();
    float acc[8];
    float bv = ob[t];
    #pragma unroll
    for (int r = 0; r < 8; r++) acc[r] = bv;
    for (int j = 0; j < 128; j++){
        float w = owt[j * 128 + t];
        #pragma unroll
        for (int r = 0; r < 8; r++) acc[r] = fmaf(vp[r][j], w, acc[r]);
    }
    #pragma unroll
    for (int r = 0; r < 8; r++)
        xs[((size_t)(b * 256 + l0 + r)) * 128 + t] += acc[r];
}

// ---------- fused spectral attention: QK+softmax+AV+SO+residual+unsort ----------
__global__ __launch_bounds__(256) void k_spe_attn(const float* __restrict__ q2,
        const float* __restrict__ k2t, const float* __restrict__ v2,
        const float* __restrict__ sowt, const float* __restrict__ sob,
        const float* __restrict__ xs, const int* __restrict__ sidx,
        float* __restrict__ xr){
    __shared__ float qs[8][256];
    __shared__ float lgp[2][8][128];
    __shared__ float sa[8][132];
    __shared__ float av[8][256];
    __shared__ float mxs[8], sms[8];
    int blk = blockIdx.x; int b = blk >> 4; int i0 = (blk & 15) << 3;
    int t = threadIdx.x;
    for (int idx = t; idx < 2048; idx += 256){
        int ii = idx >> 8, d = idx & 255;
        qs[ii][d] = q2[((size_t)(b * 128 + i0 + ii)) * 256 + d];
    }
    __syncthreads();
    {
        int j = t & 127, dh = t >> 7;
        const float* kt = k2t + (size_t)b * 32768 + dh * 16384;
        float acc[8] = {};
        for (int dd = 0; dd < 128; dd++){
            float kv = kt[dd * 128 + j];
            int d = dh * 128 + dd;
            #pragma unroll
            for (int ii = 0; ii < 8; ii++) acc[ii] = fmaf(qs[ii][d], kv, acc[ii]);
        }
        #pragma unroll
        for (int ii = 0; ii < 8; ii++) lgp[dh][ii][j] = acc[ii];
    }
    __syncthreads();
    if (t < 128){
        #pragma unroll
        for (int ii = 0; ii < 8; ii++)
            sa[ii][t] = (lgp[0][ii][t] + lgp[1][ii][t]) * (1.f / 16.f);
    }
    __syncthreads();
    if (t < 8){
        float mx = -3.4e38f;
        for (int j = 0; j < 128; j++) mx = fmaxf(mx, sa[t][j]);
        float sm = 0.f;
        for (int j = 0; j < 128; j++) sm += __expf(sa[t][j] - mx);
        mxs[t] = mx; sms[t] = 1.f / sm;
    }
    __syncthreads();
    if (t < 128){
        #pragma unroll
        for (int ii = 0; ii < 8; ii++)
            sa[ii][t] = __expf(sa[ii][t] - mxs[ii]) * sms[ii];
    }
    __syncthreads();
    {
        float acc[8] = {};
        const float* vb = v2 + (size_t)b * 32768 + t;
        for (int j = 0; j < 128; j++){
            float vv = vb[(size_t)j * 256];
            #pragma unroll
            for (int ii = 0; ii < 8; ii++) acc[ii] = fmaf(sa[ii][j], vv, acc[ii]);
        }
        #pragma unroll
        for (int ii = 0; ii < 8; ii++) av[ii][t] = acc[ii];
    }
    __syncthreads();
    float acc[8] = {};
    for (int d = 0; d < 256; d++){
        float wv = sowt[d * 256 + t];
        #pragma unroll
        for (int ii = 0; ii < 8; ii++) acc[ii] = fmaf(av[ii][d], wv, acc[ii]);
    }
    float bias = sob[t];
    int p = sidx[b * 256 + t];
    const float* xin = xs + ((size_t)(b * 256 + t)) * 128 + i0;
    float* xout = xr + ((size_t)(b * 256 + p)) * 128 + i0;
    #pragma unroll
    for (int ii = 0; ii < 8; ii++) xout[ii] = xin[ii] + acc[ii] + bias;
}

// ---------- conv GEMM split-K=4 with fused im2col (pipelined, fp32) ----------
__global__ __launch_bounds__(256) void k_conv_gemm(const float* __restrict__ xr,
                                                   const float* __restrict__ W2,
                                                   float* __restrict__ part){
    __shared__ float As[16][68];
    __shared__ float Ws[16][64];
    int j0 = blockIdx.x * 64, r0 = blockIdx.y * 64, s = blockIdx.z;
    int tid = threadIdx.x;
    int cg = tid & 15, rg = tid >> 4;
    int arow = tid >> 2, akg = tid & 3;
    int wkk = tid >> 4, wseg = tid & 15;
    int r = r0 + arow; int b = r >> 6, oh = (r >> 3) & 7, ow = r & 7;
    float acc[4][4] = {};
    int kbeg = s * 288, kend = kbeg + 288;
    float4 a4, w4;
    {
        int k = kbeg + akg * 4;
        int khw = k >> 7, c = k & 127;
        int kh = khw / 3, kw = khw - kh * 3;
        int ih = oh * 2 - 1 + kh, iw = ow * 2 - 1 + kw;
        a4 = make_float4(0.f, 0.f, 0.f, 0.f);
        if (ih >= 0 && ih < 16 && iw >= 0 && iw < 16)
            a4 = *(const float4*)(xr + ((size_t)((b << 8) + (ih << 4) + iw)) * 128 + c);
        w4 = *(const float4*)(W2 + (size_t)(kbeg + wkk) * 128 + j0 + wseg * 4);
    }
    for (int k0 = kbeg; k0 < kend; k0 += 16){
        __syncthreads();
        As[akg * 4 + 0][arow] = a4.x; As[akg * 4 + 1][arow] = a4.y;
        As[akg * 4 + 2][arow] = a4.z; As[akg * 4 + 3][arow] = a4.w;
        Ws[wkk][wseg * 4 + 0] = w4.x; Ws[wkk][wseg * 4 + 1] = w4.y;
        Ws[wkk][wseg * 4 + 2] = w4.z; Ws[wkk][wseg * 4 + 3] = w4.w;
        __syncthreads();
        bool more = (k0 + 16 < kend);
        float4 na4, nw4;
        if (more){
            int k = k0 + 16 + akg * 4;
            int khw = k >> 7, c = k & 127;
            int kh = khw / 3, kw = khw - kh * 3;
            int ih = oh * 2 - 1 + kh, iw = ow * 2 - 1 + kw;
            na4 = make_float4(0.f, 0.f, 0.f, 0.f);
            if (ih >= 0 && ih < 16 && iw >= 0 && iw < 16)
                na4 = *(const float4*)(xr + ((size_t)((b << 8) + (ih << 4) + iw)) * 128 + c);
            nw4 = *(const float4*)(W2 + (size_t)(k0 + 16 + wkk) * 128 + j0 + wseg * 4);
        }
        #pragma unroll
        for (int kk = 0; kk < 16; kk++){
            float4 av4 = *(const float4*)(&As[kk][rg << 2]);
            float4 wv4 = *(const float4*)(&Ws[kk][cg << 2]);
            float av_[4] = {av4.x, av4.y, av4.z, av4.w};
            float wv_[4] = {wv4.x, wv4.y, wv4.z, wv4.w};
            #pragma unroll
            for (int ri = 0; ri < 4; ri++)
                #pragma unroll
                for (int ci = 0; ci < 4; ci++)
                    acc[ri][ci] = fmaf(av_[ri], wv_[ci], acc[ri][ci]);
        }
        if (more){ a4 = na4; w4 = nw4; }
    }
    float* pp = part + (size_t)s * 1024 * 128;
    #pragma unroll
    for (int ri = 0; ri < 4; ri++){
        int rr = r0 + (rg << 2) + ri;
        #pragma unroll
        for (int ci = 0; ci < 4; ci++){
            int j = j0 + (cg << 2) + ci;
            pp[(size_t)rr * 128 + j] = acc[ri][ci];
        }
    }
}

// ---------- reduce split-K partials + LayerNorm ----------
__global__ void k_part_ln(const float* __restrict__ part, const float* __restrict__ lnw,
                          const float* __restrict__ lnb, float* __restrict__ out){
    __shared__ float sm[16];
    int r = blockIdx.x, t = threadIdx.x; // 128 thr
    float v = part[(size_t)r * 128 + t]
            + part[(size_t)(1024 + r) * 128 + t]
            + part[(size_t)(2048 + r) * 128 + t]
            + part[(size_t)(3072 + r) * 128 + t];
    float a = v, q = v * v;
    blk_sum2(a, q, sm);
    float mu = a * (1.f / 128.f);
    float var = q * (1.f / 128.f) - mu * mu;
    float rs = rsqrtf(var + 1e-5f);
    out[(size_t)r * 128 + t] = (v - mu) * rs * lnw[t] + lnb[t];
}

extern "C" void kernel_launch(void* const* d_in, const int* in_sizes, int n_in,
                              void* d_out, int out_size, void* d_ws, size_t ws_size,
                              hipStream_t stream) {
    const float* x          = (const float*)d_in[0];
    const int*   sidx       = (const int*)  d_in[1];
    const float* spa_ln_w   = (const float*)d_in[2];
    const float* spa_ln_b   = (const float*)d_in[3];
    const float* spa_in_w   = (const float*)d_in[4];
    const float* spa_conv_w = (const float*)d_in[5];
    const float* spa_conv_b = (const float*)d_in[6];
    const float* spa_dt_bias= (const float*)d_in[7];
    const float* spa_A_log  = (const float*)d_in[8];
    const float* spa_D      = (const float*)d_in[9];
    const float* spa_rms_w  = (const float*)d_in[10];
    const float* spa_out_w  = (const float*)d_in[11];
    const float* spe_ln_w   = (const float*)d_in[12];
    const float* spe_ln_b   = (const float*)d_in[13];
    const float* spe_in_w   = (const float*)d_in[14];
    const float* spe_conv_w = (const float*)d_in[15];
    const float* spe_conv_b = (const float*)d_in[16];
    const float* spe_dt_bias= (const float*)d_in[17];
    const float* spe_A_log  = (const float*)d_in[18];
    const float* spe_D      = (const float*)d_in[19];
    const float* spe_rms_w  = (const float*)d_in[20];
    const float* spe_out_w  = (const float*)d_in[21];
    const float* norm_w     = (const float*)d_in[22];
    const float* norm_b     = (const float*)d_in[23];
    const float* cprj_w     = (const float*)d_in[24];
    const float* cprj_b     = (const float*)d_in[25];
    const float* aq_w       = (const float*)d_in[26];
    const float* aq_b       = (const float*)d_in[27];
    const float* ak_w       = (const float*)d_in[28];
    const float* ak_b       = (const float*)d_in[29];
    const float* av_w       = (const float*)d_in[30];
    const float* av_b       = (const float*)d_in[31];
    const float* ao_w       = (const float*)d_in[32];
    const float* ao_b       = (const float*)d_in[33];
    const float* sq_w       = (const float*)d_in[34];
    const float* sq_b       = (const float*)d_in[35];
    const float* sk_w       = (const float*)d_in[36];
    const float* sk_b       = (const float*)d_in[37];
    const float* sv_w       = (const float*)d_in[38];
    const float* sv_b       = (const float*)d_in[39];
    const float* so_w       = (const float*)d_in[40];
    const float* so_b       = (const float*)d_in[41];
    const float* ds_conv_w  = (const float*)d_in[42];
    const float* ds_ln_w    = (const float*)d_in[43];
    const float* ds_ln_b    = (const float*)d_in[44];

    float* ws = (float*)d_ws;
    // loop-live arena: 0 .. 7946240
    float* xs   = ws + 0;        // 524288
    float* zx   = ws + 1048576;  // -> 3686400
    float* xc   = ws + 3686400;  // -> 5259264
    float* dtb  = ws + 5259264;  // 32768
    float* dAb  = ws + 5292032;  // 32768 (log-dA)
    float* yb   = ws + 5324800;  // -> 6373376
    float* Sbuf = ws + 6373376;  // -> 7421952
    float* h1   = ws + 7421952;  // -> 7946240
    float* clbuf = ws + 524288;  // scratch (dead between uses)
    float* xT    = ws + 524288;  // scratch (dead after k_embed)
    float* h1t   = ws + 6373376; // in Sbuf (dead before S writes)
    // weight transposes: PAST the loop-live arena
    float* owt   = ws + 7946240; // 16384 -> 7962624
    float* sowt  = ws + 7962624; // 65536 -> 8028160
    // attention-stage aliases (host regions dead post-loop)
    float* kb    = ws + 1048576;
    float* vb    = ws + 1572864;
    float* attnb = ws + 2097152;
    float* qb    = ws + 2129920;
    float* xt    = ws + 524288;
    float* q2    = ws + 3686400;
    float* k2t   = ws + 4210688;
    float* v2    = ws + 4734976;
    float* xr    = ws + 5586944; // -> 6111232
    float* part  = ws + 1048576; // kb/vb region, dead by conv_gemm

    k_tr_multi<<<592, 256, 0, stream>>>(x, xT, ao_w, owt, so_w, sowt);
    k_embed<<<4096, 128, 0, stream>>>(xT, sidx, xs);

    for (int i = 0; i < 2; i++){
        // ---- spatial mamba (L=256, nh=4, nc=4) ----
        k_gemm_ln<<<dim3(11, 64), 256, 0, stream>>>(xs, spa_in_w + (size_t)i * 644 * 128,
                                                    spa_ln_w + i * 128, spa_ln_b + i * 128,
                                                    zx, 644, 128);
        k_conv<<<4096, 256, 0, stream>>>(zx, spa_conv_w + (size_t)i * 384 * 4,
                                         spa_conv_b + i * 384, xc,
                                         spa_dt_bias + i * 4, spa_A_log + i * 4, dtb, dAb,
                                         256, 384, 644, 256, 4, 640);
        k_ssd_chunk<<<256, 256, 0, stream>>>(xc, dtb, dAb, yb, Sbuf, clbuf,
                                             256, 4, 4, 384, 256, 320, 256);
        k_chunk_y<<<256, 256, 0, stream>>>(xc, Sbuf, clbuf, spa_D + i * 4, yb,
                                           256, 4, 4, 384, 320, 256);
        k_gemm_gate<<<dim3(2, 64), 256, 0, stream>>>(yb, zx, spa_rms_w + i * 256,
                                                     spa_out_w + (size_t)i * 128 * 256,
                                                     xs, h1, 128, 256, 644, 1);
        // ---- spectral mamba (L=128, nh=8, nc=2) ----
        k_tr<<<dim3(4, 8, 16), 256, 0, stream>>>(h1, h1t, 256, 128);
        k_gemm_ln<<<dim3(19, 32), 256, 0, stream>>>(h1t, spe_in_w + (size_t)i * 1160 * 256,
                                                    spe_ln_w + i * 256, spe_ln_b + i * 256,
                                                    zx, 1160, 256);
        k_conv<<<2048, 256, 0, stream>>>(zx, spe_conv_w + (size_t)i * 640 * 4,
                                         spe_conv_b + i * 640, xc,
                                         spe_dt_bias + i * 8, spe_A_log + i * 8, dtb, dAb,
                                         128, 640, 1160, 512, 8, 1152);
        k_ssd_chunk<<<256, 256, 0, stream>>>(xc, dtb, dAb, yb, Sbuf, clbuf,
                                             128, 8, 2, 640, 512, 576, 512);
        k_chunk_y<<<256, 256, 0, stream>>>(xc, Sbuf, clbuf, spe_D + i * 8, yb,
                                           128, 8, 2, 640, 576, 512);
        k_gemm_gate<<<dim3(4, 32), 256, 0, stream>>>(yb, zx, spe_rms_w + i * 512,
                                                     spe_out_w + (size_t)i * 256 * 512,
                                                     h1, xs, 256, 512, 1160, 2);
    }

    k_ln<<<4096, 128, 0, stream>>>(xs, norm_w, norm_b, xs, 128);
    k_center_q<<<16, 128, 0, stream>>>(xs, cprj_w, cprj_b, aq_w, aq_b, qb);
    {
        GJob jk = {ak_w, ak_b, kb, 0};
        GJob jv = {av_w, av_b, vb, 0};
        k_gemm3<<<dim3(2, 64, 2), 256, 0, stream>>>(xs, jk, jv, jk, 128, 128);
    }
    k_attn<<<128, 256, 0, stream>>>(qb, kb, attnb);
    k_attn_out<<<512, 128, 0, stream>>>(vb, attnb, owt, ao_b, xs);
    k_tr<<<dim3(4, 8, 16), 256, 0, stream>>>(xs, xt, 256, 128);
    {
        GJob jq = {sq_w, sq_b, q2, 0};
        GJob jk = {sk_w, sk_b, k2t, 3};
        GJob jv = {sv_w, sv_b, v2, 0};
        k_gemm3<<<dim3(4, 32, 3), 256, 0, stream>>>(xt, jq, jk, jv, 256, 256);
    }
    k_spe_attn<<<256, 256, 0, stream>>>(q2, k2t, v2, sowt, so_b, xs, sidx, xr);
    k_conv_gemm<<<dim3(2, 16, 4), 256, 0, stream>>>(xr, ds_conv_w, part);
    k_part_ln<<<1024, 128, 0, stream>>>(part, ds_ln_w, ds_ln_b, (float*)d_out);
}